// Round 1
// baseline (9087.000 us; speedup 1.0000x reference)
//
#include <hip/hip_runtime.h>
#include <math.h>

#define DEV_INLINE __device__ __forceinline__

constexpr int H      = 256;
constexpr int NE     = 20000;
constexpr int NR     = 250;
constexpr int R2     = 500;
constexpr int TT     = 3;
constexpr int NEDGE  = 150000;
constexpr int M      = 200000;
constexpr int NNZ_E  = 320000;
constexpr int NNZ_R  = 8000;
constexpr int CH     = 50;
constexpr int NT     = 2000;
constexpr int NT2    = 4000;
constexpr int H3     = 3 * H;   // 768

// ------------------------- block reductions (blockDim == 256) -------------
DEV_INLINE float block_sum256(float v) {
  __shared__ float ws[4];
  #pragma unroll
  for (int o = 32; o > 0; o >>= 1) v += __shfl_down(v, o, 64);
  if ((threadIdx.x & 63) == 0) ws[threadIdx.x >> 6] = v;
  __syncthreads();
  float r = ws[0] + ws[1] + ws[2] + ws[3];
  __syncthreads();
  return r;
}
DEV_INLINE float block_max256(float v) {
  __shared__ float wm[4];
  #pragma unroll
  for (int o = 32; o > 0; o >>= 1) v = fmaxf(v, __shfl_down(v, o, 64));
  if ((threadIdx.x & 63) == 0) wm[threadIdx.x >> 6] = v;
  __syncthreads();
  float r = fmaxf(fmaxf(wm[0], wm[1]), fmaxf(wm[2], wm[3]));
  __syncthreads();
  return r;
}

// ------------------------- scatter kernels (atomics) ----------------------
// one wave per entry; lane l handles dims [4l, 4l+4)
__global__ void scatter_seg_gather(const float* __restrict__ src,
                                   const int* __restrict__ gidx,
                                   const int* __restrict__ sidx,
                                   float* __restrict__ acc,
                                   float* __restrict__ cnt, int n)
{
  long long tid = (long long)blockIdx.x * blockDim.x + threadIdx.x;
  int e = (int)(tid >> 6);
  if (e >= n) return;
  int lane = (int)(tid & 63);
  int g = gidx[e], s = sidx[e];
  const float4 v = *reinterpret_cast<const float4*>(src + (size_t)g * H + lane * 4);
  float* d = acc + (size_t)s * H + lane * 4;
  atomicAdd(d + 0, v.x); atomicAdd(d + 1, v.y);
  atomicAdd(d + 2, v.z); atomicAdd(d + 3, v.w);
  if (lane == 0) atomicAdd(cnt + s, 1.f);
}

__global__ void scatter_edges(const float* __restrict__ ent, const float* __restrict__ rel,
                              const int* __restrict__ esrc, const int* __restrict__ erel,
                              const int* __restrict__ edst,
                              float* __restrict__ acc, float* __restrict__ cnt, int n)
{
  long long tid = (long long)blockIdx.x * blockDim.x + threadIdx.x;
  int e = (int)(tid >> 6);
  if (e >= n) return;
  int lane = (int)(tid & 63);
  int s = esrc[e], r = erel[e], d = edst[e];
  const float4 a = *reinterpret_cast<const float4*>(ent + (size_t)s * H + lane * 4);
  const float4 b = *reinterpret_cast<const float4*>(rel + (size_t)r * H + lane * 4);
  float* o = acc + (size_t)d * H + lane * 4;
  atomicAdd(o + 0, a.x + b.x); atomicAdd(o + 1, a.y + b.y);
  atomicAdd(o + 2, a.z + b.z); atomicAdd(o + 3, a.w + b.w);
  if (lane == 0) atomicAdd(cnt + d, 1.f);
}

__global__ void scatter_hyper(const float* __restrict__ x, const float* __restrict__ val,
                              const int* __restrict__ row, const int* __restrict__ col,
                              float* __restrict__ acc, int n)
{
  long long tid = (long long)blockIdx.x * blockDim.x + threadIdx.x;
  int e = (int)(tid >> 6);
  if (e >= n) return;
  int lane = (int)(tid & 63);
  float w = val[e];
  const float4 v = *reinterpret_cast<const float4*>(x + (size_t)col[e] * H + lane * 4);
  float* o = acc + (size_t)row[e] * H + lane * 4;
  atomicAdd(o + 0, w * v.x); atomicAdd(o + 1, w * v.y);
  atomicAdd(o + 2, w * v.z); atomicAdd(o + 3, w * v.w);
}

// acc[row][h] /= max(cnt[row],1)
__global__ void seg_mean_fin(float* __restrict__ acc, const float* __restrict__ cnt, int rows)
{
  int idx = blockIdx.x * 256 + threadIdx.x;
  if (idx >= rows * H) return;
  int r = idx >> 8;
  acc[idx] /= fmaxf(cnt[r], 1.f);
}

// ------------------------- small elementwise kernels ----------------------
__global__ void build_xin(const float* __restrict__ rel, const float* __restrict__ xm,
                          float* __restrict__ xin)
{
  int idx = blockIdx.x * 256 + threadIdx.x;       // R2 * 512
  if (idx >= R2 * 2 * H) return;
  int i = idx >> 9, c = idx & 511;
  xin[idx] = (c < H) ? rel[(size_t)i * H + c] : xm[(size_t)i * H + (c - H)];
}

__global__ void gru_combine(const float* __restrict__ gi, const float* __restrict__ gh,
                            float* __restrict__ rel)
{
  int idx = blockIdx.x * 256 + threadIdx.x;       // R2 * H
  if (idx >= R2 * H) return;
  int i = idx >> 8, h = idx & 255;
  const float* gir = gi + (size_t)i * H3;
  const float* ghr = gh + (size_t)i * H3;
  float r = 1.f / (1.f + expf(-(gir[h]       + ghr[h])));
  float z = 1.f / (1.f + expf(-(gir[H + h]   + ghr[H + h])));
  float n = tanhf(gir[2 * H + h] + r * ghr[2 * H + h]);
  rel[idx] = (1.f - z) * n + z * rel[idx];
}

__global__ void ent_update(float* __restrict__ ent, const float* __restrict__ tw,
                           const float* __restrict__ curr)
{
  int idx = blockIdx.x * 256 + threadIdx.x;       // NE * H
  if (idx >= NE * H) return;
  float t = tw[idx];
  ent[idx] = t * curr[idx] + (1.f - t) * ent[idx];
}

// x[row] += y[row] / max(||y[row]||, eps)   (block per row, 256 threads = H)
__global__ void hyper_fin(const float* __restrict__ y, float* __restrict__ x)
{
  int row = blockIdx.x, h = threadIdx.x;
  float v = y[(size_t)row * H + h];
  float ss = block_sum256(v * v);
  float rn = 1.f / fmaxf(sqrtf(ss), 1e-12f);
  x[(size_t)row * H + h] += v * rn;
}

// ------------------------- generic tiled GEMM ------------------------------
// C(N x Mo) = act(A(N x K) @ B + bias); B is (Mo x K) if TRANS_B else (K x Mo).
// gridDim.z = S splits K; if S>1, raw partials are written to C + z*N*Mo.
// 64x64 tile per 256-thread block, 4x4 per thread, K-tile 16.
template<int TRANS_B, int ACT>
__global__ void gemm64(const float* __restrict__ A, const float* __restrict__ B,
                       const float* __restrict__ bias, float* __restrict__ C,
                       int N, int K, int Mo)
{
  __shared__ float As[16][68];
  __shared__ float Bs[16][68];
  const int tid = threadIdx.x;
  const int tx = tid & 15, ty = tid >> 4;
  const int rowBase = blockIdx.y * 64;
  const int colBase = blockIdx.x * 64;
  const int S = gridDim.z;
  const int klen = K / S;
  const int kbeg = blockIdx.z * klen;
  const int kend = kbeg + klen;
  float acc[4][4] = {};
  for (int k0 = kbeg; k0 < kend; k0 += 16) {
    {
      const int k = tid & 15;
      const int rb = tid >> 4;
      #pragma unroll
      for (int rr = 0; rr < 4; rr++) {
        int r = rb + rr * 16;
        int row = rowBase + r;
        As[k][r] = (row < N) ? A[(size_t)row * K + (k0 + k)] : 0.f;
      }
    }
    if (TRANS_B) {
      const int k = tid & 15;
      const int cb = tid >> 4;
      #pragma unroll
      for (int rr = 0; rr < 4; rr++) {
        int c = cb + rr * 16;
        int col = colBase + c;
        Bs[k][c] = (col < Mo) ? B[(size_t)col * K + (k0 + k)] : 0.f;
      }
    } else {
      const int c = tid & 63;
      const int kb = tid >> 6;
      const int col = colBase + c;
      #pragma unroll
      for (int rr = 0; rr < 4; rr++) {
        int k = kb + rr * 4;
        Bs[k][c] = (col < Mo) ? B[(size_t)(k0 + k) * Mo + col] : 0.f;
      }
    }
    __syncthreads();
    #pragma unroll
    for (int k = 0; k < 16; k++) {
      const float4 a4 = *reinterpret_cast<const float4*>(&As[k][ty * 4]);
      const float4 b4 = *reinterpret_cast<const float4*>(&Bs[k][tx * 4]);
      const float av[4] = {a4.x, a4.y, a4.z, a4.w};
      const float bv[4] = {b4.x, b4.y, b4.z, b4.w};
      #pragma unroll
      for (int i = 0; i < 4; i++)
        #pragma unroll
        for (int j = 0; j < 4; j++)
          acc[i][j] = fmaf(av[i], bv[j], acc[i][j]);
    }
    __syncthreads();
  }
  float* Cz = (S > 1) ? (C + (size_t)blockIdx.z * N * Mo) : C;
  #pragma unroll
  for (int i = 0; i < 4; i++) {
    int row = rowBase + ty * 4 + i;
    if (row >= N) continue;
    #pragma unroll
    for (int j = 0; j < 4; j++) {
      int col = colBase + tx * 4 + j;
      if (col >= Mo) continue;
      float v = acc[i][j];
      if (S == 1) {
        if (bias) v += bias[col];
        if (ACT == 1) v = fmaxf(v, 0.f);
        if (ACT == 2) v = 1.f / (1.f + expf(-v));
      }
      Cz[(size_t)row * Mo + col] = v;
    }
  }
}

// sum split-K partials + bias + relu -> q
__global__ void fc_reduce(const float* __restrict__ part, const float* __restrict__ bias,
                          float* __restrict__ q, int nrows, int splits)
{
  int idx = blockIdx.x * 256 + threadIdx.x;       // nrows * H
  if (idx >= nrows * H) return;
  int col = idx & 255;
  float s = bias[col];
  for (int z = 0; z < splits; z++) s += part[(size_t)z * nrows * H + idx];
  q[idx] = fmaxf(s, 0.f);
}

// ------------------------- conv (block per test row) -----------------------
__global__ void conv_feat(const float* __restrict__ ent, const float* __restrict__ rel,
                          const float* __restrict__ sent, const int* __restrict__ tt,
                          const float* __restrict__ cw, const float* __restrict__ cb,
                          float* __restrict__ out, int row0)
{
  __shared__ float f[3][258];
  __shared__ float wsm[CH * 9];
  __shared__ float bsm[CH];
  int i = row0 + blockIdx.x;
  int h = threadIdx.x;
  int j = (i < NT) ? i : i - NT;
  int a0 = (i < NT) ? tt[j * 3 + 0] : tt[j * 3 + 2];
  int a1 = (i < NT) ? tt[j * 3 + 1] : tt[j * 3 + 1] + NR;
  f[0][h + 1] = ent[(size_t)a0 * H + h];
  f[1][h + 1] = rel[(size_t)a1 * H + h];
  f[2][h + 1] = sent[(size_t)j * H + h];
  if (h < 3) { f[h][0] = 0.f; f[h][257] = 0.f; }
  for (int x = h; x < CH * 9; x += 256) wsm[x] = cw[x];
  if (h < CH) bsm[h] = cb[h];
  __syncthreads();
  float* orow = out + (size_t)blockIdx.x * (CH * H);
  for (int c = 0; c < CH; c++) {
    const float* wc = wsm + c * 9;
    float s = bsm[c];
    #pragma unroll
    for (int ic = 0; ic < 3; ic++)
      s += wc[ic * 3 + 0] * f[ic][h] + wc[ic * 3 + 1] * f[ic][h + 1] + wc[ic * 3 + 2] * f[ic][h + 2];
    orow[(size_t)c * H + h] = fmaxf(s, 0.f);
  }
}

// ------------------------- logsumexp per test row --------------------------
__global__ void lse_kernel(const float* __restrict__ sc, const int* __restrict__ tt,
                           float* __restrict__ nll, int row0)
{
  int r = blockIdx.x;
  int i = row0 + r;
  const float* s = sc + (size_t)r * NE;
  float m = -3.4e38f;
  for (int c = threadIdx.x; c < NE; c += 256) m = fmaxf(m, s[c]);
  m = block_max256(m);
  float sum = 0.f;
  for (int c = threadIdx.x; c < NE; c += 256) sum += expf(s[c] - m);
  sum = block_sum256(sum);
  if (threadIdx.x == 0) {
    int j = (i < NT) ? i : i - NT;
    int tgt = (i < NT) ? tt[j * 3 + 2] : tt[j * 3 + 0];
    nll[i] = m + logf(sum) - s[tgt];
  }
}

__global__ void mean_nll(const float* __restrict__ nll, float* __restrict__ out)
{
  float s = 0.f;
  for (int i = threadIdx.x; i < NT2; i += 256) s += nll[i];
  s = block_sum256(s);
  if (threadIdx.x == 0) out[0] = s * (1.f / NT2);
}

// ------------------------- launcher ----------------------------------------
extern "C" void kernel_launch(void* const* d_in, const int* in_sizes, int n_in,
                              void* d_out, int out_size, void* d_ws, size_t ws_size,
                              hipStream_t stream)
{
  const float* dynamic_emb = (const float*)d_in[0];
  const float* emb_rel     = (const float*)d_in[1];
  const float* gru_W_ih    = (const float*)d_in[2];
  const float* gru_W_hh    = (const float*)d_in[3];
  const float* gru_b_ih    = (const float*)d_in[4];
  const float* gru_b_hh    = (const float*)d_in[5];
  const float* agg_W       = (const float*)d_in[6];
  const float* tg_W        = (const float*)d_in[7];
  const float* tg_b        = (const float*)d_in[8];
  const float* hev         = (const float*)d_in[9];
  const float* hrv         = (const float*)d_in[10];
  const float* conv_w      = (const float*)d_in[11];
  const float* conv_b      = (const float*)d_in[12];
  const float* fc_W        = (const float*)d_in[13];
  const float* fc_b        = (const float*)d_in[14];
  const float* sent        = (const float*)d_in[15];
  const int* edge_src = (const int*)d_in[16];
  const int* edge_rel = (const int*)d_in[17];
  const int* edge_dst = (const int*)d_in[18];
  const int* r_to_e   = (const int*)d_in[19];
  const int* r_ids    = (const int*)d_in[20];
  const int* he_row   = (const int*)d_in[21];
  const int* he_col   = (const int*)d_in[22];
  const int* hr_row   = (const int*)d_in[23];
  const int* hr_col   = (const int*)d_in[24];
  const int* tt       = (const int*)d_in[25];
  float* out = (float*)d_out;

  float* w = (float*)d_ws;
  size_t off = 0;
  auto alloc = [&](size_t n) { float* p = w + off; off += n; return p; };
  float* ent    = alloc((size_t)NE * H);
  float* accE   = alloc((size_t)NE * H);
  float* curr   = alloc((size_t)NE * H);
  float* tgbuf  = alloc((size_t)NE * H);
  float* cntE   = alloc(20480);
  float* rel    = alloc((size_t)R2 * H);
  float* accR   = alloc((size_t)R2 * H);
  float* cntR   = alloc(512);
  float* xin    = alloc((size_t)R2 * 2 * H);
  float* gi     = alloc((size_t)R2 * H3);
  float* gh     = alloc((size_t)R2 * H3);
  float* q      = alloc((size_t)NT2 * H);
  float* nll    = alloc(4096);
  float* fcpart = alloc((size_t)8 * 800 * H);
  float* big    = alloc((size_t)800 * 12800);   // also fits 500*20000

  hipMemcpyAsync(ent, dynamic_emb, (size_t)NE * H * 4, hipMemcpyDeviceToDevice, stream);
  hipMemcpyAsync(rel, emb_rel, (size_t)R2 * H * 4, hipMemcpyDeviceToDevice, stream);

  for (int t = 0; t < TT; t++) {
    // --- rel update (GRU) ---
    hipMemsetAsync(accR, 0, (size_t)R2 * H * 4, stream);
    hipMemsetAsync(cntR, 0, 512 * 4, stream);
    {
      long long th = (long long)M * 64;
      int nb = (int)((th + 255) / 256);
      scatter_seg_gather<<<nb, 256, 0, stream>>>(ent, r_to_e + (size_t)t * M,
                                                 r_ids + (size_t)t * M, accR, cntR, M);
    }
    seg_mean_fin<<<(R2 * H + 255) / 256, 256, 0, stream>>>(accR, cntR, R2);
    build_xin<<<(R2 * 2 * H + 255) / 256, 256, 0, stream>>>(rel, accR, xin);
    gemm64<1, 0><<<dim3((H3 + 63) / 64, (R2 + 63) / 64, 1), 256, 0, stream>>>(
        xin, gru_W_ih, gru_b_ih, gi, R2, 2 * H, H3);
    gemm64<1, 0><<<dim3((H3 + 63) / 64, (R2 + 63) / 64, 1), 256, 0, stream>>>(
        rel, gru_W_hh, gru_b_hh, gh, R2, H, H3);
    gru_combine<<<(R2 * H + 255) / 256, 256, 0, stream>>>(gi, gh, rel);

    // --- ent update ---
    gemm64<0, 2><<<dim3((H + 63) / 64, (NE + 63) / 64, 1), 256, 0, stream>>>(
        ent, tg_W, tg_b, tgbuf, NE, H, H);   // tw = sigmoid(ent @ tg_W + b)
    hipMemsetAsync(accE, 0, (size_t)NE * H * 4, stream);
    hipMemsetAsync(cntE, 0, 20480 * 4, stream);
    {
      long long th = (long long)NEDGE * 64;
      int nb = (int)((th + 255) / 256);
      scatter_edges<<<nb, 256, 0, stream>>>(ent, rel, edge_src + (size_t)t * NEDGE,
                                            edge_rel + (size_t)t * NEDGE,
                                            edge_dst + (size_t)t * NEDGE, accE, cntE, NEDGE);
    }
    seg_mean_fin<<<(NE * H + 255) / 256, 256, 0, stream>>>(accE, cntE, NE);
    gemm64<0, 1><<<dim3((H + 63) / 64, (NE + 63) / 64, 1), 256, 0, stream>>>(
        accE, agg_W, nullptr, curr, NE, H, H);   // relu(mean @ agg_W)
    ent_update<<<(NE * H + 255) / 256, 256, 0, stream>>>(ent, tgbuf, curr);
  }

  // --- hypergraph layers ---
  for (int l = 0; l < 2; l++) {
    hipMemsetAsync(accE, 0, (size_t)NE * H * 4, stream);
    long long th = (long long)NNZ_E * 64;
    int nb = (int)((th + 255) / 256);
    scatter_hyper<<<nb, 256, 0, stream>>>(ent, hev, he_row, he_col, accE, NNZ_E);
    hyper_fin<<<NE, 256, 0, stream>>>(accE, ent);
  }
  for (int l = 0; l < 2; l++) {
    hipMemsetAsync(accR, 0, (size_t)R2 * H * 4, stream);
    long long th = (long long)NNZ_R * 64;
    int nb = (int)((th + 255) / 256);
    scatter_hyper<<<nb, 256, 0, stream>>>(rel, hrv, hr_row, hr_col, accR, NNZ_R);
    hyper_fin<<<R2, 256, 0, stream>>>(accR, rel);
  }

  // --- conv + fc (chunks of 800 rows) ---
  for (int c = 0; c < 5; c++) {
    int row0 = c * 800;
    conv_feat<<<800, 256, 0, stream>>>(ent, rel, sent, tt, conv_w, conv_b, big, row0);
    gemm64<0, 0><<<dim3((H + 63) / 64, (800 + 63) / 64, 8), 256, 0, stream>>>(
        big, fc_W, nullptr, fcpart, 800, 12800, H);
    fc_reduce<<<(800 * H + 255) / 256, 256, 0, stream>>>(fcpart, fc_b, q + (size_t)row0 * H, 800, 8);
  }

  // --- scores + logsumexp (chunks of 500 rows) ---
  for (int c = 0; c < 8; c++) {
    int row0 = c * 500;
    gemm64<1, 0><<<dim3((NE + 63) / 64, (500 + 63) / 64, 1), 256, 0, stream>>>(
        q + (size_t)row0 * H, ent, nullptr, big, 500, H, NE);
    lse_kernel<<<500, 256, 0, stream>>>(big, tt, nll, row0);
  }

  mean_nll<<<1, 256, 0, stream>>>(nll, out);
}

// Round 2
// 4346.865 us; speedup vs baseline: 2.0905x; 2.0905x over previous
//
#include <hip/hip_runtime.h>
#include <math.h>

#define DEV_INLINE __device__ __forceinline__

constexpr int H      = 256;
constexpr int NE     = 20000;
constexpr int NR     = 250;
constexpr int R2     = 500;
constexpr int TT     = 3;
constexpr int NEDGE  = 150000;
constexpr int M      = 200000;
constexpr int NNZ_E  = 320000;
constexpr int NNZ_R  = 8000;
constexpr int CH     = 50;
constexpr int NT     = 2000;
constexpr int NT2    = 4000;
constexpr int H3     = 3 * H;   // 768

// ------------------------- block reductions (blockDim == 256) -------------
DEV_INLINE float block_sum256(float v) {
  __shared__ float ws[4];
  #pragma unroll
  for (int o = 32; o > 0; o >>= 1) v += __shfl_down(v, o, 64);
  if ((threadIdx.x & 63) == 0) ws[threadIdx.x >> 6] = v;
  __syncthreads();
  float r = ws[0] + ws[1] + ws[2] + ws[3];
  __syncthreads();
  return r;
}
DEV_INLINE float block_max256(float v) {
  __shared__ float wm[4];
  #pragma unroll
  for (int o = 32; o > 0; o >>= 1) v = fmaxf(v, __shfl_down(v, o, 64));
  if ((threadIdx.x & 63) == 0) wm[threadIdx.x >> 6] = v;
  __syncthreads();
  float r = fmaxf(fmaxf(wm[0], wm[1]), fmaxf(wm[2], wm[3]));
  __syncthreads();
  return r;
}

// ------------------------- CSR build (int atomics only) --------------------
__global__ void hist_k(const int* __restrict__ keys, int n, int* __restrict__ cnt)
{
  int i = blockIdx.x * 256 + threadIdx.x;
  if (i < n) atomicAdd(&cnt[keys[i]], 1);
}

// single-block exclusive scan; writes start[0..nbins] and cursor[0..nbins-1]
__global__ void scan_k(const int* __restrict__ cnt, int* __restrict__ start,
                       int* __restrict__ cursor, int nbins)
{
  __shared__ int ps[257];
  int t = threadIdx.x;
  int per = (nbins + 255) >> 8;
  int b0 = t * per;
  int local = 0;
  for (int i = 0; i < per; i++) { int b = b0 + i; if (b < nbins) local += cnt[b]; }
  ps[t + 1] = local;
  if (t == 0) ps[0] = 0;
  __syncthreads();
  if (t == 0) { for (int i = 1; i <= 256; i++) ps[i] += ps[i - 1]; }
  __syncthreads();
  int run = ps[t];
  for (int i = 0; i < per; i++) {
    int b = b0 + i;
    if (b < nbins) { start[b] = run; cursor[b] = run; run += cnt[b]; }
  }
  if (t == 0) start[nbins] = ps[256];
}

__global__ void perm_k(const int* __restrict__ keys, int n,
                       int* __restrict__ cursor, int* __restrict__ perm)
{
  int i = blockIdx.x * 256 + threadIdx.x;
  if (i < n) { int p = atomicAdd(&cursor[keys[i]], 1); perm[p] = i; }
}

// ------------------------- gather kernels (no float atomics) ---------------
// out[r] = mean over entries of src[gidx[e]]   (block per row, thread per dim)
__global__ void gather_mean_k(const float* __restrict__ src, const int* __restrict__ gidx,
                              const int* __restrict__ perm, const int* __restrict__ start,
                              float* __restrict__ out)
{
  int r = blockIdx.x, h = threadIdx.x;
  int s0 = start[r], s1 = start[r + 1];
  float a0 = 0.f, a1 = 0.f, a2 = 0.f, a3 = 0.f;
  int j = s0;
  for (; j + 3 < s1; j += 4) {
    int e0 = gidx[perm[j + 0]];
    int e1 = gidx[perm[j + 1]];
    int e2 = gidx[perm[j + 2]];
    int e3 = gidx[perm[j + 3]];
    a0 += src[(size_t)e0 * H + h];
    a1 += src[(size_t)e1 * H + h];
    a2 += src[(size_t)e2 * H + h];
    a3 += src[(size_t)e3 * H + h];
  }
  for (; j < s1; j++) a0 += src[(size_t)gidx[perm[j]] * H + h];
  float acc = (a0 + a1) + (a2 + a3);
  out[(size_t)r * H + h] = acc / (float)max(s1 - s0, 1);
}

// out[d] = mean over entries of (ent[src[e]] + rel[rr[e]])
__global__ void gather_edges_k(const float* __restrict__ ent, const float* __restrict__ rel,
                               const int* __restrict__ esrc, const int* __restrict__ erel,
                               const int* __restrict__ perm, const int* __restrict__ start,
                               float* __restrict__ out)
{
  int d = blockIdx.x, h = threadIdx.x;
  int s0 = start[d], s1 = start[d + 1];
  float a0 = 0.f, a1 = 0.f;
  int j = s0;
  for (; j + 1 < s1; j += 2) {
    int e0 = perm[j], e1 = perm[j + 1];
    a0 += ent[(size_t)esrc[e0] * H + h] + rel[(size_t)erel[e0] * H + h];
    a1 += ent[(size_t)esrc[e1] * H + h] + rel[(size_t)erel[e1] * H + h];
  }
  for (; j < s1; j++) {
    int e = perm[j];
    a0 += ent[(size_t)esrc[e] * H + h] + rel[(size_t)erel[e] * H + h];
  }
  out[(size_t)d * H + h] = (a0 + a1) / (float)max(s1 - s0, 1);
}

// xout[r] = x[r] + y / max(||y||,eps) where y = sum val[e]*x[col[e]]
__global__ void hyper_layer_k(const float* __restrict__ x, const float* __restrict__ val,
                              const int* __restrict__ col, const int* __restrict__ perm,
                              const int* __restrict__ start, float* __restrict__ xout)
{
  int r = blockIdx.x, h = threadIdx.x;
  int s0 = start[r], s1 = start[r + 1];
  float a0 = 0.f, a1 = 0.f, a2 = 0.f, a3 = 0.f;
  int j = s0;
  for (; j + 3 < s1; j += 4) {
    int e0 = perm[j + 0], e1 = perm[j + 1], e2 = perm[j + 2], e3 = perm[j + 3];
    a0 += val[e0] * x[(size_t)col[e0] * H + h];
    a1 += val[e1] * x[(size_t)col[e1] * H + h];
    a2 += val[e2] * x[(size_t)col[e2] * H + h];
    a3 += val[e3] * x[(size_t)col[e3] * H + h];
  }
  for (; j < s1; j++) { int e = perm[j]; a0 += val[e] * x[(size_t)col[e] * H + h]; }
  float y = (a0 + a1) + (a2 + a3);
  float ss = block_sum256(y * y);
  float rn = 1.f / fmaxf(sqrtf(ss), 1e-12f);
  xout[(size_t)r * H + h] = x[(size_t)r * H + h] + y * rn;
}

// ------------------------- small elementwise kernels ----------------------
__global__ void build_xin(const float* __restrict__ rel, const float* __restrict__ xm,
                          float* __restrict__ xin)
{
  int idx = blockIdx.x * 256 + threadIdx.x;       // R2 * 512
  if (idx >= R2 * 2 * H) return;
  int i = idx >> 9, c = idx & 511;
  xin[idx] = (c < H) ? rel[(size_t)i * H + c] : xm[(size_t)i * H + (c - H)];
}

__global__ void gru_combine(const float* __restrict__ gi, const float* __restrict__ gh,
                            float* __restrict__ rel)
{
  int idx = blockIdx.x * 256 + threadIdx.x;       // R2 * H
  if (idx >= R2 * H) return;
  int i = idx >> 8, h = idx & 255;
  const float* gir = gi + (size_t)i * H3;
  const float* ghr = gh + (size_t)i * H3;
  float r = 1.f / (1.f + expf(-(gir[h]       + ghr[h])));
  float z = 1.f / (1.f + expf(-(gir[H + h]   + ghr[H + h])));
  float n = tanhf(gir[2 * H + h] + r * ghr[2 * H + h]);
  rel[idx] = (1.f - z) * n + z * rel[idx];
}

__global__ void ent_update(float* __restrict__ ent, const float* __restrict__ tw,
                           const float* __restrict__ curr)
{
  int idx = blockIdx.x * 256 + threadIdx.x;       // NE * H
  if (idx >= NE * H) return;
  float t = tw[idx];
  ent[idx] = t * curr[idx] + (1.f - t) * ent[idx];
}

// ------------------------- generic tiled GEMM ------------------------------
template<int TRANS_B, int ACT>
__global__ void gemm64(const float* __restrict__ A, const float* __restrict__ B,
                       const float* __restrict__ bias, float* __restrict__ C,
                       int N, int K, int Mo)
{
  __shared__ float As[16][68];
  __shared__ float Bs[16][68];
  const int tid = threadIdx.x;
  const int tx = tid & 15, ty = tid >> 4;
  const int rowBase = blockIdx.y * 64;
  const int colBase = blockIdx.x * 64;
  const int S = gridDim.z;
  const int klen = K / S;
  const int kbeg = blockIdx.z * klen;
  const int kend = kbeg + klen;
  float acc[4][4] = {};
  for (int k0 = kbeg; k0 < kend; k0 += 16) {
    {
      const int k = tid & 15;
      const int rb = tid >> 4;
      #pragma unroll
      for (int rr = 0; rr < 4; rr++) {
        int r = rb + rr * 16;
        int row = rowBase + r;
        As[k][r] = (row < N) ? A[(size_t)row * K + (k0 + k)] : 0.f;
      }
    }
    if (TRANS_B) {
      const int k = tid & 15;
      const int cb = tid >> 4;
      #pragma unroll
      for (int rr = 0; rr < 4; rr++) {
        int c = cb + rr * 16;
        int col = colBase + c;
        Bs[k][c] = (col < Mo) ? B[(size_t)col * K + (k0 + k)] : 0.f;
      }
    } else {
      const int c = tid & 63;
      const int kb = tid >> 6;
      const int col = colBase + c;
      #pragma unroll
      for (int rr = 0; rr < 4; rr++) {
        int k = kb + rr * 4;
        Bs[k][c] = (col < Mo) ? B[(size_t)(k0 + k) * Mo + col] : 0.f;
      }
    }
    __syncthreads();
    #pragma unroll
    for (int k = 0; k < 16; k++) {
      const float4 a4 = *reinterpret_cast<const float4*>(&As[k][ty * 4]);
      const float4 b4 = *reinterpret_cast<const float4*>(&Bs[k][tx * 4]);
      const float av[4] = {a4.x, a4.y, a4.z, a4.w};
      const float bv[4] = {b4.x, b4.y, b4.z, b4.w};
      #pragma unroll
      for (int i = 0; i < 4; i++)
        #pragma unroll
        for (int j = 0; j < 4; j++)
          acc[i][j] = fmaf(av[i], bv[j], acc[i][j]);
    }
    __syncthreads();
  }
  float* Cz = (S > 1) ? (C + (size_t)blockIdx.z * N * Mo) : C;
  #pragma unroll
  for (int i = 0; i < 4; i++) {
    int row = rowBase + ty * 4 + i;
    if (row >= N) continue;
    #pragma unroll
    for (int j = 0; j < 4; j++) {
      int col = colBase + tx * 4 + j;
      if (col >= Mo) continue;
      float v = acc[i][j];
      if (S == 1) {
        if (bias) v += bias[col];
        if (ACT == 1) v = fmaxf(v, 0.f);
        if (ACT == 2) v = 1.f / (1.f + expf(-v));
      }
      Cz[(size_t)row * Mo + col] = v;
    }
  }
}

// sum split-K partials + bias + relu -> q
__global__ void fc_reduce(const float* __restrict__ part, const float* __restrict__ bias,
                          float* __restrict__ q, int nrows, int splits)
{
  int idx = blockIdx.x * 256 + threadIdx.x;       // nrows * H
  if (idx >= nrows * H) return;
  int col = idx & 255;
  float s = bias[col];
  for (int z = 0; z < splits; z++) s += part[(size_t)z * nrows * H + idx];
  q[idx] = fmaxf(s, 0.f);
}

// ------------------------- conv (block per test row) -----------------------
__global__ void conv_feat(const float* __restrict__ ent, const float* __restrict__ rel,
                          const float* __restrict__ sent, const int* __restrict__ tt,
                          const float* __restrict__ cw, const float* __restrict__ cb,
                          float* __restrict__ out, int row0)
{
  __shared__ float f[3][258];
  __shared__ float wsm[CH * 9];
  __shared__ float bsm[CH];
  int i = row0 + blockIdx.x;
  int h = threadIdx.x;
  int j = (i < NT) ? i : i - NT;
  int a0 = (i < NT) ? tt[j * 3 + 0] : tt[j * 3 + 2];
  int a1 = (i < NT) ? tt[j * 3 + 1] : tt[j * 3 + 1] + NR;
  f[0][h + 1] = ent[(size_t)a0 * H + h];
  f[1][h + 1] = rel[(size_t)a1 * H + h];
  f[2][h + 1] = sent[(size_t)j * H + h];
  if (h < 3) { f[h][0] = 0.f; f[h][257] = 0.f; }
  for (int x = h; x < CH * 9; x += 256) wsm[x] = cw[x];
  if (h < CH) bsm[h] = cb[h];
  __syncthreads();
  float* orow = out + (size_t)blockIdx.x * (CH * H);
  for (int c = 0; c < CH; c++) {
    const float* wc = wsm + c * 9;
    float s = bsm[c];
    #pragma unroll
    for (int ic = 0; ic < 3; ic++)
      s += wc[ic * 3 + 0] * f[ic][h] + wc[ic * 3 + 1] * f[ic][h + 1] + wc[ic * 3 + 2] * f[ic][h + 2];
    orow[(size_t)c * H + h] = fmaxf(s, 0.f);
  }
}

// ------------------------- logsumexp per test row --------------------------
__global__ void lse_kernel(const float* __restrict__ sc, const int* __restrict__ tt,
                           float* __restrict__ nll, int row0)
{
  int r = blockIdx.x;
  int i = row0 + r;
  const float* s = sc + (size_t)r * NE;
  float m = -3.4e38f;
  for (int c = threadIdx.x; c < NE; c += 256) m = fmaxf(m, s[c]);
  m = block_max256(m);
  float sum = 0.f;
  for (int c = threadIdx.x; c < NE; c += 256) sum += expf(s[c] - m);
  sum = block_sum256(sum);
  if (threadIdx.x == 0) {
    int j = (i < NT) ? i : i - NT;
    int tgt = (i < NT) ? tt[j * 3 + 2] : tt[j * 3 + 0];
    nll[i] = m + logf(sum) - s[tgt];
  }
}

__global__ void mean_nll(const float* __restrict__ nll, float* __restrict__ out)
{
  float s = 0.f;
  for (int i = threadIdx.x; i < NT2; i += 256) s += nll[i];
  s = block_sum256(s);
  if (threadIdx.x == 0) out[0] = s * (1.f / NT2);
}

// ------------------------- launcher ----------------------------------------
extern "C" void kernel_launch(void* const* d_in, const int* in_sizes, int n_in,
                              void* d_out, int out_size, void* d_ws, size_t ws_size,
                              hipStream_t stream)
{
  const float* dynamic_emb = (const float*)d_in[0];
  const float* emb_rel     = (const float*)d_in[1];
  const float* gru_W_ih    = (const float*)d_in[2];
  const float* gru_W_hh    = (const float*)d_in[3];
  const float* gru_b_ih    = (const float*)d_in[4];
  const float* gru_b_hh    = (const float*)d_in[5];
  const float* agg_W       = (const float*)d_in[6];
  const float* tg_W        = (const float*)d_in[7];
  const float* tg_b        = (const float*)d_in[8];
  const float* hev         = (const float*)d_in[9];
  const float* hrv         = (const float*)d_in[10];
  const float* conv_w      = (const float*)d_in[11];
  const float* conv_b      = (const float*)d_in[12];
  const float* fc_W        = (const float*)d_in[13];
  const float* fc_b        = (const float*)d_in[14];
  const float* sent        = (const float*)d_in[15];
  const int* edge_src = (const int*)d_in[16];
  const int* edge_rel = (const int*)d_in[17];
  const int* edge_dst = (const int*)d_in[18];
  const int* r_to_e   = (const int*)d_in[19];
  const int* r_ids    = (const int*)d_in[20];
  const int* he_row   = (const int*)d_in[21];
  const int* he_col   = (const int*)d_in[22];
  const int* hr_row   = (const int*)d_in[23];
  const int* hr_col   = (const int*)d_in[24];
  const int* tt       = (const int*)d_in[25];
  float* out = (float*)d_out;

  float* w = (float*)d_ws;
  size_t off = 0;
  auto alloc = [&](size_t n) { float* p = w + off; off += n; return p; };
  float* ent    = alloc((size_t)NE * H);
  float* accE   = alloc((size_t)NE * H);   // edge-gather out; also hyper ping-pong
  float* curr   = alloc((size_t)NE * H);
  float* tgbuf  = alloc((size_t)NE * H);
  float* rel    = alloc((size_t)R2 * H);
  float* accR   = alloc((size_t)R2 * H);   // xmean; also rel hyper ping-pong
  float* xin    = alloc((size_t)R2 * 2 * H);
  float* gi     = alloc((size_t)R2 * H3);
  float* gh     = alloc((size_t)R2 * H3);
  float* q      = alloc((size_t)NT2 * H);
  float* nll    = alloc(4096);
  float* fcpart = alloc((size_t)8 * 800 * H);
  float* big    = alloc((size_t)800 * 12800);   // also fits 500*20000

  // int region
  int* ip = (int*)(w + off);
  size_t ioff = 0;
  auto ialloc = [&](size_t n) { int* p = ip + ioff; ioff += n; return p; };
  int* permM[TT]; int* sM[TT];
  int* permE[TT]; int* sE[TT];
  for (int t = 0; t < TT; t++) { permM[t] = ialloc(M);     sM[t] = ialloc(R2 + 1); }
  for (int t = 0; t < TT; t++) { permE[t] = ialloc(NEDGE); sE[t] = ialloc(NE + 1); }
  int* permHE = ialloc(NNZ_E); int* sHE = ialloc(NE + 1);
  int* permHR = ialloc(NNZ_R); int* sHR = ialloc(R2 + 1);
  int* cnt    = ialloc(NE + 1);
  int* cursor = ialloc(NE + 1);

  auto build_csr = [&](const int* keys, int n, int nbins, int* start, int* perm) {
    hipMemsetAsync(cnt, 0, (size_t)nbins * 4, stream);
    hist_k<<<(n + 255) / 256, 256, 0, stream>>>(keys, n, cnt);
    scan_k<<<1, 256, 0, stream>>>(cnt, start, cursor, nbins);
    perm_k<<<(n + 255) / 256, 256, 0, stream>>>(keys, n, cursor, perm);
  };

  for (int t = 0; t < TT; t++) build_csr(r_ids + (size_t)t * M, M, R2, sM[t], permM[t]);
  for (int t = 0; t < TT; t++) build_csr(edge_dst + (size_t)t * NEDGE, NEDGE, NE, sE[t], permE[t]);
  build_csr(he_row, NNZ_E, NE, sHE, permHE);
  build_csr(hr_row, NNZ_R, R2, sHR, permHR);

  hipMemcpyAsync(ent, dynamic_emb, (size_t)NE * H * 4, hipMemcpyDeviceToDevice, stream);
  hipMemcpyAsync(rel, emb_rel, (size_t)R2 * H * 4, hipMemcpyDeviceToDevice, stream);

  for (int t = 0; t < TT; t++) {
    // --- rel update (GRU) ---
    gather_mean_k<<<R2, 256, 0, stream>>>(ent, r_to_e + (size_t)t * M, permM[t], sM[t], accR);
    build_xin<<<(R2 * 2 * H + 255) / 256, 256, 0, stream>>>(rel, accR, xin);
    gemm64<1, 0><<<dim3((H3 + 63) / 64, (R2 + 63) / 64, 1), 256, 0, stream>>>(
        xin, gru_W_ih, gru_b_ih, gi, R2, 2 * H, H3);
    gemm64<1, 0><<<dim3((H3 + 63) / 64, (R2 + 63) / 64, 1), 256, 0, stream>>>(
        rel, gru_W_hh, gru_b_hh, gh, R2, H, H3);
    gru_combine<<<(R2 * H + 255) / 256, 256, 0, stream>>>(gi, gh, rel);

    // --- ent update ---
    gemm64<0, 2><<<dim3((H + 63) / 64, (NE + 63) / 64, 1), 256, 0, stream>>>(
        ent, tg_W, tg_b, tgbuf, NE, H, H);   // tw = sigmoid(ent @ tg_W + b)
    gather_edges_k<<<NE, 256, 0, stream>>>(ent, rel, edge_src + (size_t)t * NEDGE,
                                           edge_rel + (size_t)t * NEDGE, permE[t], sE[t], accE);
    gemm64<0, 1><<<dim3((H + 63) / 64, (NE + 63) / 64, 1), 256, 0, stream>>>(
        accE, agg_W, nullptr, curr, NE, H, H);   // relu(mean @ agg_W)
    ent_update<<<(NE * H + 255) / 256, 256, 0, stream>>>(ent, tgbuf, curr);
  }

  // --- hypergraph layers (ping-pong, ends back in ent / rel) ---
  {
    float* xa = ent; float* xb = accE;
    for (int l = 0; l < 2; l++) {
      hyper_layer_k<<<NE, 256, 0, stream>>>(xa, hev, he_col, permHE, sHE, xb);
      float* tmp = xa; xa = xb; xb = tmp;
    }
    // after 2 swaps xa == ent again
  }
  {
    float* xa = rel; float* xb = accR;
    for (int l = 0; l < 2; l++) {
      hyper_layer_k<<<R2, 256, 0, stream>>>(xa, hrv, hr_col, permHR, sHR, xb);
      float* tmp = xa; xa = xb; xb = tmp;
    }
  }

  // --- conv + fc (chunks of 800 rows) ---
  for (int c = 0; c < 5; c++) {
    int row0 = c * 800;
    conv_feat<<<800, 256, 0, stream>>>(ent, rel, sent, tt, conv_w, conv_b, big, row0);
    gemm64<0, 0><<<dim3((H + 63) / 64, (800 + 63) / 64, 8), 256, 0, stream>>>(
        big, fc_W, nullptr, fcpart, 800, 12800, H);
    fc_reduce<<<(800 * H + 255) / 256, 256, 0, stream>>>(fcpart, fc_b, q + (size_t)row0 * H, 800, 8);
  }

  // --- scores + logsumexp (chunks of 500 rows) ---
  for (int c = 0; c < 8; c++) {
    int row0 = c * 500;
    gemm64<1, 0><<<dim3((NE + 63) / 64, (500 + 63) / 64, 1), 256, 0, stream>>>(
        q + (size_t)row0 * H, ent, nullptr, big, 500, H, NE);
    lse_kernel<<<500, 256, 0, stream>>>(big, tt, nll, row0);
  }

  mean_nll<<<1, 256, 0, stream>>>(nll, out);
}

// Round 3
// 2387.979 us; speedup vs baseline: 3.8053x; 1.8203x over previous
//
#include <hip/hip_runtime.h>
#include <math.h>

#define DEV_INLINE __device__ __forceinline__

constexpr int H      = 256;
constexpr int NE     = 20000;
constexpr int NR     = 250;
constexpr int R2     = 500;
constexpr int TT     = 3;
constexpr int NEDGE  = 150000;
constexpr int M      = 200000;
constexpr int NNZ_E  = 320000;
constexpr int NNZ_R  = 8000;
constexpr int CH     = 50;
constexpr int NT     = 2000;
constexpr int NT2    = 4000;
constexpr int H3     = 3 * H;     // 768
constexpr int KFC    = CH * H;    // 12800
constexpr int SCORE_NC = 10;      // col chunks for scores
constexpr int ROWPAD   = 4032;    // 63 * 64

typedef __bf16 bf16x8 __attribute__((ext_vector_type(8)));
typedef float  f32x4  __attribute__((ext_vector_type(4)));

DEV_INLINE bf16x8 ldb8(const __bf16* p) { return *(const bf16x8*)p; }
DEV_INLINE bf16x8 zerob8() { uint4 z = make_uint4(0, 0, 0, 0); return __builtin_bit_cast(bf16x8, z); }
DEV_INLINE f32x4 mfma16(bf16x8 a, bf16x8 b, f32x4 c) {
  return __builtin_amdgcn_mfma_f32_16x16x32_bf16(a, b, c, 0, 0, 0);
}

// ------------------------- block reduction (blockDim == 256) ---------------
DEV_INLINE float block_sum256(float v) {
  __shared__ float ws[4];
  #pragma unroll
  for (int o = 32; o > 0; o >>= 1) v += __shfl_down(v, o, 64);
  if ((threadIdx.x & 63) == 0) ws[threadIdx.x >> 6] = v;
  __syncthreads();
  float r = ws[0] + ws[1] + ws[2] + ws[3];
  __syncthreads();
  return r;
}

// ------------------------- CSR build (int atomics only) --------------------
__global__ void hist_k(const int* __restrict__ keys, int n, int* __restrict__ cnt)
{
  int i = blockIdx.x * 256 + threadIdx.x;
  if (i < n) atomicAdd(&cnt[keys[i]], 1);
}

__global__ void scan_k(const int* __restrict__ cnt, int* __restrict__ start,
                       int* __restrict__ cursor, int nbins)
{
  __shared__ int ps[257];
  int t = threadIdx.x;
  int per = (nbins + 255) >> 8;
  int b0 = t * per;
  int local = 0;
  for (int i = 0; i < per; i++) { int b = b0 + i; if (b < nbins) local += cnt[b]; }
  ps[t + 1] = local;
  if (t == 0) ps[0] = 0;
  __syncthreads();
  if (t == 0) { for (int i = 1; i <= 256; i++) ps[i] += ps[i - 1]; }
  __syncthreads();
  int run = ps[t];
  for (int i = 0; i < per; i++) {
    int b = b0 + i;
    if (b < nbins) { start[b] = run; cursor[b] = run; run += cnt[b]; }
  }
  if (t == 0) start[nbins] = ps[256];
}

__global__ void perm_k(const int* __restrict__ keys, int n,
                       int* __restrict__ cursor, int* __restrict__ perm)
{
  int i = blockIdx.x * 256 + threadIdx.x;
  if (i < n) { int p = atomicAdd(&cursor[keys[i]], 1); perm[p] = i; }
}

// ------------------------- casts / transposes ------------------------------
__global__ void cast_bf16_k(const float* __restrict__ in, __bf16* __restrict__ out, int n8)
{
  int i = blockIdx.x * 256 + threadIdx.x;
  if (i >= n8) return;
  const float4* p = (const float4*)in + (size_t)i * 2;
  float4 u = p[0], v = p[1];
  bf16x8 o;
  o[0] = (__bf16)u.x; o[1] = (__bf16)u.y; o[2] = (__bf16)u.z; o[3] = (__bf16)u.w;
  o[4] = (__bf16)v.x; o[5] = (__bf16)v.y; o[6] = (__bf16)v.z; o[7] = (__bf16)v.w;
  ((bf16x8*)out)[i] = o;
}

// in: K x N fp32 row-major -> out: N x K bf16 row-major (K,N multiples of 32)
__global__ void transpose_cast_k(const float* __restrict__ in, __bf16* __restrict__ out,
                                 int K, int N)
{
  __shared__ float tile[32][33];
  int tx = threadIdx.x & 31, ty = threadIdx.x >> 5;   // 32 x 8
  int kb = blockIdx.x * 32, nb = blockIdx.y * 32;
  #pragma unroll
  for (int i = 0; i < 4; i++)
    tile[ty + i * 8][tx] = in[(size_t)(kb + ty + i * 8) * N + nb + tx];
  __syncthreads();
  #pragma unroll
  for (int i = 0; i < 4; i++)
    out[(size_t)(nb + ty + i * 8) * K + kb + tx] = (__bf16)tile[tx][ty + i * 8];
}

// ------------------------- gather kernels ----------------------------------
__global__ void gather_mean_k(const __bf16* __restrict__ src, const int* __restrict__ gidx,
                              const int* __restrict__ perm, const int* __restrict__ start,
                              float* __restrict__ out)
{
  int r = blockIdx.x, h = threadIdx.x;
  int s0 = start[r], s1 = start[r + 1];
  float a0 = 0.f, a1 = 0.f, a2 = 0.f, a3 = 0.f;
  int j = s0;
  for (; j + 3 < s1; j += 4) {
    int e0 = gidx[perm[j + 0]];
    int e1 = gidx[perm[j + 1]];
    int e2 = gidx[perm[j + 2]];
    int e3 = gidx[perm[j + 3]];
    a0 += (float)src[(size_t)e0 * H + h];
    a1 += (float)src[(size_t)e1 * H + h];
    a2 += (float)src[(size_t)e2 * H + h];
    a3 += (float)src[(size_t)e3 * H + h];
  }
  for (; j < s1; j++) a0 += (float)src[(size_t)gidx[perm[j]] * H + h];
  float acc = (a0 + a1) + (a2 + a3);
  out[(size_t)r * H + h] = acc / (float)max(s1 - s0, 1);
}

__global__ void gather_edges_k(const __bf16* __restrict__ ent, const __bf16* __restrict__ rel,
                               const int* __restrict__ esrc, const int* __restrict__ erel,
                               const int* __restrict__ perm, const int* __restrict__ start,
                               __bf16* __restrict__ out)
{
  int d = blockIdx.x, h = threadIdx.x;
  int s0 = start[d], s1 = start[d + 1];
  float a0 = 0.f, a1 = 0.f;
  int j = s0;
  for (; j + 1 < s1; j += 2) {
    int e0 = perm[j], e1 = perm[j + 1];
    a0 += (float)ent[(size_t)esrc[e0] * H + h] + (float)rel[(size_t)erel[e0] * H + h];
    a1 += (float)ent[(size_t)esrc[e1] * H + h] + (float)rel[(size_t)erel[e1] * H + h];
  }
  for (; j < s1; j++) {
    int e = perm[j];
    a0 += (float)ent[(size_t)esrc[e] * H + h] + (float)rel[(size_t)erel[e] * H + h];
  }
  out[(size_t)d * H + h] = (__bf16)((a0 + a1) / (float)max(s1 - s0, 1));
}

__global__ void hyper_layer_k(const float* __restrict__ x, const float* __restrict__ val,
                              const int* __restrict__ col, const int* __restrict__ perm,
                              const int* __restrict__ start, float* __restrict__ xout)
{
  int r = blockIdx.x, h = threadIdx.x;
  int s0 = start[r], s1 = start[r + 1];
  float a0 = 0.f, a1 = 0.f, a2 = 0.f, a3 = 0.f;
  int j = s0;
  for (; j + 3 < s1; j += 4) {
    int e0 = perm[j + 0], e1 = perm[j + 1], e2 = perm[j + 2], e3 = perm[j + 3];
    a0 += val[e0] * x[(size_t)col[e0] * H + h];
    a1 += val[e1] * x[(size_t)col[e1] * H + h];
    a2 += val[e2] * x[(size_t)col[e2] * H + h];
    a3 += val[e3] * x[(size_t)col[e3] * H + h];
  }
  for (; j < s1; j++) { int e = perm[j]; a0 += val[e] * x[(size_t)col[e] * H + h]; }
  float y = (a0 + a1) + (a2 + a3);
  float ss = block_sum256(y * y);
  float rn = 1.f / fmaxf(sqrtf(ss), 1e-12f);
  xout[(size_t)r * H + h] = x[(size_t)r * H + h] + y * rn;
}

// ------------------------- small elementwise -------------------------------
__global__ void build_xin_bf(const float* __restrict__ rel, const float* __restrict__ xm,
                             __bf16* __restrict__ xin)
{
  int idx = blockIdx.x * 256 + threadIdx.x;       // R2 * 512
  if (idx >= R2 * 2 * H) return;
  int i = idx >> 9, c = idx & 511;
  float v = (c < H) ? rel[(size_t)i * H + c] : xm[(size_t)i * H + (c - H)];
  xin[idx] = (__bf16)v;
}

__global__ void gru_combine(const float* __restrict__ gi, const float* __restrict__ gh,
                            float* __restrict__ rel)
{
  int idx = blockIdx.x * 256 + threadIdx.x;       // R2 * H
  if (idx >= R2 * H) return;
  int i = idx >> 8, h = idx & 255;
  const float* gir = gi + (size_t)i * H3;
  const float* ghr = gh + (size_t)i * H3;
  float r = 1.f / (1.f + __expf(-(gir[h]       + ghr[h])));
  float z = 1.f / (1.f + __expf(-(gir[H + h]   + ghr[H + h])));
  float n = tanhf(gir[2 * H + h] + r * ghr[2 * H + h]);
  rel[idx] = (1.f - z) * n + z * rel[idx];
}

__global__ void ent_update(float* __restrict__ ent, const float* __restrict__ tw,
                           const float* __restrict__ curr)
{
  int idx = blockIdx.x * 256 + threadIdx.x;       // NE * H
  if (idx >= NE * H) return;
  float t = tw[idx];
  ent[idx] = t * curr[idx] + (1.f - t) * ent[idx];
}

// ------------------------- MFMA GEMM ---------------------------------------
// C(MxN) = act(A @ Bt^T + bias). A: MxK bf16 row-major. Bt: NxK bf16 row-major.
// Requires N % 64 == 0, K % 32 == 0. Block 256 thr = 2x2 waves, 64x64 tile.
// SPLITK: gridDim.z partials -> C + z*M*N (no bias/act).
template<int ACT, bool SPLITK>
__global__ void mfma_gemm(const __bf16* __restrict__ A, const __bf16* __restrict__ Bt,
                          const float* __restrict__ bias, float* __restrict__ C,
                          int Mr, int K, int N)
{
  int lane = threadIdx.x & 63, wave = threadIdx.x >> 6;
  int waveM = wave >> 1, waveN = wave & 1;
  int r = lane & 15, kg = lane >> 4;
  int rowBase = blockIdx.y * 64 + waveM * 32;
  int colBase = blockIdx.x * 64 + waveN * 32;
  int kbeg = 0, kend = K;
  if (SPLITK) { int kl = K / gridDim.z; kbeg = blockIdx.z * kl; kend = kbeg + kl; }

  int row0 = rowBase + r, row1 = rowBase + 16 + r;
  int col0 = colBase + r, col1 = colBase + 16 + r;
  bool v0 = row0 < Mr, v1 = row1 < Mr;
  const __bf16* a0p = A + (size_t)row0 * K + kg * 8;
  const __bf16* a1p = A + (size_t)row1 * K + kg * 8;
  const __bf16* b0p = Bt + (size_t)col0 * K + kg * 8;
  const __bf16* b1p = Bt + (size_t)col1 * K + kg * 8;

  f32x4 acc[2][2];
  #pragma unroll
  for (int i = 0; i < 2; i++)
    #pragma unroll
    for (int j = 0; j < 2; j++) { acc[i][j][0] = 0.f; acc[i][j][1] = 0.f; acc[i][j][2] = 0.f; acc[i][j][3] = 0.f; }

  for (int k0 = kbeg; k0 < kend; k0 += 32) {
    bf16x8 a0 = v0 ? ldb8(a0p + k0) : zerob8();
    bf16x8 a1 = v1 ? ldb8(a1p + k0) : zerob8();
    bf16x8 b0 = ldb8(b0p + k0);
    bf16x8 b1 = ldb8(b1p + k0);
    acc[0][0] = mfma16(a0, b0, acc[0][0]);
    acc[0][1] = mfma16(a0, b1, acc[0][1]);
    acc[1][0] = mfma16(a1, b0, acc[1][0]);
    acc[1][1] = mfma16(a1, b1, acc[1][1]);
  }

  float* Cz = SPLITK ? (C + (size_t)blockIdx.z * Mr * N) : C;
  #pragma unroll
  for (int i = 0; i < 2; i++) {
    #pragma unroll
    for (int g = 0; g < 4; g++) {
      int row = rowBase + i * 16 + kg * 4 + g;
      if (row >= Mr) continue;
      #pragma unroll
      for (int j = 0; j < 2; j++) {
        int col = colBase + j * 16 + r;
        float v = acc[i][j][g];
        if (!SPLITK) {
          if (bias) v += bias[col];
          if (ACT == 1) v = fmaxf(v, 0.f);
          if (ACT == 2) v = 1.f / (1.f + __expf(-v));
        }
        Cz[(size_t)row * N + col] = v;
      }
    }
  }
}

// sum split-K partials + bias + relu -> q (fp32) and qb (bf16)
__global__ void fc_reduce(const float* __restrict__ part, const float* __restrict__ bias,
                          float* __restrict__ q, __bf16* __restrict__ qb, int nrows, int splits)
{
  int idx = blockIdx.x * 256 + threadIdx.x;       // nrows * H
  if (idx >= nrows * H) return;
  int col = idx & 255;
  float s = bias[col];
  for (int z = 0; z < splits; z++) s += part[(size_t)z * nrows * H + idx];
  s = fmaxf(s, 0.f);
  q[idx] = s;
  qb[idx] = (__bf16)s;
}

// ------------------------- conv (block per test row) -----------------------
__global__ void conv_feat(const float* __restrict__ ent, const float* __restrict__ rel,
                          const float* __restrict__ sent, const int* __restrict__ tt,
                          const float* __restrict__ cw, const float* __restrict__ cb,
                          __bf16* __restrict__ out, int row0)
{
  __shared__ float f[3][258];
  __shared__ float wsm[CH * 9];
  __shared__ float bsm[CH];
  int i = row0 + blockIdx.x;
  int h = threadIdx.x;
  int j = (i < NT) ? i : i - NT;
  int a0 = (i < NT) ? tt[j * 3 + 0] : tt[j * 3 + 2];
  int a1 = (i < NT) ? tt[j * 3 + 1] : tt[j * 3 + 1] + NR;
  f[0][h + 1] = ent[(size_t)a0 * H + h];
  f[1][h + 1] = rel[(size_t)a1 * H + h];
  f[2][h + 1] = sent[(size_t)j * H + h];
  if (h < 3) { f[h][0] = 0.f; f[h][257] = 0.f; }
  for (int x = h; x < CH * 9; x += 256) wsm[x] = cw[x];
  if (h < CH) bsm[h] = cb[h];
  __syncthreads();
  __bf16* orow = out + (size_t)blockIdx.x * KFC;
  for (int c = 0; c < CH; c++) {
    const float* wc = wsm + c * 9;
    float s = bsm[c];
    #pragma unroll
    for (int ic = 0; ic < 3; ic++)
      s += wc[ic * 3 + 0] * f[ic][h] + wc[ic * 3 + 1] * f[ic][h + 1] + wc[ic * 3 + 2] * f[ic][h + 2];
    orow[(size_t)c * H + h] = (__bf16)fmaxf(s, 0.f);
  }
}

// ------------------------- fused scores + partial LSE ----------------------
// grid (SCORE_NC, 63). Block = 4 waves x 16 rows = 64 q-rows.
// part_l[chunk][row] = sum_{cols in chunk} exp(score)
__global__ void scores_lse_k(const __bf16* __restrict__ qb, const __bf16* __restrict__ eb,
                             float* __restrict__ part_l)
{
  int lane = threadIdx.x & 63, wave = threadIdx.x >> 6;
  int rowBase = blockIdx.y * 64 + wave * 16;
  int r = lane & 15, kg = lane >> 4;

  bf16x8 a[8];
  int arow = rowBase + r;
  if (arow < NT2) {
    const __bf16* ap = qb + (size_t)arow * H + kg * 8;
    #pragma unroll
    for (int f = 0; f < 8; f++) a[f] = ldb8(ap + f * 32);
  } else {
    #pragma unroll
    for (int f = 0; f < 8; f++) a[f] = zerob8();
  }

  float lsum[4] = {0.f, 0.f, 0.f, 0.f};
  const int c0 = blockIdx.x * (NE / SCORE_NC);
  const int c1 = c0 + NE / SCORE_NC;
  for (int j0 = c0; j0 < c1; j0 += 16) {
    const __bf16* bp = eb + (size_t)(j0 + r) * H + kg * 8;
    f32x4 acc; acc[0] = 0.f; acc[1] = 0.f; acc[2] = 0.f; acc[3] = 0.f;
    #pragma unroll
    for (int f = 0; f < 8; f++) {
      bf16x8 b = ldb8(bp + f * 32);
      acc = mfma16(a[f], b, acc);
    }
    #pragma unroll
    for (int g = 0; g < 4; g++) lsum[g] += __expf(acc[g]);
  }
  // sum across the 16 lanes of each quarter-wave (cols)
  #pragma unroll
  for (int m = 1; m < 16; m <<= 1) {
    #pragma unroll
    for (int g = 0; g < 4; g++) lsum[g] += __shfl_xor(lsum[g], m, 64);
  }
  if (r == 0) {
    #pragma unroll
    for (int g = 0; g < 4; g++) {
      int row = rowBase + kg * 4 + g;
      part_l[(size_t)blockIdx.x * ROWPAD + row] = lsum[g];
    }
  }
}

// one wave per row: nll[row] = log(sum_c part_l) - q[row].ent[tgt]
__global__ void lse_combine(const float* __restrict__ part_l, const float* __restrict__ qf,
                            const float* __restrict__ ent, const int* __restrict__ tt,
                            float* __restrict__ nll)
{
  int gid = blockIdx.x * 256 + threadIdx.x;
  int w = gid >> 6;
  if (w >= NT2) return;
  int lane = gid & 63;
  int j = (w < NT) ? w : w - NT;
  int tgt = (w < NT) ? tt[j * 3 + 2] : tt[j * 3 + 0];
  const float4 qa = ((const float4*)(qf + (size_t)w * H))[lane];
  const float4 ea = ((const float4*)(ent + (size_t)tgt * H))[lane];
  float d = qa.x * ea.x + qa.y * ea.y + qa.z * ea.z + qa.w * ea.w;
  #pragma unroll
  for (int o = 32; o > 0; o >>= 1) d += __shfl_down(d, o, 64);
  if (lane == 0) {
    float s = 0.f;
    for (int c = 0; c < SCORE_NC; c++) s += part_l[(size_t)c * ROWPAD + w];
    nll[w] = logf(s) - d;
  }
}

__global__ void mean_nll(const float* __restrict__ nll, float* __restrict__ out)
{
  float s = 0.f;
  for (int i = threadIdx.x; i < NT2; i += 256) s += nll[i];
  s = block_sum256(s);
  if (threadIdx.x == 0) out[0] = s * (1.f / NT2);
}

// ------------------------- launcher ----------------------------------------
extern "C" void kernel_launch(void* const* d_in, const int* in_sizes, int n_in,
                              void* d_out, int out_size, void* d_ws, size_t ws_size,
                              hipStream_t stream)
{
  const float* dynamic_emb = (const float*)d_in[0];
  const float* emb_rel     = (const float*)d_in[1];
  const float* gru_W_ih    = (const float*)d_in[2];
  const float* gru_W_hh    = (const float*)d_in[3];
  const float* gru_b_ih    = (const float*)d_in[4];
  const float* gru_b_hh    = (const float*)d_in[5];
  const float* agg_W       = (const float*)d_in[6];
  const float* tg_W        = (const float*)d_in[7];
  const float* tg_b        = (const float*)d_in[8];
  const float* hev         = (const float*)d_in[9];
  const float* hrv         = (const float*)d_in[10];
  const float* conv_w      = (const float*)d_in[11];
  const float* conv_b      = (const float*)d_in[12];
  const float* fc_W        = (const float*)d_in[13];
  const float* fc_b        = (const float*)d_in[14];
  const float* sent        = (const float*)d_in[15];
  const int* edge_src = (const int*)d_in[16];
  const int* edge_rel = (const int*)d_in[17];
  const int* edge_dst = (const int*)d_in[18];
  const int* r_to_e   = (const int*)d_in[19];
  const int* r_ids    = (const int*)d_in[20];
  const int* he_row   = (const int*)d_in[21];
  const int* he_col   = (const int*)d_in[22];
  const int* hr_row   = (const int*)d_in[23];
  const int* hr_col   = (const int*)d_in[24];
  const int* tt       = (const int*)d_in[25];
  float* out = (float*)d_out;

  char* base = (char*)d_ws;
  size_t off = 0;
  auto alloc = [&](size_t bytes) { char* p = base + off; off += (bytes + 255) & ~(size_t)255; return p; };

  float* ent    = (float*)alloc((size_t)NE * H * 4);
  float* curr   = (float*)alloc((size_t)NE * H * 4);        // agg out; hyper ping-pong
  float* tgbuf  = (float*)alloc((size_t)NE * H * 4);        // gate; conv_bf overlay
  __bf16* convb = (__bf16*)tgbuf;                            // 800*12800*2 = 20.48MB (same size)
  __bf16* entb  = (__bf16*)alloc((size_t)NE * H * 2);
  __bf16* accEb = (__bf16*)alloc((size_t)NE * H * 2);       // edge-gather out; fcpart overlay
  float* fcpart = (float*)accEb;                             // 8*800*256*4 = 6.55MB < 10.24MB
  float* rel    = (float*)alloc((size_t)R2 * H * 4);
  float* accR   = (float*)alloc((size_t)R2 * H * 4);
  __bf16* relb  = (__bf16*)alloc((size_t)R2 * H * 2);
  __bf16* xinb  = (__bf16*)alloc((size_t)R2 * 2 * H * 2);
  float* gi     = (float*)alloc((size_t)R2 * H3 * 4);
  float* gh     = (float*)alloc((size_t)R2 * H3 * 4);
  float* qf     = (float*)alloc((size_t)NT2 * H * 4);
  __bf16* qb    = (__bf16*)alloc((size_t)NT2 * H * 2);
  float* part_l = (float*)alloc((size_t)SCORE_NC * ROWPAD * 4);
  float* nll    = (float*)alloc((size_t)NT2 * 4);
  __bf16* tgWtb = (__bf16*)alloc((size_t)H * H * 2);
  __bf16* aggWtb= (__bf16*)alloc((size_t)H * H * 2);
  __bf16* fcWtb = (__bf16*)alloc((size_t)H * KFC * 2);
  __bf16* Wihb  = (__bf16*)alloc((size_t)H3 * 2 * H * 2);
  __bf16* Whhb  = (__bf16*)alloc((size_t)H3 * H * 2);

  int* ip = (int*)alloc(0);
  size_t ioff = 0;
  auto ialloc = [&](size_t n) { int* p = ip + ioff; ioff += n; return p; };
  int* permM[TT]; int* sM[TT];
  int* permE[TT]; int* sE[TT];
  for (int t = 0; t < TT; t++) { permM[t] = ialloc(M);     sM[t] = ialloc(R2 + 1); }
  for (int t = 0; t < TT; t++) { permE[t] = ialloc(NEDGE); sE[t] = ialloc(NE + 1); }
  int* permHE = ialloc(NNZ_E); int* sHE = ialloc(NE + 1);
  int* permHR = ialloc(NNZ_R); int* sHR = ialloc(R2 + 1);
  int* cnt    = ialloc(NE + 1);
  int* cursor = ialloc(NE + 1);

  auto build_csr = [&](const int* keys, int n, int nbins, int* start, int* perm) {
    hipMemsetAsync(cnt, 0, (size_t)nbins * 4, stream);
    hist_k<<<(n + 255) / 256, 256, 0, stream>>>(keys, n, cnt);
    scan_k<<<1, 256, 0, stream>>>(cnt, start, cursor, nbins);
    perm_k<<<(n + 255) / 256, 256, 0, stream>>>(keys, n, cursor, perm);
  };

  // weight prep (bf16)
  transpose_cast_k<<<dim3(H / 32, H / 32), 256, 0, stream>>>(tg_W, tgWtb, H, H);
  transpose_cast_k<<<dim3(H / 32, H / 32), 256, 0, stream>>>(agg_W, aggWtb, H, H);
  transpose_cast_k<<<dim3(KFC / 32, H / 32), 256, 0, stream>>>(fc_W, fcWtb, KFC, H);
  cast_bf16_k<<<(H3 * 2 * H / 8 + 255) / 256, 256, 0, stream>>>(gru_W_ih, Wihb, H3 * 2 * H / 8);
  cast_bf16_k<<<(H3 * H / 8 + 255) / 256, 256, 0, stream>>>(gru_W_hh, Whhb, H3 * H / 8);

  for (int t = 0; t < TT; t++) build_csr(r_ids + (size_t)t * M, M, R2, sM[t], permM[t]);
  for (int t = 0; t < TT; t++) build_csr(edge_dst + (size_t)t * NEDGE, NEDGE, NE, sE[t], permE[t]);
  build_csr(he_row, NNZ_E, NE, sHE, permHE);
  build_csr(hr_row, NNZ_R, R2, sHR, permHR);

  hipMemcpyAsync(ent, dynamic_emb, (size_t)NE * H * 4, hipMemcpyDeviceToDevice, stream);
  hipMemcpyAsync(rel, emb_rel, (size_t)R2 * H * 4, hipMemcpyDeviceToDevice, stream);

  constexpr int NEH8 = NE * H / 8, R2H8 = R2 * H / 8;

  for (int t = 0; t < TT; t++) {
    cast_bf16_k<<<(NEH8 + 255) / 256, 256, 0, stream>>>(ent, entb, NEH8);
    cast_bf16_k<<<(R2H8 + 255) / 256, 256, 0, stream>>>(rel, relb, R2H8);

    // --- rel update (GRU) ---
    gather_mean_k<<<R2, 256, 0, stream>>>(entb, r_to_e + (size_t)t * M, permM[t], sM[t], accR);
    build_xin_bf<<<(R2 * 2 * H + 255) / 256, 256, 0, stream>>>(rel, accR, xinb);
    mfma_gemm<0, false><<<dim3(H3 / 64, (R2 + 63) / 64), 256, 0, stream>>>(
        xinb, Wihb, gru_b_ih, gi, R2, 2 * H, H3);
    mfma_gemm<0, false><<<dim3(H3 / 64, (R2 + 63) / 64), 256, 0, stream>>>(
        relb, Whhb, gru_b_hh, gh, R2, H, H3);
    gru_combine<<<(R2 * H + 255) / 256, 256, 0, stream>>>(gi, gh, rel);
    cast_bf16_k<<<(R2H8 + 255) / 256, 256, 0, stream>>>(rel, relb, R2H8);

    // --- ent update ---
    mfma_gemm<2, false><<<dim3(H / 64, (NE + 63) / 64), 256, 0, stream>>>(
        entb, tgWtb, tg_b, tgbuf, NE, H, H);
    gather_edges_k<<<NE, 256, 0, stream>>>(entb, relb, edge_src + (size_t)t * NEDGE,
                                           edge_rel + (size_t)t * NEDGE, permE[t], sE[t], accEb);
    mfma_gemm<1, false><<<dim3(H / 64, (NE + 63) / 64), 256, 0, stream>>>(
        accEb, aggWtb, nullptr, curr, NE, H, H);
    ent_update<<<(NE * H + 255) / 256, 256, 0, stream>>>(ent, tgbuf, curr);
  }

  // --- hypergraph layers (ping-pong; 2 layers end back in original buffer) ---
  hyper_layer_k<<<NE, 256, 0, stream>>>(ent, hev, he_col, permHE, sHE, curr);
  hyper_layer_k<<<NE, 256, 0, stream>>>(curr, hev, he_col, permHE, sHE, ent);
  hyper_layer_k<<<R2, 256, 0, stream>>>(rel, hrv, hr_col, permHR, sHR, accR);
  hyper_layer_k<<<R2, 256, 0, stream>>>(accR, hrv, hr_col, permHR, sHR, rel);

  // final bf16 ent for scores
  cast_bf16_k<<<(NEH8 + 255) / 256, 256, 0, stream>>>(ent, entb, NEH8);

  // --- conv + fc (chunks of 800 rows) ---
  for (int c = 0; c < 5; c++) {
    int row0 = c * 800;
    conv_feat<<<800, 256, 0, stream>>>(ent, rel, sent, tt, conv_w, conv_b, convb, row0);
    mfma_gemm<0, true><<<dim3(H / 64, 13, 8), 256, 0, stream>>>(
        convb, fcWtb, nullptr, fcpart, 800, KFC, H);
    fc_reduce<<<(800 * H + 255) / 256, 256, 0, stream>>>(
        fcpart, fc_b, qf + (size_t)row0 * H, qb + (size_t)row0 * H, 800, 8);
  }

  // --- fused scores + LSE ---
  scores_lse_k<<<dim3(SCORE_NC, 63), 256, 0, stream>>>(qb, entb, part_l);
  lse_combine<<<(NT2 * 64 + 255) / 256, 256, 0, stream>>>(part_l, qf, ent, tt, nll);
  mean_nll<<<1, 256, 0, stream>>>(nll, out);
}

// Round 4
// 2252.905 us; speedup vs baseline: 4.0335x; 1.0600x over previous
//
#include <hip/hip_runtime.h>
#include <math.h>

#define DEV_INLINE __device__ __forceinline__

constexpr int H      = 256;
constexpr int NE     = 20000;
constexpr int NR     = 250;
constexpr int R2     = 500;
constexpr int TT     = 3;
constexpr int NEDGE  = 150000;
constexpr int M      = 200000;
constexpr int NNZ_E  = 320000;
constexpr int NNZ_R  = 8000;
constexpr int CH     = 50;
constexpr int NT     = 2000;
constexpr int NT2    = 4000;
constexpr int H3     = 3 * H;     // 768
constexpr int KFC    = CH * H;    // 12800
constexpr int SCORE_NC = 25;      // col chunks for scores (800 cols each = 10 steps of 80)
constexpr int SCHUNK   = NE / SCORE_NC;  // 800
constexpr int ROWPAD   = 4096;    // 32 row-blocks * 128

typedef __bf16 bf16x8 __attribute__((ext_vector_type(8)));
typedef float  f32x4  __attribute__((ext_vector_type(4)));

DEV_INLINE bf16x8 ldb8(const __bf16* p) { return *(const bf16x8*)p; }
DEV_INLINE bf16x8 zerob8() { uint4 z = make_uint4(0, 0, 0, 0); return __builtin_bit_cast(bf16x8, z); }
DEV_INLINE f32x4 mfma16(bf16x8 a, bf16x8 b, f32x4 c) {
  return __builtin_amdgcn_mfma_f32_16x16x32_bf16(a, b, c, 0, 0, 0);
}

// ------------------------- block reduction (blockDim == 256) ---------------
DEV_INLINE float block_sum256(float v) {
  __shared__ float ws[4];
  #pragma unroll
  for (int o = 32; o > 0; o >>= 1) v += __shfl_down(v, o, 64);
  if ((threadIdx.x & 63) == 0) ws[threadIdx.x >> 6] = v;
  __syncthreads();
  float r = ws[0] + ws[1] + ws[2] + ws[3];
  __syncthreads();
  return r;
}

// ------------------------- CSR build (int atomics only) --------------------
__global__ void hist_k(const int* __restrict__ keys, int n, int* __restrict__ cnt)
{
  int i = blockIdx.x * 256 + threadIdx.x;
  if (i < n) atomicAdd(&cnt[keys[i]], 1);
}

__global__ void scan_k(const int* __restrict__ cnt, int* __restrict__ start,
                       int* __restrict__ cursor, int nbins)
{
  __shared__ int ps[257];
  int t = threadIdx.x;
  int per = (nbins + 255) >> 8;
  int b0 = t * per;
  int local = 0;
  for (int i = 0; i < per; i++) { int b = b0 + i; if (b < nbins) local += cnt[b]; }
  ps[t + 1] = local;
  if (t == 0) ps[0] = 0;
  __syncthreads();
  if (t == 0) { for (int i = 1; i <= 256; i++) ps[i] += ps[i - 1]; }
  __syncthreads();
  int run = ps[t];
  for (int i = 0; i < per; i++) {
    int b = b0 + i;
    if (b < nbins) { start[b] = run; cursor[b] = run; run += cnt[b]; }
  }
  if (t == 0) start[nbins] = ps[256];
}

__global__ void perm_k(const int* __restrict__ keys, int n,
                       int* __restrict__ cursor, int* __restrict__ perm)
{
  int i = blockIdx.x * 256 + threadIdx.x;
  if (i < n) { int p = atomicAdd(&cursor[keys[i]], 1); perm[p] = i; }
}

// ------------------------- casts / transposes ------------------------------
__global__ void cast_bf16_k(const float* __restrict__ in, __bf16* __restrict__ out, int n8)
{
  int i = blockIdx.x * 256 + threadIdx.x;
  if (i >= n8) return;
  const float4* p = (const float4*)in + (size_t)i * 2;
  float4 u = p[0], v = p[1];
  bf16x8 o;
  o[0] = (__bf16)u.x; o[1] = (__bf16)u.y; o[2] = (__bf16)u.z; o[3] = (__bf16)u.w;
  o[4] = (__bf16)v.x; o[5] = (__bf16)v.y; o[6] = (__bf16)v.z; o[7] = (__bf16)v.w;
  ((bf16x8*)out)[i] = o;
}

// in: K x N fp32 row-major -> out: N x K bf16 row-major (K,N multiples of 32)
__global__ void transpose_cast_k(const float* __restrict__ in, __bf16* __restrict__ out,
                                 int K, int N)
{
  __shared__ float tile[32][33];
  int tx = threadIdx.x & 31, ty = threadIdx.x >> 5;   // 32 x 8
  int kb = blockIdx.x * 32, nb = blockIdx.y * 32;
  #pragma unroll
  for (int i = 0; i < 4; i++)
    tile[ty + i * 8][tx] = in[(size_t)(kb + ty + i * 8) * N + nb + tx];
  __syncthreads();
  #pragma unroll
  for (int i = 0; i < 4; i++)
    out[(size_t)(nb + ty + i * 8) * K + kb + tx] = (__bf16)tile[tx][ty + i * 8];
}

// ------------------------- gather kernels ----------------------------------
__global__ void gather_mean_k(const __bf16* __restrict__ src, const int* __restrict__ gidx,
                              const int* __restrict__ perm, const int* __restrict__ start,
                              float* __restrict__ out)
{
  int r = blockIdx.x, h = threadIdx.x;
  int s0 = start[r], s1 = start[r + 1];
  float a0 = 0.f, a1 = 0.f, a2 = 0.f, a3 = 0.f;
  int j = s0;
  for (; j + 3 < s1; j += 4) {
    int e0 = gidx[perm[j + 0]];
    int e1 = gidx[perm[j + 1]];
    int e2 = gidx[perm[j + 2]];
    int e3 = gidx[perm[j + 3]];
    a0 += (float)src[(size_t)e0 * H + h];
    a1 += (float)src[(size_t)e1 * H + h];
    a2 += (float)src[(size_t)e2 * H + h];
    a3 += (float)src[(size_t)e3 * H + h];
  }
  for (; j < s1; j++) a0 += (float)src[(size_t)gidx[perm[j]] * H + h];
  float acc = (a0 + a1) + (a2 + a3);
  out[(size_t)r * H + h] = acc / (float)max(s1 - s0, 1);
}

__global__ void gather_edges_k(const __bf16* __restrict__ ent, const __bf16* __restrict__ rel,
                               const int* __restrict__ esrc, const int* __restrict__ erel,
                               const int* __restrict__ perm, const int* __restrict__ start,
                               __bf16* __restrict__ out)
{
  int d = blockIdx.x, h = threadIdx.x;
  int s0 = start[d], s1 = start[d + 1];
  float a0 = 0.f, a1 = 0.f;
  int j = s0;
  for (; j + 1 < s1; j += 2) {
    int e0 = perm[j], e1 = perm[j + 1];
    a0 += (float)ent[(size_t)esrc[e0] * H + h] + (float)rel[(size_t)erel[e0] * H + h];
    a1 += (float)ent[(size_t)esrc[e1] * H + h] + (float)rel[(size_t)erel[e1] * H + h];
  }
  for (; j < s1; j++) {
    int e = perm[j];
    a0 += (float)ent[(size_t)esrc[e] * H + h] + (float)rel[(size_t)erel[e] * H + h];
  }
  out[(size_t)d * H + h] = (__bf16)((a0 + a1) / (float)max(s1 - s0, 1));
}

// fp32 neighbor-read variant (small rel graph)
__global__ void hyper_layer_k(const float* __restrict__ x, const float* __restrict__ val,
                              const int* __restrict__ col, const int* __restrict__ perm,
                              const int* __restrict__ start, float* __restrict__ xout)
{
  int r = blockIdx.x, h = threadIdx.x;
  int s0 = start[r], s1 = start[r + 1];
  float a0 = 0.f, a1 = 0.f, a2 = 0.f, a3 = 0.f;
  int j = s0;
  for (; j + 3 < s1; j += 4) {
    int e0 = perm[j + 0], e1 = perm[j + 1], e2 = perm[j + 2], e3 = perm[j + 3];
    a0 += val[e0] * x[(size_t)col[e0] * H + h];
    a1 += val[e1] * x[(size_t)col[e1] * H + h];
    a2 += val[e2] * x[(size_t)col[e2] * H + h];
    a3 += val[e3] * x[(size_t)col[e3] * H + h];
  }
  for (; j < s1; j++) { int e = perm[j]; a0 += val[e] * x[(size_t)col[e] * H + h]; }
  float y = (a0 + a1) + (a2 + a3);
  float ss = block_sum256(y * y);
  float rn = 1.f / fmaxf(sqrtf(ss), 1e-12f);
  xout[(size_t)r * H + h] = x[(size_t)r * H + h] + y * rn;
}

// bf16 neighbor-read variant (halves random-read traffic); residual from fp32 x
__global__ void hyper_layer_bf_k(const float* __restrict__ x, const __bf16* __restrict__ xb,
                                 const float* __restrict__ val, const int* __restrict__ col,
                                 const int* __restrict__ perm, const int* __restrict__ start,
                                 float* __restrict__ xout)
{
  int r = blockIdx.x, h = threadIdx.x;
  int s0 = start[r], s1 = start[r + 1];
  float a0 = 0.f, a1 = 0.f, a2 = 0.f, a3 = 0.f;
  int j = s0;
  for (; j + 3 < s1; j += 4) {
    int e0 = perm[j + 0], e1 = perm[j + 1], e2 = perm[j + 2], e3 = perm[j + 3];
    a0 += val[e0] * (float)xb[(size_t)col[e0] * H + h];
    a1 += val[e1] * (float)xb[(size_t)col[e1] * H + h];
    a2 += val[e2] * (float)xb[(size_t)col[e2] * H + h];
    a3 += val[e3] * (float)xb[(size_t)col[e3] * H + h];
  }
  for (; j < s1; j++) { int e = perm[j]; a0 += val[e] * (float)xb[(size_t)col[e] * H + h]; }
  float y = (a0 + a1) + (a2 + a3);
  float ss = block_sum256(y * y);
  float rn = 1.f / fmaxf(sqrtf(ss), 1e-12f);
  xout[(size_t)r * H + h] = x[(size_t)r * H + h] + y * rn;
}

// ------------------------- small elementwise -------------------------------
__global__ void build_xin_bf(const float* __restrict__ rel, const float* __restrict__ xm,
                             __bf16* __restrict__ xin)
{
  int idx = blockIdx.x * 256 + threadIdx.x;       // R2 * 512
  if (idx >= R2 * 2 * H) return;
  int i = idx >> 9, c = idx & 511;
  float v = (c < H) ? rel[(size_t)i * H + c] : xm[(size_t)i * H + (c - H)];
  xin[idx] = (__bf16)v;
}

__global__ void gru_combine(const float* __restrict__ gi, const float* __restrict__ gh,
                            float* __restrict__ rel)
{
  int idx = blockIdx.x * 256 + threadIdx.x;       // R2 * H
  if (idx >= R2 * H) return;
  int i = idx >> 8, h = idx & 255;
  const float* gir = gi + (size_t)i * H3;
  const float* ghr = gh + (size_t)i * H3;
  float r = 1.f / (1.f + __expf(-(gir[h]       + ghr[h])));
  float z = 1.f / (1.f + __expf(-(gir[H + h]   + ghr[H + h])));
  float n = tanhf(gir[2 * H + h] + r * ghr[2 * H + h]);
  rel[idx] = (1.f - z) * n + z * rel[idx];
}

__global__ void ent_update(float* __restrict__ ent, const float* __restrict__ tw,
                           const float* __restrict__ curr)
{
  int idx = blockIdx.x * 256 + threadIdx.x;       // NE * H
  if (idx >= NE * H) return;
  float t = tw[idx];
  ent[idx] = t * curr[idx] + (1.f - t) * ent[idx];
}

// ------------------------- MFMA GEMM ---------------------------------------
// C(MxN) = act(A @ Bt^T + bias). A: MxK bf16 row-major. Bt: NxK bf16 row-major.
// Requires N % 64 == 0, K % 32 == 0. Block 256 thr = 2x2 waves, 64x64 tile.
template<int ACT, bool SPLITK>
__global__ void mfma_gemm(const __bf16* __restrict__ A, const __bf16* __restrict__ Bt,
                          const float* __restrict__ bias, float* __restrict__ C,
                          int Mr, int K, int N)
{
  int lane = threadIdx.x & 63, wave = threadIdx.x >> 6;
  int waveM = wave >> 1, waveN = wave & 1;
  int r = lane & 15, kg = lane >> 4;
  int rowBase = blockIdx.y * 64 + waveM * 32;
  int colBase = blockIdx.x * 64 + waveN * 32;
  int kbeg = 0, kend = K;
  if (SPLITK) { int kl = K / gridDim.z; kbeg = blockIdx.z * kl; kend = kbeg + kl; }

  int row0 = rowBase + r, row1 = rowBase + 16 + r;
  int col0 = colBase + r, col1 = colBase + 16 + r;
  bool v0 = row0 < Mr, v1 = row1 < Mr;
  const __bf16* a0p = A + (size_t)row0 * K + kg * 8;
  const __bf16* a1p = A + (size_t)row1 * K + kg * 8;
  const __bf16* b0p = Bt + (size_t)col0 * K + kg * 8;
  const __bf16* b1p = Bt + (size_t)col1 * K + kg * 8;

  f32x4 acc[2][2];
  #pragma unroll
  for (int i = 0; i < 2; i++)
    #pragma unroll
    for (int j = 0; j < 2; j++) { acc[i][j][0] = 0.f; acc[i][j][1] = 0.f; acc[i][j][2] = 0.f; acc[i][j][3] = 0.f; }

  for (int k0 = kbeg; k0 < kend; k0 += 32) {
    bf16x8 a0 = v0 ? ldb8(a0p + k0) : zerob8();
    bf16x8 a1 = v1 ? ldb8(a1p + k0) : zerob8();
    bf16x8 b0 = ldb8(b0p + k0);
    bf16x8 b1 = ldb8(b1p + k0);
    acc[0][0] = mfma16(a0, b0, acc[0][0]);
    acc[0][1] = mfma16(a0, b1, acc[0][1]);
    acc[1][0] = mfma16(a1, b0, acc[1][0]);
    acc[1][1] = mfma16(a1, b1, acc[1][1]);
  }

  float* Cz = SPLITK ? (C + (size_t)blockIdx.z * Mr * N) : C;
  #pragma unroll
  for (int i = 0; i < 2; i++) {
    #pragma unroll
    for (int g = 0; g < 4; g++) {
      int row = rowBase + i * 16 + kg * 4 + g;
      if (row >= Mr) continue;
      #pragma unroll
      for (int j = 0; j < 2; j++) {
        int col = colBase + j * 16 + r;
        float v = acc[i][j][g];
        if (!SPLITK) {
          if (bias) v += bias[col];
          if (ACT == 1) v = fmaxf(v, 0.f);
          if (ACT == 2) v = 1.f / (1.f + __expf(-v));
        }
        Cz[(size_t)row * N + col] = v;
      }
    }
  }
}

// sum split-K partials + bias + relu -> q (fp32) and qb (bf16, prescaled by log2 e)
__global__ void fc_reduce(const float* __restrict__ part, const float* __restrict__ bias,
                          float* __restrict__ q, __bf16* __restrict__ qb, int nrows, int splits)
{
  int idx = blockIdx.x * 256 + threadIdx.x;       // nrows * H
  if (idx >= nrows * H) return;
  int col = idx & 255;
  float s = bias[col];
  for (int z = 0; z < splits; z++) s += part[(size_t)z * nrows * H + idx];
  s = fmaxf(s, 0.f);
  q[idx] = s;
  qb[idx] = (__bf16)(s * 1.44269504f);
}

// ------------------------- conv (block per test row) -----------------------
__global__ void conv_feat(const float* __restrict__ ent, const float* __restrict__ rel,
                          const float* __restrict__ sent, const int* __restrict__ tt,
                          const float* __restrict__ cw, const float* __restrict__ cb,
                          __bf16* __restrict__ out, int row0)
{
  __shared__ float f[3][258];
  __shared__ float wsm[CH * 9];
  __shared__ float bsm[CH];
  int i = row0 + blockIdx.x;
  int h = threadIdx.x;
  int j = (i < NT) ? i : i - NT;
  int a0 = (i < NT) ? tt[j * 3 + 0] : tt[j * 3 + 2];
  int a1 = (i < NT) ? tt[j * 3 + 1] : tt[j * 3 + 1] + NR;
  f[0][h + 1] = ent[(size_t)a0 * H + h];
  f[1][h + 1] = rel[(size_t)a1 * H + h];
  f[2][h + 1] = sent[(size_t)j * H + h];
  if (h < 3) { f[h][0] = 0.f; f[h][257] = 0.f; }
  for (int x = h; x < CH * 9; x += 256) wsm[x] = cw[x];
  if (h < CH) bsm[h] = cb[h];
  __syncthreads();
  __bf16* orow = out + (size_t)blockIdx.x * KFC;
  for (int c = 0; c < CH; c++) {
    const float* wc = wsm + c * 9;
    float s = bsm[c];
    #pragma unroll
    for (int ic = 0; ic < 3; ic++)
      s += wc[ic * 3 + 0] * f[ic][h] + wc[ic * 3 + 1] * f[ic][h + 1] + wc[ic * 3 + 2] * f[ic][h + 2];
    orow[(size_t)c * H + h] = (__bf16)fmaxf(s, 0.f);
  }
}

// ------------------------- fused scores + partial LSE ----------------------
// grid (SCORE_NC, 32). Block = 4 waves; wave w owns rows [by*128 + w*32, +32).
// Per step: 80 cols (5 B-tiles), 10 independent MFMA chains, exp2-accumulate.
// part_l[chunk][row] = sum_{cols in chunk} exp(score)  (qb prescaled by log2 e)
__global__ void scores_lse_k(const __bf16* __restrict__ qb, const __bf16* __restrict__ eb,
                             float* __restrict__ part_l)
{
  int lane = threadIdx.x & 63, wave = threadIdx.x >> 6;
  int r = lane & 15, kg = lane >> 4;
  int rowBase = blockIdx.y * 128 + wave * 32;

  bf16x8 a[2][8];
  #pragma unroll
  for (int i = 0; i < 2; i++) {
    int arow = rowBase + i * 16 + r;
    if (arow < NT2) {
      const __bf16* ap = qb + (size_t)arow * H + kg * 8;
      #pragma unroll
      for (int f = 0; f < 8; f++) a[i][f] = ldb8(ap + f * 32);
    } else {
      #pragma unroll
      for (int f = 0; f < 8; f++) a[i][f] = zerob8();
    }
  }

  float lsum[2][4] = {{0.f, 0.f, 0.f, 0.f}, {0.f, 0.f, 0.f, 0.f}};
  const int c0 = blockIdx.x * SCHUNK;
  for (int s = 0; s < SCHUNK / 80; s++) {
    int j0 = c0 + s * 80;
    f32x4 acc[2][5];
    #pragma unroll
    for (int i = 0; i < 2; i++)
      #pragma unroll
      for (int c = 0; c < 5; c++) { acc[i][c][0] = 0.f; acc[i][c][1] = 0.f; acc[i][c][2] = 0.f; acc[i][c][3] = 0.f; }
    const __bf16* bp = eb + (size_t)(j0 + r) * H + kg * 8;
    #pragma unroll
    for (int f = 0; f < 8; f++) {
      #pragma unroll
      for (int c = 0; c < 5; c++) {
        bf16x8 b = ldb8(bp + (size_t)c * 16 * H + f * 32);
        acc[0][c] = mfma16(a[0][f], b, acc[0][c]);
        acc[1][c] = mfma16(a[1][f], b, acc[1][c]);
      }
    }
    #pragma unroll
    for (int i = 0; i < 2; i++)
      #pragma unroll
      for (int c = 0; c < 5; c++)
        #pragma unroll
        for (int g = 0; g < 4; g++)
          lsum[i][g] += exp2f(acc[i][c][g]);
  }
  #pragma unroll
  for (int m = 1; m < 16; m <<= 1)
    #pragma unroll
    for (int i = 0; i < 2; i++)
      #pragma unroll
      for (int g = 0; g < 4; g++)
        lsum[i][g] += __shfl_xor(lsum[i][g], m, 64);
  if (r == 0) {
    #pragma unroll
    for (int i = 0; i < 2; i++)
      #pragma unroll
      for (int g = 0; g < 4; g++)
        part_l[(size_t)blockIdx.x * ROWPAD + rowBase + i * 16 + kg * 4 + g] = lsum[i][g];
  }
}

// one wave per row: nll[row] = log(sum_c part_l) - q[row].ent[tgt]
__global__ void lse_combine(const float* __restrict__ part_l, const float* __restrict__ qf,
                            const float* __restrict__ ent, const int* __restrict__ tt,
                            float* __restrict__ nll)
{
  int gid = blockIdx.x * 256 + threadIdx.x;
  int w = gid >> 6;
  if (w >= NT2) return;
  int lane = gid & 63;
  int j = (w < NT) ? w : w - NT;
  int tgt = (w < NT) ? tt[j * 3 + 2] : tt[j * 3 + 0];
  const float4 qa = ((const float4*)(qf + (size_t)w * H))[lane];
  const float4 ea = ((const float4*)(ent + (size_t)tgt * H))[lane];
  float d = qa.x * ea.x + qa.y * ea.y + qa.z * ea.z + qa.w * ea.w;
  #pragma unroll
  for (int o = 32; o > 0; o >>= 1) d += __shfl_down(d, o, 64);
  if (lane == 0) {
    float s = 0.f;
    for (int c = 0; c < SCORE_NC; c++) s += part_l[(size_t)c * ROWPAD + w];
    nll[w] = logf(s) - d;
  }
}

__global__ void mean_nll(const float* __restrict__ nll, float* __restrict__ out)
{
  float s = 0.f;
  for (int i = threadIdx.x; i < NT2; i += 256) s += nll[i];
  s = block_sum256(s);
  if (threadIdx.x == 0) out[0] = s * (1.f / NT2);
}

// ------------------------- launcher ----------------------------------------
extern "C" void kernel_launch(void* const* d_in, const int* in_sizes, int n_in,
                              void* d_out, int out_size, void* d_ws, size_t ws_size,
                              hipStream_t stream)
{
  const float* dynamic_emb = (const float*)d_in[0];
  const float* emb_rel     = (const float*)d_in[1];
  const float* gru_W_ih    = (const float*)d_in[2];
  const float* gru_W_hh    = (const float*)d_in[3];
  const float* gru_b_ih    = (const float*)d_in[4];
  const float* gru_b_hh    = (const float*)d_in[5];
  const float* agg_W       = (const float*)d_in[6];
  const float* tg_W        = (const float*)d_in[7];
  const float* tg_b        = (const float*)d_in[8];
  const float* hev         = (const float*)d_in[9];
  const float* hrv         = (const float*)d_in[10];
  const float* conv_w      = (const float*)d_in[11];
  const float* conv_b      = (const float*)d_in[12];
  const float* fc_W        = (const float*)d_in[13];
  const float* fc_b        = (const float*)d_in[14];
  const float* sent        = (const float*)d_in[15];
  const int* edge_src = (const int*)d_in[16];
  const int* edge_rel = (const int*)d_in[17];
  const int* edge_dst = (const int*)d_in[18];
  const int* r_to_e   = (const int*)d_in[19];
  const int* r_ids    = (const int*)d_in[20];
  const int* he_row   = (const int*)d_in[21];
  const int* he_col   = (const int*)d_in[22];
  const int* hr_row   = (const int*)d_in[23];
  const int* hr_col   = (const int*)d_in[24];
  const int* tt       = (const int*)d_in[25];
  float* out = (float*)d_out;

  char* base = (char*)d_ws;
  size_t off = 0;
  auto alloc = [&](size_t bytes) { char* p = base + off; off += (bytes + 255) & ~(size_t)255; return p; };

  float* ent    = (float*)alloc((size_t)NE * H * 4);
  float* curr   = (float*)alloc((size_t)NE * H * 4);        // agg out; hyper ping-pong
  float* tgbuf  = (float*)alloc((size_t)NE * H * 4);        // gate; conv_bf overlay
  __bf16* convb = (__bf16*)tgbuf;                            // 800*12800*2 = 20.48MB (same size)
  __bf16* entb  = (__bf16*)alloc((size_t)NE * H * 2);
  __bf16* accEb = (__bf16*)alloc((size_t)NE * H * 2);       // edge-gather out; fcpart overlay
  float* fcpart = (float*)accEb;                             // 8*800*256*4 = 6.55MB < 10.24MB
  float* rel    = (float*)alloc((size_t)R2 * H * 4);
  float* accR   = (float*)alloc((size_t)R2 * H * 4);
  __bf16* relb  = (__bf16*)alloc((size_t)R2 * H * 2);
  __bf16* xinb  = (__bf16*)alloc((size_t)R2 * 2 * H * 2);
  float* gi     = (float*)alloc((size_t)R2 * H3 * 4);
  float* gh     = (float*)alloc((size_t)R2 * H3 * 4);
  float* qf     = (float*)alloc((size_t)NT2 * H * 4);
  __bf16* qb    = (__bf16*)alloc((size_t)NT2 * H * 2);
  float* part_l = (float*)alloc((size_t)SCORE_NC * ROWPAD * 4);
  float* nll    = (float*)alloc((size_t)NT2 * 4);
  __bf16* tgWtb = (__bf16*)alloc((size_t)H * H * 2);
  __bf16* aggWtb= (__bf16*)alloc((size_t)H * H * 2);
  __bf16* fcWtb = (__bf16*)alloc((size_t)H * KFC * 2);
  __bf16* Wihb  = (__bf16*)alloc((size_t)H3 * 2 * H * 2);
  __bf16* Whhb  = (__bf16*)alloc((size_t)H3 * H * 2);

  int* ip = (int*)alloc(0);
  size_t ioff = 0;
  auto ialloc = [&](size_t n) { int* p = ip + ioff; ioff += n; return p; };
  int* permM[TT]; int* sM[TT];
  int* permE[TT]; int* sE[TT];
  for (int t = 0; t < TT; t++) { permM[t] = ialloc(M);     sM[t] = ialloc(R2 + 1); }
  for (int t = 0; t < TT; t++) { permE[t] = ialloc(NEDGE); sE[t] = ialloc(NE + 1); }
  int* permHE = ialloc(NNZ_E); int* sHE = ialloc(NE + 1);
  int* permHR = ialloc(NNZ_R); int* sHR = ialloc(R2 + 1);
  int* cnt    = ialloc(NE + 1);
  int* cursor = ialloc(NE + 1);

  auto build_csr = [&](const int* keys, int n, int nbins, int* start, int* perm) {
    hipMemsetAsync(cnt, 0, (size_t)nbins * 4, stream);
    hist_k<<<(n + 255) / 256, 256, 0, stream>>>(keys, n, cnt);
    scan_k<<<1, 256, 0, stream>>>(cnt, start, cursor, nbins);
    perm_k<<<(n + 255) / 256, 256, 0, stream>>>(keys, n, cursor, perm);
  };

  // weight prep (bf16)
  transpose_cast_k<<<dim3(H / 32, H / 32), 256, 0, stream>>>(tg_W, tgWtb, H, H);
  transpose_cast_k<<<dim3(H / 32, H / 32), 256, 0, stream>>>(agg_W, aggWtb, H, H);
  transpose_cast_k<<<dim3(KFC / 32, H / 32), 256, 0, stream>>>(fc_W, fcWtb, KFC, H);
  cast_bf16_k<<<(H3 * 2 * H / 8 + 255) / 256, 256, 0, stream>>>(gru_W_ih, Wihb, H3 * 2 * H / 8);
  cast_bf16_k<<<(H3 * H / 8 + 255) / 256, 256, 0, stream>>>(gru_W_hh, Whhb, H3 * H / 8);

  for (int t = 0; t < TT; t++) build_csr(r_ids + (size_t)t * M, M, R2, sM[t], permM[t]);
  for (int t = 0; t < TT; t++) build_csr(edge_dst + (size_t)t * NEDGE, NEDGE, NE, sE[t], permE[t]);
  build_csr(he_row, NNZ_E, NE, sHE, permHE);
  build_csr(hr_row, NNZ_R, R2, sHR, permHR);

  hipMemcpyAsync(ent, dynamic_emb, (size_t)NE * H * 4, hipMemcpyDeviceToDevice, stream);
  hipMemcpyAsync(rel, emb_rel, (size_t)R2 * H * 4, hipMemcpyDeviceToDevice, stream);

  constexpr int NEH8 = NE * H / 8, R2H8 = R2 * H / 8;

  for (int t = 0; t < TT; t++) {
    cast_bf16_k<<<(NEH8 + 255) / 256, 256, 0, stream>>>(ent, entb, NEH8);
    cast_bf16_k<<<(R2H8 + 255) / 256, 256, 0, stream>>>(rel, relb, R2H8);

    // --- rel update (GRU) ---
    gather_mean_k<<<R2, 256, 0, stream>>>(entb, r_to_e + (size_t)t * M, permM[t], sM[t], accR);
    build_xin_bf<<<(R2 * 2 * H + 255) / 256, 256, 0, stream>>>(rel, accR, xinb);
    mfma_gemm<0, false><<<dim3(H3 / 64, (R2 + 63) / 64), 256, 0, stream>>>(
        xinb, Wihb, gru_b_ih, gi, R2, 2 * H, H3);
    mfma_gemm<0, false><<<dim3(H3 / 64, (R2 + 63) / 64), 256, 0, stream>>>(
        relb, Whhb, gru_b_hh, gh, R2, H, H3);
    gru_combine<<<(R2 * H + 255) / 256, 256, 0, stream>>>(gi, gh, rel);
    cast_bf16_k<<<(R2H8 + 255) / 256, 256, 0, stream>>>(rel, relb, R2H8);

    // --- ent update ---
    mfma_gemm<2, false><<<dim3(H / 64, (NE + 63) / 64), 256, 0, stream>>>(
        entb, tgWtb, tg_b, tgbuf, NE, H, H);
    gather_edges_k<<<NE, 256, 0, stream>>>(entb, relb, edge_src + (size_t)t * NEDGE,
                                           edge_rel + (size_t)t * NEDGE, permE[t], sE[t], accEb);
    mfma_gemm<1, false><<<dim3(H / 64, (NE + 63) / 64), 256, 0, stream>>>(
        accEb, aggWtb, nullptr, curr, NE, H, H);
    ent_update<<<(NE * H + 255) / 256, 256, 0, stream>>>(ent, tgbuf, curr);
  }

  // --- hypergraph layers (ent: bf16 neighbor reads; ends back in ent) ---
  cast_bf16_k<<<(NEH8 + 255) / 256, 256, 0, stream>>>(ent, entb, NEH8);
  hyper_layer_bf_k<<<NE, 256, 0, stream>>>(ent, entb, hev, he_col, permHE, sHE, curr);
  cast_bf16_k<<<(NEH8 + 255) / 256, 256, 0, stream>>>(curr, entb, NEH8);
  hyper_layer_bf_k<<<NE, 256, 0, stream>>>(curr, entb, hev, he_col, permHE, sHE, ent);
  hyper_layer_k<<<R2, 256, 0, stream>>>(rel, hrv, hr_col, permHR, sHR, accR);
  hyper_layer_k<<<R2, 256, 0, stream>>>(accR, hrv, hr_col, permHR, sHR, rel);

  // final bf16 ent for scores
  cast_bf16_k<<<(NEH8 + 255) / 256, 256, 0, stream>>>(ent, entb, NEH8);

  // --- conv + fc (chunks of 800 rows) ---
  for (int c = 0; c < 5; c++) {
    int row0 = c * 800;
    conv_feat<<<800, 256, 0, stream>>>(ent, rel, sent, tt, conv_w, conv_b, convb, row0);
    mfma_gemm<0, true><<<dim3(H / 64, 13, 8), 256, 0, stream>>>(
        convb, fcWtb, nullptr, fcpart, 800, KFC, H);
    fc_reduce<<<(800 * H + 255) / 256, 256, 0, stream>>>(
        fcpart, fc_b, qf + (size_t)row0 * H, qb + (size_t)row0 * H, 800, 8);
  }

  // --- fused scores + LSE ---
  scores_lse_k<<<dim3(SCORE_NC, 32), 256, 0, stream>>>(qb, entb, part_l);
  lse_combine<<<(NT2 * 64 + 255) / 256, 256, 0, stream>>>(part_l, qf, ent, tt, nll);
  mean_nll<<<1, 256, 0, stream>>>(nll, out);
}

// Round 5
// 2213.144 us; speedup vs baseline: 4.1059x; 1.0180x over previous
//
#include <hip/hip_runtime.h>
#include <math.h>

#define DEV_INLINE __device__ __forceinline__

constexpr int H      = 256;
constexpr int NE     = 20000;
constexpr int NR     = 250;
constexpr int R2     = 500;
constexpr int TT     = 3;
constexpr int NEDGE  = 150000;
constexpr int M      = 200000;
constexpr int NNZ_E  = 320000;
constexpr int NNZ_R  = 8000;
constexpr int CH     = 50;
constexpr int NT     = 2000;
constexpr int NT2    = 4000;
constexpr int H3     = 3 * H;     // 768
constexpr int KFC    = CH * H;    // 12800
constexpr int ROWPAD = 4096;
constexpr int NCHUNK = 64;        // 32 blockIdx.x * 2 wN slots for scores partials

typedef __bf16 bf16x8 __attribute__((ext_vector_type(8)));
typedef float  f32x4  __attribute__((ext_vector_type(4)));

DEV_INLINE bf16x8 ldb8(const __bf16* p) { return *(const bf16x8*)p; }
DEV_INLINE bf16x8 zerob8() { uint4 z = make_uint4(0, 0, 0, 0); return __builtin_bit_cast(bf16x8, z); }
DEV_INLINE f32x4 mfma16(bf16x8 a, bf16x8 b, f32x4 c) {
  return __builtin_amdgcn_mfma_f32_16x16x32_bf16(a, b, c, 0, 0, 0);
}

// ------------------------- block reduction (blockDim == 256) ---------------
DEV_INLINE float block_sum256(float v) {
  __shared__ float ws[4];
  #pragma unroll
  for (int o = 32; o > 0; o >>= 1) v += __shfl_down(v, o, 64);
  if ((threadIdx.x & 63) == 0) ws[threadIdx.x >> 6] = v;
  __syncthreads();
  float r = ws[0] + ws[1] + ws[2] + ws[3];
  __syncthreads();
  return r;
}

// ------------------------- CSR build (int atomics only) --------------------
__global__ void hist_k(const int* __restrict__ keys, int n, int* __restrict__ cnt)
{
  int i = blockIdx.x * 256 + threadIdx.x;
  if (i < n) atomicAdd(&cnt[keys[i]], 1);
}

__global__ void scan_k(const int* __restrict__ cnt, int* __restrict__ start,
                       int* __restrict__ cursor, int nbins)
{
  __shared__ int ps[257];
  int t = threadIdx.x;
  int per = (nbins + 255) >> 8;
  int b0 = t * per;
  int local = 0;
  for (int i = 0; i < per; i++) { int b = b0 + i; if (b < nbins) local += cnt[b]; }
  ps[t + 1] = local;
  if (t == 0) ps[0] = 0;
  __syncthreads();
  if (t == 0) { for (int i = 1; i <= 256; i++) ps[i] += ps[i - 1]; }
  __syncthreads();
  int run = ps[t];
  for (int i = 0; i < per; i++) {
    int b = b0 + i;
    if (b < nbins) { start[b] = run; cursor[b] = run; run += cnt[b]; }
  }
  if (t == 0) start[nbins] = ps[256];
}

__global__ void perm_k(const int* __restrict__ keys, int n,
                       int* __restrict__ cursor, int* __restrict__ perm)
{
  int i = blockIdx.x * 256 + threadIdx.x;
  if (i < n) { int p = atomicAdd(&cursor[keys[i]], 1); perm[p] = i; }
}

// ------------------------- casts / transposes ------------------------------
__global__ void cast_bf16_k(const float* __restrict__ in, __bf16* __restrict__ out, int n8)
{
  int i = blockIdx.x * 256 + threadIdx.x;
  if (i >= n8) return;
  const float4* p = (const float4*)in + (size_t)i * 2;
  float4 u = p[0], v = p[1];
  bf16x8 o;
  o[0] = (__bf16)u.x; o[1] = (__bf16)u.y; o[2] = (__bf16)u.z; o[3] = (__bf16)u.w;
  o[4] = (__bf16)v.x; o[5] = (__bf16)v.y; o[6] = (__bf16)v.z; o[7] = (__bf16)v.w;
  ((bf16x8*)out)[i] = o;
}

// in: K x N fp32 row-major -> out: N x K bf16 row-major (K,N multiples of 32)
__global__ void transpose_cast_k(const float* __restrict__ in, __bf16* __restrict__ out,
                                 int K, int N)
{
  __shared__ float tile[32][33];
  int tx = threadIdx.x & 31, ty = threadIdx.x >> 5;   // 32 x 8
  int kb = blockIdx.x * 32, nb = blockIdx.y * 32;
  #pragma unroll
  for (int i = 0; i < 4; i++)
    tile[ty + i * 8][tx] = in[(size_t)(kb + ty + i * 8) * N + nb + tx];
  __syncthreads();
  #pragma unroll
  for (int i = 0; i < 4; i++)
    out[(size_t)(nb + ty + i * 8) * K + kb + tx] = (__bf16)tile[tx][ty + i * 8];
}

// ------------------------- gather kernels ----------------------------------
__global__ void gather_mean_k(const __bf16* __restrict__ src, const int* __restrict__ gidx,
                              const int* __restrict__ perm, const int* __restrict__ start,
                              float* __restrict__ out)
{
  int r = blockIdx.x, h = threadIdx.x;
  int s0 = start[r], s1 = start[r + 1];
  float a0 = 0.f, a1 = 0.f, a2 = 0.f, a3 = 0.f;
  int j = s0;
  for (; j + 3 < s1; j += 4) {
    int e0 = gidx[perm[j + 0]];
    int e1 = gidx[perm[j + 1]];
    int e2 = gidx[perm[j + 2]];
    int e3 = gidx[perm[j + 3]];
    a0 += (float)src[(size_t)e0 * H + h];
    a1 += (float)src[(size_t)e1 * H + h];
    a2 += (float)src[(size_t)e2 * H + h];
    a3 += (float)src[(size_t)e3 * H + h];
  }
  for (; j < s1; j++) a0 += (float)src[(size_t)gidx[perm[j]] * H + h];
  float acc = (a0 + a1) + (a2 + a3);
  out[(size_t)r * H + h] = acc / (float)max(s1 - s0, 1);
}

__global__ void gather_edges_k(const __bf16* __restrict__ ent, const __bf16* __restrict__ rel,
                               const int* __restrict__ esrc, const int* __restrict__ erel,
                               const int* __restrict__ perm, const int* __restrict__ start,
                               __bf16* __restrict__ out)
{
  int d = blockIdx.x, h = threadIdx.x;
  int s0 = start[d], s1 = start[d + 1];
  float a0 = 0.f, a1 = 0.f;
  int j = s0;
  for (; j + 1 < s1; j += 2) {
    int e0 = perm[j], e1 = perm[j + 1];
    a0 += (float)ent[(size_t)esrc[e0] * H + h] + (float)rel[(size_t)erel[e0] * H + h];
    a1 += (float)ent[(size_t)esrc[e1] * H + h] + (float)rel[(size_t)erel[e1] * H + h];
  }
  for (; j < s1; j++) {
    int e = perm[j];
    a0 += (float)ent[(size_t)esrc[e] * H + h] + (float)rel[(size_t)erel[e] * H + h];
  }
  out[(size_t)d * H + h] = (__bf16)((a0 + a1) / (float)max(s1 - s0, 1));
}

// fp32 neighbor-read variant (small rel graph)
__global__ void hyper_layer_k(const float* __restrict__ x, const float* __restrict__ val,
                              const int* __restrict__ col, const int* __restrict__ perm,
                              const int* __restrict__ start, float* __restrict__ xout)
{
  int r = blockIdx.x, h = threadIdx.x;
  int s0 = start[r], s1 = start[r + 1];
  float a0 = 0.f, a1 = 0.f, a2 = 0.f, a3 = 0.f;
  int j = s0;
  for (; j + 3 < s1; j += 4) {
    int e0 = perm[j + 0], e1 = perm[j + 1], e2 = perm[j + 2], e3 = perm[j + 3];
    a0 += val[e0] * x[(size_t)col[e0] * H + h];
    a1 += val[e1] * x[(size_t)col[e1] * H + h];
    a2 += val[e2] * x[(size_t)col[e2] * H + h];
    a3 += val[e3] * x[(size_t)col[e3] * H + h];
  }
  for (; j < s1; j++) { int e = perm[j]; a0 += val[e] * x[(size_t)col[e] * H + h]; }
  float y = (a0 + a1) + (a2 + a3);
  float ss = block_sum256(y * y);
  float rn = 1.f / fmaxf(sqrtf(ss), 1e-12f);
  xout[(size_t)r * H + h] = x[(size_t)r * H + h] + y * rn;
}

// bf16 neighbor-read variant; residual from fp32 x
__global__ void hyper_layer_bf_k(const float* __restrict__ x, const __bf16* __restrict__ xb,
                                 const float* __restrict__ val, const int* __restrict__ col,
                                 const int* __restrict__ perm, const int* __restrict__ start,
                                 float* __restrict__ xout)
{
  int r = blockIdx.x, h = threadIdx.x;
  int s0 = start[r], s1 = start[r + 1];
  float a0 = 0.f, a1 = 0.f, a2 = 0.f, a3 = 0.f;
  int j = s0;
  for (; j + 3 < s1; j += 4) {
    int e0 = perm[j + 0], e1 = perm[j + 1], e2 = perm[j + 2], e3 = perm[j + 3];
    a0 += val[e0] * (float)xb[(size_t)col[e0] * H + h];
    a1 += val[e1] * (float)xb[(size_t)col[e1] * H + h];
    a2 += val[e2] * (float)xb[(size_t)col[e2] * H + h];
    a3 += val[e3] * (float)xb[(size_t)col[e3] * H + h];
  }
  for (; j < s1; j++) { int e = perm[j]; a0 += val[e] * (float)xb[(size_t)col[e] * H + h]; }
  float y = (a0 + a1) + (a2 + a3);
  float ss = block_sum256(y * y);
  float rn = 1.f / fmaxf(sqrtf(ss), 1e-12f);
  xout[(size_t)r * H + h] = x[(size_t)r * H + h] + y * rn;
}

// ------------------------- small elementwise -------------------------------
__global__ void build_xin_bf(const float* __restrict__ rel, const float* __restrict__ xm,
                             __bf16* __restrict__ xin)
{
  int idx = blockIdx.x * 256 + threadIdx.x;       // R2 * 512
  if (idx >= R2 * 2 * H) return;
  int i = idx >> 9, c = idx & 511;
  float v = (c < H) ? rel[(size_t)i * H + c] : xm[(size_t)i * H + (c - H)];
  xin[idx] = (__bf16)v;
}

__global__ void gru_combine(const float* __restrict__ gi, const float* __restrict__ gh,
                            float* __restrict__ rel)
{
  int idx = blockIdx.x * 256 + threadIdx.x;       // R2 * H
  if (idx >= R2 * H) return;
  int i = idx >> 8, h = idx & 255;
  const float* gir = gi + (size_t)i * H3;
  const float* ghr = gh + (size_t)i * H3;
  float r = 1.f / (1.f + __expf(-(gir[h]       + ghr[h])));
  float z = 1.f / (1.f + __expf(-(gir[H + h]   + ghr[H + h])));
  float n = tanhf(gir[2 * H + h] + r * ghr[2 * H + h]);
  rel[idx] = (1.f - z) * n + z * rel[idx];
}

__global__ void ent_update(float* __restrict__ ent, const float* __restrict__ tw,
                           const float* __restrict__ curr)
{
  int idx = blockIdx.x * 256 + threadIdx.x;       // NE * H
  if (idx >= NE * H) return;
  float t = tw[idx];
  ent[idx] = t * curr[idx] + (1.f - t) * ent[idx];
}

// ------------------------- panel GEMM (K = 256, LDS-staged) -----------------
// A: M x 256 bf16 row-major. B: N x 256 bf16 row-major (operand columns).
// Block = 256 thr (2x2 waves), row tile 128. A-panel staged once to LDS then
// registers a[4][8]; B staged per 128-col step through the same 64 KB LDS.
// XOR swizzle: LDS[X ^ ((row&7)<<4)] = tile[X]  (512 B per row).
// EPI: 0 = bias+store, 1 = bias+relu+store, 2 = bias+sigmoid+store,
//      3 = exp2-rowsum into part[(bx*2+wN)*ROWPAD + row]  (col<N masked)
DEV_INLINE void stage_panel(char* lds, const __bf16* src, int rowBase, int rowLimit, int tid)
{
  #pragma unroll
  for (int p = 0; p < 4; p++) {
    uint4 v[4];
    #pragma unroll
    for (int q = 0; q < 4; q++) {
      int X = ((p * 4 + q) * 256 + tid) * 16;
      int row = X >> 9, boff = X & 511;
      int grow = min(rowBase + row, rowLimit);
      v[q] = *(const uint4*)((const char*)src + (size_t)grow * 512 + boff);
    }
    #pragma unroll
    for (int q = 0; q < 4; q++) {
      int X = ((p * 4 + q) * 256 + tid) * 16;
      int row = X >> 9;
      int dst = X ^ ((row & 7) << 4);
      *(uint4*)(lds + dst) = v[q];
    }
  }
}

DEV_INLINE bf16x8 lds_frag(const char* lds, int row, int kf, int kg)
{
  int off = (kf * 64 + kg * 16) ^ ((row & 7) << 4);
  return *(const bf16x8*)(lds + row * 512 + off);
}

template<int EPI>
__global__ __launch_bounds__(256) void panel_gemm(const __bf16* __restrict__ A,
                                                  const __bf16* __restrict__ B,
                                                  const float* __restrict__ bias,
                                                  float* __restrict__ out,
                                                  int Mr, int N, int CS)
{
  __shared__ __attribute__((aligned(16))) char lds[65536];
  int tid = threadIdx.x;
  int lane = tid & 63, wave = tid >> 6;
  int wM = wave >> 1, wN = wave & 1;
  int r = lane & 15, kg = lane >> 4;
  int rowBase = blockIdx.y * 128;

  // stage A panel once, pull frags to registers
  stage_panel(lds, A, rowBase, Mr - 1, tid);
  __syncthreads();
  bf16x8 a[4][8];
  #pragma unroll
  for (int i = 0; i < 4; i++) {
    int arow = wM * 64 + i * 16 + r;
    #pragma unroll
    for (int kf = 0; kf < 8; kf++) a[i][kf] = lds_frag(lds, arow, kf, kg);
  }
  __syncthreads();

  float lsum[4][4];
  if (EPI == 3) {
    #pragma unroll
    for (int i = 0; i < 4; i++)
      #pragma unroll
      for (int g = 0; g < 4; g++) lsum[i][g] = 0.f;
  }

  int chunkBase = blockIdx.x * CS * 128;
  for (int cs = 0; cs < CS; cs++) {
    int colBase = chunkBase + cs * 128;
    stage_panel(lds, B, colBase, N - 1, tid);
    __syncthreads();

    f32x4 acc[4][4];
    #pragma unroll
    for (int i = 0; i < 4; i++)
      #pragma unroll
      for (int j = 0; j < 4; j++) {
        acc[i][j][0] = 0.f; acc[i][j][1] = 0.f; acc[i][j][2] = 0.f; acc[i][j][3] = 0.f;
      }

    #pragma unroll
    for (int kf = 0; kf < 8; kf++) {
      bf16x8 b[4];
      #pragma unroll
      for (int j = 0; j < 4; j++) b[j] = lds_frag(lds, wN * 64 + j * 16 + r, kf, kg);
      #pragma unroll
      for (int i = 0; i < 4; i++)
        #pragma unroll
        for (int j = 0; j < 4; j++)
          acc[i][j] = mfma16(a[i][kf], b[j], acc[i][j]);
    }
    __syncthreads();   // all waves done reading before next stage overwrites

    if (EPI == 3) {
      #pragma unroll
      for (int j = 0; j < 4; j++) {
        int col = colBase + wN * 64 + j * 16 + r;
        bool ok = col < N;
        #pragma unroll
        for (int i = 0; i < 4; i++)
          #pragma unroll
          for (int g = 0; g < 4; g++)
            lsum[i][g] += ok ? exp2f(acc[i][j][g]) : 0.f;
      }
    } else {
      #pragma unroll
      for (int i = 0; i < 4; i++)
        #pragma unroll
        for (int g = 0; g < 4; g++) {
          int row = rowBase + wM * 64 + i * 16 + kg * 4 + g;
          if (row >= Mr) continue;
          #pragma unroll
          for (int j = 0; j < 4; j++) {
            int col = colBase + wN * 64 + j * 16 + r;
            if (col >= N) continue;
            float v = acc[i][j][g];
            if (bias) v += bias[col];
            if (EPI == 1) v = fmaxf(v, 0.f);
            if (EPI == 2) v = 1.f / (1.f + __expf(-v));
            out[(size_t)row * N + col] = v;
          }
        }
    }
  }

  if (EPI == 3) {
    #pragma unroll
    for (int m = 1; m < 16; m <<= 1)
      #pragma unroll
      for (int i = 0; i < 4; i++)
        #pragma unroll
        for (int g = 0; g < 4; g++)
          lsum[i][g] += __shfl_xor(lsum[i][g], m, 64);
    if (r == 0) {
      size_t cslot = (size_t)(blockIdx.x * 2 + wN) * ROWPAD;
      #pragma unroll
      for (int i = 0; i < 4; i++)
        #pragma unroll
        for (int g = 0; g < 4; g++) {
          int row = rowBase + wM * 64 + i * 16 + kg * 4 + g;
          out[cslot + row] = lsum[i][g];
        }
    }
  }
}

// ------------------------- generic MFMA GEMM (GRU / fc) --------------------
template<int ACT, bool SPLITK>
__global__ void mfma_gemm(const __bf16* __restrict__ A, const __bf16* __restrict__ Bt,
                          const float* __restrict__ bias, float* __restrict__ C,
                          int Mr, int K, int N)
{
  int lane = threadIdx.x & 63, wave = threadIdx.x >> 6;
  int waveM = wave >> 1, waveN = wave & 1;
  int r = lane & 15, kg = lane >> 4;
  int rowBase = blockIdx.y * 64 + waveM * 32;
  int colBase = blockIdx.x * 64 + waveN * 32;
  int kbeg = 0, kend = K;
  if (SPLITK) { int kl = K / gridDim.z; kbeg = blockIdx.z * kl; kend = kbeg + kl; }

  int row0 = rowBase + r, row1 = rowBase + 16 + r;
  int col0 = colBase + r, col1 = colBase + 16 + r;
  bool v0 = row0 < Mr, v1 = row1 < Mr;
  const __bf16* a0p = A + (size_t)row0 * K + kg * 8;
  const __bf16* a1p = A + (size_t)row1 * K + kg * 8;
  const __bf16* b0p = Bt + (size_t)col0 * K + kg * 8;
  const __bf16* b1p = Bt + (size_t)col1 * K + kg * 8;

  f32x4 acc[2][2];
  #pragma unroll
  for (int i = 0; i < 2; i++)
    #pragma unroll
    for (int j = 0; j < 2; j++) { acc[i][j][0] = 0.f; acc[i][j][1] = 0.f; acc[i][j][2] = 0.f; acc[i][j][3] = 0.f; }

  for (int k0 = kbeg; k0 < kend; k0 += 32) {
    bf16x8 a0 = v0 ? ldb8(a0p + k0) : zerob8();
    bf16x8 a1 = v1 ? ldb8(a1p + k0) : zerob8();
    bf16x8 b0 = ldb8(b0p + k0);
    bf16x8 b1 = ldb8(b1p + k0);
    acc[0][0] = mfma16(a0, b0, acc[0][0]);
    acc[0][1] = mfma16(a0, b1, acc[0][1]);
    acc[1][0] = mfma16(a1, b0, acc[1][0]);
    acc[1][1] = mfma16(a1, b1, acc[1][1]);
  }

  float* Cz = SPLITK ? (C + (size_t)blockIdx.z * Mr * N) : C;
  #pragma unroll
  for (int i = 0; i < 2; i++) {
    #pragma unroll
    for (int g = 0; g < 4; g++) {
      int row = rowBase + i * 16 + kg * 4 + g;
      if (row >= Mr) continue;
      #pragma unroll
      for (int j = 0; j < 2; j++) {
        int col = colBase + j * 16 + r;
        float v = acc[i][j][g];
        if (!SPLITK) {
          if (bias) v += bias[col];
          if (ACT == 1) v = fmaxf(v, 0.f);
          if (ACT == 2) v = 1.f / (1.f + __expf(-v));
        }
        Cz[(size_t)row * N + col] = v;
      }
    }
  }
}

// sum split-K partials + bias + relu -> q (fp32) and qb (bf16, prescaled log2 e)
__global__ void fc_reduce(const float* __restrict__ part, const float* __restrict__ bias,
                          float* __restrict__ q, __bf16* __restrict__ qb, int nrows, int splits)
{
  int idx = blockIdx.x * 256 + threadIdx.x;       // nrows * H
  if (idx >= nrows * H) return;
  int col = idx & 255;
  float s = bias[col];
  for (int z = 0; z < splits; z++) s += part[(size_t)z * nrows * H + idx];
  s = fmaxf(s, 0.f);
  q[idx] = s;
  qb[idx] = (__bf16)(s * 1.44269504f);
}

// ------------------------- conv (block per test row) -----------------------
__global__ void conv_feat(const float* __restrict__ ent, const float* __restrict__ rel,
                          const float* __restrict__ sent, const int* __restrict__ tt,
                          const float* __restrict__ cw, const float* __restrict__ cb,
                          __bf16* __restrict__ out, int row0)
{
  __shared__ float f[3][258];
  __shared__ float wsm[CH * 9];
  __shared__ float bsm[CH];
  int i = row0 + blockIdx.x;
  int h = threadIdx.x;
  int j = (i < NT) ? i : i - NT;
  int a0 = (i < NT) ? tt[j * 3 + 0] : tt[j * 3 + 2];
  int a1 = (i < NT) ? tt[j * 3 + 1] : tt[j * 3 + 1] + NR;
  f[0][h + 1] = ent[(size_t)a0 * H + h];
  f[1][h + 1] = rel[(size_t)a1 * H + h];
  f[2][h + 1] = sent[(size_t)j * H + h];
  if (h < 3) { f[h][0] = 0.f; f[h][257] = 0.f; }
  for (int x = h; x < CH * 9; x += 256) wsm[x] = cw[x];
  if (h < CH) bsm[h] = cb[h];
  __syncthreads();
  __bf16* orow = out + (size_t)blockIdx.x * KFC;
  for (int c = 0; c < CH; c++) {
    const float* wc = wsm + c * 9;
    float s = bsm[c];
    #pragma unroll
    for (int ic = 0; ic < 3; ic++)
      s += wc[ic * 3 + 0] * f[ic][h] + wc[ic * 3 + 1] * f[ic][h + 1] + wc[ic * 3 + 2] * f[ic][h + 2];
    orow[(size_t)c * H + h] = (__bf16)fmaxf(s, 0.f);
  }
}

// one wave per row: nll[row] = log(sum_c part_l) - q[row].ent[tgt]
__global__ void lse_combine(const float* __restrict__ part_l, const float* __restrict__ qf,
                            const float* __restrict__ ent, const int* __restrict__ tt,
                            float* __restrict__ nll)
{
  int gid = blockIdx.x * 256 + threadIdx.x;
  int w = gid >> 6;
  if (w >= NT2) return;
  int lane = gid & 63;
  int j = (w < NT) ? w : w - NT;
  int tgt = (w < NT) ? tt[j * 3 + 2] : tt[j * 3 + 0];
  const float4 qa = ((const float4*)(qf + (size_t)w * H))[lane];
  const float4 ea = ((const float4*)(ent + (size_t)tgt * H))[lane];
  float d = qa.x * ea.x + qa.y * ea.y + qa.z * ea.z + qa.w * ea.w;
  float s = part_l[(size_t)lane * ROWPAD + w];   // NCHUNK == 64 == wave size
  #pragma unroll
  for (int o = 32; o > 0; o >>= 1) {
    d += __shfl_down(d, o, 64);
    s += __shfl_down(s, o, 64);
  }
  if (lane == 0) nll[w] = logf(s) - d;
}

__global__ void mean_nll(const float* __restrict__ nll, float* __restrict__ out)
{
  float s = 0.f;
  for (int i = threadIdx.x; i < NT2; i += 256) s += nll[i];
  s = block_sum256(s);
  if (threadIdx.x == 0) out[0] = s * (1.f / NT2);
}

// ------------------------- launcher ----------------------------------------
extern "C" void kernel_launch(void* const* d_in, const int* in_sizes, int n_in,
                              void* d_out, int out_size, void* d_ws, size_t ws_size,
                              hipStream_t stream)
{
  const float* dynamic_emb = (const float*)d_in[0];
  const float* emb_rel     = (const float*)d_in[1];
  const float* gru_W_ih    = (const float*)d_in[2];
  const float* gru_W_hh    = (const float*)d_in[3];
  const float* gru_b_ih    = (const float*)d_in[4];
  const float* gru_b_hh    = (const float*)d_in[5];
  const float* agg_W       = (const float*)d_in[6];
  const float* tg_W        = (const float*)d_in[7];
  const float* tg_b        = (const float*)d_in[8];
  const float* hev         = (const float*)d_in[9];
  const float* hrv         = (const float*)d_in[10];
  const float* conv_w      = (const float*)d_in[11];
  const float* conv_b      = (const float*)d_in[12];
  const float* fc_W        = (const float*)d_in[13];
  const float* fc_b        = (const float*)d_in[14];
  const float* sent        = (const float*)d_in[15];
  const int* edge_src = (const int*)d_in[16];
  const int* edge_rel = (const int*)d_in[17];
  const int* edge_dst = (const int*)d_in[18];
  const int* r_to_e   = (const int*)d_in[19];
  const int* r_ids    = (const int*)d_in[20];
  const int* he_row   = (const int*)d_in[21];
  const int* he_col   = (const int*)d_in[22];
  const int* hr_row   = (const int*)d_in[23];
  const int* hr_col   = (const int*)d_in[24];
  const int* tt       = (const int*)d_in[25];
  float* out = (float*)d_out;

  char* base = (char*)d_ws;
  size_t off = 0;
  auto alloc = [&](size_t bytes) { char* p = base + off; off += (bytes + 255) & ~(size_t)255; return p; };

  float* ent    = (float*)alloc((size_t)NE * H * 4);
  float* curr   = (float*)alloc((size_t)NE * H * 4);        // agg out; hyper ping-pong
  float* tgbuf  = (float*)alloc((size_t)NE * H * 4);        // gate; conv_bf overlay
  __bf16* convb = (__bf16*)tgbuf;                            // 800*12800*2 = 20.48MB
  __bf16* entb  = (__bf16*)alloc((size_t)NE * H * 2);
  __bf16* accEb = (__bf16*)alloc((size_t)NE * H * 2);       // edge-gather out; fcpart overlay
  float* fcpart = (float*)accEb;                             // 8*800*256*4 = 6.55MB < 10.24MB
  float* rel    = (float*)alloc((size_t)R2 * H * 4);
  float* accR   = (float*)alloc((size_t)R2 * H * 4);
  __bf16* relb  = (__bf16*)alloc((size_t)R2 * H * 2);
  __bf16* xinb  = (__bf16*)alloc((size_t)R2 * 2 * H * 2);
  float* gi     = (float*)alloc((size_t)R2 * H3 * 4);
  float* gh     = (float*)alloc((size_t)R2 * H3 * 4);
  float* qf     = (float*)alloc((size_t)NT2 * H * 4);
  __bf16* qb    = (__bf16*)alloc((size_t)NT2 * H * 2);
  float* part_l = (float*)alloc((size_t)NCHUNK * ROWPAD * 4);
  float* nll    = (float*)alloc((size_t)NT2 * 4);
  __bf16* tgWtb = (__bf16*)alloc((size_t)H * H * 2);
  __bf16* aggWtb= (__bf16*)alloc((size_t)H * H * 2);
  __bf16* fcWtb = (__bf16*)alloc((size_t)H * KFC * 2);
  __bf16* Wihb  = (__bf16*)alloc((size_t)H3 * 2 * H * 2);
  __bf16* Whhb  = (__bf16*)alloc((size_t)H3 * H * 2);

  int* ip = (int*)alloc(0);
  size_t ioff = 0;
  auto ialloc = [&](size_t n) { int* p = ip + ioff; ioff += n; return p; };
  int* permM[TT]; int* sM[TT];
  int* permE[TT]; int* sE[TT];
  for (int t = 0; t < TT; t++) { permM[t] = ialloc(M);     sM[t] = ialloc(R2 + 1); }
  for (int t = 0; t < TT; t++) { permE[t] = ialloc(NEDGE); sE[t] = ialloc(NE + 1); }
  int* permHE = ialloc(NNZ_E); int* sHE = ialloc(NE + 1);
  int* permHR = ialloc(NNZ_R); int* sHR = ialloc(R2 + 1);
  int* cnt    = ialloc(NE + 1);
  int* cursor = ialloc(NE + 1);

  auto build_csr = [&](const int* keys, int n, int nbins, int* start, int* perm) {
    hipMemsetAsync(cnt, 0, (size_t)nbins * 4, stream);
    hist_k<<<(n + 255) / 256, 256, 0, stream>>>(keys, n, cnt);
    scan_k<<<1, 256, 0, stream>>>(cnt, start, cursor, nbins);
    perm_k<<<(n + 255) / 256, 256, 0, stream>>>(keys, n, cursor, perm);
  };

  // weight prep (bf16)
  transpose_cast_k<<<dim3(H / 32, H / 32), 256, 0, stream>>>(tg_W, tgWtb, H, H);
  transpose_cast_k<<<dim3(H / 32, H / 32), 256, 0, stream>>>(agg_W, aggWtb, H, H);
  transpose_cast_k<<<dim3(KFC / 32, H / 32), 256, 0, stream>>>(fc_W, fcWtb, KFC, H);
  cast_bf16_k<<<(H3 * 2 * H / 8 + 255) / 256, 256, 0, stream>>>(gru_W_ih, Wihb, H3 * 2 * H / 8);
  cast_bf16_k<<<(H3 * H / 8 + 255) / 256, 256, 0, stream>>>(gru_W_hh, Whhb, H3 * H / 8);

  for (int t = 0; t < TT; t++) build_csr(r_ids + (size_t)t * M, M, R2, sM[t], permM[t]);
  for (int t = 0; t < TT; t++) build_csr(edge_dst + (size_t)t * NEDGE, NEDGE, NE, sE[t], permE[t]);
  build_csr(he_row, NNZ_E, NE, sHE, permHE);
  build_csr(hr_row, NNZ_R, R2, sHR, permHR);

  hipMemcpyAsync(ent, dynamic_emb, (size_t)NE * H * 4, hipMemcpyDeviceToDevice, stream);
  hipMemcpyAsync(rel, emb_rel, (size_t)R2 * H * 4, hipMemcpyDeviceToDevice, stream);

  constexpr int NEH8 = NE * H / 8, R2H8 = R2 * H / 8;
  constexpr int NE_RB = (NE + 127) / 128;   // 157 row blocks

  for (int t = 0; t < TT; t++) {
    cast_bf16_k<<<(NEH8 + 255) / 256, 256, 0, stream>>>(ent, entb, NEH8);
    cast_bf16_k<<<(R2H8 + 255) / 256, 256, 0, stream>>>(rel, relb, R2H8);

    // --- rel update (GRU) ---
    gather_mean_k<<<R2, 256, 0, stream>>>(entb, r_to_e + (size_t)t * M, permM[t], sM[t], accR);
    build_xin_bf<<<(R2 * 2 * H + 255) / 256, 256, 0, stream>>>(rel, accR, xinb);
    mfma_gemm<0, false><<<dim3(H3 / 64, (R2 + 63) / 64), 256, 0, stream>>>(
        xinb, Wihb, gru_b_ih, gi, R2, 2 * H, H3);
    mfma_gemm<0, false><<<dim3(H3 / 64, (R2 + 63) / 64), 256, 0, stream>>>(
        relb, Whhb, gru_b_hh, gh, R2, H, H3);
    gru_combine<<<(R2 * H + 255) / 256, 256, 0, stream>>>(gi, gh, rel);
    cast_bf16_k<<<(R2H8 + 255) / 256, 256, 0, stream>>>(rel, relb, R2H8);

    // --- ent update ---
    panel_gemm<2><<<dim3(1, NE_RB), 256, 0, stream>>>(entb, tgWtb, tg_b, tgbuf, NE, H, 2);
    gather_edges_k<<<NE, 256, 0, stream>>>(entb, relb, edge_src + (size_t)t * NEDGE,
                                           edge_rel + (size_t)t * NEDGE, permE[t], sE[t], accEb);
    panel_gemm<1><<<dim3(1, NE_RB), 256, 0, stream>>>(accEb, aggWtb, nullptr, curr, NE, H, 2);
    ent_update<<<(NE * H + 255) / 256, 256, 0, stream>>>(ent, tgbuf, curr);
  }

  // --- hypergraph layers (ent: bf16 neighbor reads; ends back in ent) ---
  cast_bf16_k<<<(NEH8 + 255) / 256, 256, 0, stream>>>(ent, entb, NEH8);
  hyper_layer_bf_k<<<NE, 256, 0, stream>>>(ent, entb, hev, he_col, permHE, sHE, curr);
  cast_bf16_k<<<(NEH8 + 255) / 256, 256, 0, stream>>>(curr, entb, NEH8);
  hyper_layer_bf_k<<<NE, 256, 0, stream>>>(curr, entb, hev, he_col, permHE, sHE, ent);
  hyper_layer_k<<<R2, 256, 0, stream>>>(rel, hrv, hr_col, permHR, sHR, accR);
  hyper_layer_k<<<R2, 256, 0, stream>>>(accR, hrv, hr_col, permHR, sHR, rel);

  // final bf16 ent for scores
  cast_bf16_k<<<(NEH8 + 255) / 256, 256, 0, stream>>>(ent, entb, NEH8);

  // --- conv + fc (chunks of 800 rows) ---
  for (int c = 0; c < 5; c++) {
    int row0 = c * 800;
    conv_feat<<<800, 256, 0, stream>>>(ent, rel, sent, tt, conv_w, conv_b, convb, row0);
    mfma_gemm<0, true><<<dim3(H / 64, 13, 8), 256, 0, stream>>>(
        convb, fcWtb, nullptr, fcpart, 800, KFC, H);
    fc_reduce<<<(800 * H + 255) / 256, 256, 0, stream>>>(
        fcpart, fc_b, qf + (size_t)row0 * H, qb + (size_t)row0 * H, 800, 8);
  }

  // --- fused scores + LSE: 32 col-chunks x 32 row-blocks, CS=5 (640 cols) ---
  panel_gemm<3><<<dim3(32, 32), 256, 0, stream>>>(qb, entb, nullptr, part_l, NT2, NE, 5);
  lse_combine<<<(NT2 * 64 + 255) / 256, 256, 0, stream>>>(part_l, qf, ent, tt, nll);
  mean_nll<<<1, 256, 0, stream>>>(nll, out);
}

// Round 6
// 1630.653 us; speedup vs baseline: 5.5726x; 1.3572x over previous
//
#include <hip/hip_runtime.h>
#include <math.h>

#define DEV_INLINE __device__ __forceinline__

constexpr int H      = 256;
constexpr int NE     = 20000;
constexpr int NR     = 250;
constexpr int R2     = 500;
constexpr int TT     = 3;
constexpr int NEDGE  = 150000;
constexpr int M      = 200000;
constexpr int NNZ_E  = 320000;
constexpr int NNZ_R  = 8000;
constexpr int CH     = 50;
constexpr int NT     = 2000;
constexpr int NT2    = 4000;
constexpr int H3     = 3 * H;     // 768
constexpr int KFC    = CH * H;    // 12800
constexpr int ROWPAD = 4096;
constexpr int NCHUNK = 64;
constexpr int MSPLIT = 8;         // gather_mean row split
constexpr int FSPLIT = 10;        // fc split-K (1280 = 20*64 per split)

typedef __bf16 bf16x8 __attribute__((ext_vector_type(8)));
typedef __bf16 bf16x4 __attribute__((ext_vector_type(4)));
typedef float  f32x4  __attribute__((ext_vector_type(4)));

DEV_INLINE bf16x8 ldb8(const __bf16* p) { return *(const bf16x8*)p; }
DEV_INLINE bf16x8 zerob8() { uint4 z = make_uint4(0, 0, 0, 0); return __builtin_bit_cast(bf16x8, z); }
DEV_INLINE f32x4 mfma16(bf16x8 a, bf16x8 b, f32x4 c) {
  return __builtin_amdgcn_mfma_f32_16x16x32_bf16(a, b, c, 0, 0, 0);
}

// ------------------------- block reduction (blockDim == 256) ---------------
DEV_INLINE float block_sum256(float v) {
  __shared__ float ws[4];
  #pragma unroll
  for (int o = 32; o > 0; o >>= 1) v += __shfl_down(v, o, 64);
  if ((threadIdx.x & 63) == 0) ws[threadIdx.x >> 6] = v;
  __syncthreads();
  float r = ws[0] + ws[1] + ws[2] + ws[3];
  __syncthreads();
  return r;
}

// ------------------------- CSR build (int atomics only) --------------------
__global__ void hist_k(const int* __restrict__ keys, int n, int* __restrict__ cnt)
{
  int i = blockIdx.x * 256 + threadIdx.x;
  if (i < n) atomicAdd(&cnt[keys[i]], 1);
}

__global__ void scan_k(const int* __restrict__ cnt, int* __restrict__ start,
                       int* __restrict__ cursor, int nbins)
{
  __shared__ int ps[257];
  int t = threadIdx.x;
  int per = (nbins + 255) >> 8;
  int b0 = t * per;
  int local = 0;
  for (int i = 0; i < per; i++) { int b = b0 + i; if (b < nbins) local += cnt[b]; }
  ps[t + 1] = local;
  if (t == 0) ps[0] = 0;
  __syncthreads();
  if (t == 0) { for (int i = 1; i <= 256; i++) ps[i] += ps[i - 1]; }
  __syncthreads();
  int run = ps[t];
  for (int i = 0; i < per; i++) {
    int b = b0 + i;
    if (b < nbins) { start[b] = run; cursor[b] = run; run += cnt[b]; }
  }
  if (t == 0) start[nbins] = ps[256];
}

__global__ void perm_k(const int* __restrict__ keys, int n,
                       int* __restrict__ cursor, int* __restrict__ perm)
{
  int i = blockIdx.x * 256 + threadIdx.x;
  if (i < n) { int p = atomicAdd(&cursor[keys[i]], 1); perm[p] = i; }
}

// fused-index builders (remove one indirection from gather loops)
__global__ void fuse1_k(const int* __restrict__ key, const int* __restrict__ perm,
                        int n, int* __restrict__ out)
{
  int i = blockIdx.x * 256 + threadIdx.x;
  if (i < n) out[i] = key[perm[i]];
}
__global__ void fuse2_k(const int* __restrict__ k1, const int* __restrict__ k2,
                        const int* __restrict__ perm, int n,
                        int* __restrict__ o1, int* __restrict__ o2)
{
  int i = blockIdx.x * 256 + threadIdx.x;
  if (i < n) { int p = perm[i]; o1[i] = k1[p]; o2[i] = k2[p]; }
}
__global__ void fusev_k(const int* __restrict__ key, const float* __restrict__ val,
                        const int* __restrict__ perm, int n,
                        int* __restrict__ okey, float* __restrict__ oval)
{
  int i = blockIdx.x * 256 + threadIdx.x;
  if (i < n) { int p = perm[i]; okey[i] = key[p]; oval[i] = val[p]; }
}

// ------------------------- casts / transposes ------------------------------
__global__ void cast_bf16_k(const float* __restrict__ in, __bf16* __restrict__ out, int n8)
{
  int i = blockIdx.x * 256 + threadIdx.x;
  if (i >= n8) return;
  const float4* p = (const float4*)in + (size_t)i * 2;
  float4 u = p[0], v = p[1];
  bf16x8 o;
  o[0] = (__bf16)u.x; o[1] = (__bf16)u.y; o[2] = (__bf16)u.z; o[3] = (__bf16)u.w;
  o[4] = (__bf16)v.x; o[5] = (__bf16)v.y; o[6] = (__bf16)v.z; o[7] = (__bf16)v.w;
  ((bf16x8*)out)[i] = o;
}

__global__ void transpose_cast_k(const float* __restrict__ in, __bf16* __restrict__ out,
                                 int K, int N)
{
  __shared__ float tile[32][33];
  int tx = threadIdx.x & 31, ty = threadIdx.x >> 5;   // 32 x 8
  int kb = blockIdx.x * 32, nb = blockIdx.y * 32;
  #pragma unroll
  for (int i = 0; i < 4; i++)
    tile[ty + i * 8][tx] = in[(size_t)(kb + ty + i * 8) * N + nb + tx];
  __syncthreads();
  #pragma unroll
  for (int i = 0; i < 4; i++)
    out[(size_t)(nb + ty + i * 8) * K + kb + tx] = (__bf16)tile[tx][ty + i * 8];
}

// ------------------------- gather kernels (wave-per-entry) -----------------
DEV_INLINE void bf4acc(const __bf16* p, float& a0, float& a1, float& a2, float& a3)
{
  bf16x4 v = *(const bf16x4*)p;
  a0 += (float)v[0]; a1 += (float)v[1]; a2 += (float)v[2]; a3 += (float)v[3];
}
DEV_INLINE void bf4accw(const __bf16* p, float wgt, float& a0, float& a1, float& a2, float& a3)
{
  bf16x4 v = *(const bf16x4*)p;
  a0 += wgt * (float)v[0]; a1 += wgt * (float)v[1]; a2 += wgt * (float)v[2]; a3 += wgt * (float)v[3];
}

// grid (R2, MSPLIT): partial sums into part[(r*MSPLIT+s)*H + h]
__global__ void gather_mean2_k(const __bf16* __restrict__ src, const int* __restrict__ fidx,
                               const int* __restrict__ start, float* __restrict__ part)
{
  __shared__ __align__(16) float red[4][H];
  int r = blockIdx.x, s = blockIdx.y;
  int s0 = start[r], s1 = start[r + 1];
  int len = s1 - s0;
  int chunk = (len + MSPLIT - 1) / MSPLIT;
  int jb = s0 + s * chunk, je = min(jb + chunk, s1);
  int lane = threadIdx.x & 63, w = threadIdx.x >> 6;
  float a0 = 0.f, a1 = 0.f, a2 = 0.f, a3 = 0.f;
  float b0 = 0.f, b1 = 0.f, b2 = 0.f, b3 = 0.f;
  int j = jb + w;
  for (; j + 4 < je; j += 8) {
    int e0 = fidx[j], e1 = fidx[j + 4];
    bf4acc(src + (size_t)e0 * H + lane * 4, a0, a1, a2, a3);
    bf4acc(src + (size_t)e1 * H + lane * 4, b0, b1, b2, b3);
  }
  if (j < je) bf4acc(src + (size_t)fidx[j] * H + lane * 4, a0, a1, a2, a3);
  float4 v = make_float4(a0 + b0, a1 + b1, a2 + b2, a3 + b3);
  *(float4*)&red[w][lane * 4] = v;
  __syncthreads();
  int h = threadIdx.x;
  part[((size_t)r * MSPLIT + s) * H + h] = red[0][h] + red[1][h] + red[2][h] + red[3][h];
}

__global__ void mean_combine_k(const float* __restrict__ part, const int* __restrict__ start,
                               float* __restrict__ out)
{
  int r = blockIdx.x, h = threadIdx.x;
  float s = 0.f;
  #pragma unroll
  for (int z = 0; z < MSPLIT; z++) s += part[((size_t)r * MSPLIT + z) * H + h];
  out[(size_t)r * H + h] = s / (float)max(start[r + 1] - start[r], 1);
}

// grid NE: out[d] = mean(ent[fsrc]+rel[frel]) in bf16
__global__ void gather_edges2_k(const __bf16* __restrict__ ent, const __bf16* __restrict__ rel,
                                const int* __restrict__ fsrc, const int* __restrict__ frel,
                                const int* __restrict__ start, __bf16* __restrict__ out)
{
  __shared__ __align__(16) float red[4][H];
  int d = blockIdx.x;
  int s0 = start[d], s1 = start[d + 1];
  int lane = threadIdx.x & 63, w = threadIdx.x >> 6;
  float a0 = 0.f, a1 = 0.f, a2 = 0.f, a3 = 0.f;
  for (int j = s0 + w; j < s1; j += 4) {
    int es = fsrc[j], er = frel[j];
    bf4acc(ent + (size_t)es * H + lane * 4, a0, a1, a2, a3);
    bf4acc(rel + (size_t)er * H + lane * 4, a0, a1, a2, a3);
  }
  *(float4*)&red[w][lane * 4] = make_float4(a0, a1, a2, a3);
  __syncthreads();
  int h = threadIdx.x;
  float sum = red[0][h] + red[1][h] + red[2][h] + red[3][h];
  out[(size_t)d * H + h] = (__bf16)(sum / (float)max(s1 - s0, 1));
}

// grid NE: xout = x + y/||y||, y = sum fval*xb[fcol]; also emits bf16 copy
__global__ void hyper2_k(const float* __restrict__ x, const __bf16* __restrict__ xb,
                         const float* __restrict__ fval, const int* __restrict__ fcol,
                         const int* __restrict__ start,
                         float* __restrict__ xout, __bf16* __restrict__ xoutb)
{
  __shared__ __align__(16) float red[4][H];
  int r = blockIdx.x;
  int s0 = start[r], s1 = start[r + 1];
  int lane = threadIdx.x & 63, w = threadIdx.x >> 6;
  float a0 = 0.f, a1 = 0.f, a2 = 0.f, a3 = 0.f;
  int j = s0 + w;
  for (; j + 4 < s1; j += 8) {
    int e0 = fcol[j], e1 = fcol[j + 4];
    float v0 = fval[j], v1 = fval[j + 4];
    bf4accw(xb + (size_t)e0 * H + lane * 4, v0, a0, a1, a2, a3);
    bf4accw(xb + (size_t)e1 * H + lane * 4, v1, a0, a1, a2, a3);
  }
  if (j < s1) bf4accw(xb + (size_t)fcol[j] * H + lane * 4, fval[j], a0, a1, a2, a3);
  *(float4*)&red[w][lane * 4] = make_float4(a0, a1, a2, a3);
  __syncthreads();
  int h = threadIdx.x;
  float y = red[0][h] + red[1][h] + red[2][h] + red[3][h];
  float ss = block_sum256(y * y);
  float rn = 1.f / fmaxf(sqrtf(ss), 1e-12f);
  float o = x[(size_t)r * H + h] + y * rn;
  xout[(size_t)r * H + h] = o;
  xoutb[(size_t)r * H + h] = (__bf16)o;
}

// fp32 perm-based variant (small rel graph only)
__global__ void hyper_layer_k(const float* __restrict__ x, const float* __restrict__ val,
                              const int* __restrict__ col, const int* __restrict__ perm,
                              const int* __restrict__ start, float* __restrict__ xout)
{
  int r = blockIdx.x, h = threadIdx.x;
  int s0 = start[r], s1 = start[r + 1];
  float a0 = 0.f;
  for (int j = s0; j < s1; j++) { int e = perm[j]; a0 += val[e] * x[(size_t)col[e] * H + h]; }
  float ss = block_sum256(a0 * a0);
  float rn = 1.f / fmaxf(sqrtf(ss), 1e-12f);
  xout[(size_t)r * H + h] = x[(size_t)r * H + h] + a0 * rn;
}

// ------------------------- small elementwise -------------------------------
__global__ void build_xin_bf(const float* __restrict__ rel, const float* __restrict__ xm,
                             __bf16* __restrict__ xin)
{
  int idx = blockIdx.x * 256 + threadIdx.x;       // R2 * 512
  if (idx >= R2 * 2 * H) return;
  int i = idx >> 9, c = idx & 511;
  float v = (c < H) ? rel[(size_t)i * H + c] : xm[(size_t)i * H + (c - H)];
  xin[idx] = (__bf16)v;
}

__global__ void gru_combine(const float* __restrict__ gi, const float* __restrict__ gh,
                            float* __restrict__ rel, __bf16* __restrict__ relb)
{
  int idx = blockIdx.x * 256 + threadIdx.x;       // R2 * H
  if (idx >= R2 * H) return;
  int i = idx >> 8, h = idx & 255;
  const float* gir = gi + (size_t)i * H3;
  const float* ghr = gh + (size_t)i * H3;
  float r = 1.f / (1.f + __expf(-(gir[h]       + ghr[h])));
  float z = 1.f / (1.f + __expf(-(gir[H + h]   + ghr[H + h])));
  float n = tanhf(gir[2 * H + h] + r * ghr[2 * H + h]);
  float o = (1.f - z) * n + z * rel[idx];
  rel[idx] = o;
  relb[idx] = (__bf16)o;
}

__global__ void ent_update(float* __restrict__ ent, __bf16* __restrict__ entb,
                           const float* __restrict__ tw, const float* __restrict__ curr)
{
  int idx = blockIdx.x * 256 + threadIdx.x;       // NE * H
  if (idx >= NE * H) return;
  float t = tw[idx];
  float v = t * curr[idx] + (1.f - t) * ent[idx];
  ent[idx] = v;
  entb[idx] = (__bf16)v;
}

// ------------------------- panel GEMM (K = 256, LDS-staged) -----------------
DEV_INLINE void stage_panel(char* lds, const __bf16* src, int rowBase, int rowLimit, int tid)
{
  #pragma unroll
  for (int p = 0; p < 4; p++) {
    uint4 v[4];
    #pragma unroll
    for (int q = 0; q < 4; q++) {
      int X = ((p * 4 + q) * 256 + tid) * 16;
      int row = X >> 9, boff = X & 511;
      int grow = min(rowBase + row, rowLimit);
      v[q] = *(const uint4*)((const char*)src + (size_t)grow * 512 + boff);
    }
    #pragma unroll
    for (int q = 0; q < 4; q++) {
      int X = ((p * 4 + q) * 256 + tid) * 16;
      int row = X >> 9;
      int dst = X ^ ((row & 7) << 4);
      *(uint4*)(lds + dst) = v[q];
    }
  }
}

DEV_INLINE bf16x8 lds_frag(const char* lds, int row, int kf, int kg)
{
  int off = (kf * 64 + kg * 16) ^ ((row & 7) << 4);
  return *(const bf16x8*)(lds + row * 512 + off);
}

template<int EPI>
__global__ __launch_bounds__(256) void panel_gemm(const __bf16* __restrict__ A,
                                                  const __bf16* __restrict__ B,
                                                  const float* __restrict__ bias,
                                                  float* __restrict__ out,
                                                  int Mr, int N, int CS)
{
  __shared__ __attribute__((aligned(16))) char lds[65536];
  int tid = threadIdx.x;
  int lane = tid & 63, wave = tid >> 6;
  int wM = wave >> 1, wN = wave & 1;
  int r = lane & 15, kg = lane >> 4;
  int rowBase = blockIdx.y * 128;

  stage_panel(lds, A, rowBase, Mr - 1, tid);
  __syncthreads();
  bf16x8 a[4][8];
  #pragma unroll
  for (int i = 0; i < 4; i++) {
    int arow = wM * 64 + i * 16 + r;
    #pragma unroll
    for (int kf = 0; kf < 8; kf++) a[i][kf] = lds_frag(lds, arow, kf, kg);
  }
  __syncthreads();

  float lsum[4][4];
  if (EPI == 3) {
    #pragma unroll
    for (int i = 0; i < 4; i++)
      #pragma unroll
      for (int g = 0; g < 4; g++) lsum[i][g] = 0.f;
  }

  int chunkBase = blockIdx.x * CS * 128;
  for (int cs = 0; cs < CS; cs++) {
    int colBase = chunkBase + cs * 128;
    stage_panel(lds, B, colBase, N - 1, tid);
    __syncthreads();

    f32x4 acc[4][4];
    #pragma unroll
    for (int i = 0; i < 4; i++)
      #pragma unroll
      for (int j = 0; j < 4; j++) {
        acc[i][j][0] = 0.f; acc[i][j][1] = 0.f; acc[i][j][2] = 0.f; acc[i][j][3] = 0.f;
      }

    #pragma unroll
    for (int kf = 0; kf < 8; kf++) {
      bf16x8 b[4];
      #pragma unroll
      for (int j = 0; j < 4; j++) b[j] = lds_frag(lds, wN * 64 + j * 16 + r, kf, kg);
      #pragma unroll
      for (int i = 0; i < 4; i++)
        #pragma unroll
        for (int j = 0; j < 4; j++)
          acc[i][j] = mfma16(a[i][kf], b[j], acc[i][j]);
    }
    __syncthreads();

    if (EPI == 3) {
      #pragma unroll
      for (int j = 0; j < 4; j++) {
        int col = colBase + wN * 64 + j * 16 + r;
        bool ok = col < N;
        #pragma unroll
        for (int i = 0; i < 4; i++)
          #pragma unroll
          for (int g = 0; g < 4; g++)
            lsum[i][g] += ok ? exp2f(acc[i][j][g]) : 0.f;
      }
    } else {
      #pragma unroll
      for (int i = 0; i < 4; i++)
        #pragma unroll
        for (int g = 0; g < 4; g++) {
          int row = rowBase + wM * 64 + i * 16 + kg * 4 + g;
          if (row >= Mr) continue;
          #pragma unroll
          for (int j = 0; j < 4; j++) {
            int col = colBase + wN * 64 + j * 16 + r;
            if (col >= N) continue;
            float v = acc[i][j][g];
            if (bias) v += bias[col];
            if (EPI == 1) v = fmaxf(v, 0.f);
            if (EPI == 2) v = 1.f / (1.f + __expf(-v));
            out[(size_t)row * N + col] = v;
          }
        }
    }
  }

  if (EPI == 3) {
    #pragma unroll
    for (int m = 1; m < 16; m <<= 1)
      #pragma unroll
      for (int i = 0; i < 4; i++)
        #pragma unroll
        for (int g = 0; g < 4; g++)
          lsum[i][g] += __shfl_xor(lsum[i][g], m, 64);
    if (r == 0) {
      size_t cslot = (size_t)(blockIdx.x * 2 + wN) * ROWPAD;
      #pragma unroll
      for (int i = 0; i < 4; i++)
        #pragma unroll
        for (int g = 0; g < 4; g++) {
          int row = rowBase + wM * 64 + i * 16 + kg * 4 + g;
          out[cslot + row] = lsum[i][g];
        }
    }
  }
}

// ------------------------- fc GEMM (K = 12800, LDS-staged, split-K) --------
// A: Mr x 12800 bf16. Bt: 256 x 12800 bf16. grid (FSPLIT, ceil(Mr/128)).
// part[z][row][col], z = blockIdx.x. LDS: A[128][64] + B[256][64] = 48 KB.
__global__ __launch_bounds__(256) void fc_gemm(const __bf16* __restrict__ A,
                                               const __bf16* __restrict__ Bt,
                                               float* __restrict__ part, int Mr)
{
  __shared__ __attribute__((aligned(16))) char lds[49152];
  int tid = threadIdx.x;
  int lane = tid & 63, wave = tid >> 6;
  int wM = wave >> 1, wN = wave & 1;
  int r = lane & 15, kg = lane >> 4;
  int rowBase = blockIdx.y * 128;
  int kbeg = blockIdx.x * (KFC / FSPLIT);   // 1280

  f32x4 acc[4][8];
  #pragma unroll
  for (int i = 0; i < 4; i++)
    #pragma unroll
    for (int j = 0; j < 8; j++) {
      acc[i][j][0] = 0.f; acc[i][j][1] = 0.f; acc[i][j][2] = 0.f; acc[i][j][3] = 0.f;
    }

  for (int ks = 0; ks < 20; ks++) {
    int kb = kbeg + ks * 64;
    // stage: pre-swizzled source, linear LDS dest. 12 x uint4 per thread.
    #pragma unroll
    for (int q = 0; q < 12; q++) {
      int X = (q * 256 + tid) * 16;
      int row = X >> 7;
      int off = X & 127;
      int soff = off ^ ((row & 7) << 4);
      uint4 v;
      if (row < 128) {
        int grow = min(rowBase + row, Mr - 1);
        v = *(const uint4*)((const char*)A + (size_t)grow * (KFC * 2) + kb * 2 + soff);
      } else {
        int col = row - 128;
        v = *(const uint4*)((const char*)Bt + (size_t)col * (KFC * 2) + kb * 2 + soff);
      }
      *(uint4*)(lds + X) = v;
    }
    __syncthreads();
    #pragma unroll
    for (int kf = 0; kf < 2; kf++) {
      bf16x8 a[4], b[8];
      #pragma unroll
      for (int i = 0; i < 4; i++) {
        int row = wM * 64 + i * 16 + r;
        int off = (kf * 64 + kg * 16) ^ ((row & 7) << 4);
        a[i] = *(const bf16x8*)(lds + row * 128 + off);
      }
      #pragma unroll
      for (int j = 0; j < 8; j++) {
        int row = 128 + wN * 128 + j * 16 + r;
        int off = (kf * 64 + kg * 16) ^ ((row & 7) << 4);
        b[j] = *(const bf16x8*)(lds + row * 128 + off);
      }
      #pragma unroll
      for (int i = 0; i < 4; i++)
        #pragma unroll
        for (int j = 0; j < 8; j++)
          acc[i][j] = mfma16(a[i], b[j], acc[i][j]);
    }
    __syncthreads();
  }

  float* pz = part + (size_t)blockIdx.x * Mr * H;
  #pragma unroll
  for (int i = 0; i < 4; i++)
    #pragma unroll
    for (int g = 0; g < 4; g++) {
      int row = rowBase + wM * 64 + i * 16 + kg * 4 + g;
      if (row >= Mr) continue;
      #pragma unroll
      for (int j = 0; j < 8; j++) {
        int col = wN * 128 + j * 16 + r;
        pz[(size_t)row * H + col] = acc[i][j][g];
      }
    }
}

// ------------------------- generic MFMA GEMM (GRU) -------------------------
template<int ACT>
__global__ void mfma_gemm(const __bf16* __restrict__ A, const __bf16* __restrict__ Bt,
                          const float* __restrict__ bias, float* __restrict__ C,
                          int Mr, int K, int N)
{
  int lane = threadIdx.x & 63, wave = threadIdx.x >> 6;
  int waveM = wave >> 1, waveN = wave & 1;
  int r = lane & 15, kg = lane >> 4;
  int rowBase = blockIdx.y * 64 + waveM * 32;
  int colBase = blockIdx.x * 64 + waveN * 32;

  int row0 = rowBase + r, row1 = rowBase + 16 + r;
  int col0 = colBase + r, col1 = colBase + 16 + r;
  bool v0 = row0 < Mr, v1 = row1 < Mr;
  const __bf16* a0p = A + (size_t)row0 * K + kg * 8;
  const __bf16* a1p = A + (size_t)row1 * K + kg * 8;
  const __bf16* b0p = Bt + (size_t)col0 * K + kg * 8;
  const __bf16* b1p = Bt + (size_t)col1 * K + kg * 8;

  f32x4 acc[2][2];
  #pragma unroll
  for (int i = 0; i < 2; i++)
    #pragma unroll
    for (int j = 0; j < 2; j++) { acc[i][j][0] = 0.f; acc[i][j][1] = 0.f; acc[i][j][2] = 0.f; acc[i][j][3] = 0.f; }

  for (int k0 = 0; k0 < K; k0 += 32) {
    bf16x8 a0 = v0 ? ldb8(a0p + k0) : zerob8();
    bf16x8 a1 = v1 ? ldb8(a1p + k0) : zerob8();
    bf16x8 b0 = ldb8(b0p + k0);
    bf16x8 b1 = ldb8(b1p + k0);
    acc[0][0] = mfma16(a0, b0, acc[0][0]);
    acc[0][1] = mfma16(a0, b1, acc[0][1]);
    acc[1][0] = mfma16(a1, b0, acc[1][0]);
    acc[1][1] = mfma16(a1, b1, acc[1][1]);
  }

  #pragma unroll
  for (int i = 0; i < 2; i++) {
    #pragma unroll
    for (int g = 0; g < 4; g++) {
      int row = rowBase + i * 16 + kg * 4 + g;
      if (row >= Mr) continue;
      #pragma unroll
      for (int j = 0; j < 2; j++) {
        int col = colBase + j * 16 + r;
        float v = acc[i][j][g];
        if (bias) v += bias[col];
        if (ACT == 1) v = fmaxf(v, 0.f);
        C[(size_t)row * N + col] = v;
      }
    }
  }
}

// sum split-K partials + bias + relu -> q (fp32) and qb (bf16, prescaled log2 e)
__global__ void fc_reduce(const float* __restrict__ part, const float* __restrict__ bias,
                          float* __restrict__ q, __bf16* __restrict__ qb, int nrows)
{
  int idx = blockIdx.x * 256 + threadIdx.x;       // nrows * H
  if (idx >= nrows * H) return;
  int col = idx & 255;
  float s = bias[col];
  for (int z = 0; z < FSPLIT; z++) s += part[(size_t)z * nrows * H + idx];
  s = fmaxf(s, 0.f);
  q[idx] = s;
  qb[idx] = (__bf16)(s * 1.44269504f);
}

// ------------------------- conv (block per test row) -----------------------
__global__ void conv_feat(const float* __restrict__ ent, const float* __restrict__ rel,
                          const float* __restrict__ sent, const int* __restrict__ tt,
                          const float* __restrict__ cw, const float* __restrict__ cb,
                          __bf16* __restrict__ out, int row0)
{
  __shared__ float f[3][258];
  __shared__ float wsm[CH * 9];
  __shared__ float bsm[CH];
  int i = row0 + blockIdx.x;
  int h = threadIdx.x;
  int j = (i < NT) ? i : i - NT;
  int a0 = (i < NT) ? tt[j * 3 + 0] : tt[j * 3 + 2];
  int a1 = (i < NT) ? tt[j * 3 + 1] : tt[j * 3 + 1] + NR;
  f[0][h + 1] = ent[(size_t)a0 * H + h];
  f[1][h + 1] = rel[(size_t)a1 * H + h];
  f[2][h + 1] = sent[(size_t)j * H + h];
  if (h < 3) { f[h][0] = 0.f; f[h][257] = 0.f; }
  for (int x = h; x < CH * 9; x += 256) wsm[x] = cw[x];
  if (h < CH) bsm[h] = cb[h];
  __syncthreads();
  __bf16* orow = out + (size_t)blockIdx.x * KFC;
  for (int c = 0; c < CH; c++) {
    const float* wc = wsm + c * 9;
    float s = bsm[c];
    #pragma unroll
    for (int ic = 0; ic < 3; ic++)
      s += wc[ic * 3 + 0] * f[ic][h] + wc[ic * 3 + 1] * f[ic][h + 1] + wc[ic * 3 + 2] * f[ic][h + 2];
    orow[(size_t)c * H + h] = (__bf16)fmaxf(s, 0.f);
  }
}

// one wave per row: nll[row] = log(sum_c part_l) - q[row].ent[tgt]
__global__ void lse_combine(const float* __restrict__ part_l, const float* __restrict__ qf,
                            const float* __restrict__ ent, const int* __restrict__ tt,
                            float* __restrict__ nll)
{
  int gid = blockIdx.x * 256 + threadIdx.x;
  int w = gid >> 6;
  if (w >= NT2) return;
  int lane = gid & 63;
  int j = (w < NT) ? w : w - NT;
  int tgt = (w < NT) ? tt[j * 3 + 2] : tt[j * 3 + 0];
  const float4 qa = ((const float4*)(qf + (size_t)w * H))[lane];
  const float4 ea = ((const float4*)(ent + (size_t)tgt * H))[lane];
  float d = qa.x * ea.x + qa.y * ea.y + qa.z * ea.z + qa.w * ea.w;
  float s = part_l[(size_t)lane * ROWPAD + w];
  #pragma unroll
  for (int o = 32; o > 0; o >>= 1) {
    d += __shfl_down(d, o, 64);
    s += __shfl_down(s, o, 64);
  }
  if (lane == 0) nll[w] = logf(s) - d;
}

__global__ void mean_nll(const float* __restrict__ nll, float* __restrict__ out)
{
  float s = 0.f;
  for (int i = threadIdx.x; i < NT2; i += 256) s += nll[i];
  s = block_sum256(s);
  if (threadIdx.x == 0) out[0] = s * (1.f / NT2);
}

// ------------------------- launcher ----------------------------------------
extern "C" void kernel_launch(void* const* d_in, const int* in_sizes, int n_in,
                              void* d_out, int out_size, void* d_ws, size_t ws_size,
                              hipStream_t stream)
{
  const float* dynamic_emb = (const float*)d_in[0];
  const float* emb_rel     = (const float*)d_in[1];
  const float* gru_W_ih    = (const float*)d_in[2];
  const float* gru_W_hh    = (const float*)d_in[3];
  const float* gru_b_ih    = (const float*)d_in[4];
  const float* gru_b_hh    = (const float*)d_in[5];
  const float* agg_W       = (const float*)d_in[6];
  const float* tg_W        = (const float*)d_in[7];
  const float* tg_b        = (const float*)d_in[8];
  const float* hev         = (const float*)d_in[9];
  const float* hrv         = (const float*)d_in[10];
  const float* conv_w      = (const float*)d_in[11];
  const float* conv_b      = (const float*)d_in[12];
  const float* fc_W        = (const float*)d_in[13];
  const float* fc_b        = (const float*)d_in[14];
  const float* sent        = (const float*)d_in[15];
  const int* edge_src = (const int*)d_in[16];
  const int* edge_rel = (const int*)d_in[17];
  const int* edge_dst = (const int*)d_in[18];
  const int* r_to_e   = (const int*)d_in[19];
  const int* r_ids    = (const int*)d_in[20];
  const int* he_row   = (const int*)d_in[21];
  const int* he_col   = (const int*)d_in[22];
  const int* hr_row   = (const int*)d_in[23];
  const int* hr_col   = (const int*)d_in[24];
  const int* tt       = (const int*)d_in[25];
  float* out = (float*)d_out;

  char* base = (char*)d_ws;
  size_t off = 0;
  auto alloc = [&](size_t bytes) { char* p = base + off; off += (bytes + 255) & ~(size_t)255; return p; };

  float* ent    = (float*)alloc((size_t)NE * H * 4);
  float* curr   = (float*)alloc((size_t)NE * H * 4);   // + tgbuf: conv_bf overlay (41 MB)
  float* tgbuf  = (float*)alloc((size_t)NE * H * 4);
  __bf16* convb = (__bf16*)curr;                        // 1600*12800*2 = 40.96 MB = curr+tgbuf
  __bf16* entb  = (__bf16*)alloc((size_t)NE * H * 2);
  __bf16* entb2 = (__bf16*)alloc((size_t)NE * H * 2);
  __bf16* accEb = (__bf16*)alloc((size_t)NE * H * 2);
  float* rel    = (float*)alloc((size_t)R2 * H * 4);
  float* accR   = (float*)alloc((size_t)R2 * H * 4);
  __bf16* relb  = (__bf16*)alloc((size_t)R2 * H * 2);
  __bf16* xinb  = (__bf16*)alloc((size_t)R2 * 2 * H * 2);
  float* gi     = (float*)alloc((size_t)R2 * H3 * 4);
  float* gh     = (float*)alloc((size_t)R2 * H3 * 4);
  float* qf     = (float*)alloc((size_t)NT2 * H * 4);
  __bf16* qb    = (__bf16*)alloc((size_t)NT2 * H * 2);
  float* part_l = (float*)alloc((size_t)NCHUNK * ROWPAD * 4);
  float* partM  = (float*)alloc((size_t)R2 * MSPLIT * H * 4);   // 4.1 MB
  float* fcpart = (float*)alloc((size_t)FSPLIT * 1600 * H * 4); // 16.4 MB
  float* nll    = (float*)alloc((size_t)NT2 * 4);
  __bf16* tgWtb = (__bf16*)alloc((size_t)H * H * 2);
  __bf16* aggWtb= (__bf16*)alloc((size_t)H * H * 2);
  __bf16* fcWtb = (__bf16*)alloc((size_t)H * KFC * 2);
  __bf16* Wihb  = (__bf16*)alloc((size_t)H3 * 2 * H * 2);
  __bf16* Whhb  = (__bf16*)alloc((size_t)H3 * H * 2);

  int* ip = (int*)alloc(0);
  size_t ioff = 0;
  auto ialloc = [&](size_t n) { int* p = ip + ioff; ioff += n; return p; };
  int* permM[TT]; int* sM[TT]; int* fidxM[TT];
  int* permE[TT]; int* sE[TT]; int* fsrcE[TT]; int* frelE[TT];
  for (int t = 0; t < TT; t++) { permM[t] = ialloc(M); sM[t] = ialloc(R2 + 1); fidxM[t] = ialloc(M); }
  for (int t = 0; t < TT; t++) {
    permE[t] = ialloc(NEDGE); sE[t] = ialloc(NE + 1);
    fsrcE[t] = ialloc(NEDGE); frelE[t] = ialloc(NEDGE);
  }
  int* permHE = ialloc(NNZ_E); int* sHE = ialloc(NE + 1);
  int* fcolHE = ialloc(NNZ_E); float* fvalHE = (float*)ialloc(NNZ_E);
  int* permHR = ialloc(NNZ_R); int* sHR = ialloc(R2 + 1);
  int* cnt    = ialloc(NE + 1);
  int* cursor = ialloc(NE + 1);

  auto build_csr = [&](const int* keys, int n, int nbins, int* start, int* perm) {
    hipMemsetAsync(cnt, 0, (size_t)nbins * 4, stream);
    hist_k<<<(n + 255) / 256, 256, 0, stream>>>(keys, n, cnt);
    scan_k<<<1, 256, 0, stream>>>(cnt, start, cursor, nbins);
    perm_k<<<(n + 255) / 256, 256, 0, stream>>>(keys, n, cursor, perm);
  };

  // weight prep (bf16)
  transpose_cast_k<<<dim3(H / 32, H / 32), 256, 0, stream>>>(tg_W, tgWtb, H, H);
  transpose_cast_k<<<dim3(H / 32, H / 32), 256, 0, stream>>>(agg_W, aggWtb, H, H);
  transpose_cast_k<<<dim3(KFC / 32, H / 32), 256, 0, stream>>>(fc_W, fcWtb, KFC, H);
  cast_bf16_k<<<(H3 * 2 * H / 8 + 255) / 256, 256, 0, stream>>>(gru_W_ih, Wihb, H3 * 2 * H / 8);
  cast_bf16_k<<<(H3 * H / 8 + 255) / 256, 256, 0, stream>>>(gru_W_hh, Whhb, H3 * H / 8);

  for (int t = 0; t < TT; t++) {
    build_csr(r_ids + (size_t)t * M, M, R2, sM[t], permM[t]);
    fuse1_k<<<(M + 255) / 256, 256, 0, stream>>>(r_to_e + (size_t)t * M, permM[t], M, fidxM[t]);
  }
  for (int t = 0; t < TT; t++) {
    build_csr(edge_dst + (size_t)t * NEDGE, NEDGE, NE, sE[t], permE[t]);
    fuse2_k<<<(NEDGE + 255) / 256, 256, 0, stream>>>(edge_src + (size_t)t * NEDGE,
        edge_rel + (size_t)t * NEDGE, permE[t], NEDGE, fsrcE[t], frelE[t]);
  }
  build_csr(he_row, NNZ_E, NE, sHE, permHE);
  fusev_k<<<(NNZ_E + 255) / 256, 256, 0, stream>>>(he_col, hev, permHE, NNZ_E, fcolHE, fvalHE);
  build_csr(hr_row, NNZ_R, R2, sHR, permHR);

  hipMemcpyAsync(ent, dynamic_emb, (size_t)NE * H * 4, hipMemcpyDeviceToDevice, stream);
  hipMemcpyAsync(rel, emb_rel, (size_t)R2 * H * 4, hipMemcpyDeviceToDevice, stream);

  constexpr int NEH8 = NE * H / 8, R2H8 = R2 * H / 8;
  constexpr int NE_RB = (NE + 127) / 128;

  cast_bf16_k<<<(NEH8 + 255) / 256, 256, 0, stream>>>(ent, entb, NEH8);
  cast_bf16_k<<<(R2H8 + 255) / 256, 256, 0, stream>>>(rel, relb, R2H8);

  for (int t = 0; t < TT; t++) {
    // --- rel update (GRU) ---
    gather_mean2_k<<<dim3(R2, MSPLIT), 256, 0, stream>>>(entb, fidxM[t], sM[t], partM);
    mean_combine_k<<<R2, 256, 0, stream>>>(partM, sM[t], accR);
    build_xin_bf<<<(R2 * 2 * H + 255) / 256, 256, 0, stream>>>(rel, accR, xinb);
    mfma_gemm<0><<<dim3(H3 / 64, (R2 + 63) / 64), 256, 0, stream>>>(
        xinb, Wihb, gru_b_ih, gi, R2, 2 * H, H3);
    mfma_gemm<0><<<dim3(H3 / 64, (R2 + 63) / 64), 256, 0, stream>>>(
        relb, Whhb, gru_b_hh, gh, R2, H, H3);
    gru_combine<<<(R2 * H + 255) / 256, 256, 0, stream>>>(gi, gh, rel, relb);

    // --- ent update ---
    panel_gemm<2><<<dim3(1, NE_RB), 256, 0, stream>>>(entb, tgWtb, tg_b, tgbuf, NE, H, 2);
    gather_edges2_k<<<NE, 256, 0, stream>>>(entb, relb, fsrcE[t], frelE[t], sE[t], accEb);
    panel_gemm<1><<<dim3(1, NE_RB), 256, 0, stream>>>(accEb, aggWtb, nullptr, curr, NE, H, 2);
    ent_update<<<(NE * H + 255) / 256, 256, 0, stream>>>(ent, entb, tgbuf, curr);
  }

  // --- hypergraph layers (ent side: fused bf16 out; ends in ent/entb) ---
  hyper2_k<<<NE, 256, 0, stream>>>(ent, entb, fvalHE, fcolHE, sHE, curr, entb2);
  hyper2_k<<<NE, 256, 0, stream>>>(curr, entb2, fvalHE, fcolHE, sHE, ent, entb);
  hyper_layer_k<<<R2, 256, 0, stream>>>(rel, hrv, hr_col, permHR, sHR, accR);
  hyper_layer_k<<<R2, 256, 0, stream>>>(accR, hrv, hr_col, permHR, sHR, rel);

  // --- conv + fc (3 chunks: 1600, 1600, 800 rows) ---
  for (int c = 0; c < 3; c++) {
    int row0 = c * 1600;
    int rows = min(1600, NT2 - row0);
    conv_feat<<<rows, 256, 0, stream>>>(ent, rel, sent, tt, conv_w, conv_b, convb, row0);
    fc_gemm<<<dim3(FSPLIT, (rows + 127) / 128), 256, 0, stream>>>(convb, fcWtb, fcpart, rows);
    fc_reduce<<<(rows * H + 255) / 256, 256, 0, stream>>>(
        fcpart, fc_b, qf + (size_t)row0 * H, qb + (size_t)row0 * H, rows);
  }

  // --- fused scores + LSE ---
  panel_gemm<3><<<dim3(32, 32), 256, 0, stream>>>(qb, entb, nullptr, part_l, NT2, NE, 5);
  lse_combine<<<(NT2 * 64 + 255) / 256, 256, 0, stream>>>(part_l, qf, ent, tt, nll);
  mean_nll<<<1, 256, 0, stream>>>(nll, out);
}

// Round 7
// 1379.050 us; speedup vs baseline: 6.5893x; 1.1824x over previous
//
#include <hip/hip_runtime.h>
#include <math.h>

#define DEV_INLINE __device__ __forceinline__

constexpr int H      = 256;
constexpr int NE     = 20000;
constexpr int NR     = 250;
constexpr int R2     = 500;
constexpr int TT     = 3;
constexpr int NEDGE  = 150000;
constexpr int M      = 200000;
constexpr int NNZ_E  = 320000;
constexpr int NNZ_R  = 8000;
constexpr int CH     = 50;
constexpr int NT     = 2000;
constexpr int NT2    = 4000;
constexpr int H3     = 3 * H;     // 768
constexpr int KFC    = CH * H;    // 12800
constexpr int ROWPAD = 4096;
constexpr int NCHUNK = 32;        // scores col chunks
constexpr int MSPLIT = 8;         // gather_mean row split
constexpr int FSPLIT = 10;        // fc split-K

// cnt/start/cursor packed region (ints)
constexpr int CNT_NE_BASE   = 2048;
constexpr int CNT_NE_STRIDE = 20224;
constexpr int CNT_TOTAL     = CNT_NE_BASE + 4 * CNT_NE_STRIDE;  // 82944

typedef __bf16 bf16x8 __attribute__((ext_vector_type(8)));
typedef __bf16 bf16x4 __attribute__((ext_vector_type(4)));
typedef float  f32x4  __attribute__((ext_vector_type(4)));

DEV_INLINE bf16x8 ldb8(const __bf16* p) { return *(const bf16x8*)p; }
DEV_INLINE bf16x8 zerob8() { uint4 z = make_uint4(0, 0, 0, 0); return __builtin_bit_cast(bf16x8, z); }
DEV_INLINE f32x4 mfma16(bf16x8 a, bf16x8 b, f32x4 c) {
  return __builtin_amdgcn_mfma_f32_16x16x32_bf16(a, b, c, 0, 0, 0);
}

// ------------------------- block reduction (blockDim == 256) ---------------
DEV_INLINE float block_sum256(float v) {
  __shared__ float ws[4];
  #pragma unroll
  for (int o = 32; o > 0; o >>= 1) v += __shfl_down(v, o, 64);
  if ((threadIdx.x & 63) == 0) ws[threadIdx.x >> 6] = v;
  __syncthreads();
  float r = ws[0] + ws[1] + ws[2] + ws[3];
  __syncthreads();
  return r;
}

// ------------------------- CSR build (int atomics only) --------------------
__global__ void hist_k(const int* __restrict__ keys, int n, int* __restrict__ cnt)
{
  int i = blockIdx.x * 256 + threadIdx.x;
  if (i < n) atomicAdd(&cnt[keys[i]], 1);
}

// grid 8: one block scans one CSR's bins
__global__ void scan_all_k(const int* __restrict__ cnt_all, int* __restrict__ start_all,
                           int* __restrict__ cursor_all)
{
  __shared__ int ps[257];
  int b = blockIdx.x;
  int off, nbins;
  if (b < 3)       { off = b * 512;                        nbins = R2; }
  else if (b == 3) { off = 1536;                           nbins = R2; }
  else if (b < 7)  { off = CNT_NE_BASE + (b - 4) * CNT_NE_STRIDE; nbins = NE; }
  else             { off = CNT_NE_BASE + 3 * CNT_NE_STRIDE;      nbins = NE; }
  const int* cnt = cnt_all + off;
  int* start  = start_all + off;
  int* cursor = cursor_all + off;

  int t = threadIdx.x;
  int per = (nbins + 255) >> 8;
  int b0 = t * per;
  int local = 0;
  for (int i = 0; i < per; i++) { int bb = b0 + i; if (bb < nbins) local += cnt[bb]; }
  ps[t + 1] = local;
  if (t == 0) ps[0] = 0;
  __syncthreads();
  if (t == 0) { for (int i = 1; i <= 256; i++) ps[i] += ps[i - 1]; }
  __syncthreads();
  int run = ps[t];
  for (int i = 0; i < per; i++) {
    int bb = b0 + i;
    if (bb < nbins) { start[bb] = run; cursor[bb] = run; run += cnt[bb]; }
  }
  if (t == 0) start[nbins] = ps[256];
}

__global__ void perm_k(const int* __restrict__ keys, int n,
                       int* __restrict__ cursor, int* __restrict__ perm)
{
  int i = blockIdx.x * 256 + threadIdx.x;
  if (i < n) { int p = atomicAdd(&cursor[keys[i]], 1); perm[p] = i; }
}

__global__ void fuse1_k(const int* __restrict__ key, const int* __restrict__ perm,
                        int n, int* __restrict__ out)
{
  int i = blockIdx.x * 256 + threadIdx.x;
  if (i < n) out[i] = key[perm[i]];
}
__global__ void fuse2_k(const int* __restrict__ k1, const int* __restrict__ k2,
                        const int* __restrict__ perm, int n,
                        int* __restrict__ o1, int* __restrict__ o2)
{
  int i = blockIdx.x * 256 + threadIdx.x;
  if (i < n) { int p = perm[i]; o1[i] = k1[p]; o2[i] = k2[p]; }
}
__global__ void fusev_k(const int* __restrict__ key, const float* __restrict__ val,
                        const int* __restrict__ perm, int n,
                        int* __restrict__ okey, float* __restrict__ oval)
{
  int i = blockIdx.x * 256 + threadIdx.x;
  if (i < n) { int p = perm[i]; okey[i] = key[p]; oval[i] = val[p]; }
}

// ------------------------- casts / transposes ------------------------------
__global__ void cast_bf16_k(const float* __restrict__ in, __bf16* __restrict__ out, int n8)
{
  int i = blockIdx.x * 256 + threadIdx.x;
  if (i >= n8) return;
  const float4* p = (const float4*)in + (size_t)i * 2;
  float4 u = p[0], v = p[1];
  bf16x8 o;
  o[0] = (__bf16)u.x; o[1] = (__bf16)u.y; o[2] = (__bf16)u.z; o[3] = (__bf16)u.w;
  o[4] = (__bf16)v.x; o[5] = (__bf16)v.y; o[6] = (__bf16)v.z; o[7] = (__bf16)v.w;
  ((bf16x8*)out)[i] = o;
}

__global__ void transpose_cast_k(const float* __restrict__ in, __bf16* __restrict__ out,
                                 int K, int N)
{
  __shared__ float tile[32][33];
  int tx = threadIdx.x & 31, ty = threadIdx.x >> 5;   // 32 x 8
  int kb = blockIdx.x * 32, nb = blockIdx.y * 32;
  #pragma unroll
  for (int i = 0; i < 4; i++)
    tile[ty + i * 8][tx] = in[(size_t)(kb + ty + i * 8) * N + nb + tx];
  __syncthreads();
  #pragma unroll
  for (int i = 0; i < 4; i++)
    out[(size_t)(nb + ty + i * 8) * K + kb + tx] = (__bf16)tile[tx][ty + i * 8];
}

// ------------------------- gather kernels (wave-per-entry) -----------------
DEV_INLINE void bf4acc(const __bf16* p, float& a0, float& a1, float& a2, float& a3)
{
  bf16x4 v = *(const bf16x4*)p;
  a0 += (float)v[0]; a1 += (float)v[1]; a2 += (float)v[2]; a3 += (float)v[3];
}
DEV_INLINE void bf4accw(const __bf16* p, float wgt, float& a0, float& a1, float& a2, float& a3)
{
  bf16x4 v = *(const bf16x4*)p;
  a0 += wgt * (float)v[0]; a1 += wgt * (float)v[1]; a2 += wgt * (float)v[2]; a3 += wgt * (float)v[3];
}

// grid (R2, MSPLIT): partial sums into part[(r*MSPLIT+s)*H + h]
__global__ void gather_mean2_k(const __bf16* __restrict__ src, const int* __restrict__ fidx,
                               const int* __restrict__ start, float* __restrict__ part)
{
  __shared__ __align__(16) float red[4][H];
  int r = blockIdx.x, s = blockIdx.y;
  int s0 = start[r], s1 = start[r + 1];
  int len = s1 - s0;
  int chunk = (len + MSPLIT - 1) / MSPLIT;
  int jb = s0 + s * chunk, je = min(jb + chunk, s1);
  int lane = threadIdx.x & 63, w = threadIdx.x >> 6;
  float a0 = 0.f, a1 = 0.f, a2 = 0.f, a3 = 0.f;
  int j = jb + w;
  for (; j + 12 < je; j += 16) {
    int e0 = fidx[j], e1 = fidx[j + 4], e2 = fidx[j + 8], e3 = fidx[j + 12];
    bf4acc(src + (size_t)e0 * H + lane * 4, a0, a1, a2, a3);
    bf4acc(src + (size_t)e1 * H + lane * 4, a0, a1, a2, a3);
    bf4acc(src + (size_t)e2 * H + lane * 4, a0, a1, a2, a3);
    bf4acc(src + (size_t)e3 * H + lane * 4, a0, a1, a2, a3);
  }
  for (; j < je; j += 4)
    bf4acc(src + (size_t)fidx[j] * H + lane * 4, a0, a1, a2, a3);
  *(float4*)&red[w][lane * 4] = make_float4(a0, a1, a2, a3);
  __syncthreads();
  int h = threadIdx.x;
  part[((size_t)r * MSPLIT + s) * H + h] = red[0][h] + red[1][h] + red[2][h] + red[3][h];
}

// grid R2: mean-combine + build xin (bf16 [rel | xmean])
__global__ void mean_xin_k(const float* __restrict__ partM, const int* __restrict__ start,
                           const float* __restrict__ rel, __bf16* __restrict__ xin)
{
  int r = blockIdx.x, h = threadIdx.x;
  float s = 0.f;
  #pragma unroll
  for (int z = 0; z < MSPLIT; z++) s += partM[((size_t)r * MSPLIT + z) * H + h];
  float xm = s / (float)max(start[r + 1] - start[r], 1);
  xin[(size_t)r * 2 * H + h]     = (__bf16)rel[(size_t)r * H + h];
  xin[(size_t)r * 2 * H + H + h] = (__bf16)xm;
}

// grid NE: out[d] = mean(ent[fsrc]+rel[frel]) in bf16
__global__ void gather_edges2_k(const __bf16* __restrict__ ent, const __bf16* __restrict__ rel,
                                const int* __restrict__ fsrc, const int* __restrict__ frel,
                                const int* __restrict__ start, __bf16* __restrict__ out)
{
  __shared__ __align__(16) float red[4][H];
  int d = blockIdx.x;
  int s0 = start[d], s1 = start[d + 1];
  int lane = threadIdx.x & 63, w = threadIdx.x >> 6;
  float a0 = 0.f, a1 = 0.f, a2 = 0.f, a3 = 0.f;
  int j = s0 + w;
  for (; j + 4 < s1; j += 8) {
    int es0 = fsrc[j], er0 = frel[j];
    int es1 = fsrc[j + 4], er1 = frel[j + 4];
    bf4acc(ent + (size_t)es0 * H + lane * 4, a0, a1, a2, a3);
    bf4acc(rel + (size_t)er0 * H + lane * 4, a0, a1, a2, a3);
    bf4acc(ent + (size_t)es1 * H + lane * 4, a0, a1, a2, a3);
    bf4acc(rel + (size_t)er1 * H + lane * 4, a0, a1, a2, a3);
  }
  for (; j < s1; j += 4) {
    bf4acc(ent + (size_t)fsrc[j] * H + lane * 4, a0, a1, a2, a3);
    bf4acc(rel + (size_t)frel[j] * H + lane * 4, a0, a1, a2, a3);
  }
  *(float4*)&red[w][lane * 4] = make_float4(a0, a1, a2, a3);
  __syncthreads();
  int h = threadIdx.x;
  float sum = red[0][h] + red[1][h] + red[2][h] + red[3][h];
  out[(size_t)d * H + h] = (__bf16)(sum / (float)max(s1 - s0, 1));
}

// grid NE: xout = x + y/||y||, y = sum fval*xb[fcol]; also emits bf16 copy
__global__ void hyper2_k(const float* __restrict__ x, const __bf16* __restrict__ xb,
                         const float* __restrict__ fval, const int* __restrict__ fcol,
                         const int* __restrict__ start,
                         float* __restrict__ xout, __bf16* __restrict__ xoutb)
{
  __shared__ __align__(16) float red[4][H];
  int r = blockIdx.x;
  int s0 = start[r], s1 = start[r + 1];
  int lane = threadIdx.x & 63, w = threadIdx.x >> 6;
  float a0 = 0.f, a1 = 0.f, a2 = 0.f, a3 = 0.f;
  int j = s0 + w;
  for (; j + 12 < s1; j += 16) {
    int e0 = fcol[j], e1 = fcol[j + 4], e2 = fcol[j + 8], e3 = fcol[j + 12];
    float w0 = fval[j], w1 = fval[j + 4], w2 = fval[j + 8], w3 = fval[j + 12];
    bf4accw(xb + (size_t)e0 * H + lane * 4, w0, a0, a1, a2, a3);
    bf4accw(xb + (size_t)e1 * H + lane * 4, w1, a0, a1, a2, a3);
    bf4accw(xb + (size_t)e2 * H + lane * 4, w2, a0, a1, a2, a3);
    bf4accw(xb + (size_t)e3 * H + lane * 4, w3, a0, a1, a2, a3);
  }
  for (; j < s1; j += 4)
    bf4accw(xb + (size_t)fcol[j] * H + lane * 4, fval[j], a0, a1, a2, a3);
  *(float4*)&red[w][lane * 4] = make_float4(a0, a1, a2, a3);
  __syncthreads();
  int h = threadIdx.x;
  float y = red[0][h] + red[1][h] + red[2][h] + red[3][h];
  float ss = block_sum256(y * y);
  float rn = 1.f / fmaxf(sqrtf(ss), 1e-12f);
  float o = x[(size_t)r * H + h] + y * rn;
  xout[(size_t)r * H + h] = o;
  xoutb[(size_t)r * H + h] = (__bf16)o;
}

// fp32 perm-based variant (small rel graph only)
__global__ void hyper_layer_k(const float* __restrict__ x, const float* __restrict__ val,
                              const int* __restrict__ col, const int* __restrict__ perm,
                              const int* __restrict__ start, float* __restrict__ xout)
{
  int r = blockIdx.x, h = threadIdx.x;
  int s0 = start[r], s1 = start[r + 1];
  float a0 = 0.f;
  for (int j = s0; j < s1; j++) { int e = perm[j]; a0 += val[e] * x[(size_t)col[e] * H + h]; }
  float ss = block_sum256(a0 * a0);
  float rn = 1.f / fmaxf(sqrtf(ss), 1e-12f);
  xout[(size_t)r * H + h] = x[(size_t)r * H + h] + a0 * rn;
}

// ------------------------- small elementwise -------------------------------
__global__ void gru_combine(const float* __restrict__ gi, const float* __restrict__ gh,
                            float* __restrict__ rel, __bf16* __restrict__ relb)
{
  int idx = blockIdx.x * 256 + threadIdx.x;       // R2 * H
  if (idx >= R2 * H) return;
  int i = idx >> 8, h = idx & 255;
  const float* gir = gi + (size_t)i * H3;
  const float* ghr = gh + (size_t)i * H3;
  float r = 1.f / (1.f + __expf(-(gir[h]       + ghr[h])));
  float z = 1.f / (1.f + __expf(-(gir[H + h]   + ghr[H + h])));
  float n = tanhf(gir[2 * H + h] + r * ghr[2 * H + h]);
  float o = (1.f - z) * n + z * rel[idx];
  rel[idx] = o;
  relb[idx] = (__bf16)o;
}

__global__ void ent_update(float* __restrict__ ent, __bf16* __restrict__ entb,
                           const float* __restrict__ tw, const float* __restrict__ curr)
{
  int idx = blockIdx.x * 256 + threadIdx.x;       // NE * H
  if (idx >= NE * H) return;
  float t = tw[idx];
  float v = t * curr[idx] + (1.f - t) * ent[idx];
  ent[idx] = v;
  entb[idx] = (__bf16)v;
}

// ------------------------- panel2 GEMM (K=256, dbuf 64-col B panels) --------
// A: M x 256 bf16. B: N x 256 bf16 (operand rows = output cols).
// Block = 4 row-waves x 32 rows = 128 rows. B panels of 64 cols double-buffered
// (2 x 32 KB LDS). T14: issue next panel's loads before MFMA, ds_write after.
// EPI: 1 = bias+relu store, 2 = bias+sigmoid store,
//      3 = exp2-rowsum into out[bx*ROWPAD + row] (cols masked to < N)
DEV_INLINE void stage64_load(uint4* v, const __bf16* src, int rowBase, int rowLimit, int tid)
{
  #pragma unroll
  for (int q = 0; q < 8; q++) {
    int X = (q * 256 + tid) * 16;
    int row = X >> 9, boff = X & 511;
    int grow = min(rowBase + row, rowLimit);
    v[q] = *(const uint4*)((const char*)src + (size_t)grow * 512 + boff);
  }
}
DEV_INLINE void stage64_write(char* lds, const uint4* v, int tid)
{
  #pragma unroll
  for (int q = 0; q < 8; q++) {
    int X = (q * 256 + tid) * 16;
    int row = X >> 9;
    *(uint4*)(lds + (X ^ ((row & 7) << 4))) = v[q];
  }
}
DEV_INLINE bf16x8 frag64(const char* lds, int row, int kf, int kg)
{
  int off = (kf * 64 + kg * 16) ^ ((row & 7) << 4);
  return *(const bf16x8*)(lds + row * 512 + off);
}

template<int EPI>
__global__ __launch_bounds__(256) void panel2_gemm(const __bf16* __restrict__ A,
                                                   const __bf16* __restrict__ B,
                                                   const float* __restrict__ bias,
                                                   float* __restrict__ out,
                                                   int Mr, int N, int PS)
{
  __shared__ __attribute__((aligned(16))) char lds0[32768];
  __shared__ __attribute__((aligned(16))) char lds1[32768];
  int tid = threadIdx.x;
  int lane = tid & 63, wM = tid >> 6;
  int r = lane & 15, kg = lane >> 4;
  int rowBase = blockIdx.y * 128;

  uint4 va[8], vb[8];
  stage64_load(va, A, rowBase, Mr - 1, tid);
  stage64_load(vb, A, rowBase + 64, Mr - 1, tid);
  stage64_write(lds0, va, tid);
  stage64_write(lds1, vb, tid);
  __syncthreads();

  bf16x8 a[2][8];
  {
    int base = wM * 32;
    const char* ab = (base >= 64) ? lds1 : lds0;
    #pragma unroll
    for (int i = 0; i < 2; i++) {
      int ar = (base + i * 16 + r) & 63;
      #pragma unroll
      for (int kf = 0; kf < 8; kf++) a[i][kf] = frag64(ab, ar, kf, kg);
    }
  }
  int p0 = blockIdx.x * PS;
  stage64_load(va, B, p0 * 64, N - 1, tid);
  __syncthreads();                 // all waves done reading A from LDS
  stage64_write(lds0, va, tid);
  __syncthreads();                 // panel 0 ready

  float lsum[2][4];
  if (EPI == 3) {
    #pragma unroll
    for (int i = 0; i < 2; i++)
      #pragma unroll
      for (int g = 0; g < 4; g++) lsum[i][g] = 0.f;
  }

  for (int p = 0; p < PS; p++) {
    char* cur = (p & 1) ? lds1 : lds0;
    char* nxt = (p & 1) ? lds0 : lds1;
    bool pre = (p + 1 < PS);
    if (pre) stage64_load(va, B, (p0 + p + 1) * 64, N - 1, tid);   // loads in flight

    f32x4 acc[2][4];
    #pragma unroll
    for (int i = 0; i < 2; i++)
      #pragma unroll
      for (int j = 0; j < 4; j++) {
        acc[i][j][0] = 0.f; acc[i][j][1] = 0.f; acc[i][j][2] = 0.f; acc[i][j][3] = 0.f;
      }
    #pragma unroll
    for (int kf = 0; kf < 8; kf++) {
      bf16x8 b[4];
      #pragma unroll
      for (int j = 0; j < 4; j++) b[j] = frag64(cur, j * 16 + r, kf, kg);
      #pragma unroll
      for (int i = 0; i < 2; i++)
        #pragma unroll
        for (int j = 0; j < 4; j++)
          acc[i][j] = mfma16(a[i][kf], b[j], acc[i][j]);
    }
    if (pre) stage64_write(nxt, va, tid);   // vmcnt wait lands here, after compute

    if (EPI == 3) {
      #pragma unroll
      for (int j = 0; j < 4; j++) {
        int col = (p0 + p) * 64 + j * 16 + r;
        bool ok = col < N;
        #pragma unroll
        for (int i = 0; i < 2; i++)
          #pragma unroll
          for (int g = 0; g < 4; g++)
            lsum[i][g] += ok ? exp2f(acc[i][j][g]) : 0.f;
      }
    } else {
      #pragma unroll
      for (int i = 0; i < 2; i++)
        #pragma unroll
        for (int g = 0; g < 4; g++) {
          int row = rowBase + wM * 32 + i * 16 + kg * 4 + g;
          if (row >= Mr) continue;
          #pragma unroll
          for (int j = 0; j < 4; j++) {
            int col = (p0 + p) * 64 + j * 16 + r;
            if (col >= N) continue;
            float v = acc[i][j][g];
            if (bias) v += bias[col];
            if (EPI == 1) v = fmaxf(v, 0.f);
            if (EPI == 2) v = 1.f / (1.f + __expf(-v));
            out[(size_t)row * N + col] = v;
          }
        }
    }
    __syncthreads();
  }

  if (EPI == 3) {
    #pragma unroll
    for (int m = 1; m < 16; m <<= 1)
      #pragma unroll
      for (int i = 0; i < 2; i++)
        #pragma unroll
        for (int g = 0; g < 4; g++)
          lsum[i][g] += __shfl_xor(lsum[i][g], m, 64);
    if (r == 0) {
      #pragma unroll
      for (int i = 0; i < 2; i++)
        #pragma unroll
        for (int g = 0; g < 4; g++) {
          int row = rowBase + wM * 32 + i * 16 + kg * 4 + g;
          out[(size_t)blockIdx.x * ROWPAD + row] = lsum[i][g];
        }
    }
  }
}

// ------------------------- fc GEMM (K = 12800, LDS-staged, split-K) --------
__global__ __launch_bounds__(256) void fc_gemm(const __bf16* __restrict__ A,
                                               const __bf16* __restrict__ Bt,
                                               float* __restrict__ part, int Mr)
{
  __shared__ __attribute__((aligned(16))) char lds[49152];
  int tid = threadIdx.x;
  int lane = tid & 63, wave = tid >> 6;
  int wM = wave >> 1, wN = wave & 1;
  int r = lane & 15, kg = lane >> 4;
  int rowBase = blockIdx.y * 128;
  int kbeg = blockIdx.x * (KFC / FSPLIT);   // 1280

  f32x4 acc[4][8];
  #pragma unroll
  for (int i = 0; i < 4; i++)
    #pragma unroll
    for (int j = 0; j < 8; j++) {
      acc[i][j][0] = 0.f; acc[i][j][1] = 0.f; acc[i][j][2] = 0.f; acc[i][j][3] = 0.f;
    }

  for (int ks = 0; ks < 20; ks++) {
    int kb = kbeg + ks * 64;
    #pragma unroll
    for (int q = 0; q < 12; q++) {
      int X = (q * 256 + tid) * 16;
      int row = X >> 7;
      int off = X & 127;
      int soff = off ^ ((row & 7) << 4);
      uint4 v;
      if (row < 128) {
        int grow = min(rowBase + row, Mr - 1);
        v = *(const uint4*)((const char*)A + (size_t)grow * (KFC * 2) + kb * 2 + soff);
      } else {
        int col = row - 128;
        v = *(const uint4*)((const char*)Bt + (size_t)col * (KFC * 2) + kb * 2 + soff);
      }
      *(uint4*)(lds + X) = v;
    }
    __syncthreads();
    #pragma unroll
    for (int kf = 0; kf < 2; kf++) {
      bf16x8 a[4], b[8];
      #pragma unroll
      for (int i = 0; i < 4; i++) {
        int row = wM * 64 + i * 16 + r;
        int off = (kf * 64 + kg * 16) ^ ((row & 7) << 4);
        a[i] = *(const bf16x8*)(lds + row * 128 + off);
      }
      #pragma unroll
      for (int j = 0; j < 8; j++) {
        int row = 128 + wN * 128 + j * 16 + r;
        int off = (kf * 64 + kg * 16) ^ ((row & 7) << 4);
        b[j] = *(const bf16x8*)(lds + row * 128 + off);
      }
      #pragma unroll
      for (int i = 0; i < 4; i++)
        #pragma unroll
        for (int j = 0; j < 8; j++)
          acc[i][j] = mfma16(a[i], b[j], acc[i][j]);
    }
    __syncthreads();
  }

  float* pz = part + (size_t)blockIdx.x * Mr * H;
  #pragma unroll
  for (int i = 0; i < 4; i++)
    #pragma unroll
    for (int g = 0; g < 4; g++) {
      int row = rowBase + wM * 64 + i * 16 + kg * 4 + g;
      if (row >= Mr) continue;
      #pragma unroll
      for (int j = 0; j < 8; j++) {
        int col = wN * 128 + j * 16 + r;
        pz[(size_t)row * H + col] = acc[i][j][g];
      }
    }
}

// ------------------------- generic MFMA GEMM (GRU) -------------------------
template<int ACT>
__global__ void mfma_gemm(const __bf16* __restrict__ A, const __bf16* __restrict__ Bt,
                          const float* __restrict__ bias, float* __restrict__ C,
                          int Mr, int K, int N)
{
  int lane = threadIdx.x & 63, wave = threadIdx.x >> 6;
  int waveM = wave >> 1, waveN = wave & 1;
  int r = lane & 15, kg = lane >> 4;
  int rowBase = blockIdx.y * 64 + waveM * 32;
  int colBase = blockIdx.x * 64 + waveN * 32;

  int row0 = rowBase + r, row1 = rowBase + 16 + r;
  int col0 = colBase + r, col1 = colBase + 16 + r;
  bool v0 = row0 < Mr, v1 = row1 < Mr;
  const __bf16* a0p = A + (size_t)row0 * K + kg * 8;
  const __bf16* a1p = A + (size_t)row1 * K + kg * 8;
  const __bf16* b0p = Bt + (size_t)col0 * K + kg * 8;
  const __bf16* b1p = Bt + (size_t)col1 * K + kg * 8;

  f32x4 acc[2][2];
  #pragma unroll
  for (int i = 0; i < 2; i++)
    #pragma unroll
    for (int j = 0; j < 2; j++) { acc[i][j][0] = 0.f; acc[i][j][1] = 0.f; acc[i][j][2] = 0.f; acc[i][j][3] = 0.f; }

  for (int k0 = 0; k0 < K; k0 += 32) {
    bf16x8 a0 = v0 ? ldb8(a0p + k0) : zerob8();
    bf16x8 a1 = v1 ? ldb8(a1p + k0) : zerob8();
    bf16x8 b0 = ldb8(b0p + k0);
    bf16x8 b1 = ldb8(b1p + k0);
    acc[0][0] = mfma16(a0, b0, acc[0][0]);
    acc[0][1] = mfma16(a0, b1, acc[0][1]);
    acc[1][0] = mfma16(a1, b0, acc[1][0]);
    acc[1][1] = mfma16(a1, b1, acc[1][1]);
  }

  #pragma unroll
  for (int i = 0; i < 2; i++) {
    #pragma unroll
    for (int g = 0; g < 4; g++) {
      int row = rowBase + i * 16 + kg * 4 + g;
      if (row >= Mr) continue;
      #pragma unroll
      for (int j = 0; j < 2; j++) {
        int col = colBase + j * 16 + r;
        float v = acc[i][j][g];
        if (bias) v += bias[col];
        if (ACT == 1) v = fmaxf(v, 0.f);
        C[(size_t)row * N + col] = v;
      }
    }
  }
}

// sum split-K partials + bias + relu -> q (fp32) and qb (bf16, prescaled log2 e)
__global__ void fc_reduce(const float* __restrict__ part, const float* __restrict__ bias,
                          float* __restrict__ q, __bf16* __restrict__ qb, int nrows)
{
  int idx = blockIdx.x * 256 + threadIdx.x;       // nrows * H
  if (idx >= nrows * H) return;
  int col = idx & 255;
  float s = bias[col];
  for (int z = 0; z < FSPLIT; z++) s += part[(size_t)z * nrows * H + idx];
  s = fmaxf(s, 0.f);
  q[idx] = s;
  qb[idx] = (__bf16)(s * 1.44269504f);
}

// ------------------------- conv (block per test row) -----------------------
__global__ void conv_feat(const float* __restrict__ ent, const float* __restrict__ rel,
                          const float* __restrict__ sent, const int* __restrict__ tt,
                          const float* __restrict__ cw, const float* __restrict__ cb,
                          __bf16* __restrict__ out, int row0)
{
  __shared__ float f[3][258];
  __shared__ float wsm[CH * 9];
  __shared__ float bsm[CH];
  int i = row0 + blockIdx.x;
  int h = threadIdx.x;
  int j = (i < NT) ? i : i - NT;
  int a0 = (i < NT) ? tt[j * 3 + 0] : tt[j * 3 + 2];
  int a1 = (i < NT) ? tt[j * 3 + 1] : tt[j * 3 + 1] + NR;
  f[0][h + 1] = ent[(size_t)a0 * H + h];
  f[1][h + 1] = rel[(size_t)a1 * H + h];
  f[2][h + 1] = sent[(size_t)j * H + h];
  if (h < 3) { f[h][0] = 0.f; f[h][257] = 0.f; }
  for (int x = h; x < CH * 9; x += 256) wsm[x] = cw[x];
  if (h < CH) bsm[h] = cb[h];
  __syncthreads();
  __bf16* orow = out + (size_t)blockIdx.x * KFC;
  for (int c = 0; c < CH; c++) {
    const float* wc = wsm + c * 9;
    float s = bsm[c];
    #pragma unroll
    for (int ic = 0; ic < 3; ic++)
      s += wc[ic * 3 + 0] * f[ic][h] + wc[ic * 3 + 1] * f[ic][h + 1] + wc[ic * 3 + 2] * f[ic][h + 2];
    orow[(size_t)c * H + h] = (__bf16)fmaxf(s, 0.f);
  }
}

// one wave per row: nll[row] = log(sum_c part_l) - q[row].ent[tgt]
__global__ void lse_combine(const float* __restrict__ part_l, const float* __restrict__ qf,
                            const float* __restrict__ ent, const int* __restrict__ tt,
                            float* __restrict__ nll)
{
  int gid = blockIdx.x * 256 + threadIdx.x;
  int w = gid >> 6;
  if (w >= NT2) return;
  int lane = gid & 63;
  int j = (w < NT) ? w : w - NT;
  int tgt = (w < NT) ? tt[j * 3 + 2] : tt[j * 3 + 0];
  const float4 qa = ((const float4*)(qf + (size_t)w * H))[lane];
  const float4 ea = ((const float4*)(ent + (size_t)tgt * H))[lane];
  float d = qa.x * ea.x + qa.y * ea.y + qa.z * ea.z + qa.w * ea.w;
  float s = (lane < NCHUNK) ? part_l[(size_t)lane * ROWPAD + w] : 0.f;
  #pragma unroll
  for (int o = 32; o > 0; o >>= 1) {
    d += __shfl_down(d, o, 64);
    s += __shfl_down(s, o, 64);
  }
  if (lane == 0) nll[w] = logf(s) - d;
}

__global__ void mean_nll(const float* __restrict__ nll, float* __restrict__ out)
{
  float s = 0.f;
  for (int i = threadIdx.x; i < NT2; i += 256) s += nll[i];
  s = block_sum256(s);
  if (threadIdx.x == 0) out[0] = s * (1.f / NT2);
}

// ------------------------- launcher ----------------------------------------
extern "C" void kernel_launch(void* const* d_in, const int* in_sizes, int n_in,
                              void* d_out, int out_size, void* d_ws, size_t ws_size,
                              hipStream_t stream)
{
  const float* dynamic_emb = (const float*)d_in[0];
  const float* emb_rel     = (const float*)d_in[1];
  const float* gru_W_ih    = (const float*)d_in[2];
  const float* gru_W_hh    = (const float*)d_in[3];
  const float* gru_b_ih    = (const float*)d_in[4];
  const float* gru_b_hh    = (const float*)d_in[5];
  const float* agg_W       = (const float*)d_in[6];
  const float* tg_W        = (const float*)d_in[7];
  const float* tg_b        = (const float*)d_in[8];
  const float* hev         = (const float*)d_in[9];
  const float* hrv         = (const float*)d_in[10];
  const float* conv_w      = (const float*)d_in[11];
  const float* conv_b      = (const float*)d_in[12];
  const float* fc_W        = (const float*)d_in[13];
  const float* fc_b        = (const float*)d_in[14];
  const float* sent        = (const float*)d_in[15];
  const int* edge_src = (const int*)d_in[16];
  const int* edge_rel = (const int*)d_in[17];
  const int* edge_dst = (const int*)d_in[18];
  const int* r_to_e   = (const int*)d_in[19];
  const int* r_ids    = (const int*)d_in[20];
  const int* he_row   = (const int*)d_in[21];
  const int* he_col   = (const int*)d_in[22];
  const int* hr_row   = (const int*)d_in[23];
  const int* hr_col   = (const int*)d_in[24];
  const int* tt       = (const int*)d_in[25];
  float* out = (float*)d_out;

  char* base = (char*)d_ws;
  size_t off = 0;
  auto alloc = [&](size_t bytes) { char* p = base + off; off += (bytes + 255) & ~(size_t)255; return p; };

  float* ent    = (float*)alloc((size_t)NE * H * 4);
  float* curr   = (float*)alloc((size_t)NE * H * 4);   // + tgbuf: conv_bf overlay (41 MB)
  float* tgbuf  = (float*)alloc((size_t)NE * H * 4);
  __bf16* convb = (__bf16*)curr;                        // 1600*12800*2 = 40.96 MB
  __bf16* entb  = (__bf16*)alloc((size_t)NE * H * 2);
  __bf16* entb2 = (__bf16*)alloc((size_t)NE * H * 2);
  __bf16* accEb = (__bf16*)alloc((size_t)NE * H * 2);
  float* rel    = (float*)alloc((size_t)R2 * H * 4);
  float* accR   = (float*)alloc((size_t)R2 * H * 4);
  __bf16* relb  = (__bf16*)alloc((size_t)R2 * H * 2);
  __bf16* xinb  = (__bf16*)alloc((size_t)R2 * 2 * H * 2);
  float* gi     = (float*)alloc((size_t)R2 * H3 * 4);
  float* gh     = (float*)alloc((size_t)R2 * H3 * 4);
  float* qf     = (float*)alloc((size_t)NT2 * H * 4);
  __bf16* qb    = (__bf16*)alloc((size_t)NT2 * H * 2);
  float* part_l = (float*)alloc((size_t)NCHUNK * ROWPAD * 4);
  float* partM  = (float*)alloc((size_t)R2 * MSPLIT * H * 4);
  float* fcpart = (float*)alloc((size_t)FSPLIT * 1600 * H * 4);
  float* nll    = (float*)alloc((size_t)NT2 * 4);
  __bf16* tgWtb = (__bf16*)alloc((size_t)H * H * 2);
  __bf16* aggWtb= (__bf16*)alloc((size_t)H * H * 2);
  __bf16* fcWtb = (__bf16*)alloc((size_t)H * KFC * 2);
  __bf16* Wihb  = (__bf16*)alloc((size_t)H3 * 2 * H * 2);
  __bf16* Whhb  = (__bf16*)alloc((size_t)H3 * H * 2);

  int* ip = (int*)alloc(0);
  size_t ioff = 0;
  auto ialloc = [&](size_t n) { int* p = ip + ioff; ioff += n; return p; };
  int* permM[TT]; int* fidxM[TT];
  int* permE[TT]; int* fsrcE[TT]; int* frelE[TT];
  for (int t = 0; t < TT; t++) { permM[t] = ialloc(M); fidxM[t] = ialloc(M); }
  for (int t = 0; t < TT; t++) {
    permE[t] = ialloc(NEDGE); fsrcE[t] = ialloc(NEDGE); frelE[t] = ialloc(NEDGE);
  }
  int* permHE = ialloc(NNZ_E);
  int* fcolHE = ialloc(NNZ_E); float* fvalHE = (float*)ialloc(NNZ_E);
  int* permHR = ialloc(NNZ_R);
  int* cnt_all    = ialloc(CNT_TOTAL);
  int* start_all  = ialloc(CNT_TOTAL);
  int* cursor_all = ialloc(CNT_TOTAL);

  // CSR slot offsets: 0-2 = r_ids t; 3 = hr; 4-6 = edge_dst t; 7 = he
  int* sM[TT];  for (int t = 0; t < TT; t++) sM[t] = start_all + t * 512;
  int* sHR = start_all + 1536;
  int* sE[TT];  for (int t = 0; t < TT; t++) sE[t] = start_all + CNT_NE_BASE + t * CNT_NE_STRIDE;
  int* sHE = start_all + CNT_NE_BASE + 3 * CNT_NE_STRIDE;

  // --- weight prep (bf16) ---
  transpose_cast_k<<<dim3(H / 32, H / 32), 256, 0, stream>>>(tg_W, tgWtb, H, H);
  transpose_cast_k<<<dim3(H / 32, H / 32), 256, 0, stream>>>(agg_W, aggWtb, H, H);
  transpose_cast_k<<<dim3(KFC / 32, H / 32), 256, 0, stream>>>(fc_W, fcWtb, KFC, H);
  cast_bf16_k<<<(H3 * 2 * H / 8 + 255) / 256, 256, 0, stream>>>(gru_W_ih, Wihb, H3 * 2 * H / 8);
  cast_bf16_k<<<(H3 * H / 8 + 255) / 256, 256, 0, stream>>>(gru_W_hh, Whhb, H3 * H / 8);

  // --- batched CSR build ---
  hipMemsetAsync(cnt_all, 0, (size_t)CNT_TOTAL * 4, stream);
  for (int t = 0; t < TT; t++)
    hist_k<<<(M + 255) / 256, 256, 0, stream>>>(r_ids + (size_t)t * M, M, cnt_all + t * 512);
  hist_k<<<(NNZ_R + 255) / 256, 256, 0, stream>>>(hr_row, NNZ_R, cnt_all + 1536);
  for (int t = 0; t < TT; t++)
    hist_k<<<(NEDGE + 255) / 256, 256, 0, stream>>>(edge_dst + (size_t)t * NEDGE, NEDGE,
                                                    cnt_all + CNT_NE_BASE + t * CNT_NE_STRIDE);
  hist_k<<<(NNZ_E + 255) / 256, 256, 0, stream>>>(he_row, NNZ_E,
                                                  cnt_all + CNT_NE_BASE + 3 * CNT_NE_STRIDE);
  scan_all_k<<<8, 256, 0, stream>>>(cnt_all, start_all, cursor_all);
  for (int t = 0; t < TT; t++)
    perm_k<<<(M + 255) / 256, 256, 0, stream>>>(r_ids + (size_t)t * M, M,
                                                cursor_all + t * 512, permM[t]);
  perm_k<<<(NNZ_R + 255) / 256, 256, 0, stream>>>(hr_row, NNZ_R, cursor_all + 1536, permHR);
  for (int t = 0; t < TT; t++)
    perm_k<<<(NEDGE + 255) / 256, 256, 0, stream>>>(edge_dst + (size_t)t * NEDGE, NEDGE,
        cursor_all + CNT_NE_BASE + t * CNT_NE_STRIDE, permE[t]);
  perm_k<<<(NNZ_E + 255) / 256, 256, 0, stream>>>(he_row, NNZ_E,
      cursor_all + CNT_NE_BASE + 3 * CNT_NE_STRIDE, permHE);
  for (int t = 0; t < TT; t++)
    fuse1_k<<<(M + 255) / 256, 256, 0, stream>>>(r_to_e + (size_t)t * M, permM[t], M, fidxM[t]);
  for (int t = 0; t < TT; t++)
    fuse2_k<<<(NEDGE + 255) / 256, 256, 0, stream>>>(edge_src + (size_t)t * NEDGE,
        edge_rel + (size_t)t * NEDGE, permE[t], NEDGE, fsrcE[t], frelE[t]);
  fusev_k<<<(NNZ_E + 255) / 256, 256, 0, stream>>>(he_col, hev, permHE, NNZ_E, fcolHE, fvalHE);

  hipMemcpyAsync(ent, dynamic_emb, (size_t)NE * H * 4, hipMemcpyDeviceToDevice, stream);
  hipMemcpyAsync(rel, emb_rel, (size_t)R2 * H * 4, hipMemcpyDeviceToDevice, stream);

  constexpr int NEH8 = NE * H / 8, R2H8 = R2 * H / 8;
  constexpr int NE_RB = (NE + 127) / 128;   // 157

  cast_bf16_k<<<(NEH8 + 255) / 256, 256, 0, stream>>>(ent, entb, NEH8);
  cast_bf16_k<<<(R2H8 + 255) / 256, 256, 0, stream>>>(rel, relb, R2H8);

  for (int t = 0; t < TT; t++) {
    // --- rel update (GRU) ---
    gather_mean2_k<<<dim3(R2, MSPLIT), 256, 0, stream>>>(entb, fidxM[t], sM[t], partM);
    mean_xin_k<<<R2, 256, 0, stream>>>(partM, sM[t], rel, xinb);
    mfma_gemm<0><<<dim3(H3 / 64, (R2 + 63) / 64), 256, 0, stream>>>(
        xinb, Wihb, gru_b_ih, gi, R2, 2 * H, H3);
    mfma_gemm<0><<<dim3(H3 / 64, (R2 + 63) / 64), 256, 0, stream>>>(
        relb, Whhb, gru_b_hh, gh, R2, H, H3);
    gru_combine<<<(R2 * H + 255) / 256, 256, 0, stream>>>(gi, gh, rel, relb);

    // --- ent update ---
    panel2_gemm<2><<<dim3(2, NE_RB), 256, 0, stream>>>(entb, tgWtb, tg_b, tgbuf, NE, H, 2);
    gather_edges2_k<<<NE, 256, 0, stream>>>(entb, relb, fsrcE[t], frelE[t], sE[t], accEb);
    panel2_gemm<1><<<dim3(2, NE_RB), 256, 0, stream>>>(accEb, aggWtb, nullptr, curr, NE, H, 2);
    ent_update<<<(NE * H + 255) / 256, 256, 0, stream>>>(ent, entb, tgbuf, curr);
  }

  // --- hypergraph layers ---
  hyper2_k<<<NE, 256, 0, stream>>>(ent, entb, fvalHE, fcolHE, sHE, curr, entb2);
  hyper2_k<<<NE, 256, 0, stream>>>(curr, entb2, fvalHE, fcolHE, sHE, ent, entb);
  hyper_layer_k<<<R2, 256, 0, stream>>>(rel, hrv, hr_col, permHR, sHR, accR);
  hyper_layer_k<<<R2, 256, 0, stream>>>(accR, hrv, hr_col, permHR, sHR, rel);

  // --- conv + fc (3 chunks: 1600, 1600, 800 rows) ---
  for (int c = 0; c < 3; c++) {
    int row0 = c * 1600;
    int rows = min(1600, NT2 - row0);
    conv_feat<<<rows, 256, 0, stream>>>(ent, rel, sent, tt, conv_w, conv_b, convb, row0);
    fc_gemm<<<dim3(FSPLIT, (rows + 127) / 128), 256, 0, stream>>>(convb, fcWtb, fcpart, rows);
    fc_reduce<<<(rows * H + 255) / 256, 256, 0, stream>>>(
        fcpart, fc_b, qf + (size_t)row0 * H, qb + (size_t)row0 * H, rows);
  }

  // --- fused scores + LSE: 32 col-chunks x 32 row-blocks, PS=10 (640 cols) ---
  panel2_gemm<3><<<dim3(NCHUNK, 32), 256, 0, stream>>>(qb, entb, nullptr, part_l, NT2, NE, 10);
  lse_combine<<<(NT2 * 64 + 255) / 256, 256, 0, stream>>>(part_l, qf, ent, tt, nll);
  mean_nll<<<1, 256, 0, stream>>>(nll, out);
}

// Round 8
// 1358.167 us; speedup vs baseline: 6.6906x; 1.0154x over previous
//
#include <hip/hip_runtime.h>
#include <math.h>

#define DEV_INLINE __device__ __forceinline__

constexpr int H      = 256;
constexpr int NE     = 20000;
constexpr int NR     = 250;
constexpr int R2     = 500;
constexpr int TT     = 3;
constexpr int NEDGE  = 150000;
constexpr int M      = 200000;
constexpr int NNZ_E  = 320000;
constexpr int NNZ_R  = 8000;
constexpr int CH     = 50;
constexpr int NT     = 2000;
constexpr int NT2    = 4000;
constexpr int H3     = 3 * H;     // 768
constexpr int KFC    = CH * H;    // 12800
constexpr int ROWPAD = 4096;
constexpr int NCHUNK = 32;        // scores col chunks
constexpr int MSPLIT = 8;         // gather_mean row split
constexpr int FSPLIT = 10;        // fc split-K

// cnt/start/cursor packed region (ints)
constexpr int CNT_NE_BASE   = 2048;
constexpr int CNT_NE_STRIDE = 20224;
constexpr int CNT_TOTAL     = CNT_NE_BASE + 4 * CNT_NE_STRIDE;  // 82944

typedef __bf16 bf16x8 __attribute__((ext_vector_type(8)));
typedef float  f32x4  __attribute__((ext_vector_type(4)));

DEV_INLINE bf16x8 ldb8(const __bf16* p) { return *(const bf16x8*)p; }
DEV_INLINE bf16x8 zerob8() { uint4 z = make_uint4(0, 0, 0, 0); return __builtin_bit_cast(bf16x8, z); }
DEV_INLINE f32x4 mfma16(bf16x8 a, bf16x8 b, f32x4 c) {
  return __builtin_amdgcn_mfma_f32_16x16x32_bf16(a, b, c, 0, 0, 0);
}

// ------------------------- block reduction (blockDim == 256) ---------------
DEV_INLINE float block_sum256(float v) {
  __shared__ float ws[4];
  #pragma unroll
  for (int o = 32; o > 0; o >>= 1) v += __shfl_down(v, o, 64);
  if ((threadIdx.x & 63) == 0) ws[threadIdx.x >> 6] = v;
  __syncthreads();
  float r = ws[0] + ws[1] + ws[2] + ws[3];
  __syncthreads();
  return r;
}

// ------------------------- CSR build (int atomics only) --------------------
// 8 histograms in one launch; blockIdx.y selects the array
__global__ void hist_all_k(const int* __restrict__ r_ids, const int* __restrict__ edge_dst,
                           const int* __restrict__ hr_row, const int* __restrict__ he_row,
                           int* __restrict__ cnt_all)
{
  int a = blockIdx.y;
  const int* keys; int n; int* cnt;
  if (a < 3)       { keys = r_ids + (size_t)a * M;            n = M;      cnt = cnt_all + a * 512; }
  else if (a == 3) { keys = hr_row;                            n = NNZ_R;  cnt = cnt_all + 1536; }
  else if (a < 7)  { keys = edge_dst + (size_t)(a - 4) * NEDGE; n = NEDGE; cnt = cnt_all + CNT_NE_BASE + (a - 4) * CNT_NE_STRIDE; }
  else             { keys = he_row;                            n = NNZ_E;  cnt = cnt_all + CNT_NE_BASE + 3 * CNT_NE_STRIDE; }
  int i = blockIdx.x * 256 + threadIdx.x;
  if (i < n) atomicAdd(&cnt[keys[i]], 1);
}

// grid 8: one block scans one CSR's bins
__global__ void scan_all_k(const int* __restrict__ cnt_all, int* __restrict__ start_all,
                           int* __restrict__ cursor_all)
{
  __shared__ int ps[257];
  int b = blockIdx.x;
  int off, nbins;
  if (b < 3)       { off = b * 512;                        nbins = R2; }
  else if (b == 3) { off = 1536;                           nbins = R2; }
  else if (b < 7)  { off = CNT_NE_BASE + (b - 4) * CNT_NE_STRIDE; nbins = NE; }
  else             { off = CNT_NE_BASE + 3 * CNT_NE_STRIDE;      nbins = NE; }
  const int* cnt = cnt_all + off;
  int* start  = start_all + off;
  int* cursor = cursor_all + off;

  int t = threadIdx.x;
  int per = (nbins + 255) >> 8;
  int b0 = t * per;
  int local = 0;
  for (int i = 0; i < per; i++) { int bb = b0 + i; if (bb < nbins) local += cnt[bb]; }
  ps[t + 1] = local;
  if (t == 0) ps[0] = 0;
  __syncthreads();
  if (t == 0) { for (int i = 1; i <= 256; i++) ps[i] += ps[i - 1]; }
  __syncthreads();
  int run = ps[t];
  for (int i = 0; i < per; i++) {
    int bb = b0 + i;
    if (bb < nbins) { start[bb] = run; cursor[bb] = run; run += cnt[bb]; }
  }
  if (t == 0) start[nbins] = ps[256];
}

// permute + gather fused (perm array itself never materialized)
__global__ void perm_fuse1_k(const int* __restrict__ keys, const int* __restrict__ other,
                             int n, int* __restrict__ cursor, int* __restrict__ fidx)
{
  int i = blockIdx.x * 256 + threadIdx.x;
  if (i < n) { int p = atomicAdd(&cursor[keys[i]], 1); fidx[p] = other[i]; }
}
__global__ void perm_fuse2_k(const int* __restrict__ keys, const int* __restrict__ o1,
                             const int* __restrict__ o2, int n, int* __restrict__ cursor,
                             int* __restrict__ f1, int* __restrict__ f2)
{
  int i = blockIdx.x * 256 + threadIdx.x;
  if (i < n) { int p = atomicAdd(&cursor[keys[i]], 1); f1[p] = o1[i]; f2[p] = o2[i]; }
}
__global__ void perm_fusev_k(const int* __restrict__ keys, const int* __restrict__ col,
                             const float* __restrict__ val, int n, int* __restrict__ cursor,
                             int* __restrict__ fcol, float* __restrict__ fval)
{
  int i = blockIdx.x * 256 + threadIdx.x;
  if (i < n) { int p = atomicAdd(&cursor[keys[i]], 1); fcol[p] = col[i]; fval[p] = val[i]; }
}

// ------------------------- casts / transposes ------------------------------
__global__ void cast_bf16_k(const float* __restrict__ in, __bf16* __restrict__ out, int n8)
{
  int i = blockIdx.x * 256 + threadIdx.x;
  if (i >= n8) return;
  const float4* p = (const float4*)in + (size_t)i * 2;
  float4 u = p[0], v = p[1];
  bf16x8 o;
  o[0] = (__bf16)u.x; o[1] = (__bf16)u.y; o[2] = (__bf16)u.z; o[3] = (__bf16)u.w;
  o[4] = (__bf16)v.x; o[5] = (__bf16)v.y; o[6] = (__bf16)v.z; o[7] = (__bf16)v.w;
  ((bf16x8*)out)[i] = o;
}

__global__ void transpose_cast_k(const float* __restrict__ in, __bf16* __restrict__ out,
                                 int K, int N)
{
  __shared__ float tile[32][33];
  int tx = threadIdx.x & 31, ty = threadIdx.x >> 5;   // 32 x 8
  int kb = blockIdx.x * 32, nb = blockIdx.y * 32;
  #pragma unroll
  for (int i = 0; i < 4; i++)
    tile[ty + i * 8][tx] = in[(size_t)(kb + ty + i * 8) * N + nb + tx];
  __syncthreads();
  #pragma unroll
  for (int i = 0; i < 4; i++)
    out[(size_t)(nb + ty + i * 8) * K + kb + tx] = (__bf16)tile[tx][ty + i * 8];
}

// ------------------------- gather kernels (16 B/lane, 32-lane halves) ------
// grid (R2, MSPLIT): partial sums into part[(r*MSPLIT+s)*H + h]
__global__ void gather_mean2_k(const __bf16* __restrict__ src, const int* __restrict__ fidx,
                               const int* __restrict__ start, float* __restrict__ part)
{
  __shared__ __align__(16) float red[4][H];
  int r = blockIdx.x, s = blockIdx.y;
  int s0 = start[r], s1 = start[r + 1];
  int len = s1 - s0;
  int chunk = (len + MSPLIT - 1) / MSPLIT;
  int jb = s0 + s * chunk, je = min(jb + chunk, s1);
  int tid = threadIdx.x, lane = tid & 63, w = tid >> 6;
  int half = lane >> 5, l = lane & 31;
  float acc[8] = {0.f, 0.f, 0.f, 0.f, 0.f, 0.f, 0.f, 0.f};
  for (int j = jb + w * 2 + half; j < je; j += 8) {
    int e = fidx[j];
    bf16x8 v = ldb8(src + (size_t)e * H + l * 8);
    #pragma unroll
    for (int q = 0; q < 8; q++) acc[q] += (float)v[q];
  }
  #pragma unroll
  for (int q = 0; q < 8; q++) acc[q] += __shfl_xor(acc[q], 32, 64);
  if (half == 0) {
    *(float4*)&red[w][l * 8]     = make_float4(acc[0], acc[1], acc[2], acc[3]);
    *(float4*)&red[w][l * 8 + 4] = make_float4(acc[4], acc[5], acc[6], acc[7]);
  }
  __syncthreads();
  int h = tid;
  part[((size_t)r * MSPLIT + s) * H + h] = red[0][h] + red[1][h] + red[2][h] + red[3][h];
}

// grid R2: mean-combine + build xin (bf16 [rel | xmean])
__global__ void mean_xin_k(const float* __restrict__ partM, const int* __restrict__ start,
                           const float* __restrict__ rel, __bf16* __restrict__ xin)
{
  int r = blockIdx.x, h = threadIdx.x;
  float s = 0.f;
  #pragma unroll
  for (int z = 0; z < MSPLIT; z++) s += partM[((size_t)r * MSPLIT + z) * H + h];
  float xm = s / (float)max(start[r + 1] - start[r], 1);
  xin[(size_t)r * 2 * H + h]     = (__bf16)rel[(size_t)r * H + h];
  xin[(size_t)r * 2 * H + H + h] = (__bf16)xm;
}

// grid NE: lanes 0-31 read ent row, lanes 32-63 read rel row of the same edge
__global__ void gather_edges3_k(const __bf16* __restrict__ ent, const __bf16* __restrict__ rel,
                                const int* __restrict__ fsrc, const int* __restrict__ frel,
                                const int* __restrict__ start, __bf16* __restrict__ out)
{
  __shared__ __align__(16) float red[4][H];
  int d = blockIdx.x;
  int s0 = start[d], s1 = start[d + 1];
  int tid = threadIdx.x, lane = tid & 63, w = tid >> 6;
  int half = lane >> 5, l = lane & 31;
  const __bf16* srcbase = half ? rel : ent;
  const int* idx = half ? frel : fsrc;
  float acc[8] = {0.f, 0.f, 0.f, 0.f, 0.f, 0.f, 0.f, 0.f};
  for (int j = s0 + w; j < s1; j += 4) {
    int e = idx[j];
    bf16x8 v = ldb8(srcbase + (size_t)e * H + l * 8);
    #pragma unroll
    for (int q = 0; q < 8; q++) acc[q] += (float)v[q];
  }
  #pragma unroll
  for (int q = 0; q < 8; q++) acc[q] += __shfl_xor(acc[q], 32, 64);
  if (half == 0) {
    *(float4*)&red[w][l * 8]     = make_float4(acc[0], acc[1], acc[2], acc[3]);
    *(float4*)&red[w][l * 8 + 4] = make_float4(acc[4], acc[5], acc[6], acc[7]);
  }
  __syncthreads();
  int h = tid;
  float sum = red[0][h] + red[1][h] + red[2][h] + red[3][h];
  out[(size_t)d * H + h] = (__bf16)(sum / (float)max(s1 - s0, 1));
}

// grid NE: xout = x + y/||y||, y = sum fval*xb[fcol]; also emits bf16 copy
__global__ void hyper3_k(const float* __restrict__ x, const __bf16* __restrict__ xb,
                         const float* __restrict__ fval, const int* __restrict__ fcol,
                         const int* __restrict__ start,
                         float* __restrict__ xout, __bf16* __restrict__ xoutb)
{
  __shared__ __align__(16) float red[4][H];
  int r = blockIdx.x;
  int s0 = start[r], s1 = start[r + 1];
  int tid = threadIdx.x, lane = tid & 63, w = tid >> 6;
  int half = lane >> 5, l = lane & 31;
  float acc[8] = {0.f, 0.f, 0.f, 0.f, 0.f, 0.f, 0.f, 0.f};
  for (int j = s0 + w * 2 + half; j < s1; j += 8) {
    int e = fcol[j];
    float wt = fval[j];
    bf16x8 v = ldb8(xb + (size_t)e * H + l * 8);
    #pragma unroll
    for (int q = 0; q < 8; q++) acc[q] += wt * (float)v[q];
  }
  #pragma unroll
  for (int q = 0; q < 8; q++) acc[q] += __shfl_xor(acc[q], 32, 64);
  if (half == 0) {
    *(float4*)&red[w][l * 8]     = make_float4(acc[0], acc[1], acc[2], acc[3]);
    *(float4*)&red[w][l * 8 + 4] = make_float4(acc[4], acc[5], acc[6], acc[7]);
  }
  __syncthreads();
  int h = tid;
  float y = red[0][h] + red[1][h] + red[2][h] + red[3][h];
  float ss = block_sum256(y * y);
  float rn = 1.f / fmaxf(sqrtf(ss), 1e-12f);
  float o = x[(size_t)r * H + h] + y * rn;
  xout[(size_t)r * H + h] = o;
  xoutb[(size_t)r * H + h] = (__bf16)o;
}

// rel hypergraph (small): fused-index fp32 variant
__global__ void hyper_rel_k(const float* __restrict__ x, const float* __restrict__ fval,
                            const int* __restrict__ fcol, const int* __restrict__ start,
                            float* __restrict__ xout)
{
  int r = blockIdx.x, h = threadIdx.x;
  int s0 = start[r], s1 = start[r + 1];
  float a0 = 0.f;
  for (int j = s0; j < s1; j++) a0 += fval[j] * x[(size_t)fcol[j] * H + h];
  float ss = block_sum256(a0 * a0);
  float rn = 1.f / fmaxf(sqrtf(ss), 1e-12f);
  xout[(size_t)r * H + h] = x[(size_t)r * H + h] + a0 * rn;
}

// ------------------------- small elementwise -------------------------------
__global__ void gru_combine(const float* __restrict__ gi, const float* __restrict__ gh,
                            float* __restrict__ rel, __bf16* __restrict__ relb)
{
  int idx = blockIdx.x * 256 + threadIdx.x;       // R2 * H
  if (idx >= R2 * H) return;
  int i = idx >> 8, h = idx & 255;
  const float* gir = gi + (size_t)i * H3;
  const float* ghr = gh + (size_t)i * H3;
  float r = 1.f / (1.f + __expf(-(gir[h]       + ghr[h])));
  float z = 1.f / (1.f + __expf(-(gir[H + h]   + ghr[H + h])));
  float n = tanhf(gir[2 * H + h] + r * ghr[2 * H + h]);
  float o = (1.f - z) * n + z * rel[idx];
  rel[idx] = o;
  relb[idx] = (__bf16)o;
}

__global__ void ent_update(float* __restrict__ ent, __bf16* __restrict__ entb,
                           const float* __restrict__ tw, const float* __restrict__ curr)
{
  int idx = blockIdx.x * 256 + threadIdx.x;       // NE * H
  if (idx >= NE * H) return;
  float t = tw[idx];
  float v = t * curr[idx] + (1.f - t) * ent[idx];
  ent[idx] = v;
  entb[idx] = (__bf16)v;
}

// ------------------------- panel2 GEMM (K=256, dbuf 64-col B panels) --------
// Half-staging keeps prefetch liveness at 4 uint4 (16 VGPR) — no spill.
DEV_INLINE void stage64_load(uint4* v, const __bf16* src, int rowBase, int rowLimit, int tid)
{
  #pragma unroll
  for (int q = 0; q < 8; q++) {
    int X = (q * 256 + tid) * 16;
    int row = X >> 9, boff = X & 511;
    int grow = min(rowBase + row, rowLimit);
    v[q] = *(const uint4*)((const char*)src + (size_t)grow * 512 + boff);
  }
}
DEV_INLINE void stage64_write(char* lds, const uint4* v, int tid)
{
  #pragma unroll
  for (int q = 0; q < 8; q++) {
    int X = (q * 256 + tid) * 16;
    int row = X >> 9;
    *(uint4*)(lds + (X ^ ((row & 7) << 4))) = v[q];
  }
}
DEV_INLINE void stage32_load(uint4* v, const __bf16* src, int rowBase, int rowLimit, int tid, int hf)
{
  #pragma unroll
  for (int q = 0; q < 4; q++) {
    int X = ((hf * 4 + q) * 256 + tid) * 16;
    int row = X >> 9, boff = X & 511;
    int grow = min(rowBase + row, rowLimit);
    v[q] = *(const uint4*)((const char*)src + (size_t)grow * 512 + boff);
  }
}
DEV_INLINE void stage32_write(char* lds, const uint4* v, int tid, int hf)
{
  #pragma unroll
  for (int q = 0; q < 4; q++) {
    int X = ((hf * 4 + q) * 256 + tid) * 16;
    int row = X >> 9;
    *(uint4*)(lds + (X ^ ((row & 7) << 4))) = v[q];
  }
}
DEV_INLINE bf16x8 frag64(const char* lds, int row, int kf, int kg)
{
  int off = (kf * 64 + kg * 16) ^ ((row & 7) << 4);
  return *(const bf16x8*)(lds + row * 512 + off);
}

template<int EPI>
__global__ __launch_bounds__(256, 2) void panel2_gemm(const __bf16* __restrict__ A,
                                                      const __bf16* __restrict__ B,
                                                      const float* __restrict__ bias,
                                                      float* __restrict__ out,
                                                      int Mr, int N, int PS)
{
  __shared__ __attribute__((aligned(16))) char lds0[32768];
  __shared__ __attribute__((aligned(16))) char lds1[32768];
  int tid = threadIdx.x;
  int lane = tid & 63, wM = tid >> 6;
  int r = lane & 15, kg = lane >> 4;
  int rowBase = blockIdx.y * 128;

  {
    uint4 va[8];
    stage64_load(va, A, rowBase, Mr - 1, tid);
    stage64_write(lds0, va, tid);
    stage64_load(va, A, rowBase + 64, Mr - 1, tid);
    stage64_write(lds1, va, tid);
  }
  __syncthreads();

  bf16x8 a[2][8];
  {
    int base = wM * 32;
    const char* ab = (base >= 64) ? lds1 : lds0;
    #pragma unroll
    for (int i = 0; i < 2; i++) {
      int ar = (base + i * 16 + r) & 63;
      #pragma unroll
      for (int kf = 0; kf < 8; kf++) a[i][kf] = frag64(ab, ar, kf, kg);
    }
  }
  int p0 = blockIdx.x * PS;
  __syncthreads();                 // all waves done reading A from LDS
  {
    uint4 va[8];
    stage64_load(va, B, p0 * 64, N - 1, tid);
    stage64_write(lds0, va, tid);
  }
  __syncthreads();                 // panel 0 ready

  float lsum[2][4];
  if (EPI == 3) {
    #pragma unroll
    for (int i = 0; i < 2; i++)
      #pragma unroll
      for (int g = 0; g < 4; g++) lsum[i][g] = 0.f;
  }

  for (int p = 0; p < PS; p++) {
    char* cur = (p & 1) ? lds1 : lds0;
    char* nxt = (p & 1) ? lds0 : lds1;
    bool pre = (p + 1 < PS);
    uint4 v4[4];
    if (pre) stage32_load(v4, B, (p0 + p + 1) * 64, N - 1, tid, 0);

    f32x4 acc[2][4];
    #pragma unroll
    for (int i = 0; i < 2; i++)
      #pragma unroll
      for (int j = 0; j < 4; j++) {
        acc[i][j][0] = 0.f; acc[i][j][1] = 0.f; acc[i][j][2] = 0.f; acc[i][j][3] = 0.f;
      }
    __builtin_amdgcn_s_setprio(1);
    #pragma unroll
    for (int kf = 0; kf < 4; kf++) {
      bf16x8 b[4];
      #pragma unroll
      for (int j = 0; j < 4; j++) b[j] = frag64(cur, j * 16 + r, kf, kg);
      #pragma unroll
      for (int i = 0; i < 2; i++)
        #pragma unroll
        for (int j = 0; j < 4; j++)
          acc[i][j] = mfma16(a[i][kf], b[j], acc[i][j]);
    }
    __builtin_amdgcn_s_setprio(0);
    if (pre) {
      stage32_write(nxt, v4, tid, 0);
      stage32_load(v4, B, (p0 + p + 1) * 64, N - 1, tid, 1);
    }
    __builtin_amdgcn_s_setprio(1);
    #pragma unroll
    for (int kf = 4; kf < 8; kf++) {
      bf16x8 b[4];
      #pragma unroll
      for (int j = 0; j < 4; j++) b[j] = frag64(cur, j * 16 + r, kf, kg);
      #pragma unroll
      for (int i = 0; i < 2; i++)
        #pragma unroll
        for (int j = 0; j < 4; j++)
          acc[i][j] = mfma16(a[i][kf], b[j], acc[i][j]);
    }
    __builtin_amdgcn_s_setprio(0);
    if (pre) stage32_write(nxt, v4, tid, 1);

    if (EPI == 3) {
      #pragma unroll
      for (int j = 0; j < 4; j++) {
        int col = (p0 + p) * 64 + j * 16 + r;
        bool ok = col < N;
        #pragma unroll
        for (int i = 0; i < 2; i++)
          #pragma unroll
          for (int g = 0; g < 4; g++)
            lsum[i][g] += ok ? exp2f(acc[i][j][g]) : 0.f;
      }
    } else {
      #pragma unroll
      for (int i = 0; i < 2; i++)
        #pragma unroll
        for (int g = 0; g < 4; g++) {
          int row = rowBase + wM * 32 + i * 16 + kg * 4 + g;
          if (row >= Mr) continue;
          #pragma unroll
          for (int j = 0; j < 4; j++) {
            int col = (p0 + p) * 64 + j * 16 + r;
            if (col >= N) continue;
            float v = acc[i][j][g];
            if (bias) v += bias[col];
            if (EPI == 1) v = fmaxf(v, 0.f);
            if (EPI == 2) v = 1.f / (1.f + __expf(-v));
            out[(size_t)row * N + col] = v;
          }
        }
    }
    __syncthreads();
  }

  if (EPI == 3) {
    #pragma unroll
    for (int m = 1; m < 16; m <<= 1)
      #pragma unroll
      for (int i = 0; i < 2; i++)
        #pragma unroll
        for (int g = 0; g < 4; g++)
          lsum[i][g] += __shfl_xor(lsum[i][g], m, 64);
    if (r == 0) {
      #pragma unroll
      for (int i = 0; i < 2; i++)
        #pragma unroll
        for (int g = 0; g < 4; g++) {
          int row = rowBase + wM * 32 + i * 16 + kg * 4 + g;
          out[(size_t)blockIdx.x * ROWPAD + row] = lsum[i][g];
        }
    }
  }
}

// ------------------------- fc GEMM (K = 12800, LDS-staged, split-K) --------
__global__ __launch_bounds__(256) void fc_gemm(const __bf16* __restrict__ A,
                                               const __bf16* __restrict__ Bt,
                                               float* __restrict__ part, int Mr)
{
  __shared__ __attribute__((aligned(16))) char lds[49152];
  int tid = threadIdx.x;
  int lane = tid & 63, wave = tid >> 6;
  int wM = wave >> 1, wN = wave & 1;
  int r = lane & 15, kg = lane >> 4;
  int rowBase = blockIdx.y * 128;
  int kbeg = blockIdx.x * (KFC / FSPLIT);   // 1280

  f32x4 acc[4][8];
  #pragma unroll
  for (int i = 0; i < 4; i++)
    #pragma unroll
    for (int j = 0; j < 8; j++) {
      acc[i][j][0] = 0.f; acc[i][j][1] = 0.f; acc[i][j][2] = 0.f; acc[i][j][3] = 0.f;
    }

  for (int ks = 0; ks < 20; ks++) {
    int kb = kbeg + ks * 64;
    #pragma unroll
    for (int q = 0; q < 12; q++) {
      int X = (q * 256 + tid) * 16;
      int row = X >> 7;
      int off = X & 127;
      int soff = off ^ ((row & 7) << 4);
      uint4 v;
      if (row < 128) {
        int grow = min(rowBase + row, Mr - 1);
        v = *(const uint4*)((const char*)A + (size_t)grow * (KFC * 2) + kb * 2 + soff);
      } else {
        int col = row - 128;
        v = *(const uint4*)((const char*)Bt + (size_t)col * (KFC * 2) + kb * 2 + soff);
      }
      *(uint4*)(lds + X) = v;
    }
    __syncthreads();
    #pragma unroll
    for (int kf = 0; kf < 2; kf++) {
      bf16x8 a[4], b[8];
      #pragma unroll
      for (int i = 0; i < 4; i++) {
        int row = wM * 64 + i * 16 + r;
        int off = (kf * 64 + kg * 16) ^ ((row & 7) << 4);
        a[i] = *(const bf16x8*)(lds + row * 128 + off);
      }
      #pragma unroll
      for (int j = 0; j < 8; j++) {
        int row = 128 + wN * 128 + j * 16 + r;
        int off = (kf * 64 + kg * 16) ^ ((row & 7) << 4);
        b[j] = *(const bf16x8*)(lds + row * 128 + off);
      }
      #pragma unroll
      for (int i = 0; i < 4; i++)
        #pragma unroll
        for (int j = 0; j < 8; j++)
          acc[i][j] = mfma16(a[i], b[j], acc[i][j]);
    }
    __syncthreads();
  }

  float* pz = part + (size_t)blockIdx.x * Mr * H;
  #pragma unroll
  for (int i = 0; i < 4; i++)
    #pragma unroll
    for (int g = 0; g < 4; g++) {
      int row = rowBase + wM * 64 + i * 16 + kg * 4 + g;
      if (row >= Mr) continue;
      #pragma unroll
      for (int j = 0; j < 8; j++) {
        int col = wN * 128 + j * 16 + r;
        pz[(size_t)row * H + col] = acc[i][j][g];
      }
    }
}

// ------------------------- generic MFMA GEMM (GRU) -------------------------
template<int ACT>
__global__ void mfma_gemm(const __bf16* __restrict__ A, const __bf16* __restrict__ Bt,
                          const float* __restrict__ bias, float* __restrict__ C,
                          int Mr, int K, int N)
{
  int lane = threadIdx.x & 63, wave = threadIdx.x >> 6;
  int waveM = wave >> 1, waveN = wave & 1;
  int r = lane & 15, kg = lane >> 4;
  int rowBase = blockIdx.y * 64 + waveM * 32;
  int colBase = blockIdx.x * 64 + waveN * 32;

  int row0 = rowBase + r, row1 = rowBase + 16 + r;
  int col0 = colBase + r, col1 = colBase + 16 + r;
  bool v0 = row0 < Mr, v1 = row1 < Mr;
  const __bf16* a0p = A + (size_t)row0 * K + kg * 8;
  const __bf16* a1p = A + (size_t)row1 * K + kg * 8;
  const __bf16* b0p = Bt + (size_t)col0 * K + kg * 8;
  const __bf16* b1p = Bt + (size_t)col1 * K + kg * 8;

  f32x4 acc[2][2];
  #pragma unroll
  for (int i = 0; i < 2; i++)
    #pragma unroll
    for (int j = 0; j < 2; j++) { acc[i][j][0] = 0.f; acc[i][j][1] = 0.f; acc[i][j][2] = 0.f; acc[i][j][3] = 0.f; }

  for (int k0 = 0; k0 < K; k0 += 32) {
    bf16x8 a0 = v0 ? ldb8(a0p + k0) : zerob8();
    bf16x8 a1 = v1 ? ldb8(a1p + k0) : zerob8();
    bf16x8 b0 = ldb8(b0p + k0);
    bf16x8 b1 = ldb8(b1p + k0);
    acc[0][0] = mfma16(a0, b0, acc[0][0]);
    acc[0][1] = mfma16(a0, b1, acc[0][1]);
    acc[1][0] = mfma16(a1, b0, acc[1][0]);
    acc[1][1] = mfma16(a1, b1, acc[1][1]);
  }

  #pragma unroll
  for (int i = 0; i < 2; i++) {
    #pragma unroll
    for (int g = 0; g < 4; g++) {
      int row = rowBase + i * 16 + kg * 4 + g;
      if (row >= Mr) continue;
      #pragma unroll
      for (int j = 0; j < 2; j++) {
        int col = colBase + j * 16 + r;
        float v = acc[i][j][g];
        if (bias) v += bias[col];
        if (ACT == 1) v = fmaxf(v, 0.f);
        C[(size_t)row * N + col] = v;
      }
    }
  }
}

// sum split-K partials + bias + relu -> q (fp32) and qb (bf16, prescaled log2 e)
__global__ void fc_reduce(const float* __restrict__ part, const float* __restrict__ bias,
                          float* __restrict__ q, __bf16* __restrict__ qb, int nrows)
{
  int idx = blockIdx.x * 256 + threadIdx.x;       // nrows * H
  if (idx >= nrows * H) return;
  int col = idx & 255;
  float s = bias[col];
  for (int z = 0; z < FSPLIT; z++) s += part[(size_t)z * nrows * H + idx];
  s = fmaxf(s, 0.f);
  q[idx] = s;
  qb[idx] = (__bf16)(s * 1.44269504f);
}

// ------------------------- conv (block per test row) -----------------------
__global__ void conv_feat(const float* __restrict__ ent, const float* __restrict__ rel,
                          const float* __restrict__ sent, const int* __restrict__ tt,
                          const float* __restrict__ cw, const float* __restrict__ cb,
                          __bf16* __restrict__ out, int row0)
{
  __shared__ float f[3][258];
  __shared__ float wsm[CH * 9];
  __shared__ float bsm[CH];
  int i = row0 + blockIdx.x;
  int h = threadIdx.x;
  int j = (i < NT) ? i : i - NT;
  int a0 = (i < NT) ? tt[j * 3 + 0] : tt[j * 3 + 2];
  int a1 = (i < NT) ? tt[j * 3 + 1] : tt[j * 3 + 1] + NR;
  f[0][h + 1] = ent[(size_t)a0 * H + h];
  f[1][h + 1] = rel[(size_t)a1 * H + h];
  f[2][h + 1] = sent[(size_t)j * H + h];
  if (h < 3) { f[h][0] = 0.f; f[h][257] = 0.f; }
  for (int x = h; x < CH * 9; x += 256) wsm[x] = cw[x];
  if (h < CH) bsm[h] = cb[h];
  __syncthreads();
  __bf16* orow = out + (size_t)blockIdx.x * KFC;
  for (int c = 0; c < CH; c++) {
    const float* wc = wsm + c * 9;
    float s = bsm[c];
    #pragma unroll
    for (int ic = 0; ic < 3; ic++)
      s += wc[ic * 3 + 0] * f[ic][h] + wc[ic * 3 + 1] * f[ic][h + 1] + wc[ic * 3 + 2] * f[ic][h + 2];
    orow[(size_t)c * H + h] = (__bf16)fmaxf(s, 0.f);
  }
}

// one wave per row: nll[row] = log(sum_c part_l) - q[row].ent[tgt]
__global__ void lse_combine(const float* __restrict__ part_l, const float* __restrict__ qf,
                            const float* __restrict__ ent, const int* __restrict__ tt,
                            float* __restrict__ nll)
{
  int gid = blockIdx.x * 256 + threadIdx.x;
  int w = gid >> 6;
  if (w >= NT2) return;
  int lane = gid & 63;
  int j = (w < NT) ? w : w - NT;
  int tgt = (w < NT) ? tt[j * 3 + 2] : tt[j * 3 + 0];
  const float4 qa = ((const float4*)(qf + (size_t)w * H))[lane];
  const float4 ea = ((const float4*)(ent + (size_t)tgt * H))[lane];
  float d = qa.x * ea.x + qa.y * ea.y + qa.z * ea.z + qa.w * ea.w;
  float s = (lane < NCHUNK) ? part_l[(size_t)lane * ROWPAD + w] : 0.f;
  #pragma unroll
  for (int o = 32; o > 0; o >>= 1) {
    d += __shfl_down(d, o, 64);
    s += __shfl_down(s, o, 64);
  }
  if (lane == 0) nll[w] = logf(s) - d;
}

__global__ void mean_nll(const float* __restrict__ nll, float* __restrict__ out)
{
  float s = 0.f;
  for (int i = threadIdx.x; i < NT2; i += 256) s += nll[i];
  s = block_sum256(s);
  if (threadIdx.x == 0) out[0] = s * (1.f / NT2);
}

// ------------------------- launcher ----------------------------------------
extern "C" void kernel_launch(void* const* d_in, const int* in_sizes, int n_in,
                              void* d_out, int out_size, void* d_ws, size_t ws_size,
                              hipStream_t stream)
{
  const float* dynamic_emb = (const float*)d_in[0];
  const float* emb_rel     = (const float*)d_in[1];
  const float* gru_W_ih    = (const float*)d_in[2];
  const float* gru_W_hh    = (const float*)d_in[3];
  const float* gru_b_ih    = (const float*)d_in[4];
  const float* gru_b_hh    = (const float*)d_in[5];
  const float* agg_W       = (const float*)d_in[6];
  const float* tg_W        = (const float*)d_in[7];
  const float* tg_b        = (const float*)d_in[8];
  const float* hev         = (const float*)d_in[9];
  const float* hrv         = (const float*)d_in[10];
  const float* conv_w      = (const float*)d_in[11];
  const float* conv_b      = (const float*)d_in[12];
  const float* fc_W        = (const float*)d_in[13];
  const float* fc_b        = (const float*)d_in[14];
  const float* sent        = (const float*)d_in[15];
  const int* edge_src = (const int*)d_in[16];
  const int* edge_rel = (const int*)d_in[17];
  const int* edge_dst = (const int*)d_in[18];
  const int* r_to_e   = (const int*)d_in[19];
  const int* r_ids    = (const int*)d_in[20];
  const int* he_row   = (const int*)d_in[21];
  const int* he_col   = (const int*)d_in[22];
  const int* hr_row   = (const int*)d_in[23];
  const int* hr_col   = (const int*)d_in[24];
  const int* tt       = (const int*)d_in[25];
  float* out = (float*)d_out;

  char* base = (char*)d_ws;
  size_t off = 0;
  auto alloc = [&](size_t bytes) { char* p = base + off; off += (bytes + 255) & ~(size_t)255; return p; };

  float* ent    = (float*)alloc((size_t)NE * H * 4);
  float* curr   = (float*)alloc((size_t)NE * H * 4);   // + tgbuf: conv_bf overlay (41 MB)
  float* tgbuf  = (float*)alloc((size_t)NE * H * 4);
  __bf16* convb = (__bf16*)curr;                        // 1600*12800*2 = 40.96 MB
  __bf16* entb  = (__bf16*)alloc((size_t)NE * H * 2);
  __bf16* entb2 = (__bf16*)alloc((size_t)NE * H * 2);
  __bf16* accEb = (__bf16*)alloc((size_t)NE * H * 2);
  float* rel    = (float*)alloc((size_t)R2 * H * 4);
  float* accR   = (float*)alloc((size_t)R2 * H * 4);
  __bf16* relb  = (__bf16*)alloc((size_t)R2 * H * 2);
  __bf16* xinb  = (__bf16*)alloc((size_t)R2 * 2 * H * 2);
  float* gi     = (float*)alloc((size_t)R2 * H3 * 4);
  float* gh     = (float*)alloc((size_t)R2 * H3 * 4);
  float* qf     = (float*)alloc((size_t)NT2 * H * 4);
  __bf16* qb    = (__bf16*)alloc((size_t)NT2 * H * 2);
  float* part_l = (float*)alloc((size_t)NCHUNK * ROWPAD * 4);
  float* partM  = (float*)alloc((size_t)R2 * MSPLIT * H * 4);
  float* fcpart = (float*)alloc((size_t)FSPLIT * 1600 * H * 4);
  float* nll    = (float*)alloc((size_t)NT2 * 4);
  __bf16* tgWtb = (__bf16*)alloc((size_t)H * H * 2);
  __bf16* aggWtb= (__bf16*)alloc((size_t)H * H * 2);
  __bf16* fcWtb = (__bf16*)alloc((size_t)H * KFC * 2);
  __bf16* Wihb  = (__bf16*)alloc((size_t)H3 * 2 * H * 2);
  __bf16* Whhb  = (__bf16*)alloc((size_t)H3 * H * 2);

  int* ip = (int*)alloc(0);
  size_t ioff = 0;
  auto ialloc = [&](size_t n) { int* p = ip + ioff; ioff += n; return p; };
  int* fidxM[TT];
  int* fsrcE[TT]; int* frelE[TT];
  for (int t = 0; t < TT; t++) fidxM[t] = ialloc(M);
  for (int t = 0; t < TT; t++) { fsrcE[t] = ialloc(NEDGE); frelE[t] = ialloc(NEDGE); }
  int* fcolHE = ialloc(NNZ_E); float* fvalHE = (float*)ialloc(NNZ_E);
  int* fcolHR = ialloc(NNZ_R); float* fvalHR = (float*)ialloc(NNZ_R);
  int* cnt_all    = ialloc(CNT_TOTAL);
  int* start_all  = ialloc(CNT_TOTAL);
  int* cursor_all = ialloc(CNT_TOTAL);

  // CSR slot offsets: 0-2 = r_ids t; 3 = hr; 4-6 = edge_dst t; 7 = he
  int* sM[TT];  for (int t = 0; t < TT; t++) sM[t] = start_all + t * 512;
  int* sHR = start_all + 1536;
  int* sE[TT];  for (int t = 0; t < TT; t++) sE[t] = start_all + CNT_NE_BASE + t * CNT_NE_STRIDE;
  int* sHE = start_all + CNT_NE_BASE + 3 * CNT_NE_STRIDE;

  // --- weight prep (bf16) ---
  transpose_cast_k<<<dim3(H / 32, H / 32), 256, 0, stream>>>(tg_W, tgWtb, H, H);
  transpose_cast_k<<<dim3(H / 32, H / 32), 256, 0, stream>>>(agg_W, aggWtb, H, H);
  transpose_cast_k<<<dim3(KFC / 32, H / 32), 256, 0, stream>>>(fc_W, fcWtb, KFC, H);
  cast_bf16_k<<<(H3 * 2 * H / 8 + 255) / 256, 256, 0, stream>>>(gru_W_ih, Wihb, H3 * 2 * H / 8);
  cast_bf16_k<<<(H3 * H / 8 + 255) / 256, 256, 0, stream>>>(gru_W_hh, Whhb, H3 * H / 8);

  // --- batched CSR build ---
  hipMemsetAsync(cnt_all, 0, (size_t)CNT_TOTAL * 4, stream);
  hist_all_k<<<dim3((NNZ_E + 255) / 256, 8), 256, 0, stream>>>(r_ids, edge_dst, hr_row, he_row, cnt_all);
  scan_all_k<<<8, 256, 0, stream>>>(cnt_all, start_all, cursor_all);
  for (int t = 0; t < TT; t++)
    perm_fuse1_k<<<(M + 255) / 256, 256, 0, stream>>>(
        r_ids + (size_t)t * M, r_to_e + (size_t)t * M, M, cursor_all + t * 512, fidxM[t]);
  for (int t = 0; t < TT; t++)
    perm_fuse2_k<<<(NEDGE + 255) / 256, 256, 0, stream>>>(
        edge_dst + (size_t)t * NEDGE, edge_src + (size_t)t * NEDGE, edge_rel + (size_t)t * NEDGE,
        NEDGE, cursor_all + CNT_NE_BASE + t * CNT_NE_STRIDE, fsrcE[t], frelE[t]);
  perm_fusev_k<<<(NNZ_E + 255) / 256, 256, 0, stream>>>(
      he_row, he_col, hev, NNZ_E, cursor_all + CNT_NE_BASE + 3 * CNT_NE_STRIDE, fcolHE, fvalHE);
  perm_fusev_k<<<(NNZ_R + 255) / 256, 256, 0, stream>>>(
      hr_row, hr_col, hrv, NNZ_R, cursor_all + 1536, fcolHR, fvalHR);

  hipMemcpyAsync(ent, dynamic_emb, (size_t)NE * H * 4, hipMemcpyDeviceToDevice, stream);
  hipMemcpyAsync(rel, emb_rel, (size_t)R2 * H * 4, hipMemcpyDeviceToDevice, stream);

  constexpr int NEH8 = NE * H / 8, R2H8 = R2 * H / 8;
  constexpr int NE_RB = (NE + 127) / 128;   // 157

  cast_bf16_k<<<(NEH8 + 255) / 256, 256, 0, stream>>>(ent, entb, NEH8);
  cast_bf16_k<<<(R2H8 + 255) / 256, 256, 0, stream>>>(rel, relb, R2H8);

  for (int t = 0; t < TT; t++) {
    // --- rel update (GRU) ---
    gather_mean2_k<<<dim3(R2, MSPLIT), 256, 0, stream>>>(entb, fidxM[t], sM[t], partM);
    mean_xin_k<<<R2, 256, 0, stream>>>(partM, sM[t], rel, xinb);
    mfma_gemm<0><<<dim3(H3 / 64, (R2 + 63) / 64), 256, 0, stream>>>(
        xinb, Wihb, gru_b_ih, gi, R2, 2 * H, H3);
    mfma_gemm<0><<<dim3(H3 / 64, (R2 + 63) / 64), 256, 0, stream>>>(
        relb, Whhb, gru_b_hh, gh, R2, H, H3);
    gru_combine<<<(R2 * H + 255) / 256, 256, 0, stream>>>(gi, gh, rel, relb);

    // --- ent update ---
    panel2_gemm<2><<<dim3(2, NE_RB), 256, 0, stream>>>(entb, tgWtb, tg_b, tgbuf, NE, H, 2);
    gather_edges3_k<<<NE, 256, 0, stream>>>(entb, relb, fsrcE[t], frelE[t], sE[t], accEb);
    panel2_gemm<1><<<dim3(2, NE_RB), 256, 0, stream>>>(accEb, aggWtb, nullptr, curr, NE, H, 2);
    ent_update<<<(NE * H + 255) / 256, 256, 0, stream>>>(ent, entb, tgbuf, curr);
  }

  // --- hypergraph layers ---
  hyper3_k<<<NE, 256, 0, stream>>>(ent, entb, fvalHE, fcolHE, sHE, curr, entb2);
  hyper3_k<<<NE, 256, 0, stream>>>(curr, entb2, fvalHE, fcolHE, sHE, ent, entb);
  hyper_rel_k<<<R2, 256, 0, stream>>>(rel, fvalHR, fcolHR, sHR, accR);
  hyper_rel_k<<<R2, 256, 0, stream>>>(accR, fvalHR, fcolHR, sHR, rel);

  // --- conv + fc (3 chunks: 1600, 1600, 800 rows) ---
  for (int c = 0; c < 3; c++) {
    int row0 = c * 1600;
    int rows = min(1600, NT2 - row0);
    conv_feat<<<rows, 256, 0, stream>>>(ent, rel, sent, tt, conv_w, conv_b, convb, row0);
    fc_gemm<<<dim3(FSPLIT, (rows + 127) / 128), 256, 0, stream>>>(convb, fcWtb, fcpart, rows);
    fc_reduce<<<(rows * H + 255) / 256, 256, 0, stream>>>(
        fcpart, fc_b, qf + (size_t)row0 * H, qb + (size_t)row0 * H, rows);
  }

  // --- fused scores + LSE: 32 col-chunks x 32 row-blocks, PS=10 (640 cols) ---
  panel2_gemm<3><<<dim3(NCHUNK, 32), 256, 0, stream>>>(qb, entb, nullptr, part_l, NT2, NE, 10);
  lse_combine<<<(NT2 * 64 + 255) / 256, 256, 0, stream>>>(part_l, qf, ent, tt, nll);
  mean_nll<<<1, 256, 0, stream>>>(nll, out);
}

// Round 9
// 1089.897 us; speedup vs baseline: 8.3375x; 1.2461x over previous
//
#include <hip/hip_runtime.h>
#include <math.h>

#define DEV_INLINE __device__ __forceinline__

constexpr int H      = 256;
constexpr int NE     = 20000;
constexpr int NR     = 250;
constexpr int R2     = 500;
constexpr int TT     = 3;
constexpr int NEDGE  = 150000;
constexpr int M      = 200000;
constexpr int NNZ_E  = 320000;
constexpr int NNZ_R  = 8000;
constexpr int CH     = 50;
constexpr int NT     = 2000;
constexpr int NT2    = 4000;
constexpr int H3     = 3 * H;     // 768
constexpr int KFC    = CH * H;    // 12800
constexpr int ROWPAD = 4096;
constexpr int NCHUNK = 32;        // scores col chunks
constexpr int MSPLIT = 8;         // gather_mean row split
constexpr int FSPLIT = 10;        // fc split-K
constexpr int NB_CS  = 64;        // counting-sort blocks per R2 array

// cnt/start/cursor packed region (ints)
constexpr int CNT_NE_BASE   = 2048;
constexpr int CNT_NE_STRIDE = 20224;
constexpr int CNT_TOTAL     = CNT_NE_BASE + 4 * CNT_NE_STRIDE;  // 82944

typedef __bf16 bf16x8 __attribute__((ext_vector_type(8)));
typedef float  f32x4  __attribute__((ext_vector_type(4)));

DEV_INLINE bf16x8 ldb8(const __bf16* p) { return *(const bf16x8*)p; }
DEV_INLINE bf16x8 zerob8() { uint4 z = make_uint4(0, 0, 0, 0); return __builtin_bit_cast(bf16x8, z); }
DEV_INLINE f32x4 mfma16(bf16x8 a, bf16x8 b, f32x4 c) {
  return __builtin_amdgcn_mfma_f32_16x16x32_bf16(a, b, c, 0, 0, 0);
}

// ------------------------- block reduction (blockDim == 256) ---------------
DEV_INLINE float block_sum256(float v) {
  __shared__ float ws[4];
  #pragma unroll
  for (int o = 32; o > 0; o >>= 1) v += __shfl_down(v, o, 64);
  if ((threadIdx.x & 63) == 0) ws[threadIdx.x >> 6] = v;
  __syncthreads();
  float r = ws[0] + ws[1] + ws[2] + ws[3];
  __syncthreads();
  return r;
}

// ------------------- counting-sort CSR (R2-keyed arrays, no global atomics) --
// arrays: a=0..2 -> r_ids[t] (n=M), a=3 -> hr_row (n=NNZ_R). bins < 512.
__global__ void cs_hist_k(const int* __restrict__ r_ids, const int* __restrict__ hr_row,
                          int* __restrict__ bcnt)
{
  __shared__ int lh[512];
  int a = blockIdx.y;
  const int* keys = (a < 3) ? r_ids + (size_t)a * M : hr_row;
  int n = (a < 3) ? M : NNZ_R;
  int t = threadIdx.x;
  lh[t] = 0; lh[t + 256] = 0;
  __syncthreads();
  int chunk = (n + NB_CS - 1) / NB_CS;
  int i0 = blockIdx.x * chunk, i1 = min(i0 + chunk, n);
  for (int i = i0 + t; i < i1; i += 256) atomicAdd(&lh[keys[i]], 1);
  __syncthreads();
  int* outp = bcnt + ((size_t)a * NB_CS + blockIdx.x) * 512;
  outp[t] = lh[t]; outp[t + 256] = lh[t + 256];
}

// grid 4: per-array scan. Writes start[0..511] (bins>=500 saturate to total)
// and per-block bases bbase[a][blk][bin].
__global__ void cs_scan_k(const int* __restrict__ bcnt, int* __restrict__ bbase,
                          int* __restrict__ start_all)
{
  __shared__ int ps[257];
  int a = blockIdx.x;
  int* start = start_all + ((a < 3) ? a * 512 : 1536);
  const int* bc = bcnt + (size_t)a * NB_CS * 512;
  int* bb = bbase + (size_t)a * NB_CS * 512;
  int t = threadIdx.x;
  int b0 = 2 * t, b1 = 2 * t + 1;
  int tot0 = 0, tot1 = 0;
  for (int blk = 0; blk < NB_CS; blk++) {
    tot0 += bc[blk * 512 + b0];
    tot1 += bc[blk * 512 + b1];
  }
  ps[t + 1] = tot0 + tot1;
  if (t == 0) ps[0] = 0;
  __syncthreads();
  if (t == 0) { for (int i = 1; i <= 256; i++) ps[i] += ps[i - 1]; }
  __syncthreads();
  int run0 = ps[t], run1 = ps[t] + tot0;
  start[b0] = run0;
  start[b1] = run1;
  for (int blk = 0; blk < NB_CS; blk++) {
    bb[blk * 512 + b0] = run0; run0 += bc[blk * 512 + b0];
    bb[blk * 512 + b1] = run1; run1 += bc[blk * 512 + b1];
  }
}

// grid (NB_CS, 4): LDS-cursor scatter; emits fused index/value arrays directly.
__global__ void cs_scatter_k(const int* __restrict__ r_ids, const int* __restrict__ r_to_e,
                             const int* __restrict__ hr_row, const int* __restrict__ hr_col,
                             const float* __restrict__ hrv, const int* __restrict__ bbase,
                             int* __restrict__ f0, int* __restrict__ f1, int* __restrict__ f2,
                             int* __restrict__ fcolHR, float* __restrict__ fvalHR)
{
  __shared__ int cur[512];
  int a = blockIdx.y;
  const int* keys = (a < 3) ? r_ids + (size_t)a * M : hr_row;
  int n = (a < 3) ? M : NNZ_R;
  int t = threadIdx.x;
  const int* bb = bbase + ((size_t)a * NB_CS + blockIdx.x) * 512;
  cur[t] = bb[t]; cur[t + 256] = bb[t + 256];
  __syncthreads();
  int chunk = (n + NB_CS - 1) / NB_CS;
  int i0 = blockIdx.x * chunk, i1 = min(i0 + chunk, n);
  if (a < 3) {
    const int* other = r_to_e + (size_t)a * M;
    int* f = (a == 0) ? f0 : (a == 1) ? f1 : f2;
    for (int i = i0 + t; i < i1; i += 256) {
      int p = atomicAdd(&cur[keys[i]], 1);
      f[p] = other[i];
    }
  } else {
    for (int i = i0 + t; i < i1; i += 256) {
      int p = atomicAdd(&cur[keys[i]], 1);
      fcolHR[p] = hr_col[i];
      fvalHR[p] = hrv[i];
    }
  }
}

// ------------------- NE-keyed CSR (low contention, global atomics ok) ------
__global__ void hist_ne_k(const int* __restrict__ edge_dst, const int* __restrict__ he_row,
                          int* __restrict__ cnt_all)
{
  int a = blockIdx.y;
  const int* keys = (a < 3) ? edge_dst + (size_t)a * NEDGE : he_row;
  int n = (a < 3) ? NEDGE : NNZ_E;
  int* cnt = cnt_all + CNT_NE_BASE + a * CNT_NE_STRIDE;
  int i = blockIdx.x * 256 + threadIdx.x;
  if (i < n) atomicAdd(&cnt[keys[i]], 1);
}

__global__ void scan_ne_k(const int* __restrict__ cnt_all, int* __restrict__ start_all,
                          int* __restrict__ cursor_all)
{
  __shared__ int ps[257];
  int off = CNT_NE_BASE + blockIdx.x * CNT_NE_STRIDE;
  const int nbins = NE;
  const int* cnt = cnt_all + off;
  int* start  = start_all + off;
  int* cursor = cursor_all + off;
  int t = threadIdx.x;
  int per = (nbins + 255) >> 8;
  int b0 = t * per;
  int local = 0;
  for (int i = 0; i < per; i++) { int bb = b0 + i; if (bb < nbins) local += cnt[bb]; }
  ps[t + 1] = local;
  if (t == 0) ps[0] = 0;
  __syncthreads();
  if (t == 0) { for (int i = 1; i <= 256; i++) ps[i] += ps[i - 1]; }
  __syncthreads();
  int run = ps[t];
  for (int i = 0; i < per; i++) {
    int bb = b0 + i;
    if (bb < nbins) { start[bb] = run; cursor[bb] = run; run += cnt[bb]; }
  }
  if (t == 0) start[nbins] = ps[256];
}

__global__ void perm_fuse2_k(const int* __restrict__ keys, const int* __restrict__ o1,
                             const int* __restrict__ o2, int n, int* __restrict__ cursor,
                             int* __restrict__ f1, int* __restrict__ f2)
{
  int i = blockIdx.x * 256 + threadIdx.x;
  if (i < n) { int p = atomicAdd(&cursor[keys[i]], 1); f1[p] = o1[i]; f2[p] = o2[i]; }
}
__global__ void perm_fusev_k(const int* __restrict__ keys, const int* __restrict__ col,
                             const float* __restrict__ val, int n, int* __restrict__ cursor,
                             int* __restrict__ fcol, float* __restrict__ fval)
{
  int i = blockIdx.x * 256 + threadIdx.x;
  if (i < n) { int p = atomicAdd(&cursor[keys[i]], 1); fcol[p] = col[i]; fval[p] = val[i]; }
}

// ------------------------- casts / transposes ------------------------------
__global__ void cast_bf16_k(const float* __restrict__ in, __bf16* __restrict__ out, int n8)
{
  int i = blockIdx.x * 256 + threadIdx.x;
  if (i >= n8) return;
  const float4* p = (const float4*)in + (size_t)i * 2;
  float4 u = p[0], v = p[1];
  bf16x8 o;
  o[0] = (__bf16)u.x; o[1] = (__bf16)u.y; o[2] = (__bf16)u.z; o[3] = (__bf16)u.w;
  o[4] = (__bf16)v.x; o[5] = (__bf16)v.y; o[6] = (__bf16)v.z; o[7] = (__bf16)v.w;
  ((bf16x8*)out)[i] = o;
}

__global__ void transpose_cast_k(const float* __restrict__ in, __bf16* __restrict__ out,
                                 int K, int N)
{
  __shared__ float tile[32][33];
  int tx = threadIdx.x & 31, ty = threadIdx.x >> 5;   // 32 x 8
  int kb = blockIdx.x * 32, nb = blockIdx.y * 32;
  #pragma unroll
  for (int i = 0; i < 4; i++)
    tile[ty + i * 8][tx] = in[(size_t)(kb + ty + i * 8) * N + nb + tx];
  __syncthreads();
  #pragma unroll
  for (int i = 0; i < 4; i++)
    out[(size_t)(nb + ty + i * 8) * K + kb + tx] = (__bf16)tile[tx][ty + i * 8];
}

// ------------------------- gather kernels (16 B/lane, 32-lane halves) ------
// grid (R2, MSPLIT): partial sums into part[(r*MSPLIT+s)*H + h]
__global__ void gather_mean2_k(const __bf16* __restrict__ src, const int* __restrict__ fidx,
                               const int* __restrict__ start, float* __restrict__ part)
{
  __shared__ __align__(16) float red[4][H];
  int r = blockIdx.x, s = blockIdx.y;
  int s0 = start[r], s1 = start[r + 1];
  int len = s1 - s0;
  int chunk = (len + MSPLIT - 1) / MSPLIT;
  int jb = s0 + s * chunk, je = min(jb + chunk, s1);
  int tid = threadIdx.x, lane = tid & 63, w = tid >> 6;
  int half = lane >> 5, l = lane & 31;
  float acc[8] = {0.f, 0.f, 0.f, 0.f, 0.f, 0.f, 0.f, 0.f};
  for (int j = jb + w * 2 + half; j < je; j += 8) {
    int e = fidx[j];
    bf16x8 v = ldb8(src + (size_t)e * H + l * 8);
    #pragma unroll
    for (int q = 0; q < 8; q++) acc[q] += (float)v[q];
  }
  #pragma unroll
  for (int q = 0; q < 8; q++) acc[q] += __shfl_xor(acc[q], 32, 64);
  if (half == 0) {
    *(float4*)&red[w][l * 8]     = make_float4(acc[0], acc[1], acc[2], acc[3]);
    *(float4*)&red[w][l * 8 + 4] = make_float4(acc[4], acc[5], acc[6], acc[7]);
  }
  __syncthreads();
  int h = tid;
  part[((size_t)r * MSPLIT + s) * H + h] = red[0][h] + red[1][h] + red[2][h] + red[3][h];
}

// grid R2: mean-combine + build xin (bf16 [rel | xmean])
__global__ void mean_xin_k(const float* __restrict__ partM, const int* __restrict__ start,
                           const float* __restrict__ rel, __bf16* __restrict__ xin)
{
  int r = blockIdx.x, h = threadIdx.x;
  float s = 0.f;
  #pragma unroll
  for (int z = 0; z < MSPLIT; z++) s += partM[((size_t)r * MSPLIT + z) * H + h];
  float xm = s / (float)max(start[r + 1] - start[r], 1);
  xin[(size_t)r * 2 * H + h]     = (__bf16)rel[(size_t)r * H + h];
  xin[(size_t)r * 2 * H + H + h] = (__bf16)xm;
}

// grid NE: lanes 0-31 read ent row, lanes 32-63 read rel row of the same edge
__global__ void gather_edges3_k(const __bf16* __restrict__ ent, const __bf16* __restrict__ rel,
                                const int* __restrict__ fsrc, const int* __restrict__ frel,
                                const int* __restrict__ start, __bf16* __restrict__ out)
{
  __shared__ __align__(16) float red[4][H];
  int d = blockIdx.x;
  int s0 = start[d], s1 = start[d + 1];
  int tid = threadIdx.x, lane = tid & 63, w = tid >> 6;
  int half = lane >> 5, l = lane & 31;
  const __bf16* srcbase = half ? rel : ent;
  const int* idx = half ? frel : fsrc;
  float acc[8] = {0.f, 0.f, 0.f, 0.f, 0.f, 0.f, 0.f, 0.f};
  for (int j = s0 + w; j < s1; j += 4) {
    int e = idx[j];
    bf16x8 v = ldb8(srcbase + (size_t)e * H + l * 8);
    #pragma unroll
    for (int q = 0; q < 8; q++) acc[q] += (float)v[q];
  }
  #pragma unroll
  for (int q = 0; q < 8; q++) acc[q] += __shfl_xor(acc[q], 32, 64);
  if (half == 0) {
    *(float4*)&red[w][l * 8]     = make_float4(acc[0], acc[1], acc[2], acc[3]);
    *(float4*)&red[w][l * 8 + 4] = make_float4(acc[4], acc[5], acc[6], acc[7]);
  }
  __syncthreads();
  int h = tid;
  float sum = red[0][h] + red[1][h] + red[2][h] + red[3][h];
  out[(size_t)d * H + h] = (__bf16)(sum / (float)max(s1 - s0, 1));
}

// grid NE: xout = x + y/||y||, y = sum fval*xb[fcol]; also emits bf16 copy
__global__ void hyper3_k(const float* __restrict__ x, const __bf16* __restrict__ xb,
                         const float* __restrict__ fval, const int* __restrict__ fcol,
                         const int* __restrict__ start,
                         float* __restrict__ xout, __bf16* __restrict__ xoutb)
{
  __shared__ __align__(16) float red[4][H];
  int r = blockIdx.x;
  int s0 = start[r], s1 = start[r + 1];
  int tid = threadIdx.x, lane = tid & 63, w = tid >> 6;
  int half = lane >> 5, l = lane & 31;
  float acc[8] = {0.f, 0.f, 0.f, 0.f, 0.f, 0.f, 0.f, 0.f};
  for (int j = s0 + w * 2 + half; j < s1; j += 8) {
    int e = fcol[j];
    float wt = fval[j];
    bf16x8 v = ldb8(xb + (size_t)e * H + l * 8);
    #pragma unroll
    for (int q = 0; q < 8; q++) acc[q] += wt * (float)v[q];
  }
  #pragma unroll
  for (int q = 0; q < 8; q++) acc[q] += __shfl_xor(acc[q], 32, 64);
  if (half == 0) {
    *(float4*)&red[w][l * 8]     = make_float4(acc[0], acc[1], acc[2], acc[3]);
    *(float4*)&red[w][l * 8 + 4] = make_float4(acc[4], acc[5], acc[6], acc[7]);
  }
  __syncthreads();
  int h = tid;
  float y = red[0][h] + red[1][h] + red[2][h] + red[3][h];
  float ss = block_sum256(y * y);
  float rn = 1.f / fmaxf(sqrtf(ss), 1e-12f);
  float o = x[(size_t)r * H + h] + y * rn;
  xout[(size_t)r * H + h] = o;
  xoutb[(size_t)r * H + h] = (__bf16)o;
}

// rel hypergraph (small): fused-index fp32 variant
__global__ void hyper_rel_k(const float* __restrict__ x, const float* __restrict__ fval,
                            const int* __restrict__ fcol, const int* __restrict__ start,
                            float* __restrict__ xout)
{
  int r = blockIdx.x, h = threadIdx.x;
  int s0 = start[r], s1 = start[r + 1];
  float a0 = 0.f;
  for (int j = s0; j < s1; j++) a0 += fval[j] * x[(size_t)fcol[j] * H + h];
  float ss = block_sum256(a0 * a0);
  float rn = 1.f / fmaxf(sqrtf(ss), 1e-12f);
  xout[(size_t)r * H + h] = x[(size_t)r * H + h] + a0 * rn;
}

// ------------------------- small elementwise -------------------------------
__global__ void gru_combine(const float* __restrict__ gi, const float* __restrict__ gh,
                            float* __restrict__ rel, __bf16* __restrict__ relb)
{
  int idx = blockIdx.x * 256 + threadIdx.x;       // R2 * H
  if (idx >= R2 * H) return;
  int i = idx >> 8, h = idx & 255;
  const float* gir = gi + (size_t)i * H3;
  const float* ghr = gh + (size_t)i * H3;
  float r = 1.f / (1.f + __expf(-(gir[h]       + ghr[h])));
  float z = 1.f / (1.f + __expf(-(gir[H + h]   + ghr[H + h])));
  float n = tanhf(gir[2 * H + h] + r * ghr[2 * H + h]);
  float o = (1.f - z) * n + z * rel[idx];
  rel[idx] = o;
  relb[idx] = (__bf16)o;
}

__global__ void ent_update(float* __restrict__ ent, __bf16* __restrict__ entb,
                           const float* __restrict__ tw, const float* __restrict__ curr)
{
  int idx = blockIdx.x * 256 + threadIdx.x;       // NE * H
  if (idx >= NE * H) return;
  float t = tw[idx];
  float v = t * curr[idx] + (1.f - t) * ent[idx];
  ent[idx] = v;
  entb[idx] = (__bf16)v;
}

// ------------------------- panel2 GEMM (K=256, dbuf 64-col B panels) --------
DEV_INLINE void stage64_load(uint4* v, const __bf16* src, int rowBase, int rowLimit, int tid)
{
  #pragma unroll
  for (int q = 0; q < 8; q++) {
    int X = (q * 256 + tid) * 16;
    int row = X >> 9, boff = X & 511;
    int grow = min(rowBase + row, rowLimit);
    v[q] = *(const uint4*)((const char*)src + (size_t)grow * 512 + boff);
  }
}
DEV_INLINE void stage64_write(char* lds, const uint4* v, int tid)
{
  #pragma unroll
  for (int q = 0; q < 8; q++) {
    int X = (q * 256 + tid) * 16;
    int row = X >> 9;
    *(uint4*)(lds + (X ^ ((row & 7) << 4))) = v[q];
  }
}
DEV_INLINE void stage32_load(uint4* v, const __bf16* src, int rowBase, int rowLimit, int tid, int hf)
{
  #pragma unroll
  for (int q = 0; q < 4; q++) {
    int X = ((hf * 4 + q) * 256 + tid) * 16;
    int row = X >> 9, boff = X & 511;
    int grow = min(rowBase + row, rowLimit);
    v[q] = *(const uint4*)((const char*)src + (size_t)grow * 512 + boff);
  }
}
DEV_INLINE void stage32_write(char* lds, const uint4* v, int tid, int hf)
{
  #pragma unroll
  for (int q = 0; q < 4; q++) {
    int X = ((hf * 4 + q) * 256 + tid) * 16;
    int row = X >> 9;
    *(uint4*)(lds + (X ^ ((row & 7) << 4))) = v[q];
  }
}
DEV_INLINE bf16x8 frag64(const char* lds, int row, int kf, int kg)
{
  int off = (kf * 64 + kg * 16) ^ ((row & 7) << 4);
  return *(const bf16x8*)(lds + row * 512 + off);
}

template<int EPI>
__global__ __launch_bounds__(256, 2) void panel2_gemm(const __bf16* __restrict__ A,
                                                      const __bf16* __restrict__ B,
                                                      const float* __restrict__ bias,
                                                      float* __restrict__ out,
                                                      int Mr, int N, int PS)
{
  __shared__ __attribute__((aligned(16))) char lds0[32768];
  __shared__ __attribute__((aligned(16))) char lds1[32768];
  int tid = threadIdx.x;
  int lane = tid & 63, wM = tid >> 6;
  int r = lane & 15, kg = lane >> 4;
  int rowBase = blockIdx.y * 128;

  {
    uint4 va[8];
    stage64_load(va, A, rowBase, Mr - 1, tid);
    stage64_write(lds0, va, tid);
    stage64_load(va, A, rowBase + 64, Mr - 1, tid);
    stage64_write(lds1, va, tid);
  }
  __syncthreads();

  bf16x8 a[2][8];
  {
    int base = wM * 32;
    const char* ab = (base >= 64) ? lds1 : lds0;
    #pragma unroll
    for (int i = 0; i < 2; i++) {
      int ar = (base + i * 16 + r) & 63;
      #pragma unroll
      for (int kf = 0; kf < 8; kf++) a[i][kf] = frag64(ab, ar, kf, kg);
    }
  }
  int p0 = blockIdx.x * PS;
  __syncthreads();                 // all waves done reading A from LDS
  {
    uint4 va[8];
    stage64_load(va, B, p0 * 64, N - 1, tid);
    stage64_write(lds0, va, tid);
  }
  __syncthreads();                 // panel 0 ready

  float lsum[2][4];
  if (EPI == 3) {
    #pragma unroll
    for (int i = 0; i < 2; i++)
      #pragma unroll
      for (int g = 0; g < 4; g++) lsum[i][g] = 0.f;
  }

  for (int p = 0; p < PS; p++) {
    char* cur = (p & 1) ? lds1 : lds0;
    char* nxt = (p & 1) ? lds0 : lds1;
    bool pre = (p + 1 < PS);
    uint4 v4[4];
    if (pre) stage32_load(v4, B, (p0 + p + 1) * 64, N - 1, tid, 0);

    f32x4 acc[2][4];
    #pragma unroll
    for (int i = 0; i < 2; i++)
      #pragma unroll
      for (int j = 0; j < 4; j++) {
        acc[i][j][0] = 0.f; acc[i][j][1] = 0.f; acc[i][j][2] = 0.f; acc[i][j][3] = 0.f;
      }
    __builtin_amdgcn_s_setprio(1);
    #pragma unroll
    for (int kf = 0; kf < 4; kf++) {
      bf16x8 b[4];
      #pragma unroll
      for (int j = 0; j < 4; j++) b[j] = frag64(cur, j * 16 + r, kf, kg);
      #pragma unroll
      for (int i = 0; i < 2; i++)
        #pragma unroll
        for (int j = 0; j < 4; j++)
          acc[i][j] = mfma16(a[i][kf], b[j], acc[i][j]);
    }
    __builtin_amdgcn_s_setprio(0);
    if (pre) {
      stage32_write(nxt, v4, tid, 0);
      stage32_load(v4, B, (p0 + p + 1) * 64, N - 1, tid, 1);
    }
    __builtin_amdgcn_s_setprio(1);
    #pragma unroll
    for (int kf = 4; kf < 8; kf++) {
      bf16x8 b[4];
      #pragma unroll
      for (int j = 0; j < 4; j++) b[j] = frag64(cur, j * 16 + r, kf, kg);
      #pragma unroll
      for (int i = 0; i < 2; i++)
        #pragma unroll
        for (int j = 0; j < 4; j++)
          acc[i][j] = mfma16(a[i][kf], b[j], acc[i][j]);
    }
    __builtin_amdgcn_s_setprio(0);
    if (pre) stage32_write(nxt, v4, tid, 1);

    if (EPI == 3) {
      #pragma unroll
      for (int j = 0; j < 4; j++) {
        int col = (p0 + p) * 64 + j * 16 + r;
        bool ok = col < N;
        #pragma unroll
        for (int i = 0; i < 2; i++)
          #pragma unroll
          for (int g = 0; g < 4; g++)
            lsum[i][g] += ok ? exp2f(acc[i][j][g]) : 0.f;
      }
    } else {
      #pragma unroll
      for (int i = 0; i < 2; i++)
        #pragma unroll
        for (int g = 0; g < 4; g++) {
          int row = rowBase + wM * 32 + i * 16 + kg * 4 + g;
          if (row >= Mr) continue;
          #pragma unroll
          for (int j = 0; j < 4; j++) {
            int col = (p0 + p) * 64 + j * 16 + r;
            if (col >= N) continue;
            float v = acc[i][j][g];
            if (bias) v += bias[col];
            if (EPI == 1) v = fmaxf(v, 0.f);
            if (EPI == 2) v = 1.f / (1.f + __expf(-v));
            out[(size_t)row * N + col] = v;
          }
        }
    }
    __syncthreads();
  }

  if (EPI == 3) {
    #pragma unroll
    for (int m = 1; m < 16; m <<= 1)
      #pragma unroll
      for (int i = 0; i < 2; i++)
        #pragma unroll
        for (int g = 0; g < 4; g++)
          lsum[i][g] += __shfl_xor(lsum[i][g], m, 64);
    if (r == 0) {
      #pragma unroll
      for (int i = 0; i < 2; i++)
        #pragma unroll
        for (int g = 0; g < 4; g++) {
          int row = rowBase + wM * 32 + i * 16 + kg * 4 + g;
          out[(size_t)blockIdx.x * ROWPAD + row] = lsum[i][g];
        }
    }
  }
}

// ------------------------- fc GEMM (K = 12800, LDS-staged, split-K) --------
__global__ __launch_bounds__(256) void fc_gemm(const __bf16* __restrict__ A,
                                               const __bf16* __restrict__ Bt,
                                               float* __restrict__ part, int Mr)
{
  __shared__ __attribute__((aligned(16))) char lds[49152];
  int tid = threadIdx.x;
  int lane = tid & 63, wave = tid >> 6;
  int wM = wave >> 1, wN = wave & 1;
  int r = lane & 15, kg = lane >> 4;
  int rowBase = blockIdx.y * 128;
  int kbeg = blockIdx.x * (KFC / FSPLIT);   // 1280

  f32x4 acc[4][8];
  #pragma unroll
  for (int i = 0; i < 4; i++)
    #pragma unroll
    for (int j = 0; j < 8; j++) {
      acc[i][j][0] = 0.f; acc[i][j][1] = 0.f; acc[i][j][2] = 0.f; acc[i][j][3] = 0.f;
    }

  for (int ks = 0; ks < 20; ks++) {
    int kb = kbeg + ks * 64;
    #pragma unroll
    for (int q = 0; q < 12; q++) {
      int X = (q * 256 + tid) * 16;
      int row = X >> 7;
      int off = X & 127;
      int soff = off ^ ((row & 7) << 4);
      uint4 v;
      if (row < 128) {
        int grow = min(rowBase + row, Mr - 1);
        v = *(const uint4*)((const char*)A + (size_t)grow * (KFC * 2) + kb * 2 + soff);
      } else {
        int col = row - 128;
        v = *(const uint4*)((const char*)Bt + (size_t)col * (KFC * 2) + kb * 2 + soff);
      }
      *(uint4*)(lds + X) = v;
    }
    __syncthreads();
    #pragma unroll
    for (int kf = 0; kf < 2; kf++) {
      bf16x8 a[4], b[8];
      #pragma unroll
      for (int i = 0; i < 4; i++) {
        int row = wM * 64 + i * 16 + r;
        int off = (kf * 64 + kg * 16) ^ ((row & 7) << 4);
        a[i] = *(const bf16x8*)(lds + row * 128 + off);
      }
      #pragma unroll
      for (int j = 0; j < 8; j++) {
        int row = 128 + wN * 128 + j * 16 + r;
        int off = (kf * 64 + kg * 16) ^ ((row & 7) << 4);
        b[j] = *(const bf16x8*)(lds + row * 128 + off);
      }
      #pragma unroll
      for (int i = 0; i < 4; i++)
        #pragma unroll
        for (int j = 0; j < 8; j++)
          acc[i][j] = mfma16(a[i], b[j], acc[i][j]);
    }
    __syncthreads();
  }

  float* pz = part + (size_t)blockIdx.x * Mr * H;
  #pragma unroll
  for (int i = 0; i < 4; i++)
    #pragma unroll
    for (int g = 0; g < 4; g++) {
      int row = rowBase + wM * 64 + i * 16 + kg * 4 + g;
      if (row >= Mr) continue;
      #pragma unroll
      for (int j = 0; j < 8; j++) {
        int col = wN * 128 + j * 16 + r;
        pz[(size_t)row * H + col] = acc[i][j][g];
      }
    }
}

// ------------------------- generic MFMA GEMM (GRU) -------------------------
template<int ACT>
__global__ void mfma_gemm(const __bf16* __restrict__ A, const __bf16* __restrict__ Bt,
                          const float* __restrict__ bias, float* __restrict__ C,
                          int Mr, int K, int N)
{
  int lane = threadIdx.x & 63, wave = threadIdx.x >> 6;
  int waveM = wave >> 1, waveN = wave & 1;
  int r = lane & 15, kg = lane >> 4;
  int rowBase = blockIdx.y * 64 + waveM * 32;
  int colBase = blockIdx.x * 64 + waveN * 32;

  int row0 = rowBase + r, row1 = rowBase + 16 + r;
  int col0 = colBase + r, col1 = colBase + 16 + r;
  bool v0 = row0 < Mr, v1 = row1 < Mr;
  const __bf16* a0p = A + (size_t)row0 * K + kg * 8;
  const __bf16* a1p = A + (size_t)row1 * K + kg * 8;
  const __bf16* b0p = Bt + (size_t)col0 * K + kg * 8;
  const __bf16* b1p = Bt + (size_t)col1 * K + kg * 8;

  f32x4 acc[2][2];
  #pragma unroll
  for (int i = 0; i < 2; i++)
    #pragma unroll
    for (int j = 0; j < 2; j++) { acc[i][j][0] = 0.f; acc[i][j][1] = 0.f; acc[i][j][2] = 0.f; acc[i][j][3] = 0.f; }

  for (int k0 = 0; k0 < K; k0 += 32) {
    bf16x8 a0 = v0 ? ldb8(a0p + k0) : zerob8();
    bf16x8 a1 = v1 ? ldb8(a1p + k0) : zerob8();
    bf16x8 b0 = ldb8(b0p + k0);
    bf16x8 b1 = ldb8(b1p + k0);
    acc[0][0] = mfma16(a0, b0, acc[0][0]);
    acc[0][1] = mfma16(a0, b1, acc[0][1]);
    acc[1][0] = mfma16(a1, b0, acc[1][0]);
    acc[1][1] = mfma16(a1, b1, acc[1][1]);
  }

  #pragma unroll
  for (int i = 0; i < 2; i++) {
    #pragma unroll
    for (int g = 0; g < 4; g++) {
      int row = rowBase + i * 16 + kg * 4 + g;
      if (row >= Mr) continue;
      #pragma unroll
      for (int j = 0; j < 2; j++) {
        int col = colBase + j * 16 + r;
        float v = acc[i][j][g];
        if (bias) v += bias[col];
        if (ACT == 1) v = fmaxf(v, 0.f);
        C[(size_t)row * N + col] = v;
      }
    }
  }
}

// sum split-K partials + bias + relu -> q (fp32) and qb (bf16, prescaled log2 e)
__global__ void fc_reduce(const float* __restrict__ part, const float* __restrict__ bias,
                          float* __restrict__ q, __bf16* __restrict__ qb, int nrows)
{
  int idx = blockIdx.x * 256 + threadIdx.x;       // nrows * H
  if (idx >= nrows * H) return;
  int col = idx & 255;
  float s = bias[col];
  for (int z = 0; z < FSPLIT; z++) s += part[(size_t)z * nrows * H + idx];
  s = fmaxf(s, 0.f);
  q[idx] = s;
  qb[idx] = (__bf16)(s * 1.44269504f);
}

// ------------------------- conv (block per test row) -----------------------
__global__ void conv_feat(const float* __restrict__ ent, const float* __restrict__ rel,
                          const float* __restrict__ sent, const int* __restrict__ tt,
                          const float* __restrict__ cw, const float* __restrict__ cb,
                          __bf16* __restrict__ out, int row0)
{
  __shared__ float f[3][258];
  __shared__ float wsm[CH * 9];
  __shared__ float bsm[CH];
  int i = row0 + blockIdx.x;
  int h = threadIdx.x;
  int j = (i < NT) ? i : i - NT;
  int a0 = (i < NT) ? tt[j * 3 + 0] : tt[j * 3 + 2];
  int a1 = (i < NT) ? tt[j * 3 + 1] : tt[j * 3 + 1] + NR;
  f[0][h + 1] = ent[(size_t)a0 * H + h];
  f[1][h + 1] = rel[(size_t)a1 * H + h];
  f[2][h + 1] = sent[(size_t)j * H + h];
  if (h < 3) { f[h][0] = 0.f; f[h][257] = 0.f; }
  for (int x = h; x < CH * 9; x += 256) wsm[x] = cw[x];
  if (h < CH) bsm[h] = cb[h];
  __syncthreads();
  __bf16* orow = out + (size_t)blockIdx.x * KFC;
  for (int c = 0; c < CH; c++) {
    const float* wc = wsm + c * 9;
    float s = bsm[c];
    #pragma unroll
    for (int ic = 0; ic < 3; ic++)
      s += wc[ic * 3 + 0] * f[ic][h] + wc[ic * 3 + 1] * f[ic][h + 1] + wc[ic * 3 + 2] * f[ic][h + 2];
    orow[(size_t)c * H + h] = (__bf16)fmaxf(s, 0.f);
  }
}

// one wave per row: nll[row] = log(sum_c part_l) - q[row].ent[tgt]
__global__ void lse_combine(const float* __restrict__ part_l, const float* __restrict__ qf,
                            const float* __restrict__ ent, const int* __restrict__ tt,
                            float* __restrict__ nll)
{
  int gid = blockIdx.x * 256 + threadIdx.x;
  int w = gid >> 6;
  if (w >= NT2) return;
  int lane = gid & 63;
  int j = (w < NT) ? w : w - NT;
  int tgt = (w < NT) ? tt[j * 3 + 2] : tt[j * 3 + 0];
  const float4 qa = ((const float4*)(qf + (size_t)w * H))[lane];
  const float4 ea = ((const float4*)(ent + (size_t)tgt * H))[lane];
  float d = qa.x * ea.x + qa.y * ea.y + qa.z * ea.z + qa.w * ea.w;
  float s = (lane < NCHUNK) ? part_l[(size_t)lane * ROWPAD + w] : 0.f;
  #pragma unroll
  for (int o = 32; o > 0; o >>= 1) {
    d += __shfl_down(d, o, 64);
    s += __shfl_down(s, o, 64);
  }
  if (lane == 0) nll[w] = logf(s) - d;
}

__global__ void mean_nll(const float* __restrict__ nll, float* __restrict__ out)
{
  float s = 0.f;
  for (int i = threadIdx.x; i < NT2; i += 256) s += nll[i];
  s = block_sum256(s);
  if (threadIdx.x == 0) out[0] = s * (1.f / NT2);
}

// ------------------------- launcher ----------------------------------------
extern "C" void kernel_launch(void* const* d_in, const int* in_sizes, int n_in,
                              void* d_out, int out_size, void* d_ws, size_t ws_size,
                              hipStream_t stream)
{
  const float* dynamic_emb = (const float*)d_in[0];
  const float* emb_rel     = (const float*)d_in[1];
  const float* gru_W_ih    = (const float*)d_in[2];
  const float* gru_W_hh    = (const float*)d_in[3];
  const float* gru_b_ih    = (const float*)d_in[4];
  const float* gru_b_hh    = (const float*)d_in[5];
  const float* agg_W       = (const float*)d_in[6];
  const float* tg_W        = (const float*)d_in[7];
  const float* tg_b        = (const float*)d_in[8];
  const float* hev         = (const float*)d_in[9];
  const float* hrv         = (const float*)d_in[10];
  const float* conv_w      = (const float*)d_in[11];
  const float* conv_b      = (const float*)d_in[12];
  const float* fc_W        = (const float*)d_in[13];
  const float* fc_b        = (const float*)d_in[14];
  const float* sent        = (const float*)d_in[15];
  const int* edge_src = (const int*)d_in[16];
  const int* edge_rel = (const int*)d_in[17];
  const int* edge_dst = (const int*)d_in[18];
  const int* r_to_e   = (const int*)d_in[19];
  const int* r_ids    = (const int*)d_in[20];
  const int* he_row   = (const int*)d_in[21];
  const int* he_col   = (const int*)d_in[22];
  const int* hr_row   = (const int*)d_in[23];
  const int* hr_col   = (const int*)d_in[24];
  const int* tt       = (const int*)d_in[25];
  float* out = (float*)d_out;

  char* base = (char*)d_ws;
  size_t off = 0;
  auto alloc = [&](size_t bytes) { char* p = base + off; off += (bytes + 255) & ~(size_t)255; return p; };

  float* ent    = (float*)alloc((size_t)NE * H * 4);
  float* curr   = (float*)alloc((size_t)NE * H * 4);   // + tgbuf: conv_bf overlay (41 MB)
  float* tgbuf  = (float*)alloc((size_t)NE * H * 4);
  __bf16* convb = (__bf16*)curr;                        // 1600*12800*2 = 40.96 MB
  __bf16* entb  = (__bf16*)alloc((size_t)NE * H * 2);
  __bf16* entb2 = (__bf16*)alloc((size_t)NE * H * 2);
  __bf16* accEb = (__bf16*)alloc((size_t)NE * H * 2);
  float* rel    = (float*)alloc((size_t)R2 * H * 4);
  float* accR   = (float*)alloc((size_t)R2 * H * 4);
  __bf16* relb  = (__bf16*)alloc((size_t)R2 * H * 2);
  __bf16* xinb  = (__bf16*)alloc((size_t)R2 * 2 * H * 2);
  float* gi     = (float*)alloc((size_t)R2 * H3 * 4);
  float* gh     = (float*)alloc((size_t)R2 * H3 * 4);
  float* qf     = (float*)alloc((size_t)NT2 * H * 4);
  __bf16* qb    = (__bf16*)alloc((size_t)NT2 * H * 2);
  float* part_l = (float*)alloc((size_t)NCHUNK * ROWPAD * 4);
  float* partM  = (float*)alloc((size_t)R2 * MSPLIT * H * 4);
  float* fcpart = (float*)alloc((size_t)FSPLIT * 1600 * H * 4);
  float* nll    = (float*)alloc((size_t)NT2 * 4);
  __bf16* tgWtb = (__bf16*)alloc((size_t)H * H * 2);
  __bf16* aggWtb= (__bf16*)alloc((size_t)H * H * 2);
  __bf16* fcWtb = (__bf16*)alloc((size_t)H * KFC * 2);
  __bf16* Wihb  = (__bf16*)alloc((size_t)H3 * 2 * H * 2);
  __bf16* Whhb  = (__bf16*)alloc((size_t)H3 * H * 2);

  int* ip = (int*)alloc(0);
  size_t ioff = 0;
  auto ialloc = [&](size_t n) { int* p = ip + ioff; ioff += n; return p; };
  int* fidxM[TT];
  int* fsrcE[TT]; int* frelE[TT];
  for (int t = 0; t < TT; t++) fidxM[t] = ialloc(M);
  for (int t = 0; t < TT; t++) { fsrcE[t] = ialloc(NEDGE); frelE[t] = ialloc(NEDGE); }
  int* fcolHE = ialloc(NNZ_E); float* fvalHE = (float*)ialloc(NNZ_E);
  int* fcolHR = ialloc(NNZ_R); float* fvalHR = (float*)ialloc(NNZ_R);
  int* cnt_all    = ialloc(CNT_TOTAL);
  int* start_all  = ialloc(CNT_TOTAL);
  int* cursor_all = ialloc(CNT_TOTAL);
  int* bcnt  = ialloc((size_t)4 * NB_CS * 512);
  int* bbase = ialloc((size_t)4 * NB_CS * 512);

  // CSR slot offsets: 0-2 = r_ids t; 3 = hr; 4-6 = edge_dst t; 7 = he
  int* sM[TT];  for (int t = 0; t < TT; t++) sM[t] = start_all + t * 512;
  int* sHR = start_all + 1536;
  int* sE[TT];  for (int t = 0; t < TT; t++) sE[t] = start_all + CNT_NE_BASE + t * CNT_NE_STRIDE;
  int* sHE = start_all + CNT_NE_BASE + 3 * CNT_NE_STRIDE;

  // --- weight prep (bf16) ---
  transpose_cast_k<<<dim3(H / 32, H / 32), 256, 0, stream>>>(tg_W, tgWtb, H, H);
  transpose_cast_k<<<dim3(H / 32, H / 32), 256, 0, stream>>>(agg_W, aggWtb, H, H);
  transpose_cast_k<<<dim3(KFC / 32, H / 32), 256, 0, stream>>>(fc_W, fcWtb, KFC, H);
  cast_bf16_k<<<(H3 * 2 * H / 8 + 255) / 256, 256, 0, stream>>>(gru_W_ih, Wihb, H3 * 2 * H / 8);
  cast_bf16_k<<<(H3 * H / 8 + 255) / 256, 256, 0, stream>>>(gru_W_hh, Whhb, H3 * H / 8);

  // --- CSR build: counting-sort for R2-keyed arrays (no global atomics) ---
  cs_hist_k<<<dim3(NB_CS, 4), 256, 0, stream>>>(r_ids, hr_row, bcnt);
  cs_scan_k<<<4, 256, 0, stream>>>(bcnt, bbase, start_all);
  cs_scatter_k<<<dim3(NB_CS, 4), 256, 0, stream>>>(r_ids, r_to_e, hr_row, hr_col, hrv, bbase,
                                                   fidxM[0], fidxM[1], fidxM[2], fcolHR, fvalHR);

  // --- CSR build: NE-keyed arrays (low contention, atomics fine) ---
  hipMemsetAsync(cnt_all + CNT_NE_BASE, 0, (size_t)(CNT_TOTAL - CNT_NE_BASE) * 4, stream);
  hist_ne_k<<<dim3((NNZ_E + 255) / 256, 4), 256, 0, stream>>>(edge_dst, he_row, cnt_all);
  scan_ne_k<<<4, 256, 0, stream>>>(cnt_all, start_all, cursor_all);
  for (int t = 0; t < TT; t++)
    perm_fuse2_k<<<(NEDGE + 255) / 256, 256, 0, stream>>>(
        edge_dst + (size_t)t * NEDGE, edge_src + (size_t)t * NEDGE, edge_rel + (size_t)t * NEDGE,
        NEDGE, cursor_all + CNT_NE_BASE + t * CNT_NE_STRIDE, fsrcE[t], frelE[t]);
  perm_fusev_k<<<(NNZ_E + 255) / 256, 256, 0, stream>>>(
      he_row, he_col, hev, NNZ_E, cursor_all + CNT_NE_BASE + 3 * CNT_NE_STRIDE, fcolHE, fvalHE);

  hipMemcpyAsync(ent, dynamic_emb, (size_t)NE * H * 4, hipMemcpyDeviceToDevice, stream);
  hipMemcpyAsync(rel, emb_rel, (size_t)R2 * H * 4, hipMemcpyDeviceToDevice, stream);

  constexpr int NEH8 = NE * H / 8, R2H8 = R2 * H / 8;
  constexpr int NE_RB = (NE + 127) / 128;   // 157

  cast_bf16_k<<<(NEH8 + 255) / 256, 256, 0, stream>>>(ent, entb, NEH8);
  cast_bf16_k<<<(R2H8 + 255) / 256, 256, 0, stream>>>(rel, relb, R2H8);

  for (int t = 0; t < TT; t++) {
    // --- rel update (GRU) ---
    gather_mean2_k<<<dim3(R2, MSPLIT), 256, 0, stream>>>(entb, fidxM[t], sM[t], partM);
    mean_xin_k<<<R2, 256, 0, stream>>>(partM, sM[t], rel, xinb);
    mfma_gemm<0><<<dim3(H3 / 64, (R2 + 63) / 64), 256, 0, stream>>>(
        xinb, Wihb, gru_b_ih, gi, R2, 2 * H, H3);
    mfma_gemm<0><<<dim3(H3 / 64, (R2 + 63) / 64), 256, 0, stream>>>(
        relb, Whhb, gru_b_hh, gh, R2, H, H3);
    gru_combine<<<(R2 * H + 255) / 256, 256, 0, stream>>>(gi, gh, rel, relb);

    // --- ent update ---
    panel2_gemm<2><<<dim3(2, NE_RB), 256, 0, stream>>>(entb, tgWtb, tg_b, tgbuf, NE, H, 2);
    gather_edges3_k<<<NE, 256, 0, stream>>>(entb, relb, fsrcE[t], frelE[t], sE[t], accEb);
    panel2_gemm<1><<<dim3(2, NE_RB), 256, 0, stream>>>(accEb, aggWtb, nullptr, curr, NE, H, 2);
    ent_update<<<(NE * H + 255) / 256, 256, 0, stream>>>(ent, entb, tgbuf, curr);
  }

  // --- hypergraph layers ---
  hyper3_k<<<NE, 256, 0, stream>>>(ent, entb, fvalHE, fcolHE, sHE, curr, entb2);
  hyper3_k<<<NE, 256, 0, stream>>>(curr, entb2, fvalHE, fcolHE, sHE, ent, entb);
  hyper_rel_k<<<R2, 256, 0, stream>>>(rel, fvalHR, fcolHR, sHR, accR);
  hyper_rel_k<<<R2, 256, 0, stream>>>(accR, fvalHR, fcolHR, sHR, rel);

  // --- conv + fc (3 chunks: 1600, 1600, 800 rows) ---
  for (int c = 0; c < 3; c++) {
    int row0 = c * 1600;
    int rows = min(1600, NT2 - row0);
    conv_feat<<<rows, 256, 0, stream>>>(ent, rel, sent, tt, conv_w, conv_b, convb, row0);
    fc_gemm<<<dim3(FSPLIT, (rows + 127) / 128), 256, 0, stream>>>(convb, fcWtb, fcpart, rows);
    fc_reduce<<<(rows * H + 255) / 256, 256, 0, stream>>>(
        fcpart, fc_b, qf + (size_t)row0 * H, qb + (size_t)row0 * H, rows);
  }

  // --- fused scores + LSE: 32 col-chunks x 32 row-blocks, PS=10 (640 cols) ---
  panel2_gemm<3><<<dim3(NCHUNK, 32), 256, 0, stream>>>(qb, entb, nullptr, part_l, NT2, NE, 10);
  lse_combine<<<(NT2 * 64 + 255) / 256, 256, 0, stream>>>(part_l, qf, ent, tt, nll);
  mean_nll<<<1, 256, 0, stream>>>(nll, out);
}

// Round 10
// 1049.686 us; speedup vs baseline: 8.6569x; 1.0383x over previous
//
#include <hip/hip_runtime.h>
#include <math.h>

#define DEV_INLINE __device__ __forceinline__

constexpr int H      = 256;
constexpr int NE     = 20000;
constexpr int NR     = 250;
constexpr int R2     = 500;
constexpr int TT     = 3;
constexpr int NEDGE  = 150000;
constexpr int M      = 200000;
constexpr int NNZ_E  = 320000;
constexpr int NNZ_R  = 8000;
constexpr int CH     = 50;
constexpr int NT     = 2000;
constexpr int NT2    = 4000;
constexpr int H3     = 3 * H;     // 768
constexpr int KFC    = CH * H;    // 12800
constexpr int ROWPAD = 4096;
constexpr int NCHUNK = 32;        // scores col chunks (x PS=10 panels x 64 cols)
constexpr int MSPLIT = 8;         // gather_mean row split
constexpr int FSPLIT = 10;        // fc split-K
constexpr int NB_CS  = 64;        // counting-sort blocks per R2 array
constexpr int NEPAD  = 20480;     // ent rows padded to 64

// cnt/start/cursor packed region (ints)
constexpr int CNT_NE_BASE   = 2048;
constexpr int CNT_NE_STRIDE = 20224;
constexpr int CNT_TOTAL     = CNT_NE_BASE + 4 * CNT_NE_STRIDE;  // 82944

typedef __bf16 bf16x8 __attribute__((ext_vector_type(8)));
typedef float  f32x4  __attribute__((ext_vector_type(4)));

DEV_INLINE bf16x8 ldb8(const __bf16* p) { return *(const bf16x8*)p; }
DEV_INLINE bf16x8 zerob8() { uint4 z = make_uint4(0, 0, 0, 0); return __builtin_bit_cast(bf16x8, z); }
DEV_INLINE f32x4 mfma16(bf16x8 a, bf16x8 b, f32x4 c) {
  return __builtin_amdgcn_mfma_f32_16x16x32_bf16(a, b, c, 0, 0, 0);
}
DEV_INLINE void gload_lds16(const void* g, void* l) {
  __builtin_amdgcn_global_load_lds((const __attribute__((address_space(1))) void*)g,
                                   (__attribute__((address_space(3))) void*)l, 16, 0, 0);
}

// ------------------------- block reduction (blockDim == 256) ---------------
DEV_INLINE float block_sum256(float v) {
  __shared__ float ws[4];
  #pragma unroll
  for (int o = 32; o > 0; o >>= 1) v += __shfl_down(v, o, 64);
  if ((threadIdx.x & 63) == 0) ws[threadIdx.x >> 6] = v;
  __syncthreads();
  float r = ws[0] + ws[1] + ws[2] + ws[3];
  __syncthreads();
  return r;
}

// ------------------- counting-sort CSR (R2-keyed arrays) -------------------
__global__ void cs_hist_k(const int* __restrict__ r_ids, const int* __restrict__ hr_row,
                          int* __restrict__ bcnt)
{
  __shared__ int lh[512];
  int a = blockIdx.y;
  const int* keys = (a < 3) ? r_ids + (size_t)a * M : hr_row;
  int n = (a < 3) ? M : NNZ_R;
  int t = threadIdx.x;
  lh[t] = 0; lh[t + 256] = 0;
  __syncthreads();
  int chunk = (n + NB_CS - 1) / NB_CS;
  int i0 = blockIdx.x * chunk, i1 = min(i0 + chunk, n);
  for (int i = i0 + t; i < i1; i += 256) atomicAdd(&lh[keys[i]], 1);
  __syncthreads();
  int* outp = bcnt + ((size_t)a * NB_CS + blockIdx.x) * 512;
  outp[t] = lh[t]; outp[t + 256] = lh[t + 256];
}

__global__ void cs_scan_k(const int* __restrict__ bcnt, int* __restrict__ bbase,
                          int* __restrict__ start_all)
{
  __shared__ int ps[257];
  int a = blockIdx.x;
  int* start = start_all + ((a < 3) ? a * 512 : 1536);
  const int* bc = bcnt + (size_t)a * NB_CS * 512;
  int* bb = bbase + (size_t)a * NB_CS * 512;
  int t = threadIdx.x;
  int b0 = 2 * t, b1 = 2 * t + 1;
  int tot0 = 0, tot1 = 0;
  for (int blk = 0; blk < NB_CS; blk++) {
    tot0 += bc[blk * 512 + b0];
    tot1 += bc[blk * 512 + b1];
  }
  ps[t + 1] = tot0 + tot1;
  if (t == 0) ps[0] = 0;
  __syncthreads();
  if (t == 0) { for (int i = 1; i <= 256; i++) ps[i] += ps[i - 1]; }
  __syncthreads();
  int run0 = ps[t], run1 = ps[t] + tot0;
  start[b0] = run0;
  start[b1] = run1;
  for (int blk = 0; blk < NB_CS; blk++) {
    bb[blk * 512 + b0] = run0; run0 += bc[blk * 512 + b0];
    bb[blk * 512 + b1] = run1; run1 += bc[blk * 512 + b1];
  }
}

__global__ void cs_scatter_k(const int* __restrict__ r_ids, const int* __restrict__ r_to_e,
                             const int* __restrict__ hr_row, const int* __restrict__ hr_col,
                             const float* __restrict__ hrv, const int* __restrict__ bbase,
                             int* __restrict__ f0, int* __restrict__ f1, int* __restrict__ f2,
                             int* __restrict__ fcolHR, float* __restrict__ fvalHR)
{
  __shared__ int cur[512];
  int a = blockIdx.y;
  const int* keys = (a < 3) ? r_ids + (size_t)a * M : hr_row;
  int n = (a < 3) ? M : NNZ_R;
  int t = threadIdx.x;
  const int* bb = bbase + ((size_t)a * NB_CS + blockIdx.x) * 512;
  cur[t] = bb[t]; cur[t + 256] = bb[t + 256];
  __syncthreads();
  int chunk = (n + NB_CS - 1) / NB_CS;
  int i0 = blockIdx.x * chunk, i1 = min(i0 + chunk, n);
  if (a < 3) {
    const int* other = r_to_e + (size_t)a * M;
    int* f = (a == 0) ? f0 : (a == 1) ? f1 : f2;
    for (int i = i0 + t; i < i1; i += 256) {
      int p = atomicAdd(&cur[keys[i]], 1);
      f[p] = other[i];
    }
  } else {
    for (int i = i0 + t; i < i1; i += 256) {
      int p = atomicAdd(&cur[keys[i]], 1);
      fcolHR[p] = hr_col[i];
      fvalHR[p] = hrv[i];
    }
  }
}

// ------------------- NE-keyed CSR (low contention) -------------------------
__global__ void hist_ne_k(const int* __restrict__ edge_dst, const int* __restrict__ he_row,
                          int* __restrict__ cnt_all)
{
  int a = blockIdx.y;
  const int* keys = (a < 3) ? edge_dst + (size_t)a * NEDGE : he_row;
  int n = (a < 3) ? NEDGE : NNZ_E;
  int* cnt = cnt_all + CNT_NE_BASE + a * CNT_NE_STRIDE;
  int i = blockIdx.x * 256 + threadIdx.x;
  if (i < n) atomicAdd(&cnt[keys[i]], 1);
}

__global__ void scan_ne_k(const int* __restrict__ cnt_all, int* __restrict__ start_all,
                          int* __restrict__ cursor_all)
{
  __shared__ int ps[257];
  int off = CNT_NE_BASE + blockIdx.x * CNT_NE_STRIDE;
  const int nbins = NE;
  const int* cnt = cnt_all + off;
  int* start  = start_all + off;
  int* cursor = cursor_all + off;
  int t = threadIdx.x;
  int per = (nbins + 255) >> 8;
  int b0 = t * per;
  int local = 0;
  for (int i = 0; i < per; i++) { int bb = b0 + i; if (bb < nbins) local += cnt[bb]; }
  ps[t + 1] = local;
  if (t == 0) ps[0] = 0;
  __syncthreads();
  if (t == 0) { for (int i = 1; i <= 256; i++) ps[i] += ps[i - 1]; }
  __syncthreads();
  int run = ps[t];
  for (int i = 0; i < per; i++) {
    int bb = b0 + i;
    if (bb < nbins) { start[bb] = run; cursor[bb] = run; run += cnt[bb]; }
  }
  if (t == 0) start[nbins] = ps[256];
}

__global__ void perm_fuse2_k(const int* __restrict__ keys, const int* __restrict__ o1,
                             const int* __restrict__ o2, int n, int* __restrict__ cursor,
                             int* __restrict__ f1, int* __restrict__ f2)
{
  int i = blockIdx.x * 256 + threadIdx.x;
  if (i < n) { int p = atomicAdd(&cursor[keys[i]], 1); f1[p] = o1[i]; f2[p] = o2[i]; }
}
__global__ void perm_fusev_k(const int* __restrict__ keys, const int* __restrict__ col,
                             const float* __restrict__ val, int n, int* __restrict__ cursor,
                             int* __restrict__ fcol, float* __restrict__ fval)
{
  int i = blockIdx.x * 256 + threadIdx.x;
  if (i < n) { int p = atomicAdd(&cursor[keys[i]], 1); fcol[p] = col[i]; fval[p] = val[i]; }
}

// ------------------------- casts / transposes ------------------------------
__global__ void cast_bf16_k(const float* __restrict__ in, __bf16* __restrict__ out, int n8)
{
  int i = blockIdx.x * 256 + threadIdx.x;
  if (i >= n8) return;
  const float4* p = (const float4*)in + (size_t)i * 2;
  float4 u = p[0], v = p[1];
  bf16x8 o;
  o[0] = (__bf16)u.x; o[1] = (__bf16)u.y; o[2] = (__bf16)u.z; o[3] = (__bf16)u.w;
  o[4] = (__bf16)v.x; o[5] = (__bf16)v.y; o[6] = (__bf16)v.z; o[7] = (__bf16)v.w;
  ((bf16x8*)out)[i] = o;
}

__global__ void transpose_cast_k(const float* __restrict__ in, __bf16* __restrict__ out,
                                 int K, int N)
{
  __shared__ float tile[32][33];
  int tx = threadIdx.x & 31, ty = threadIdx.x >> 5;   // 32 x 8
  int kb = blockIdx.x * 32, nb = blockIdx.y * 32;
  #pragma unroll
  for (int i = 0; i < 4; i++)
    tile[ty + i * 8][tx] = in[(size_t)(kb + ty + i * 8) * N + nb + tx];
  __syncthreads();
  #pragma unroll
  for (int i = 0; i < 4; i++)
    out[(size_t)(nb + ty + i * 8) * K + kb + tx] = (__bf16)tile[tx][ty + i * 8];
}

// reorder [rows][256] bf16 into MFMA-frag-linear layout:
// chunk index = (((row>>6)*4 + ((row>>4)&3))*8 + kf)*4 + kg)*16 + (row&15), 16B each
// where s = chunk-in-row (0..31), kf = s>>2, kg = s&3. rows >= Mr read as zero.
__global__ void pack_frag_k(const __bf16* __restrict__ src, __bf16* __restrict__ dst,
                            int nchunks, int Mr)
{
  int i = blockIdx.x * 256 + threadIdx.x;
  if (i >= nchunks) return;
  int c = i >> 5, s = i & 31;
  bf16x8 v = (c < Mr) ? ldb8(src + (size_t)c * H + s * 8) : zerob8();
  int kf = s >> 2, kg = s & 3;
  size_t d = ((((size_t)(c >> 6) * 4 + ((c >> 4) & 3)) * 8 + kf) * 4 + kg) * 16 + (c & 15);
  *(bf16x8*)(dst + d * 8) = v;
}

// ------------------------- gather kernels (16 B/lane, 32-lane halves) ------
__global__ void gather_mean2_k(const __bf16* __restrict__ src, const int* __restrict__ fidx,
                               const int* __restrict__ start, float* __restrict__ part)
{
  __shared__ __align__(16) float red[4][H];
  int r = blockIdx.x, s = blockIdx.y;
  int s0 = start[r], s1 = start[r + 1];
  int len = s1 - s0;
  int chunk = (len + MSPLIT - 1) / MSPLIT;
  int jb = s0 + s * chunk, je = min(jb + chunk, s1);
  int tid = threadIdx.x, lane = tid & 63, w = tid >> 6;
  int half = lane >> 5, l = lane & 31;
  float acc[8] = {0.f, 0.f, 0.f, 0.f, 0.f, 0.f, 0.f, 0.f};
  for (int j = jb + w * 2 + half; j < je; j += 8) {
    int e = fidx[j];
    bf16x8 v = ldb8(src + (size_t)e * H + l * 8);
    #pragma unroll
    for (int q = 0; q < 8; q++) acc[q] += (float)v[q];
  }
  #pragma unroll
  for (int q = 0; q < 8; q++) acc[q] += __shfl_xor(acc[q], 32, 64);
  if (half == 0) {
    *(float4*)&red[w][l * 8]     = make_float4(acc[0], acc[1], acc[2], acc[3]);
    *(float4*)&red[w][l * 8 + 4] = make_float4(acc[4], acc[5], acc[6], acc[7]);
  }
  __syncthreads();
  int h = tid;
  part[((size_t)r * MSPLIT + s) * H + h] = red[0][h] + red[1][h] + red[2][h] + red[3][h];
}

__global__ void mean_xin_k(const float* __restrict__ partM, const int* __restrict__ start,
                           const float* __restrict__ rel, __bf16* __restrict__ xin)
{
  int r = blockIdx.x, h = threadIdx.x;
  float s = 0.f;
  #pragma unroll
  for (int z = 0; z < MSPLIT; z++) s += partM[((size_t)r * MSPLIT + z) * H + h];
  float xm = s / (float)max(start[r + 1] - start[r], 1);
  xin[(size_t)r * 2 * H + h]     = (__bf16)rel[(size_t)r * H + h];
  xin[(size_t)r * 2 * H + H + h] = (__bf16)xm;
}

__global__ void gather_edges3_k(const __bf16* __restrict__ ent, const __bf16* __restrict__ rel,
                                const int* __restrict__ fsrc, const int* __restrict__ frel,
                                const int* __restrict__ start, __bf16* __restrict__ out)
{
  __shared__ __align__(16) float red[4][H];
  int d = blockIdx.x;
  int s0 = start[d], s1 = start[d + 1];
  int tid = threadIdx.x, lane = tid & 63, w = tid >> 6;
  int half = lane >> 5, l = lane & 31;
  const __bf16* srcbase = half ? rel : ent;
  const int* idx = half ? frel : fsrc;
  float acc[8] = {0.f, 0.f, 0.f, 0.f, 0.f, 0.f, 0.f, 0.f};
  for (int j = s0 + w; j < s1; j += 4) {
    int e = idx[j];
    bf16x8 v = ldb8(srcbase + (size_t)e * H + l * 8);
    #pragma unroll
    for (int q = 0; q < 8; q++) acc[q] += (float)v[q];
  }
  #pragma unroll
  for (int q = 0; q < 8; q++) acc[q] += __shfl_xor(acc[q], 32, 64);
  if (half == 0) {
    *(float4*)&red[w][l * 8]     = make_float4(acc[0], acc[1], acc[2], acc[3]);
    *(float4*)&red[w][l * 8 + 4] = make_float4(acc[4], acc[5], acc[6], acc[7]);
  }
  __syncthreads();
  int h = tid;
  float sum = red[0][h] + red[1][h] + red[2][h] + red[3][h];
  out[(size_t)d * H + h] = (__bf16)(sum / (float)max(s1 - s0, 1));
}

__global__ void hyper3_k(const float* __restrict__ x, const __bf16* __restrict__ xb,
                         const float* __restrict__ fval, const int* __restrict__ fcol,
                         const int* __restrict__ start,
                         float* __restrict__ xout, __bf16* __restrict__ xoutb)
{
  __shared__ __align__(16) float red[4][H];
  int r = blockIdx.x;
  int s0 = start[r], s1 = start[r + 1];
  int tid = threadIdx.x, lane = tid & 63, w = tid >> 6;
  int half = lane >> 5, l = lane & 31;
  float acc[8] = {0.f, 0.f, 0.f, 0.f, 0.f, 0.f, 0.f, 0.f};
  for (int j = s0 + w * 2 + half; j < s1; j += 8) {
    int e = fcol[j];
    float wt = fval[j];
    bf16x8 v = ldb8(xb + (size_t)e * H + l * 8);
    #pragma unroll
    for (int q = 0; q < 8; q++) acc[q] += wt * (float)v[q];
  }
  #pragma unroll
  for (int q = 0; q < 8; q++) acc[q] += __shfl_xor(acc[q], 32, 64);
  if (half == 0) {
    *(float4*)&red[w][l * 8]     = make_float4(acc[0], acc[1], acc[2], acc[3]);
    *(float4*)&red[w][l * 8 + 4] = make_float4(acc[4], acc[5], acc[6], acc[7]);
  }
  __syncthreads();
  int h = tid;
  float y = red[0][h] + red[1][h] + red[2][h] + red[3][h];
  float ss = block_sum256(y * y);
  float rn = 1.f / fmaxf(sqrtf(ss), 1e-12f);
  float o = x[(size_t)r * H + h] + y * rn;
  xout[(size_t)r * H + h] = o;
  xoutb[(size_t)r * H + h] = (__bf16)o;
}

__global__ void hyper_rel_k(const float* __restrict__ x, const float* __restrict__ fval,
                            const int* __restrict__ fcol, const int* __restrict__ start,
                            float* __restrict__ xout)
{
  int r = blockIdx.x, h = threadIdx.x;
  int s0 = start[r], s1 = start[r + 1];
  float a0 = 0.f;
  for (int j = s0; j < s1; j++) a0 += fval[j] * x[(size_t)fcol[j] * H + h];
  float ss = block_sum256(a0 * a0);
  float rn = 1.f / fmaxf(sqrtf(ss), 1e-12f);
  xout[(size_t)r * H + h] = x[(size_t)r * H + h] + a0 * rn;
}

// ------------------------- small elementwise -------------------------------
__global__ void gru_combine(const float* __restrict__ gi, const float* __restrict__ gh,
                            float* __restrict__ rel, __bf16* __restrict__ relb)
{
  int idx = blockIdx.x * 256 + threadIdx.x;       // R2 * H
  if (idx >= R2 * H) return;
  int i = idx >> 8, h = idx & 255;
  const float* gir = gi + (size_t)i * H3;
  const float* ghr = gh + (size_t)i * H3;
  float r = 1.f / (1.f + __expf(-(gir[h]       + ghr[h])));
  float z = 1.f / (1.f + __expf(-(gir[H + h]   + ghr[H + h])));
  float n = tanhf(gir[2 * H + h] + r * ghr[2 * H + h]);
  float o = (1.f - z) * n + z * rel[idx];
  rel[idx] = o;
  relb[idx] = (__bf16)o;
}

__global__ void ent_update(float* __restrict__ ent, __bf16* __restrict__ entb,
                           const float* __restrict__ tw, const float* __restrict__ curr)
{
  int idx = blockIdx.x * 256 + threadIdx.x;       // NE * H
  if (idx >= NE * H) return;
  float t = tw[idx];
  float v = t * curr[idx] + (1.f - t) * ent[idx];
  ent[idx] = v;
  entb[idx] = (__bf16)v;
}

// ------------------------- panel2 GEMM (K=256, dbuf 64-col B panels) --------
DEV_INLINE void stage64_load(uint4* v, const __bf16* src, int rowBase, int rowLimit, int tid)
{
  #pragma unroll
  for (int q = 0; q < 8; q++) {
    int X = (q * 256 + tid) * 16;
    int row = X >> 9, boff = X & 511;
    int grow = min(rowBase + row, rowLimit);
    v[q] = *(const uint4*)((const char*)src + (size_t)grow * 512 + boff);
  }
}
DEV_INLINE void stage64_write(char* lds, const uint4* v, int tid)
{
  #pragma unroll
  for (int q = 0; q < 8; q++) {
    int X = (q * 256 + tid) * 16;
    int row = X >> 9;
    *(uint4*)(lds + (X ^ ((row & 7) << 4))) = v[q];
  }
}
DEV_INLINE void stage32_load(uint4* v, const __bf16* src, int rowBase, int rowLimit, int tid, int hf)
{
  #pragma unroll
  for (int q = 0; q < 4; q++) {
    int X = ((hf * 4 + q) * 256 + tid) * 16;
    int row = X >> 9, boff = X & 511;
    int grow = min(rowBase + row, rowLimit);
    v[q] = *(const uint4*)((const char*)src + (size_t)grow * 512 + boff);
  }
}
DEV_INLINE void stage32_write(char* lds, const uint4* v, int tid, int hf)
{
  #pragma unroll
  for (int q = 0; q < 4; q++) {
    int X = ((hf * 4 + q) * 256 + tid) * 16;
    int row = X >> 9;
    *(uint4*)(lds + (X ^ ((row & 7) << 4))) = v[q];
  }
}
DEV_INLINE bf16x8 frag64(const char* lds, int row, int kf, int kg)
{
  int off = (kf * 64 + kg * 16) ^ ((row & 7) << 4);
  return *(const bf16x8*)(lds + row * 512 + off);
}

template<int EPI>
__global__ __launch_bounds__(256, 2) void panel2_gemm(const __bf16* __restrict__ A,
                                                      const __bf16* __restrict__ B,
                                                      const float* __restrict__ bias,
                                                      float* __restrict__ out,
                                                      int Mr, int N, int PS)
{
  __shared__ __attribute__((aligned(16))) char lds0[32768];
  __shared__ __attribute__((aligned(16))) char lds1[32768];
  int tid = threadIdx.x;
  int lane = tid & 63, wM = tid >> 6;
  int r = lane & 15, kg = lane >> 4;
  int rowBase = blockIdx.y * 128;

  {
    uint4 va[8];
    stage64_load(va, A, rowBase, Mr - 1, tid);
    stage64_write(lds0, va, tid);
    stage64_load(va, A, rowBase + 64, Mr - 1, tid);
    stage64_write(lds1, va, tid);
  }
  __syncthreads();

  bf16x8 a[2][8];
  {
    int base = wM * 32;
    const char* ab = (base >= 64) ? lds1 : lds0;
    #pragma unroll
    for (int i = 0; i < 2; i++) {
      int ar = (base + i * 16 + r) & 63;
      #pragma unroll
      for (int kf = 0; kf < 8; kf++) a[i][kf] = frag64(ab, ar, kf, kg);
    }
  }
  int p0 = blockIdx.x * PS;
  __syncthreads();
  {
    uint4 va[8];
    stage64_load(va, B, p0 * 64, N - 1, tid);
    stage64_write(lds0, va, tid);
  }
  __syncthreads();

  for (int p = 0; p < PS; p++) {
    char* cur = (p & 1) ? lds1 : lds0;
    char* nxt = (p & 1) ? lds0 : lds1;
    bool pre = (p + 1 < PS);
    uint4 v4[4];
    if (pre) stage32_load(v4, B, (p0 + p + 1) * 64, N - 1, tid, 0);

    f32x4 acc[2][4];
    #pragma unroll
    for (int i = 0; i < 2; i++)
      #pragma unroll
      for (int j = 0; j < 4; j++) {
        acc[i][j][0] = 0.f; acc[i][j][1] = 0.f; acc[i][j][2] = 0.f; acc[i][j][3] = 0.f;
      }
    __builtin_amdgcn_s_setprio(1);
    #pragma unroll
    for (int kf = 0; kf < 4; kf++) {
      bf16x8 b[4];
      #pragma unroll
      for (int j = 0; j < 4; j++) b[j] = frag64(cur, j * 16 + r, kf, kg);
      #pragma unroll
      for (int i = 0; i < 2; i++)
        #pragma unroll
        for (int j = 0; j < 4; j++)
          acc[i][j] = mfma16(a[i][kf], b[j], acc[i][j]);
    }
    __builtin_amdgcn_s_setprio(0);
    if (pre) {
      stage32_write(nxt, v4, tid, 0);
      stage32_load(v4, B, (p0 + p + 1) * 64, N - 1, tid, 1);
    }
    __builtin_amdgcn_s_setprio(1);
    #pragma unroll
    for (int kf = 4; kf < 8; kf++) {
      bf16x8 b[4];
      #pragma unroll
      for (int j = 0; j < 4; j++) b[j] = frag64(cur, j * 16 + r, kf, kg);
      #pragma unroll
      for (int i = 0; i < 2; i++)
        #pragma unroll
        for (int j = 0; j < 4; j++)
          acc[i][j] = mfma16(a[i][kf], b[j], acc[i][j]);
    }
    __builtin_amdgcn_s_setprio(0);
    if (pre) stage32_write(nxt, v4, tid, 1);

    #pragma unroll
    for (int i = 0; i < 2; i++)
      #pragma unroll
      for (int g = 0; g < 4; g++) {
        int row = rowBase + wM * 32 + i * 16 + kg * 4 + g;
        if (row >= Mr) continue;
        #pragma unroll
        for (int j = 0; j < 4; j++) {
          int col = (p0 + p) * 64 + j * 16 + r;
          if (col >= N) continue;
          float v = acc[i][j][g];
          if (bias) v += bias[col];
          if (EPI == 1) v = fmaxf(v, 0.f);
          if (EPI == 2) v = 1.f / (1.f + __expf(-v));
          out[(size_t)row * N + col] = v;
        }
      }
    __syncthreads();
  }
}

// ------------------------- scores_v3 (frag-packed, 64-row waves) -----------
// A: qbf frag-packed (4096 rows). B: ebf frag-packed (20480 cols), panels of
// 64 cols = 32KB contiguous, staged linearly into LDS via global_load_lds.
// grid (NCHUNK=32, 16). Block = 4 waves x 64 rows = 256 rows.
// out: part_l[chunk][row] = sum_cols exp2(score)  (qb prescaled by log2 e)
__global__ __launch_bounds__(256, 2) void scores_v3(const __bf16* __restrict__ qbf,
                                                    const __bf16* __restrict__ ebf,
                                                    float* __restrict__ part_l)
{
  __shared__ __attribute__((aligned(16))) char lds[2][32768];
  int tid = threadIdx.x, lane = tid & 63, w = tid >> 6;
  int r = lane & 15, kg = lane >> 4;

  auto stage = [&](int buf, int p) {
    const char* g = (const char*)ebf + ((size_t)(blockIdx.x * 10 + p)) * 32768;
    int wbase = (tid & ~63) * 16;     // wave*1024
    #pragma unroll
    for (int q = 0; q < 8; q++) {
      int o = q * 4096 + wbase;
      gload_lds16(g + o + (lane * 16), lds[buf] + o);
    }
  };

  stage(0, 0);   // panel 0 in flight

  // A fragments: rows = blockIdx.y*256 + w*64 + i*16 + r  (cb = by*4 + w)
  bf16x8 a[4][8];
  {
    const __bf16* ap = qbf + ((size_t)(blockIdx.y * 4 + w)) * 16384 + kg * 128 + r * 8;
    #pragma unroll
    for (int i = 0; i < 4; i++)
      #pragma unroll
      for (int kf = 0; kf < 8; kf++)
        a[i][kf] = ldb8(ap + (i * 8 + kf) * 512);
  }
  __syncthreads();   // drains stage(0) too

  float lsum[4][4];
  #pragma unroll
  for (int i = 0; i < 4; i++)
    #pragma unroll
    for (int g = 0; g < 4; g++) lsum[i][g] = 0.f;

  const char* lane_off0 = lds[0] + kg * 256 + r * 16;
  const char* lane_off1 = lds[1] + kg * 256 + r * 16;

  for (int p = 0; p < 10; p++) {
    if (p + 1 < 10) stage((p + 1) & 1, p + 1);   // async, in flight across MFMA
    const char* cur = (p & 1) ? lane_off1 : lane_off0;

    f32x4 acc[4][4];
    #pragma unroll
    for (int i = 0; i < 4; i++)
      #pragma unroll
      for (int j = 0; j < 4; j++) {
        acc[i][j][0] = 0.f; acc[i][j][1] = 0.f; acc[i][j][2] = 0.f; acc[i][j][3] = 0.f;
      }
    __builtin_amdgcn_s_setprio(1);
    #pragma unroll
    for (int kf = 0; kf < 8; kf++) {
      bf16x8 b[4];
      #pragma unroll
      for (int j = 0; j < 4; j++)
        b[j] = *(const bf16x8*)(cur + (j * 8 + kf) * 1024);
      #pragma unroll
      for (int i = 0; i < 4; i++)
        #pragma unroll
        for (int j = 0; j < 4; j++)
          acc[i][j] = mfma16(a[i][kf], b[j], acc[i][j]);
    }
    __builtin_amdgcn_s_setprio(0);

    #pragma unroll
    for (int j = 0; j < 4; j++) {
      int col = (blockIdx.x * 10 + p) * 64 + j * 16 + r;
      bool ok = col < NE;
      #pragma unroll
      for (int i = 0; i < 4; i++)
        #pragma unroll
        for (int g = 0; g < 4; g++)
          lsum[i][g] += ok ? exp2f(acc[i][j][g]) : 0.f;
    }
    __syncthreads();   // drains next-panel loads (vmcnt0) + barrier
  }

  #pragma unroll
  for (int m = 1; m < 16; m <<= 1)
    #pragma unroll
    for (int i = 0; i < 4; i++)
      #pragma unroll
      for (int g = 0; g < 4; g++)
        lsum[i][g] += __shfl_xor(lsum[i][g], m, 64);
  if (r == 0) {
    #pragma unroll
    for (int i = 0; i < 4; i++)
      #pragma unroll
      for (int g = 0; g < 4; g++) {
        int row = blockIdx.y * 256 + w * 64 + i * 16 + kg * 4 + g;
        part_l[(size_t)blockIdx.x * ROWPAD + row] = lsum[i][g];
      }
  }
}

// ------------------------- fc GEMM (K = 12800, LDS-staged, split-K) --------
__global__ __launch_bounds__(256) void fc_gemm(const __bf16* __restrict__ A,
                                               const __bf16* __restrict__ Bt,
                                               float* __restrict__ part, int Mr)
{
  __shared__ __attribute__((aligned(16))) char lds[49152];
  int tid = threadIdx.x;
  int lane = tid & 63, wave = tid >> 6;
  int wM = wave >> 1, wN = wave & 1;
  int r = lane & 15, kg = lane >> 4;
  int rowBase = blockIdx.y * 128;
  int kbeg = blockIdx.x * (KFC / FSPLIT);   // 1280

  f32x4 acc[4][8];
  #pragma unroll
  for (int i = 0; i < 4; i++)
    #pragma unroll
    for (int j = 0; j < 8; j++) {
      acc[i][j][0] = 0.f; acc[i][j][1] = 0.f; acc[i][j][2] = 0.f; acc[i][j][3] = 0.f;
    }

  for (int ks = 0; ks < 20; ks++) {
    int kb = kbeg + ks * 64;
    #pragma unroll
    for (int q = 0; q < 12; q++) {
      int X = (q * 256 + tid) * 16;
      int row = X >> 7;
      int off = X & 127;
      int soff = off ^ ((row & 7) << 4);
      uint4 v;
      if (row < 128) {
        int grow = min(rowBase + row, Mr - 1);
        v = *(const uint4*)((const char*)A + (size_t)grow * (KFC * 2) + kb * 2 + soff);
      } else {
        int col = row - 128;
        v = *(const uint4*)((const char*)Bt + (size_t)col * (KFC * 2) + kb * 2 + soff);
      }
      *(uint4*)(lds + X) = v;
    }
    __syncthreads();
    #pragma unroll
    for (int kf = 0; kf < 2; kf++) {
      bf16x8 a[4], b[8];
      #pragma unroll
      for (int i = 0; i < 4; i++) {
        int row = wM * 64 + i * 16 + r;
        int off = (kf * 64 + kg * 16) ^ ((row & 7) << 4);
        a[i] = *(const bf16x8*)(lds + row * 128 + off);
      }
      #pragma unroll
      for (int j = 0; j < 8; j++) {
        int row = 128 + wN * 128 + j * 16 + r;
        int off = (kf * 64 + kg * 16) ^ ((row & 7) << 4);
        b[j] = *(const bf16x8*)(lds + row * 128 + off);
      }
      #pragma unroll
      for (int i = 0; i < 4; i++)
        #pragma unroll
        for (int j = 0; j < 8; j++)
          acc[i][j] = mfma16(a[i], b[j], acc[i][j]);
    }
    __syncthreads();
  }

  float* pz = part + (size_t)blockIdx.x * Mr * H;
  #pragma unroll
  for (int i = 0; i < 4; i++)
    #pragma unroll
    for (int g = 0; g < 4; g++) {
      int row = rowBase + wM * 64 + i * 16 + kg * 4 + g;
      if (row >= Mr) continue;
      #pragma unroll
      for (int j = 0; j < 8; j++) {
        int col = wN * 128 + j * 16 + r;
        pz[(size_t)row * H + col] = acc[i][j][g];
      }
    }
}

// ------------------------- generic MFMA GEMM (GRU) -------------------------
template<int ACT>
__global__ void mfma_gemm(const __bf16* __restrict__ A, const __bf16* __restrict__ Bt,
                          const float* __restrict__ bias, float* __restrict__ C,
                          int Mr, int K, int N)
{
  int lane = threadIdx.x & 63, wave = threadIdx.x >> 6;
  int waveM = wave >> 1, waveN = wave & 1;
  int r = lane & 15, kg = lane >> 4;
  int rowBase = blockIdx.y * 64 + waveM * 32;
  int colBase = blockIdx.x * 64 + waveN * 32;

  int row0 = rowBase + r, row1 = rowBase + 16 + r;
  int col0 = colBase + r, col1 = colBase + 16 + r;
  bool v0 = row0 < Mr, v1 = row1 < Mr;
  const __bf16* a0p = A + (size_t)row0 * K + kg * 8;
  const __bf16* a1p = A + (size_t)row1 * K + kg * 8;
  const __bf16* b0p = Bt + (size_t)col0 * K + kg * 8;
  const __bf16* b1p = Bt + (size_t)col1 * K + kg * 8;

  f32x4 acc[2][2];
  #pragma unroll
  for (int i = 0; i < 2; i++)
    #pragma unroll
    for (int j = 0; j < 2; j++) { acc[i][j][0] = 0.f; acc[i][j][1] = 0.f; acc[i][j][2] = 0.f; acc[i][j][3] = 0.f; }

  for (int k0 = 0; k0 < K; k0 += 32) {
    bf16x8 a0 = v0 ? ldb8(a0p + k0) : zerob8();
    bf16x8 a1 = v1 ? ldb8(a1p + k0) : zerob8();
    bf16x8 b0 = ldb8(b0p + k0);
    bf16x8 b1 = ldb8(b1p + k0);
    acc[0][0] = mfma16(a0, b0, acc[0][0]);
    acc[0][1] = mfma16(a0, b1, acc[0][1]);
    acc[1][0] = mfma16(a1, b0, acc[1][0]);
    acc[1][1] = mfma16(a1, b1, acc[1][1]);
  }

  #pragma unroll
  for (int i = 0; i < 2; i++) {
    #pragma unroll
    for (int g = 0; g < 4; g++) {
      int row = rowBase + i * 16 + kg * 4 + g;
      if (row >= Mr) continue;
      #pragma unroll
      for (int j = 0; j < 2; j++) {
        int col = colBase + j * 16 + r;
        float v = acc[i][j][g];
        if (bias) v += bias[col];
        if (ACT == 1) v = fmaxf(v, 0.f);
        C[(size_t)row * N + col] = v;
      }
    }
  }
}

// sum split-K partials + bias + relu -> q (fp32) and qb (bf16, prescaled log2 e)
__global__ void fc_reduce(const float* __restrict__ part, const float* __restrict__ bias,
                          float* __restrict__ q, __bf16* __restrict__ qb, int nrows)
{
  int idx = blockIdx.x * 256 + threadIdx.x;       // nrows * H
  if (idx >= nrows * H) return;
  int col = idx & 255;
  float s = bias[col];
  for (int z = 0; z < FSPLIT; z++) s += part[(size_t)z * nrows * H + idx];
  s = fmaxf(s, 0.f);
  q[idx] = s;
  qb[idx] = (__bf16)(s * 1.44269504f);
}

// ------------------------- conv (block per test row) -----------------------
__global__ void conv_feat(const float* __restrict__ ent, const float* __restrict__ rel,
                          const float* __restrict__ sent, const int* __restrict__ tt,
                          const float* __restrict__ cw, const float* __restrict__ cb,
                          __bf16* __restrict__ out, int row0)
{
  __shared__ float f[3][258];
  __shared__ float wsm[CH * 9];
  __shared__ float bsm[CH];
  int i = row0 + blockIdx.x;
  int h = threadIdx.x;
  int j = (i < NT) ? i : i - NT;
  int a0 = (i < NT) ? tt[j * 3 + 0] : tt[j * 3 + 2];
  int a1 = (i < NT) ? tt[j * 3 + 1] : tt[j * 3 + 1] + NR;
  f[0][h + 1] = ent[(size_t)a0 * H + h];
  f[1][h + 1] = rel[(size_t)a1 * H + h];
  f[2][h + 1] = sent[(size_t)j * H + h];
  if (h < 3) { f[h][0] = 0.f; f[h][257] = 0.f; }
  for (int x = h; x < CH * 9; x += 256) wsm[x] = cw[x];
  if (h < CH) bsm[h] = cb[h];
  __syncthreads();
  __bf16* orow = out + (size_t)blockIdx.x * KFC;
  for (int c = 0; c < CH; c++) {
    const float* wc = wsm + c * 9;
    float s = bsm[c];
    #pragma unroll
    for (int ic = 0; ic < 3; ic++)
      s += wc[ic * 3 + 0] * f[ic][h] + wc[ic * 3 + 1] * f[ic][h + 1] + wc[ic * 3 + 2] * f[ic][h + 2];
    orow[(size_t)c * H + h] = (__bf16)fmaxf(s, 0.f);
  }
}

// one wave per row: nll[row] = log(sum_c part_l) - q[row].ent[tgt]
__global__ void lse_combine(const float* __restrict__ part_l, const float* __restrict__ qf,
                            const float* __restrict__ ent, const int* __restrict__ tt,
                            float* __restrict__ nll)
{
  int gid = blockIdx.x * 256 + threadIdx.x;
  int w = gid >> 6;
  if (w >= NT2) return;
  int lane = gid & 63;
  int j = (w < NT) ? w : w - NT;
  int tgt = (w < NT) ? tt[j * 3 + 2] : tt[j * 3 + 0];
  const float4 qa = ((const float4*)(qf + (size_t)w * H))[lane];
  const float4 ea = ((const float4*)(ent + (size_t)tgt * H))[lane];
  float d = qa.x * ea.x + qa.y * ea.y + qa.z * ea.z + qa.w * ea.w;
  float s = (lane < NCHUNK) ? part_l[(size_t)lane * ROWPAD + w] : 0.f;
  #pragma unroll
  for (int o = 32; o > 0; o >>= 1) {
    d += __shfl_down(d, o, 64);
    s += __shfl_down(s, o, 64);
  }
  if (lane == 0) nll[w] = logf(s) - d;
}

__global__ void mean_nll(const float* __restrict__ nll, float* __restrict__ out)
{
  float s = 0.f;
  for (int i = threadIdx.x; i < NT2; i += 256) s += nll[i];
  s = block_sum256(s);
  if (threadIdx.x == 0) out[0] = s * (1.f / NT2);
}

// ------------------------- launcher ----------------------------------------
extern "C" void kernel_launch(void* const* d_in, const int* in_sizes, int n_in,
                              void* d_out, int out_size, void* d_ws, size_t ws_size,
                              hipStream_t stream)
{
  const float* dynamic_emb = (const float*)d_in[0];
  const float* emb_rel     = (const float*)d_in[1];
  const float* gru_W_ih    = (const float*)d_in[2];
  const float* gru_W_hh    = (const float*)d_in[3];
  const float* gru_b_ih    = (const float*)d_in[4];
  const float* gru_b_hh    = (const float*)d_in[5];
  const float* agg_W       = (const float*)d_in[6];
  const float* tg_W        = (const float*)d_in[7];
  const float* tg_b        = (const float*)d_in[8];
  const float* hev         = (const float*)d_in[9];
  const float* hrv         = (const float*)d_in[10];
  const float* conv_w      = (const float*)d_in[11];
  const float* conv_b      = (const float*)d_in[12];
  const float* fc_W        = (const float*)d_in[13];
  const float* fc_b        = (const float*)d_in[14];
  const float* sent        = (const float*)d_in[15];
  const int* edge_src = (const int*)d_in[16];
  const int* edge_rel = (const int*)d_in[17];
  const int* edge_dst = (const int*)d_in[18];
  const int* r_to_e   = (const int*)d_in[19];
  const int* r_ids    = (const int*)d_in[20];
  const int* he_row   = (const int*)d_in[21];
  const int* he_col   = (const int*)d_in[22];
  const int* hr_row   = (const int*)d_in[23];
  const int* hr_col   = (const int*)d_in[24];
  const int* tt       = (const int*)d_in[25];
  float* out = (float*)d_out;

  char* base = (char*)d_ws;
  size_t off = 0;
  auto alloc = [&](size_t bytes) { char* p = base + off; off += (bytes + 255) & ~(size_t)255; return p; };

  float* ent    = (float*)alloc((size_t)NE * H * 4);
  float* curr   = (float*)alloc((size_t)NE * H * 4);   // + tgbuf: conv_bf overlay (41 MB)
  float* tgbuf  = (float*)alloc((size_t)NE * H * 4);
  __bf16* convb = (__bf16*)curr;                        // 1600*12800*2 = 40.96 MB
  __bf16* entb  = (__bf16*)alloc((size_t)NE * H * 2);
  __bf16* entb2 = (__bf16*)alloc((size_t)NE * H * 2);
  __bf16* accEb = (__bf16*)alloc((size_t)NE * H * 2);
  __bf16* ebf   = (__bf16*)alloc((size_t)NEPAD * H * 2);   // frag-packed ent
  __bf16* qbf   = (__bf16*)alloc((size_t)ROWPAD * H * 2);  // frag-packed q
  float* rel    = (float*)alloc((size_t)R2 * H * 4);
  float* accR   = (float*)alloc((size_t)R2 * H * 4);
  __bf16* relb  = (__bf16*)alloc((size_t)R2 * H * 2);
  __bf16* xinb  = (__bf16*)alloc((size_t)R2 * 2 * H * 2);
  float* gi     = (float*)alloc((size_t)R2 * H3 * 4);
  float* gh     = (float*)alloc((size_t)R2 * H3 * 4);
  float* qf     = (float*)alloc((size_t)NT2 * H * 4);
  __bf16* qb    = (__bf16*)alloc((size_t)NT2 * H * 2);
  float* part_l = (float*)alloc((size_t)NCHUNK * ROWPAD * 4);
  float* partM  = (float*)alloc((size_t)R2 * MSPLIT * H * 4);
  float* fcpart = (float*)alloc((size_t)FSPLIT * 1600 * H * 4);
  float* nll    = (float*)alloc((size_t)NT2 * 4);
  __bf16* tgWtb = (__bf16*)alloc((size_t)H * H * 2);
  __bf16* aggWtb= (__bf16*)alloc((size_t)H * H * 2);
  __bf16* fcWtb = (__bf16*)alloc((size_t)H * KFC * 2);
  __bf16* Wihb  = (__bf16*)alloc((size_t)H3 * 2 * H * 2);
  __bf16* Whhb  = (__bf16*)alloc((size_t)H3 * H * 2);

  int* ip = (int*)alloc(0);
  size_t ioff = 0;
  auto ialloc = [&](size_t n) { int* p = ip + ioff; ioff += n; return p; };
  int* fidxM[TT];
  int* fsrcE[TT]; int* frelE[TT];
  for (int t = 0; t < TT; t++) fidxM[t] = ialloc(M);
  for (int t = 0; t < TT; t++) { fsrcE[t] = ialloc(NEDGE); frelE[t] = ialloc(NEDGE); }
  int* fcolHE = ialloc(NNZ_E); float* fvalHE = (float*)ialloc(NNZ_E);
  int* fcolHR = ialloc(NNZ_R); float* fvalHR = (float*)ialloc(NNZ_R);
  int* cnt_all    = ialloc(CNT_TOTAL);
  int* start_all  = ialloc(CNT_TOTAL);
  int* cursor_all = ialloc(CNT_TOTAL);
  int* bcnt  = ialloc((size_t)4 * NB_CS * 512);
  int* bbase = ialloc((size_t)4 * NB_CS * 512);

  int* sM[TT];  for (int t = 0; t < TT; t++) sM[t] = start_all + t * 512;
  int* sHR = start_all + 1536;
  int* sE[TT];  for (int t = 0; t < TT; t++) sE[t] = start_all + CNT_NE_BASE + t * CNT_NE_STRIDE;
  int* sHE = start_all + CNT_NE_BASE + 3 * CNT_NE_STRIDE;

  // --- weight prep (bf16) ---
  transpose_cast_k<<<dim3(H / 32, H / 32), 256, 0, stream>>>(tg_W, tgWtb, H, H);
  transpose_cast_k<<<dim3(H / 32, H / 32), 256, 0, stream>>>(agg_W, aggWtb, H, H);
  transpose_cast_k<<<dim3(KFC / 32, H / 32), 256, 0, stream>>>(fc_W, fcWtb, KFC, H);
  cast_bf16_k<<<(H3 * 2 * H / 8 + 255) / 256, 256, 0, stream>>>(gru_W_ih, Wihb, H3 * 2 * H / 8);
  cast_bf16_k<<<(H3 * H / 8 + 255) / 256, 256, 0, stream>>>(gru_W_hh, Whhb, H3 * H / 8);

  // --- CSR build: counting-sort for R2-keyed arrays ---
  cs_hist_k<<<dim3(NB_CS, 4), 256, 0, stream>>>(r_ids, hr_row, bcnt);
  cs_scan_k<<<4, 256, 0, stream>>>(bcnt, bbase, start_all);
  cs_scatter_k<<<dim3(NB_CS, 4), 256, 0, stream>>>(r_ids, r_to_e, hr_row, hr_col, hrv, bbase,
                                                   fidxM[0], fidxM[1], fidxM[2], fcolHR, fvalHR);

  // --- CSR build: NE-keyed arrays ---
  hipMemsetAsync(cnt_all + CNT_NE_BASE, 0, (size_t)(CNT_TOTAL - CNT_NE_BASE) * 4, stream);
  hist_ne_k<<<dim3((NNZ_E + 255) / 256, 4), 256, 0, stream>>>(edge_dst, he_row, cnt_all);
  scan_ne_k<<<4, 256, 0, stream>>>(cnt_all, start_all, cursor_all);
  for (int t = 0; t < TT; t++)
    perm_fuse2_k<<<(NEDGE + 255) / 256, 256, 0, stream>>>(
        edge_dst + (size_t)t * NEDGE, edge_src + (size_t)t * NEDGE, edge_rel + (size_t)t * NEDGE,
        NEDGE, cursor_all + CNT_NE_BASE + t * CNT_NE_STRIDE, fsrcE[t], frelE[t]);
  perm_fusev_k<<<(NNZ_E + 255) / 256, 256, 0, stream>>>(
      he_row, he_col, hev, NNZ_E, cursor_all + CNT_NE_BASE + 3 * CNT_NE_STRIDE, fcolHE, fvalHE);

  hipMemcpyAsync(ent, dynamic_emb, (size_t)NE * H * 4, hipMemcpyDeviceToDevice, stream);
  hipMemcpyAsync(rel, emb_rel, (size_t)R2 * H * 4, hipMemcpyDeviceToDevice, stream);

  constexpr int NEH8 = NE * H / 8, R2H8 = R2 * H / 8;
  constexpr int NE_RB = (NE + 127) / 128;   // 157

  cast_bf16_k<<<(NEH8 + 255) / 256, 256, 0, stream>>>(ent, entb, NEH8);
  cast_bf16_k<<<(R2H8 + 255) / 256, 256, 0, stream>>>(rel, relb, R2H8);

  for (int t = 0; t < TT; t++) {
    // --- rel update (GRU) ---
    gather_mean2_k<<<dim3(R2, MSPLIT), 256, 0, stream>>>(entb, fidxM[t], sM[t], partM);
    mean_xin_k<<<R2, 256, 0, stream>>>(partM, sM[t], rel, xinb);
    mfma_gemm<0><<<dim3(H3 / 64, (R2 + 63) / 64), 256, 0, stream>>>(
        xinb, Wihb, gru_b_ih, gi, R2, 2 * H, H3);
    mfma_gemm<0><<<dim3(H3 / 64, (R2 + 63) / 64), 256, 0, stream>>>(
        relb, Whhb, gru_b_hh, gh, R2, H, H3);
    gru_combine<<<(R2 * H + 255) / 256, 256, 0, stream>>>(gi, gh, rel, relb);

    // --- ent update ---
    panel2_gemm<2><<<dim3(2, NE_RB), 256, 0, stream>>>(entb, tgWtb, tg_b, tgbuf, NE, H, 2);
    gather_edges3_k<<<NE, 256, 0, stream>>>(entb, relb, fsrcE[t], frelE[t], sE[t], accEb);
    panel2_gemm<1><<<dim3(2, NE_RB), 256, 0, stream>>>(accEb, aggWtb, nullptr, curr, NE, H, 2);
    ent_update<<<(NE * H + 255) / 256, 256, 0, stream>>>(ent, entb, tgbuf, curr);
  }

  // --- hypergraph layers ---
  hyper3_k<<<NE, 256, 0, stream>>>(ent, entb, fvalHE, fcolHE, sHE, curr, entb2);
  hyper3_k<<<NE, 256, 0, stream>>>(curr, entb2, fvalHE, fcolHE, sHE, ent, entb);
  hyper_rel_k<<<R2, 256, 0, stream>>>(rel, fvalHR, fcolHR, sHR, accR);
  hyper_rel_k<<<R2, 256, 0, stream>>>(accR, fvalHR, fcolHR, sHR, rel);

  // frag-pack final ent for scores B
  pack_frag_k<<<(NEPAD * 32 + 255) / 256, 256, 0, stream>>>(entb, ebf, NEPAD * 32, NE);

  // --- conv + fc (3 chunks: 1600, 1600, 800 rows) ---
  for (int c = 0; c < 3; c++) {
    int row0 = c * 1600;
    int rows = min(1600, NT2 - row0);
    conv_feat<<<rows, 256, 0, stream>>>(ent, rel, sent, tt, conv_w, conv_b, convb, row0);
    fc_gemm<<<dim3(FSPLIT, (rows + 127) / 128), 256, 0, stream>>>(convb, fcWtb, fcpart, rows);
    fc_reduce<<<(rows * H + 255) / 256, 256, 0, stream>>>(
        fcpart, fc_b, qf + (size_t)row0 * H, qb + (size_t)row0 * H, rows);
  }

  // frag-pack q for scores A
  pack_frag_k<<<(ROWPAD * 32 + 255) / 256, 256, 0, stream>>>(qb, qbf, ROWPAD * 32, NT2);

  // --- fused scores + LSE: frag-direct, 32 chunks x 16 row-blocks ---
  scores_v3<<<dim3(NCHUNK, 16), 256, 0, stream>>>(qbf, ebf, part_l);
  lse_combine<<<(NT2 * 64 + 255) / 256, 256, 0, stream>>>(part_l, qf, ent, tt, nll);
  mean_nll<<<1, 256, 0, stream>>>(nll, out);
}

// Round 11
// 928.089 us; speedup vs baseline: 9.7911x; 1.1310x over previous
//
#include <hip/hip_runtime.h>
#include <math.h>

#define DEV_INLINE __device__ __forceinline__

constexpr int H      = 256;
constexpr int NE     = 20000;
constexpr int NR     = 250;
constexpr int R2     = 500;
constexpr int TT     = 3;
constexpr int NEDGE  = 150000;
constexpr int M      = 200000;
constexpr int NNZ_E  = 320000;
constexpr int NNZ_R  = 8000;
constexpr int CH     = 50;
constexpr int NT     = 2000;
constexpr int NT2    = 4000;
constexpr int H3     = 3 * H;     // 768
constexpr int KFC    = CH * H;    // 12800
constexpr int ROWPAD = 4096;
constexpr int NCHUNK = 32;        // scores col chunks (x PS=10 panels x 64 cols)
constexpr int MSPLIT = 8;         // gather_mean row split
constexpr int FSPLIT = 10;        // fc split-K
constexpr int NB_CS  = 64;        // counting-sort blocks per R2 array
constexpr int NEPAD  = 20480;     // ent rows padded to 64
constexpr int NB_NE  = 80;        // NE-scan blocks per array

// cnt/start/cursor packed region (ints)
constexpr int CNT_NE_BASE   = 2048;
constexpr int CNT_NE_STRIDE = 20224;
constexpr int CNT_TOTAL     = CNT_NE_BASE + 4 * CNT_NE_STRIDE;  // 82944

typedef __bf16 bf16x8 __attribute__((ext_vector_type(8)));
typedef float  f32x4  __attribute__((ext_vector_type(4)));

DEV_INLINE bf16x8 ldb8(const __bf16* p) { return *(const bf16x8*)p; }
DEV_INLINE bf16x8 zerob8() { uint4 z = make_uint4(0, 0, 0, 0); return __builtin_bit_cast(bf16x8, z); }
DEV_INLINE f32x4 mfma16(bf16x8 a, bf16x8 b, f32x4 c) {
  return __builtin_amdgcn_mfma_f32_16x16x32_bf16(a, b, c, 0, 0, 0);
}
DEV_INLINE void gload_lds16(const void* g, void* l) {
  __builtin_amdgcn_global_load_lds((const __attribute__((address_space(1))) void*)g,
                                   (__attribute__((address_space(3))) void*)l, 16, 0, 0);
}

// ------------------------- block reduction (blockDim == 256) ---------------
DEV_INLINE float block_sum256(float v) {
  __shared__ float ws[4];
  #pragma unroll
  for (int o = 32; o > 0; o >>= 1) v += __shfl_down(v, o, 64);
  if ((threadIdx.x & 63) == 0) ws[threadIdx.x >> 6] = v;
  __syncthreads();
  float r = ws[0] + ws[1] + ws[2] + ws[3];
  __syncthreads();
  return r;
}

// ------------------- counting-sort CSR (R2-keyed arrays) -------------------
__global__ void cs_hist_k(const int* __restrict__ r_ids, const int* __restrict__ hr_row,
                          int* __restrict__ bcnt)
{
  __shared__ int lh[512];
  int a = blockIdx.y;
  const int* keys = (a < 3) ? r_ids + (size_t)a * M : hr_row;
  int n = (a < 3) ? M : NNZ_R;
  int t = threadIdx.x;
  lh[t] = 0; lh[t + 256] = 0;
  __syncthreads();
  int chunk = (n + NB_CS - 1) / NB_CS;
  int i0 = blockIdx.x * chunk, i1 = min(i0 + chunk, n);
  for (int i = i0 + t; i < i1; i += 256) atomicAdd(&lh[keys[i]], 1);
  __syncthreads();
  int* outp = bcnt + ((size_t)a * NB_CS + blockIdx.x) * 512;
  outp[t] = lh[t]; outp[t + 256] = lh[t + 256];
}

__global__ void cs_scan_k(const int* __restrict__ bcnt, int* __restrict__ bbase,
                          int* __restrict__ start_all)
{
  __shared__ int ps[257];
  int a = blockIdx.x;
  int* start = start_all + ((a < 3) ? a * 512 : 1536);
  const int* bc = bcnt + (size_t)a * NB_CS * 512;
  int* bb = bbase + (size_t)a * NB_CS * 512;
  int t = threadIdx.x;
  int b0 = 2 * t, b1 = 2 * t + 1;
  int tot0 = 0, tot1 = 0;
  for (int blk = 0; blk < NB_CS; blk++) {
    tot0 += bc[blk * 512 + b0];
    tot1 += bc[blk * 512 + b1];
  }
  ps[t + 1] = tot0 + tot1;
  if (t == 0) ps[0] = 0;
  __syncthreads();
  if (t == 0) { for (int i = 1; i <= 256; i++) ps[i] += ps[i - 1]; }
  __syncthreads();
  int run0 = ps[t], run1 = ps[t] + tot0;
  start[b0] = run0;
  start[b1] = run1;
  for (int blk = 0; blk < NB_CS; blk++) {
    bb[blk * 512 + b0] = run0; run0 += bc[blk * 512 + b0];
    bb[blk * 512 + b1] = run1; run1 += bc[blk * 512 + b1];
  }
}

__global__ void cs_scatter_k(const int* __restrict__ r_ids, const int* __restrict__ r_to_e,
                             const int* __restrict__ hr_row, const int* __restrict__ hr_col,
                             const float* __restrict__ hrv, const int* __restrict__ bbase,
                             int* __restrict__ f0, int* __restrict__ f1, int* __restrict__ f2,
                             int2* __restrict__ fcvHR)
{
  __shared__ int cur[512];
  int a = blockIdx.y;
  const int* keys = (a < 3) ? r_ids + (size_t)a * M : hr_row;
  int n = (a < 3) ? M : NNZ_R;
  int t = threadIdx.x;
  const int* bb = bbase + ((size_t)a * NB_CS + blockIdx.x) * 512;
  cur[t] = bb[t]; cur[t + 256] = bb[t + 256];
  __syncthreads();
  int chunk = (n + NB_CS - 1) / NB_CS;
  int i0 = blockIdx.x * chunk, i1 = min(i0 + chunk, n);
  if (a < 3) {
    const int* other = r_to_e + (size_t)a * M;
    int* f = (a == 0) ? f0 : (a == 1) ? f1 : f2;
    for (int i = i0 + t; i < i1; i += 256) {
      int p = atomicAdd(&cur[keys[i]], 1);
      f[p] = other[i];
    }
  } else {
    for (int i = i0 + t; i < i1; i += 256) {
      int p = atomicAdd(&cur[keys[i]], 1);
      fcvHR[p] = make_int2(hr_col[i], __float_as_int(hrv[i]));
    }
  }
}

// ------------------- NE-keyed CSR (low contention) -------------------------
__global__ void hist_ne_k(const int* __restrict__ edge_dst, const int* __restrict__ he_row,
                          int* __restrict__ cnt_all)
{
  int a = blockIdx.y;
  const int* keys = (a < 3) ? edge_dst + (size_t)a * NEDGE : he_row;
  int n = (a < 3) ? NEDGE : NNZ_E;
  int* cnt = cnt_all + CNT_NE_BASE + a * CNT_NE_STRIDE;
  int i = blockIdx.x * 256 + threadIdx.x;
  if (i < n) atomicAdd(&cnt[keys[i]], 1);
}

// parallel 3-phase scan over NE bins, grid (NB_NE, 4)
__global__ void scan_ne1_k(const int* __restrict__ cnt_all, int* __restrict__ start_all,
                           int* __restrict__ bsum)
{
  __shared__ int wtot[4];
  int a = blockIdx.y;
  int off = CNT_NE_BASE + a * CNT_NE_STRIDE;
  int bin = blockIdx.x * 256 + threadIdx.x;
  int lane = threadIdx.x & 63, w = threadIdx.x >> 6;
  int v = (bin < NE) ? cnt_all[off + bin] : 0;
  int orig = v;
  #pragma unroll
  for (int o = 1; o < 64; o <<= 1) {
    int n = __shfl_up(v, o, 64);
    if (lane >= o) v += n;
  }
  if (lane == 63) wtot[w] = v;
  __syncthreads();
  int wo = 0;
  #pragma unroll
  for (int i = 0; i < 4; i++) if (i < w) wo += wtot[i];
  if (bin < NE) start_all[off + bin] = v - orig + wo;   // local exclusive prefix
  if (threadIdx.x == 255) bsum[a * NB_NE + blockIdx.x] = wo + v;
}

__global__ void scan_ne2_k(int* __restrict__ bsum, int* __restrict__ start_all)
{
  __shared__ int s[NB_NE + 1];
  int a = blockIdx.x;
  int t = threadIdx.x;
  if (t < NB_NE) s[t + 1] = bsum[a * NB_NE + t];
  if (t == 0) s[0] = 0;
  __syncthreads();
  if (t == 0) { for (int i = 1; i <= NB_NE; i++) s[i] += s[i - 1]; }
  __syncthreads();
  if (t < NB_NE) bsum[a * NB_NE + t] = s[t];
  if (t == 0) start_all[CNT_NE_BASE + a * CNT_NE_STRIDE + NE] = s[NB_NE];
}

__global__ void scan_ne3_k(int* __restrict__ start_all, int* __restrict__ cursor_all,
                           const int* __restrict__ bsum)
{
  int a = blockIdx.y;
  int off = CNT_NE_BASE + a * CNT_NE_STRIDE;
  int bin = blockIdx.x * 256 + threadIdx.x;
  if (bin >= NE) return;
  int v = start_all[off + bin] + bsum[a * NB_NE + blockIdx.x];
  start_all[off + bin] = v;
  cursor_all[off + bin] = v;
}

// permute + gather fused, int2 payload (one scattered line per entry)
__global__ void perm_fuse2i_k(const int* __restrict__ keys, const int* __restrict__ o1,
                              const int* __restrict__ o2, int n, int* __restrict__ cursor,
                              int2* __restrict__ f)
{
  int i = blockIdx.x * 256 + threadIdx.x;
  if (i < n) { int p = atomicAdd(&cursor[keys[i]], 1); f[p] = make_int2(o1[i], o2[i]); }
}
__global__ void perm_fusevi_k(const int* __restrict__ keys, const int* __restrict__ col,
                              const float* __restrict__ val, int n, int* __restrict__ cursor,
                              int2* __restrict__ f)
{
  int i = blockIdx.x * 256 + threadIdx.x;
  if (i < n) {
    int p = atomicAdd(&cursor[keys[i]], 1);
    f[p] = make_int2(col[i], __float_as_int(val[i]));
  }
}

// ------------------------- casts / transposes ------------------------------
__global__ void cast_bf16_k(const float* __restrict__ in, __bf16* __restrict__ out, int n8)
{
  int i = blockIdx.x * 256 + threadIdx.x;
  if (i >= n8) return;
  const float4* p = (const float4*)in + (size_t)i * 2;
  float4 u = p[0], v = p[1];
  bf16x8 o;
  o[0] = (__bf16)u.x; o[1] = (__bf16)u.y; o[2] = (__bf16)u.z; o[3] = (__bf16)u.w;
  o[4] = (__bf16)v.x; o[5] = (__bf16)v.y; o[6] = (__bf16)v.z; o[7] = (__bf16)v.w;
  ((bf16x8*)out)[i] = o;
}

__global__ void transpose_cast_k(const float* __restrict__ in, __bf16* __restrict__ out,
                                 int K, int N)
{
  __shared__ float tile[32][33];
  int tx = threadIdx.x & 31, ty = threadIdx.x >> 5;   // 32 x 8
  int kb = blockIdx.x * 32, nb = blockIdx.y * 32;
  #pragma unroll
  for (int i = 0; i < 4; i++)
    tile[ty + i * 8][tx] = in[(size_t)(kb + ty + i * 8) * N + nb + tx];
  __syncthreads();
  #pragma unroll
  for (int i = 0; i < 4; i++)
    out[(size_t)(nb + ty + i * 8) * K + kb + tx] = (__bf16)tile[tx][ty + i * 8];
}

// reorder [rows][256] bf16 into MFMA-frag-linear layout
__global__ void pack_frag_k(const __bf16* __restrict__ src, __bf16* __restrict__ dst,
                            int nchunks, int Mr)
{
  int i = blockIdx.x * 256 + threadIdx.x;
  if (i >= nchunks) return;
  int c = i >> 5, s = i & 31;
  bf16x8 v = (c < Mr) ? ldb8(src + (size_t)c * H + s * 8) : zerob8();
  int kf = s >> 2, kg = s & 3;
  size_t d = ((((size_t)(c >> 6) * 4 + ((c >> 4) & 3)) * 8 + kf) * 4 + kg) * 16 + (c & 15);
  *(bf16x8*)(dst + d * 8) = v;
}

// ------------------------- gather kernels (16 B/lane, 32-lane halves) ------
__global__ void gather_mean2_k(const __bf16* __restrict__ src, const int* __restrict__ fidx,
                               const int* __restrict__ start, float* __restrict__ part)
{
  __shared__ __align__(16) float red[4][H];
  int r = blockIdx.x, s = blockIdx.y;
  int s0 = start[r], s1 = start[r + 1];
  int len = s1 - s0;
  int chunk = (len + MSPLIT - 1) / MSPLIT;
  int jb = s0 + s * chunk, je = min(jb + chunk, s1);
  int tid = threadIdx.x, lane = tid & 63, w = tid >> 6;
  int half = lane >> 5, l = lane & 31;
  float acc[8] = {0.f, 0.f, 0.f, 0.f, 0.f, 0.f, 0.f, 0.f};
  for (int j = jb + w * 2 + half; j < je; j += 8) {
    int e = fidx[j];
    bf16x8 v = ldb8(src + (size_t)e * H + l * 8);
    #pragma unroll
    for (int q = 0; q < 8; q++) acc[q] += (float)v[q];
  }
  #pragma unroll
  for (int q = 0; q < 8; q++) acc[q] += __shfl_xor(acc[q], 32, 64);
  if (half == 0) {
    *(float4*)&red[w][l * 8]     = make_float4(acc[0], acc[1], acc[2], acc[3]);
    *(float4*)&red[w][l * 8 + 4] = make_float4(acc[4], acc[5], acc[6], acc[7]);
  }
  __syncthreads();
  int h = tid;
  part[((size_t)r * MSPLIT + s) * H + h] = red[0][h] + red[1][h] + red[2][h] + red[3][h];
}

__global__ void mean_xin_k(const float* __restrict__ partM, const int* __restrict__ start,
                           const float* __restrict__ rel, __bf16* __restrict__ xin)
{
  int r = blockIdx.x, h = threadIdx.x;
  float s = 0.f;
  #pragma unroll
  for (int z = 0; z < MSPLIT; z++) s += partM[((size_t)r * MSPLIT + z) * H + h];
  float xm = s / (float)max(start[r + 1] - start[r], 1);
  xin[(size_t)r * 2 * H + h]     = (__bf16)rel[(size_t)r * H + h];
  xin[(size_t)r * 2 * H + H + h] = (__bf16)xm;
}

// lanes 0-31 read ent row, lanes 32-63 read rel row of the same edge (int2 idx)
__global__ void gather_edges3_k(const __bf16* __restrict__ ent, const __bf16* __restrict__ rel,
                                const int2* __restrict__ fsr,
                                const int* __restrict__ start, __bf16* __restrict__ out)
{
  __shared__ __align__(16) float red[4][H];
  int d = blockIdx.x;
  int s0 = start[d], s1 = start[d + 1];
  int tid = threadIdx.x, lane = tid & 63, w = tid >> 6;
  int half = lane >> 5, l = lane & 31;
  const __bf16* srcbase = half ? rel : ent;
  float acc[8] = {0.f, 0.f, 0.f, 0.f, 0.f, 0.f, 0.f, 0.f};
  for (int j = s0 + w; j < s1; j += 4) {
    int2 e2 = fsr[j];
    int e = half ? e2.y : e2.x;
    bf16x8 v = ldb8(srcbase + (size_t)e * H + l * 8);
    #pragma unroll
    for (int q = 0; q < 8; q++) acc[q] += (float)v[q];
  }
  #pragma unroll
  for (int q = 0; q < 8; q++) acc[q] += __shfl_xor(acc[q], 32, 64);
  if (half == 0) {
    *(float4*)&red[w][l * 8]     = make_float4(acc[0], acc[1], acc[2], acc[3]);
    *(float4*)&red[w][l * 8 + 4] = make_float4(acc[4], acc[5], acc[6], acc[7]);
  }
  __syncthreads();
  int h = tid;
  float sum = red[0][h] + red[1][h] + red[2][h] + red[3][h];
  out[(size_t)d * H + h] = (__bf16)(sum / (float)max(s1 - s0, 1));
}

// xout = x + y/||y||, y = sum val*xb[col] (int2 payload); emits bf16 copy
__global__ void hyper3_k(const float* __restrict__ x, const __bf16* __restrict__ xb,
                         const int2* __restrict__ fcv,
                         const int* __restrict__ start,
                         float* __restrict__ xout, __bf16* __restrict__ xoutb)
{
  __shared__ __align__(16) float red[4][H];
  int r = blockIdx.x;
  int s0 = start[r], s1 = start[r + 1];
  int tid = threadIdx.x, lane = tid & 63, w = tid >> 6;
  int half = lane >> 5, l = lane & 31;
  float acc[8] = {0.f, 0.f, 0.f, 0.f, 0.f, 0.f, 0.f, 0.f};
  for (int j = s0 + w * 2 + half; j < s1; j += 8) {
    int2 cv = fcv[j];
    float wt = __int_as_float(cv.y);
    bf16x8 v = ldb8(xb + (size_t)cv.x * H + l * 8);
    #pragma unroll
    for (int q = 0; q < 8; q++) acc[q] += wt * (float)v[q];
  }
  #pragma unroll
  for (int q = 0; q < 8; q++) acc[q] += __shfl_xor(acc[q], 32, 64);
  if (half == 0) {
    *(float4*)&red[w][l * 8]     = make_float4(acc[0], acc[1], acc[2], acc[3]);
    *(float4*)&red[w][l * 8 + 4] = make_float4(acc[4], acc[5], acc[6], acc[7]);
  }
  __syncthreads();
  int h = tid;
  float y = red[0][h] + red[1][h] + red[2][h] + red[3][h];
  float ss = block_sum256(y * y);
  float rn = 1.f / fmaxf(sqrtf(ss), 1e-12f);
  float o = x[(size_t)r * H + h] + y * rn;
  xout[(size_t)r * H + h] = o;
  xoutb[(size_t)r * H + h] = (__bf16)o;
}

__global__ void hyper_rel_k(const float* __restrict__ x, const int2* __restrict__ fcv,
                            const int* __restrict__ start, float* __restrict__ xout)
{
  int r = blockIdx.x, h = threadIdx.x;
  int s0 = start[r], s1 = start[r + 1];
  float a0 = 0.f;
  for (int j = s0; j < s1; j++) {
    int2 cv = fcv[j];
    a0 += __int_as_float(cv.y) * x[(size_t)cv.x * H + h];
  }
  float ss = block_sum256(a0 * a0);
  float rn = 1.f / fmaxf(sqrtf(ss), 1e-12f);
  xout[(size_t)r * H + h] = x[(size_t)r * H + h] + a0 * rn;
}

// ------------------------- small elementwise -------------------------------
__global__ void gru_combine(const float* __restrict__ gi, const float* __restrict__ gh,
                            float* __restrict__ rel, __bf16* __restrict__ relb)
{
  int idx = blockIdx.x * 256 + threadIdx.x;       // R2 * H
  if (idx >= R2 * H) return;
  int i = idx >> 8, h = idx & 255;
  const float* gir = gi + (size_t)i * H3;
  const float* ghr = gh + (size_t)i * H3;
  float r = 1.f / (1.f + __expf(-(gir[h]       + ghr[h])));
  float z = 1.f / (1.f + __expf(-(gir[H + h]   + ghr[H + h])));
  float n = tanhf(gir[2 * H + h] + r * ghr[2 * H + h]);
  float o = (1.f - z) * n + z * rel[idx];
  rel[idx] = o;
  relb[idx] = (__bf16)o;
}

__global__ void ent_update(float* __restrict__ ent, __bf16* __restrict__ entb,
                           const float* __restrict__ tw, const float* __restrict__ curr)
{
  int idx = blockIdx.x * 256 + threadIdx.x;       // NE * H
  if (idx >= NE * H) return;
  float t = tw[idx];
  float v = t * curr[idx] + (1.f - t) * ent[idx];
  ent[idx] = v;
  entb[idx] = (__bf16)v;
}

// ------------------------- panel2 GEMM (K=256, dbuf 64-col B panels) --------
DEV_INLINE void stage64_load(uint4* v, const __bf16* src, int rowBase, int rowLimit, int tid)
{
  #pragma unroll
  for (int q = 0; q < 8; q++) {
    int X = (q * 256 + tid) * 16;
    int row = X >> 9, boff = X & 511;
    int grow = min(rowBase + row, rowLimit);
    v[q] = *(const uint4*)((const char*)src + (size_t)grow * 512 + boff);
  }
}
DEV_INLINE void stage64_write(char* lds, const uint4* v, int tid)
{
  #pragma unroll
  for (int q = 0; q < 8; q++) {
    int X = (q * 256 + tid) * 16;
    int row = X >> 9;
    *(uint4*)(lds + (X ^ ((row & 7) << 4))) = v[q];
  }
}
DEV_INLINE void stage32_load(uint4* v, const __bf16* src, int rowBase, int rowLimit, int tid, int hf)
{
  #pragma unroll
  for (int q = 0; q < 4; q++) {
    int X = ((hf * 4 + q) * 256 + tid) * 16;
    int row = X >> 9, boff = X & 511;
    int grow = min(rowBase + row, rowLimit);
    v[q] = *(const uint4*)((const char*)src + (size_t)grow * 512 + boff);
  }
}
DEV_INLINE void stage32_write(char* lds, const uint4* v, int tid, int hf)
{
  #pragma unroll
  for (int q = 0; q < 4; q++) {
    int X = ((hf * 4 + q) * 256 + tid) * 16;
    int row = X >> 9;
    *(uint4*)(lds + (X ^ ((row & 7) << 4))) = v[q];
  }
}
DEV_INLINE bf16x8 frag64(const char* lds, int row, int kf, int kg)
{
  int off = (kf * 64 + kg * 16) ^ ((row & 7) << 4);
  return *(const bf16x8*)(lds + row * 512 + off);
}

template<int EPI>
__global__ __launch_bounds__(256, 2) void panel2_gemm(const __bf16* __restrict__ A,
                                                      const __bf16* __restrict__ B,
                                                      const float* __restrict__ bias,
                                                      float* __restrict__ out,
                                                      int Mr, int N, int PS)
{
  __shared__ __attribute__((aligned(16))) char lds0[32768];
  __shared__ __attribute__((aligned(16))) char lds1[32768];
  int tid = threadIdx.x;
  int lane = tid & 63, wM = tid >> 6;
  int r = lane & 15, kg = lane >> 4;
  int rowBase = blockIdx.y * 128;

  {
    uint4 va[8];
    stage64_load(va, A, rowBase, Mr - 1, tid);
    stage64_write(lds0, va, tid);
    stage64_load(va, A, rowBase + 64, Mr - 1, tid);
    stage64_write(lds1, va, tid);
  }
  __syncthreads();

  bf16x8 a[2][8];
  {
    int base = wM * 32;
    const char* ab = (base >= 64) ? lds1 : lds0;
    #pragma unroll
    for (int i = 0; i < 2; i++) {
      int ar = (base + i * 16 + r) & 63;
      #pragma unroll
      for (int kf = 0; kf < 8; kf++) a[i][kf] = frag64(ab, ar, kf, kg);
    }
  }
  int p0 = blockIdx.x * PS;
  __syncthreads();
  {
    uint4 va[8];
    stage64_load(va, B, p0 * 64, N - 1, tid);
    stage64_write(lds0, va, tid);
  }
  __syncthreads();

  for (int p = 0; p < PS; p++) {
    char* cur = (p & 1) ? lds1 : lds0;
    char* nxt = (p & 1) ? lds0 : lds1;
    bool pre = (p + 1 < PS);
    uint4 v4[4];
    if (pre) stage32_load(v4, B, (p0 + p + 1) * 64, N - 1, tid, 0);

    f32x4 acc[2][4];
    #pragma unroll
    for (int i = 0; i < 2; i++)
      #pragma unroll
      for (int j = 0; j < 4; j++) {
        acc[i][j][0] = 0.f; acc[i][j][1] = 0.f; acc[i][j][2] = 0.f; acc[i][j][3] = 0.f;
      }
    __builtin_amdgcn_s_setprio(1);
    #pragma unroll
    for (int kf = 0; kf < 4; kf++) {
      bf16x8 b[4];
      #pragma unroll
      for (int j = 0; j < 4; j++) b[j] = frag64(cur, j * 16 + r, kf, kg);
      #pragma unroll
      for (int i = 0; i < 2; i++)
        #pragma unroll
        for (int j = 0; j < 4; j++)
          acc[i][j] = mfma16(a[i][kf], b[j], acc[i][j]);
    }
    __builtin_amdgcn_s_setprio(0);
    if (pre) {
      stage32_write(nxt, v4, tid, 0);
      stage32_load(v4, B, (p0 + p + 1) * 64, N - 1, tid, 1);
    }
    __builtin_amdgcn_s_setprio(1);
    #pragma unroll
    for (int kf = 4; kf < 8; kf++) {
      bf16x8 b[4];
      #pragma unroll
      for (int j = 0; j < 4; j++) b[j] = frag64(cur, j * 16 + r, kf, kg);
      #pragma unroll
      for (int i = 0; i < 2; i++)
        #pragma unroll
        for (int j = 0; j < 4; j++)
          acc[i][j] = mfma16(a[i][kf], b[j], acc[i][j]);
    }
    __builtin_amdgcn_s_setprio(0);
    if (pre) stage32_write(nxt, v4, tid, 1);

    #pragma unroll
    for (int i = 0; i < 2; i++)
      #pragma unroll
      for (int g = 0; g < 4; g++) {
        int row = rowBase + wM * 32 + i * 16 + kg * 4 + g;
        if (row >= Mr) continue;
        #pragma unroll
        for (int j = 0; j < 4; j++) {
          int col = (p0 + p) * 64 + j * 16 + r;
          if (col >= N) continue;
          float v = acc[i][j][g];
          if (bias) v += bias[col];
          if (EPI == 1) v = fmaxf(v, 0.f);
          if (EPI == 2) v = 1.f / (1.f + __expf(-v));
          out[(size_t)row * N + col] = v;
        }
      }
    __syncthreads();
  }
}

// ------------------------- scores_v3 (frag-packed, 64-row waves) -----------
__global__ __launch_bounds__(256, 2) void scores_v3(const __bf16* __restrict__ qbf,
                                                    const __bf16* __restrict__ ebf,
                                                    float* __restrict__ part_l)
{
  __shared__ __attribute__((aligned(16))) char lds[2][32768];
  int tid = threadIdx.x, lane = tid & 63, w = tid >> 6;
  int r = lane & 15, kg = lane >> 4;

  auto stage = [&](int buf, int p) {
    const char* g = (const char*)ebf + ((size_t)(blockIdx.x * 10 + p)) * 32768;
    int wbase = (tid & ~63) * 16;     // wave*1024
    #pragma unroll
    for (int q = 0; q < 8; q++) {
      int o = q * 4096 + wbase;
      gload_lds16(g + o + (lane * 16), lds[buf] + o);
    }
  };

  stage(0, 0);

  bf16x8 a[4][8];
  {
    const __bf16* ap = qbf + ((size_t)(blockIdx.y * 4 + w)) * 16384 + kg * 128 + r * 8;
    #pragma unroll
    for (int i = 0; i < 4; i++)
      #pragma unroll
      for (int kf = 0; kf < 8; kf++)
        a[i][kf] = ldb8(ap + (i * 8 + kf) * 512);
  }
  __syncthreads();

  float lsum[4][4];
  #pragma unroll
  for (int i = 0; i < 4; i++)
    #pragma unroll
    for (int g = 0; g < 4; g++) lsum[i][g] = 0.f;

  const char* lane_off0 = lds[0] + kg * 256 + r * 16;
  const char* lane_off1 = lds[1] + kg * 256 + r * 16;

  for (int p = 0; p < 10; p++) {
    if (p + 1 < 10) stage((p + 1) & 1, p + 1);
    const char* cur = (p & 1) ? lane_off1 : lane_off0;

    f32x4 acc[4][4];
    #pragma unroll
    for (int i = 0; i < 4; i++)
      #pragma unroll
      for (int j = 0; j < 4; j++) {
        acc[i][j][0] = 0.f; acc[i][j][1] = 0.f; acc[i][j][2] = 0.f; acc[i][j][3] = 0.f;
      }
    __builtin_amdgcn_s_setprio(1);
    #pragma unroll
    for (int kf = 0; kf < 8; kf++) {
      bf16x8 b[4];
      #pragma unroll
      for (int j = 0; j < 4; j++)
        b[j] = *(const bf16x8*)(cur + (j * 8 + kf) * 1024);
      #pragma unroll
      for (int i = 0; i < 4; i++)
        #pragma unroll
        for (int j = 0; j < 4; j++)
          acc[i][j] = mfma16(a[i][kf], b[j], acc[i][j]);
    }
    __builtin_amdgcn_s_setprio(0);

    #pragma unroll
    for (int j = 0; j < 4; j++) {
      int col = (blockIdx.x * 10 + p) * 64 + j * 16 + r;
      bool ok = col < NE;
      #pragma unroll
      for (int i = 0; i < 4; i++)
        #pragma unroll
        for (int g = 0; g < 4; g++)
          lsum[i][g] += ok ? exp2f(acc[i][j][g]) : 0.f;
    }
    __syncthreads();
  }

  #pragma unroll
  for (int m = 1; m < 16; m <<= 1)
    #pragma unroll
    for (int i = 0; i < 4; i++)
      #pragma unroll
      for (int g = 0; g < 4; g++)
        lsum[i][g] += __shfl_xor(lsum[i][g], m, 64);
  if (r == 0) {
    #pragma unroll
    for (int i = 0; i < 4; i++)
      #pragma unroll
      for (int g = 0; g < 4; g++) {
        int row = blockIdx.y * 256 + w * 64 + i * 16 + kg * 4 + g;
        part_l[(size_t)blockIdx.x * ROWPAD + row] = lsum[i][g];
      }
  }
}

// ------------------------- fc GEMM (K = 12800, LDS-staged, split-K) --------
__global__ __launch_bounds__(256) void fc_gemm(const __bf16* __restrict__ A,
                                               const __bf16* __restrict__ Bt,
                                               float* __restrict__ part, int Mr)
{
  __shared__ __attribute__((aligned(16))) char lds[49152];
  int tid = threadIdx.x;
  int lane = tid & 63, wave = tid >> 6;
  int wM = wave >> 1, wN = wave & 1;
  int r = lane & 15, kg = lane >> 4;
  int rowBase = blockIdx.y * 128;
  int kbeg = blockIdx.x * (KFC / FSPLIT);   // 1280

  f32x4 acc[4][8];
  #pragma unroll
  for (int i = 0; i < 4; i++)
    #pragma unroll
    for (int j = 0; j < 8; j++) {
      acc[i][j][0] = 0.f; acc[i][j][1] = 0.f; acc[i][j][2] = 0.f; acc[i][j][3] = 0.f;
    }

  for (int ks = 0; ks < 20; ks++) {
    int kb = kbeg + ks * 64;
    #pragma unroll
    for (int q = 0; q < 12; q++) {
      int X = (q * 256 + tid) * 16;
      int row = X >> 7;
      int off = X & 127;
      int soff = off ^ ((row & 7) << 4);
      uint4 v;
      if (row < 128) {
        int grow = min(rowBase + row, Mr - 1);
        v = *(const uint4*)((const char*)A + (size_t)grow * (KFC * 2) + kb * 2 + soff);
      } else {
        int col = row - 128;
        v = *(const uint4*)((const char*)Bt + (size_t)col * (KFC * 2) + kb * 2 + soff);
      }
      *(uint4*)(lds + X) = v;
    }
    __syncthreads();
    #pragma unroll
    for (int kf = 0; kf < 2; kf++) {
      bf16x8 a[4], b[8];
      #pragma unroll
      for (int i = 0; i < 4; i++) {
        int row = wM * 64 + i * 16 + r;
        int off = (kf * 64 + kg * 16) ^ ((row & 7) << 4);
        a[i] = *(const bf16x8*)(lds + row * 128 + off);
      }
      #pragma unroll
      for (int j = 0; j < 8; j++) {
        int row = 128 + wN * 128 + j * 16 + r;
        int off = (kf * 64 + kg * 16) ^ ((row & 7) << 4);
        b[j] = *(const bf16x8*)(lds + row * 128 + off);
      }
      #pragma unroll
      for (int i = 0; i < 4; i++)
        #pragma unroll
        for (int j = 0; j < 8; j++)
          acc[i][j] = mfma16(a[i], b[j], acc[i][j]);
    }
    __syncthreads();
  }

  float* pz = part + (size_t)blockIdx.x * Mr * H;
  #pragma unroll
  for (int i = 0; i < 4; i++)
    #pragma unroll
    for (int g = 0; g < 4; g++) {
      int row = rowBase + wM * 64 + i * 16 + kg * 4 + g;
      if (row >= Mr) continue;
      #pragma unroll
      for (int j = 0; j < 8; j++) {
        int col = wN * 128 + j * 16 + r;
        pz[(size_t)row * H + col] = acc[i][j][g];
      }
    }
}

// ------------------------- generic MFMA GEMM (GRU) -------------------------
template<int ACT>
__global__ void mfma_gemm(const __bf16* __restrict__ A, const __bf16* __restrict__ Bt,
                          const float* __restrict__ bias, float* __restrict__ C,
                          int Mr, int K, int N)
{
  int lane = threadIdx.x & 63, wave = threadIdx.x >> 6;
  int waveM = wave >> 1, waveN = wave & 1;
  int r = lane & 15, kg = lane >> 4;
  int rowBase = blockIdx.y * 64 + waveM * 32;
  int colBase = blockIdx.x * 64 + waveN * 32;

  int row0 = rowBase + r, row1 = rowBase + 16 + r;
  int col0 = colBase + r, col1 = colBase + 16 + r;
  bool v0 = row0 < Mr, v1 = row1 < Mr;
  const __bf16* a0p = A + (size_t)row0 * K + kg * 8;
  const __bf16* a1p = A + (size_t)row1 * K + kg * 8;
  const __bf16* b0p = Bt + (size_t)col0 * K + kg * 8;
  const __bf16* b1p = Bt + (size_t)col1 * K + kg * 8;

  f32x4 acc[2][2];
  #pragma unroll
  for (int i = 0; i < 2; i++)
    #pragma unroll
    for (int j = 0; j < 2; j++) { acc[i][j][0] = 0.f; acc[i][j][1] = 0.f; acc[i][j][2] = 0.f; acc[i][j][3] = 0.f; }

  for (int k0 = 0; k0 < K; k0 += 32) {
    bf16x8 a0 = v0 ? ldb8(a0p + k0) : zerob8();
    bf16x8 a1 = v1 ? ldb8(a1p + k0) : zerob8();
    bf16x8 b0 = ldb8(b0p + k0);
    bf16x8 b1 = ldb8(b1p + k0);
    acc[0][0] = mfma16(a0, b0, acc[0][0]);
    acc[0][1] = mfma16(a0, b1, acc[0][1]);
    acc[1][0] = mfma16(a1, b0, acc[1][0]);
    acc[1][1] = mfma16(a1, b1, acc[1][1]);
  }

  #pragma unroll
  for (int i = 0; i < 2; i++) {
    #pragma unroll
    for (int g = 0; g < 4; g++) {
      int row = rowBase + i * 16 + kg * 4 + g;
      if (row >= Mr) continue;
      #pragma unroll
      for (int j = 0; j < 2; j++) {
        int col = colBase + j * 16 + r;
        float v = acc[i][j][g];
        if (bias) v += bias[col];
        if (ACT == 1) v = fmaxf(v, 0.f);
        C[(size_t)row * N + col] = v;
      }
    }
  }
}

// sum split-K partials + bias + relu -> q (fp32) and qb (bf16, prescaled log2 e)
__global__ void fc_reduce(const float* __restrict__ part, const float* __restrict__ bias,
                          float* __restrict__ q, __bf16* __restrict__ qb, int nrows)
{
  int idx = blockIdx.x * 256 + threadIdx.x;       // nrows * H
  if (idx >= nrows * H) return;
  int col = idx & 255;
  float s = bias[col];
  for (int z = 0; z < FSPLIT; z++) s += part[(size_t)z * nrows * H + idx];
  s = fmaxf(s, 0.f);
  q[idx] = s;
  qb[idx] = (__bf16)(s * 1.44269504f);
}

// ------------------------- conv (block per test row) -----------------------
__global__ void conv_feat(const float* __restrict__ ent, const float* __restrict__ rel,
                          const float* __restrict__ sent, const int* __restrict__ tt,
                          const float* __restrict__ cw, const float* __restrict__ cb,
                          __bf16* __restrict__ out, int row0)
{
  __shared__ float f[3][258];
  __shared__ float wsm[CH * 9];
  __shared__ float bsm[CH];
  int i = row0 + blockIdx.x;
  int h = threadIdx.x;
  int j = (i < NT) ? i : i - NT;
  int a0 = (i < NT) ? tt[j * 3 + 0] : tt[j * 3 + 2];
  int a1 = (i < NT) ? tt[j * 3 + 1] : tt[j * 3 + 1] + NR;
  f[0][h + 1] = ent[(size_t)a0 * H + h];
  f[1][h + 1] = rel[(size_t)a1 * H + h];
  f[2][h + 1] = sent[(size_t)j * H + h];
  if (h < 3) { f[h][0] = 0.f; f[h][257] = 0.f; }
  for (int x = h; x < CH * 9; x += 256) wsm[x] = cw[x];
  if (h < CH) bsm[h] = cb[h];
  __syncthreads();
  __bf16* orow = out + (size_t)blockIdx.x * KFC;
  for (int c = 0; c < CH; c++) {
    const float* wc = wsm + c * 9;
    float s = bsm[c];
    #pragma unroll
    for (int ic = 0; ic < 3; ic++)
      s += wc[ic * 3 + 0] * f[ic][h] + wc[ic * 3 + 1] * f[ic][h + 1] + wc[ic * 3 + 2] * f[ic][h + 2];
    orow[(size_t)c * H + h] = (__bf16)fmaxf(s, 0.f);
  }
}

// one wave per row: nll[row] = log(sum_c part_l) - q[row].ent[tgt]
__global__ void lse_combine(const float* __restrict__ part_l, const float* __restrict__ qf,
                            const float* __restrict__ ent, const int* __restrict__ tt,
                            float* __restrict__ nll)
{
  int gid = blockIdx.x * 256 + threadIdx.x;
  int w = gid >> 6;
  if (w >= NT2) return;
  int lane = gid & 63;
  int j = (w < NT) ? w : w - NT;
  int tgt = (w < NT) ? tt[j * 3 + 2] : tt[j * 3 + 0];
  const float4 qa = ((const float4*)(qf + (size_t)w * H))[lane];
  const float4 ea = ((const float4*)(ent + (size_t)tgt * H))[lane];
  float d = qa.x * ea.x + qa.y * ea.y + qa.z * ea.z + qa.w * ea.w;
  float s = (lane < NCHUNK) ? part_l[(size_t)lane * ROWPAD + w] : 0.f;
  #pragma unroll
  for (int o = 32; o > 0; o >>= 1) {
    d += __shfl_down(d, o, 64);
    s += __shfl_down(s, o, 64);
  }
  if (lane == 0) nll[w] = logf(s) - d;
}

__global__ void mean_nll(const float* __restrict__ nll, float* __restrict__ out)
{
  float s = 0.f;
  for (int i = threadIdx.x; i < NT2; i += 256) s += nll[i];
  s = block_sum256(s);
  if (threadIdx.x == 0) out[0] = s * (1.f / NT2);
}

// ------------------------- launcher ----------------------------------------
extern "C" void kernel_launch(void* const* d_in, const int* in_sizes, int n_in,
                              void* d_out, int out_size, void* d_ws, size_t ws_size,
                              hipStream_t stream)
{
  const float* dynamic_emb = (const float*)d_in[0];
  const float* emb_rel     = (const float*)d_in[1];
  const float* gru_W_ih    = (const float*)d_in[2];
  const float* gru_W_hh    = (const float*)d_in[3];
  const float* gru_b_ih    = (const float*)d_in[4];
  const float* gru_b_hh    = (const float*)d_in[5];
  const float* agg_W       = (const float*)d_in[6];
  const float* tg_W        = (const float*)d_in[7];
  const float* tg_b        = (const float*)d_in[8];
  const float* hev         = (const float*)d_in[9];
  const float* hrv         = (const float*)d_in[10];
  const float* conv_w      = (const float*)d_in[11];
  const float* conv_b      = (const float*)d_in[12];
  const float* fc_W        = (const float*)d_in[13];
  const float* fc_b        = (const float*)d_in[14];
  const float* sent        = (const float*)d_in[15];
  const int* edge_src = (const int*)d_in[16];
  const int* edge_rel = (const int*)d_in[17];
  const int* edge_dst = (const int*)d_in[18];
  const int* r_to_e   = (const int*)d_in[19];
  const int* r_ids    = (const int*)d_in[20];
  const int* he_row   = (const int*)d_in[21];
  const int* he_col   = (const int*)d_in[22];
  const int* hr_row   = (const int*)d_in[23];
  const int* hr_col   = (const int*)d_in[24];
  const int* tt       = (const int*)d_in[25];
  float* out = (float*)d_out;

  char* base = (char*)d_ws;
  size_t off = 0;
  auto alloc = [&](size_t bytes) { char* p = base + off; off += (bytes + 255) & ~(size_t)255; return p; };

  float* ent    = (float*)alloc((size_t)NE * H * 4);
  float* curr   = (float*)alloc((size_t)NE * H * 4);   // + tgbuf: conv_bf overlay (41 MB)
  float* tgbuf  = (float*)alloc((size_t)NE * H * 4);
  __bf16* convb = (__bf16*)curr;                        // 1600*12800*2 = 40.96 MB
  __bf16* entb  = (__bf16*)alloc((size_t)NE * H * 2);
  __bf16* entb2 = (__bf16*)alloc((size_t)NE * H * 2);
  __bf16* accEb = (__bf16*)alloc((size_t)NE * H * 2);
  __bf16* ebf   = (__bf16*)alloc((size_t)NEPAD * H * 2);   // frag-packed ent
  __bf16* qbf   = (__bf16*)alloc((size_t)ROWPAD * H * 2);  // frag-packed q
  float* rel    = (float*)alloc((size_t)R2 * H * 4);
  float* accR   = (float*)alloc((size_t)R2 * H * 4);
  __bf16* relb  = (__bf16*)alloc((size_t)R2 * H * 2);
  __bf16* xinb  = (__bf16*)alloc((size_t)R2 * 2 * H * 2);
  float* gi     = (float*)alloc((size_t)R2 * H3 * 4);
  float* gh     = (float*)alloc((size_t)R2 * H3 * 4);
  float* qf     = (float*)alloc((size_t)NT2 * H * 4);
  __bf16* qb    = (__bf16*)alloc((size_t)NT2 * H * 2);
  float* part_l = (float*)alloc((size_t)NCHUNK * ROWPAD * 4);
  float* partM  = (float*)alloc((size_t)R2 * MSPLIT * H * 4);
  float* fcpart = (float*)alloc((size_t)FSPLIT * 1600 * H * 4);
  float* nll    = (float*)alloc((size_t)NT2 * 4);
  __bf16* tgWtb = (__bf16*)alloc((size_t)H * H * 2);
  __bf16* aggWtb= (__bf16*)alloc((size_t)H * H * 2);
  __bf16* fcWtb = (__bf16*)alloc((size_t)H * KFC * 2);
  __bf16* Wihb  = (__bf16*)alloc((size_t)H3 * 2 * H * 2);
  __bf16* Whhb  = (__bf16*)alloc((size_t)H3 * H * 2);

  int* ip = (int*)alloc(0);
  size_t ioff = 0;
  auto ialloc = [&](size_t n) { int* p = ip + ioff; ioff += n; return p; };
  int* fidxM[TT];
  int2* fsrE[TT];
  for (int t = 0; t < TT; t++) fidxM[t] = ialloc(M);
  for (int t = 0; t < TT; t++) fsrE[t] = (int2*)ialloc((size_t)NEDGE * 2);
  int2* fcvHE = (int2*)ialloc((size_t)NNZ_E * 2);
  int2* fcvHR = (int2*)ialloc((size_t)NNZ_R * 2);
  int* cnt_all    = ialloc(CNT_TOTAL);
  int* start_all  = ialloc(CNT_TOTAL);
  int* cursor_all = ialloc(CNT_TOTAL);
  int* bcnt  = ialloc((size_t)4 * NB_CS * 512);
  int* bbase = ialloc((size_t)4 * NB_CS * 512);
  int* bsumNE = ialloc((size_t)4 * NB_NE);

  int* sM[TT];  for (int t = 0; t < TT; t++) sM[t] = start_all + t * 512;
  int* sHR = start_all + 1536;
  int* sE[TT];  for (int t = 0; t < TT; t++) sE[t] = start_all + CNT_NE_BASE + t * CNT_NE_STRIDE;
  int* sHE = start_all + CNT_NE_BASE + 3 * CNT_NE_STRIDE;

  // --- weight prep (bf16) ---
  transpose_cast_k<<<dim3(H / 32, H / 32), 256, 0, stream>>>(tg_W, tgWtb, H, H);
  transpose_cast_k<<<dim3(H / 32, H / 32), 256, 0, stream>>>(agg_W, aggWtb, H, H);
  transpose_cast_k<<<dim3(KFC / 32, H / 32), 256, 0, stream>>>(fc_W, fcWtb, KFC, H);
  cast_bf16_k<<<(H3 * 2 * H / 8 + 255) / 256, 256, 0, stream>>>(gru_W_ih, Wihb, H3 * 2 * H / 8);
  cast_bf16_k<<<(H3 * H / 8 + 255) / 256, 256, 0, stream>>>(gru_W_hh, Whhb, H3 * H / 8);

  // --- CSR build: counting-sort for R2-keyed arrays ---
  cs_hist_k<<<dim3(NB_CS, 4), 256, 0, stream>>>(r_ids, hr_row, bcnt);
  cs_scan_k<<<4, 256, 0, stream>>>(bcnt, bbase, start_all);
  cs_scatter_k<<<dim3(NB_CS, 4), 256, 0, stream>>>(r_ids, r_to_e, hr_row, hr_col, hrv, bbase,
                                                   fidxM[0], fidxM[1], fidxM[2], fcvHR);

  // --- CSR build: NE-keyed arrays (parallel 3-phase scan) ---
  hipMemsetAsync(cnt_all + CNT_NE_BASE, 0, (size_t)(CNT_TOTAL - CNT_NE_BASE) * 4, stream);
  hist_ne_k<<<dim3((NNZ_E + 255) / 256, 4), 256, 0, stream>>>(edge_dst, he_row, cnt_all);
  scan_ne1_k<<<dim3(NB_NE, 4), 256, 0, stream>>>(cnt_all, start_all, bsumNE);
  scan_ne2_k<<<4, 256, 0, stream>>>(bsumNE, start_all);
  scan_ne3_k<<<dim3(NB_NE, 4), 256, 0, stream>>>(start_all, cursor_all, bsumNE);
  for (int t = 0; t < TT; t++)
    perm_fuse2i_k<<<(NEDGE + 255) / 256, 256, 0, stream>>>(
        edge_dst + (size_t)t * NEDGE, edge_src + (size_t)t * NEDGE, edge_rel + (size_t)t * NEDGE,
        NEDGE, cursor_all + CNT_NE_BASE + t * CNT_NE_STRIDE, fsrE[t]);
  perm_fusevi_k<<<(NNZ_E + 255) / 256, 256, 0, stream>>>(
      he_row, he_col, hev, NNZ_E, cursor_all + CNT_NE_BASE + 3 * CNT_NE_STRIDE, fcvHE);

  hipMemcpyAsync(ent, dynamic_emb, (size_t)NE * H * 4, hipMemcpyDeviceToDevice, stream);
  hipMemcpyAsync(rel, emb_rel, (size_t)R2 * H * 4, hipMemcpyDeviceToDevice, stream);

  constexpr int NEH8 = NE * H / 8, R2H8 = R2 * H / 8;
  constexpr int NE_RB = (NE + 127) / 128;   // 157

  cast_bf16_k<<<(NEH8 + 255) / 256, 256, 0, stream>>>(ent, entb, NEH8);
  cast_bf16_k<<<(R2H8 + 255) / 256, 256, 0, stream>>>(rel, relb, R2H8);

  for (int t = 0; t < TT; t++) {
    // --- rel update (GRU) ---
    gather_mean2_k<<<dim3(R2, MSPLIT), 256, 0, stream>>>(entb, fidxM[t], sM[t], partM);
    mean_xin_k<<<R2, 256, 0, stream>>>(partM, sM[t], rel, xinb);
    mfma_gemm<0><<<dim3(H3 / 64, (R2 + 63) / 64), 256, 0, stream>>>(
        xinb, Wihb, gru_b_ih, gi, R2, 2 * H, H3);
    mfma_gemm<0><<<dim3(H3 / 64, (R2 + 63) / 64), 256, 0, stream>>>(
        relb, Whhb, gru_b_hh, gh, R2, H, H3);
    gru_combine<<<(R2 * H + 255) / 256, 256, 0, stream>>>(gi, gh, rel, relb);

    // --- ent update ---
    panel2_gemm<2><<<dim3(2, NE_RB), 256, 0, stream>>>(entb, tgWtb, tg_b, tgbuf, NE, H, 2);
    gather_edges3_k<<<NE, 256, 0, stream>>>(entb, relb, fsrE[t], sE[t], accEb);
    panel2_gemm<1><<<dim3(2, NE_RB), 256, 0, stream>>>(accEb, aggWtb, nullptr, curr, NE, H, 2);
    ent_update<<<(NE * H + 255) / 256, 256, 0, stream>>>(ent, entb, tgbuf, curr);
  }

  // --- hypergraph layers ---
  hyper3_k<<<NE, 256, 0, stream>>>(ent, entb, fcvHE, sHE, curr, entb2);
  hyper3_k<<<NE, 256, 0, stream>>>(curr, entb2, fcvHE, sHE, ent, entb);
  hyper_rel_k<<<R2, 256, 0, stream>>>(rel, fcvHR, sHR, accR);
  hyper_rel_k<<<R2, 256, 0, stream>>>(accR, fcvHR, sHR, rel);

  // frag-pack final ent for scores B
  pack_frag_k<<<(NEPAD * 32 + 255) / 256, 256, 0, stream>>>(entb, ebf, NEPAD * 32, NE);

  // --- conv + fc (3 chunks: 1600, 1600, 800 rows) ---
  for (int c = 0; c < 3; c++) {
    int row0 = c * 1600;
    int rows = min(1600, NT2 - row0);
    conv_feat<<<rows, 256, 0, stream>>>(ent, rel, sent, tt, conv_w, conv_b, convb, row0);
    fc_gemm<<<dim3(FSPLIT, (rows + 127) / 128), 256, 0, stream>>>(convb, fcWtb, fcpart, rows);
    fc_reduce<<<(rows * H + 255) / 256, 256, 0, stream>>>(
        fcpart, fc_b, qf + (size_t)row0 * H, qb + (size_t)row0 * H, rows);
  }

  // frag-pack q for scores A
  pack_frag_k<<<(ROWPAD * 32 + 255) / 256, 256, 0, stream>>>(qb, qbf, ROWPAD * 32, NT2);

  // --- fused scores + LSE ---
  scores_v3<<<dim3(NCHUNK, 16), 256, 0, stream>>>(qbf, ebf, part_l);
  lse_combine<<<(NT2 * 64 + 255) / 256, 256, 0, stream>>>(part_l, qf, ent, tt, nll);
  mean_nll<<<1, 256, 0, stream>>>(nll, out);
}